// Round 2
// baseline (3866.512 us; speedup 1.0000x reference)
//
#include <hip/hip_runtime.h>
#include <hip/hip_bf16.h>
#include <cstdint>
#include <cstddef>

typedef unsigned short u16;
typedef unsigned int u32;
typedef __attribute__((ext_vector_type(8))) __bf16 bfx8;
typedef __attribute__((ext_vector_type(4))) float f32x4;

static __device__ __forceinline__ float bitf(u32 v){ float f; __builtin_memcpy(&f,&v,4); return f; }
static __device__ __forceinline__ float bf2f(u16 v){ return bitf(((u32)v)<<16); }
static __device__ __forceinline__ u16 f2bf(float f){ __bf16 b=(__bf16)f; u16 r; __builtin_memcpy(&r,&b,2); return r; }
static __device__ __forceinline__ u32 pk2(float a,float b){ return (u32)f2bf(a) | ((u32)f2bf(b)<<16); }
static __device__ __forceinline__ void unpk8(uint4 r, float* o){
  o[0]=bitf(r.x<<16); o[1]=bitf(r.x&0xffff0000u);
  o[2]=bitf(r.y<<16); o[3]=bitf(r.y&0xffff0000u);
  o[4]=bitf(r.z<<16); o[5]=bitf(r.z&0xffff0000u);
  o[6]=bitf(r.w<<16); o[7]=bitf(r.w&0xffff0000u);
}
static __device__ __forceinline__ void async16(void* lds, const void* g){
  __builtin_amdgcn_global_load_lds((const __attribute__((address_space(1))) u32*)g,
                                   (__attribute__((address_space(3))) u32*)lds, 16, 0, 0);
}

// ---------------- GEMM: C[M][N] = A[M][K] @ B[N][K]^T (+ epilogue) -----------
// AMODE: 0=linear, 1=dir-permuted rows, 2=conv3 implicit (padded in), 3=conv1
// EPI:   0=+bias->bf16, 2=BN(scale,shift)+ReLU->bf16, 3=+bias+addsrc->bf16
struct GemmArgs {
  const u16* A; long aZ; int lda;
  const u16* Bw; long bZ;
  const float* bias; int biasZ;
  const float* scale; const float* shift;
  const u16* add; long addZ;
  u16* C; long cZ; int ldc; int colOff;
  int K;
  const u16* pad;
  int dirBase;
};

template<int AMODE, int EPI>
__global__ __launch_bounds__(256)
void gemm_bt(GemmArgs g)
{
  __shared__ u16 smA[128*64];
  __shared__ u16 smB[128*64];
  const int tid = threadIdx.x;
  const int l = tid & 63;
  const int wv = tid >> 6;
  const int wr = wv >> 1, wc = wv & 1;
  const int z = blockIdx.z;
  const int r0 = blockIdx.x * 128;
  const int n0 = blockIdx.y * 128;

  const u16* Abase = g.A + (size_t)z * g.aZ;
  const u16* Bbase = g.Bw + (size_t)z * g.bZ;

  f32x4 acc[4][4];
  #pragma unroll
  for (int i=0;i<4;i++)
    #pragma unroll
    for (int j=0;j<4;j++) acc[i][j] = (f32x4){0.f,0.f,0.f,0.f};

  const int nkt = g.K >> 6;
  #pragma unroll 1
  for (int kt=0; kt<nkt; ++kt) {
    const int k0 = kt << 6;
    #pragma unroll
    for (int it=0; it<4; ++it) {
      const int s = it*256 + tid;
      const int row = s >> 3, ch = s & 7;
      const u16* ga;
      if (AMODE == 0) {
        ga = Abase + (size_t)(r0+row) * g.lda + k0 + ch*8;
      } else if (AMODE == 1) {
        int rr = r0 + row; int li = rr & 4095; int bb = rr >> 12;
        int dir = g.dirBase + z;
        int l2 = (dir & 2) ? (4095 - li) : li;
        int sl = (dir & 1) ? (((l2 & 63) << 6) | (l2 >> 6)) : l2;
        ga = Abase + (size_t)((bb << 12) | sl) * g.lda + k0 + ch*8;
      } else if (AMODE == 2) {
        int rr = r0 + row; int bb = rr >> 12; int li = rr & 4095;
        int yy = li >> 6, xx = li & 63;
        int tap = k0 >> 9, kin = k0 & 511;
        int dy = tap / 3 - 1, dx = tap % 3 - 1;
        ga = g.pad + (((size_t)(bb*66 + yy+dy+1))*66 + (xx+dx+1))*512 + kin + ch*8;
      } else {
        int rr = r0 + row; int bb = rr >> 12; int li = rr & 4095;
        int yy = li >> 6, xx = li & 63;
        ga = g.pad + (((size_t)(bb*66 + yy+1))*66 + (xx+1))*512 + k0 + ch*8;
      }
      async16(&smA[(size_t)(it*256 + (tid & ~63))*8], ga);
      const u16* gb = Bbase + (size_t)(n0+row) * g.K + k0 + ch*8;
      async16(&smB[(size_t)(it*256 + (tid & ~63))*8], gb);
    }
    __syncthreads();
    #pragma unroll
    for (int kk=0; kk<2; ++kk) {
      bfx8 av[4], bv[4];
      #pragma unroll
      for (int mi=0; mi<4; ++mi) {
        int ra = wr*64 + mi*16 + (l & 15);
        av[mi] = *(const bfx8*)&smA[ra*64 + kk*32 + (l>>4)*8];
      }
      #pragma unroll
      for (int ni=0; ni<4; ++ni) {
        int rb = wc*64 + ni*16 + (l & 15);
        bv[ni] = *(const bfx8*)&smB[rb*64 + kk*32 + (l>>4)*8];
      }
      #pragma unroll
      for (int mi=0; mi<4; ++mi)
        #pragma unroll
        for (int ni=0; ni<4; ++ni)
          acc[mi][ni] = __builtin_amdgcn_mfma_f32_16x16x32_bf16(av[mi], bv[ni], acc[mi][ni], 0, 0, 0);
    }
    __syncthreads();
  }

  const float* bias_d = (EPI != 2) ? g.bias + (size_t)z * g.biasZ : nullptr;
  const u16* add_d = (EPI == 3) ? g.add + (size_t)z * g.addZ : nullptr;
  u16* Cd = g.C + (size_t)z * g.cZ;
  #pragma unroll
  for (int mi=0; mi<4; ++mi) {
    #pragma unroll
    for (int ni=0; ni<4; ++ni) {
      f32x4 v = acc[mi][ni];
      const int gr = r0 + wr*64 + mi*16 + ((l >> 4) << 2);
      const int gc = n0 + wc*64 + ni*16 + (l & 15);
      #pragma unroll
      for (int q=0; q<4; ++q) {
        const int r = gr + q;
        float x = v[q];
        if (EPI == 2) {
          x = fmaxf(fmaf(x, g.scale[gc], g.shift[gc]), 0.f);
        } else if (EPI == 3) {
          x += bias_d[gc] + bf2f(add_d[(size_t)r * g.ldc + gc]);
        } else {
          x += bias_d[gc];
        }
        Cd[(size_t)r * g.ldc + g.colOff + gc] = f2bf(x);
      }
    }
  }
}

// ---------------- small utility kernels --------------------------------------
__global__ void castk(const float* __restrict__ s, u16* __restrict__ d, int n)
{
  int i = (blockIdx.x*256 + threadIdx.x)*4;
  if (i < n){
    float4 v = *(const float4*)(s+i);
    ushort4 o; o.x=f2bf(v.x); o.y=f2bf(v.y); o.z=f2bf(v.z); o.w=f2bf(v.w);
    *(ushort4*)(d+i) = o;
  }
}

__global__ void c3rep(const float* __restrict__ w, u16* __restrict__ o)
{
  int id = blockIdx.x*256 + threadIdx.x; // 128*4608
  int oc = id / 4608, rem = id % 4608;
  int tap = rem >> 9, ic = rem & 511;
  o[id] = f2bf(w[((size_t)oc*512 + ic)*9 + tap]);
}

__global__ void bnssk(const float* g3,const float* b3,const float* m3,const float* v3,
                      const float* g1,const float* b1,const float* m1,const float* v1,
                      float* out)
{
  int t = threadIdx.x; int i = t & 127;
  if (t < 128){ float sc = g3[i]*rsqrtf(v3[i]+1e-5f); out[i]=sc; out[128+i]=b3[i]-m3[i]*sc; }
  else        { float sc = g1[i]*rsqrtf(v1[i]+1e-5f); out[256+i]=sc; out[384+i]=b1[i]-m1[i]*sc; }
}

__global__ __launch_bounds__(256)
void padk(const float* __restrict__ curr, const float* __restrict__ prev, u16* __restrict__ pad)
{
  const int id = blockIdx.x*256 + threadIdx.x; // 4*66*66*64
  const int c8 = id & 63;
  int t = id >> 6;
  const int xx = t % 66; t /= 66;
  const int yy = t % 66; const int b = t / 66;
  const int c0 = c8*8;
  uint4 o;
  if (yy==0 || yy==65 || xx==0 || xx==65){ o.x=0;o.y=0;o.z=0;o.w=0; }
  else {
    const int l = (yy-1)*64 + (xx-1);
    const float* s = (c0 < 256) ? curr + ((size_t)b*4096 + l)*256 + c0
                                : prev + ((size_t)b*4096 + l)*256 + (c0-256);
    float4 a = *(const float4*)s, bb = *(const float4*)(s+4);
    o.x = pk2(a.x,a.y); o.y = pk2(a.z,a.w); o.z = pk2(bb.x,bb.y); o.w = pk2(bb.z,bb.w);
  }
  *(uint4*)(pad + (((size_t)b*66 + yy)*66 + xx)*512 + c0) = o;
}

__global__ __launch_bounds__(256)
void ln256(const u16* __restrict__ in, long inZ, u16* __restrict__ out, long outZ,
           const float* __restrict__ gw, const float* __restrict__ bw, int pz)
{
  const int z = blockIdx.z;
  const int row = blockIdx.x*4 + (threadIdx.x>>6);
  const int l = threadIdx.x & 63;
  const u16* ip = in + (size_t)z*inZ + (size_t)row*256 + l*4;
  ushort4 rr = *(const ushort4*)ip;
  float v0=bf2f(rr.x), v1=bf2f(rr.y), v2=bf2f(rr.z), v3=bf2f(rr.w);
  float s = v0+v1+v2+v3;
  float ss = v0*v0+v1*v1+v2*v2+v3*v3;
  #pragma unroll
  for(int m=1;m<64;m<<=1){ s += __shfl_xor(s,m); ss += __shfl_xor(ss,m); }
  float mu = s*(1.f/256.f);
  float var = ss*(1.f/256.f) - mu*mu;
  float rs = rsqrtf(var + 1e-5f);
  const float* g = gw + (size_t)z*pz; const float* b = bw + (size_t)z*pz;
  int c = l*4;
  u16* op = out + (size_t)z*outZ + (size_t)row*256 + c;
  ushort4 o; o.x=f2bf((v0-mu)*rs*g[c]+b[c]); o.y=f2bf((v1-mu)*rs*g[c+1]+b[c+1]);
  o.z=f2bf((v2-mu)*rs*g[c+2]+b[c+2]); o.w=f2bf((v3-mu)*rs*g[c+3]+b[c+3]);
  *(ushort4*)op = o;
}

__global__ __launch_bounds__(256)
void rms512(u16* __restrict__ Y, const float* __restrict__ gw)
{
  const int z = blockIdx.z;
  const int row = blockIdx.x*4 + (threadIdx.x>>6);
  const int l = threadIdx.x & 63;
  u16* p = Y + ((size_t)z*16384 + row)*512 + l*8;
  uint4 raw = *(const uint4*)p;
  float v[8]; unpk8(raw, v);
  float ss = 0.f;
  #pragma unroll
  for (int j=0;j<8;j++) ss += v[j]*v[j];
  #pragma unroll
  for (int m=1;m<64;m<<=1) ss += __shfl_xor(ss, m);
  const float sc = rsqrtf(ss*(1.f/512.f) + 1e-5f);
  const float* g = gw + (size_t)z*512 + l*8;
  uint4 o;
  o.x = pk2(v[0]*sc*g[0], v[1]*sc*g[1]);
  o.y = pk2(v[2]*sc*g[2], v[3]*sc*g[3]);
  o.z = pk2(v[4]*sc*g[4], v[5]*sc*g[5]);
  o.w = pk2(v[6]*sc*g[6], v[7]*sc*g[7]);
  *(uint4*)p = o;
}

// fp32 dt head
__global__ __launch_bounds__(256)
void dtk(const u16* __restrict__ xln, const float* __restrict__ minW,
         const float* __restrict__ minB, const float* __restrict__ dtb,
         const float* __restrict__ alog, float* __restrict__ DT, float* __restrict__ DA)
{
  __shared__ float sx[32*257];
  const int z = blockIdx.z;
  const int r0 = blockIdx.x * 32;
  const int tid = threadIdx.x;
  {
    const int rr = tid >> 3, cc = (tid & 7) * 32;
    const u16* src = xln + ((size_t)z*16384 + r0 + rr)*256 + cc;
    #pragma unroll
    for (int q=0;q<4;q++){
      uint4 raw = *(const uint4*)(src + q*8);
      float v[8]; unpk8(raw, v);
      #pragma unroll
      for (int j=0;j<8;j++) sx[rr*257 + cc + q*8 + j] = v[j];
    }
  }
  __syncthreads();
  const int ri = tid >> 3, hv = tid & 7;
  const float* wrow = minW + ((size_t)z*1288 + 1280 + hv)*256;
  float acc = 0.f;
  #pragma unroll 4
  for (int k=0; k<256; k+=4){
    float4 wq = *(const float4*)(wrow + k);
    acc += sx[ri*257+k]*wq.x + sx[ri*257+k+1]*wq.y + sx[ri*257+k+2]*wq.z + sx[ri*257+k+3]*wq.w;
  }
  acc += minB[(size_t)z*1288 + 1280 + hv] + dtb[z*8 + hv];
  float dt = (acc > 20.f) ? acc : log1pf(expf(acc));
  float da = expf(-dt * expf(alog[z*8 + hv]));
  size_t o = ((size_t)z*16384 + r0 + ri)*8 + hv;
  DT[o] = dt; DA[o] = da;
}

// causal depthwise conv1d (4 taps) + SiLU over a 256-column chunk of xBC
__global__ __launch_bounds__(256)
void convc(const u16* __restrict__ xch, u16* __restrict__ xbcc,
           const float* __restrict__ cw, const float* __restrict__ cb, int cbase)
{
  const int id = blockIdx.x*256 + threadIdx.x; // nd*16384*32
  const int c8 = id & 31;
  const int r = (id >> 5) & 16383;
  const int d = id >> 19;
  const int li = r & 4095;
  const int ch = cbase + c8*8;
  const u16* base = xch + ((size_t)d*16384 + (size_t)(r - li))*256 + c8*8;
  float acc[8];
  #pragma unroll
  for (int j=0;j<8;j++) acc[j] = cb[d*768 + ch + j];
  #pragma unroll
  for (int tap=0; tap<4; ++tap){
    int lt = li - 3 + tap;
    if (lt >= 0){
      uint4 raw = *(const uint4*)(base + (size_t)lt*256);
      float v[8]; unpk8(raw, v);
      #pragma unroll
      for (int j=0;j<8;j++)
        acc[j] = fmaf(v[j], cw[((size_t)d*768 + ch + j)*4 + tap], acc[j]);
    }
  }
  float s[8];
  #pragma unroll
  for (int j=0;j<8;j++) s[j] = acc[j] / (1.f + __expf(-acc[j]));
  uint4 o;
  o.x = pk2(s[0],s[1]); o.y = pk2(s[2],s[3]); o.z = pk2(s[4],s[5]); o.w = pk2(s[6],s[7]);
  *(uint4*)(xbcc + ((size_t)d*16384 + r)*768 + ch) = o;
}

// sequential selective scan; consumes z-gate in place (Y aliases zgate)
__global__ __launch_bounds__(256)
void scank(const u16* __restrict__ xbcc, const u16* __restrict__ zgate,
           const float* __restrict__ DT, const float* __restrict__ DA,
           const float* __restrict__ Dp, u16* __restrict__ Y)
{
  const int wg = blockIdx.x;              // nd*128 = nd*4b*8h*4pg
  const int pg = wg & 3, hh = (wg >> 2) & 7, db = wg >> 5;
  const int d = db >> 2, b = db & 3;
  const int tid = threadIdx.x;
  const int pl = tid >> 4, nb = (tid & 15) * 8;
  const int p = pg*16 + pl;

  const size_t rbase = (size_t)d*16384 + (size_t)b*4096;
  const u16* xc = xbcc + rbase*768;
  const u16* zg = zgate + rbase*512 + hh*64 + p;
  const float* dtp = DT + rbase*8 + hh;
  const float* dap = DA + rbase*8 + hh;
  u16* yp = Y + rbase*512 + hh*64 + p;
  const float Dh = Dp[d*8 + hh];

  float hs[8];
  #pragma unroll
  for (int j=0;j<8;j++) hs[j]=0.f;

  uint4 Bpf = *(const uint4*)(xc + 512 + nb);
  uint4 Cpf = *(const uint4*)(xc + 640 + nb);
  u16 xpf = xc[hh*64 + p];
  u16 zpf = zg[0];
  float dtpf = dtp[0], dapf = dap[0];

  #pragma unroll 2
  for (int t=0; t<4096; ++t) {
    uint4 Bc = Bpf, Cc = Cpf; u16 xv = xpf, zv = zpf;
    float dtc = dtpf, dac = dapf;
    if (t < 4095) {
      const u16* nx = xc + (size_t)(t+1)*768;
      Bpf = *(const uint4*)(nx + 512 + nb);
      Cpf = *(const uint4*)(nx + 640 + nb);
      xpf = nx[hh*64 + p];
      zpf = zg[(size_t)(t+1)*512];
      dtpf = dtp[(size_t)(t+1)*8];
      dapf = dap[(size_t)(t+1)*8];
    }
    float Bf[8], Cf[8];
    unpk8(Bc, Bf); unpk8(Cc, Cf);
    const float xf = bf2f(xv);
    const float u = dtc * xf;
    float acc = 0.f;
    #pragma unroll
    for (int j=0;j<8;j++){
      hs[j] = fmaf(hs[j], dac, u * Bf[j]);
      acc = fmaf(hs[j], Cf[j], acc);
    }
    acc += __shfl_xor(acc, 1);
    acc += __shfl_xor(acc, 2);
    acc += __shfl_xor(acc, 4);
    acc += __shfl_xor(acc, 8);
    if ((tid & 15) == 0) {
      float zf = bf2f(zv);
      float yv = (acc + Dh * xf) * (zf / (1.f + __expf(-zf)));
      yp[(size_t)t * 512] = f2bf(yv);
    }
  }
}

__global__ __launch_bounds__(256)
void finalk(const float* __restrict__ curr, const u16* __restrict__ outs, float* __restrict__ o)
{
  const int row = blockIdx.x*4 + (threadIdx.x>>6);
  const int c4 = (threadIdx.x & 63)*4;
  const int b = row >> 12, li = row & 4095;
  const int T = ((li & 63) << 6) | (li >> 6);
  const size_t rb = (size_t)b*4096;
  const ushort4 a0 = *(const ushort4*)(outs + (size_t)0*4194304 + ((rb+li)*256 + c4));
  const ushort4 a1 = *(const ushort4*)(outs + (size_t)1*4194304 + ((rb+T)*256 + c4));
  const ushort4 a2 = *(const ushort4*)(outs + (size_t)2*4194304 + ((rb+4095-li)*256 + c4));
  const ushort4 a3 = *(const ushort4*)(outs + (size_t)3*4194304 + ((rb+4095-T)*256 + c4));
  float4 cv = *(const float4*)(curr + (size_t)row*256 + c4);
  float4 r;
  r.x = cv.x + 0.25f*(bf2f(a0.x)+bf2f(a1.x)+bf2f(a2.x)+bf2f(a3.x));
  r.y = cv.y + 0.25f*(bf2f(a0.y)+bf2f(a1.y)+bf2f(a2.y)+bf2f(a3.y));
  r.z = cv.z + 0.25f*(bf2f(a0.z)+bf2f(a1.z)+bf2f(a2.z)+bf2f(a3.z));
  r.w = cv.w + 0.25f*(bf2f(a0.w)+bf2f(a1.w)+bf2f(a2.w)+bf2f(a3.w));
  *(float4*)(o + (size_t)row*256 + c4) = r;
}

// ---------------------------------------------------------------------------
extern "C" void kernel_launch(void* const* d_in, const int* in_sizes, int n_in,
                              void* d_out, int out_size, void* d_ws, size_t ws_size,
                              hipStream_t stream)
{
  (void)in_sizes; (void)n_in; (void)out_size;
  const float* curr   = (const float*)d_in[0];
  const float* prev   = (const float*)d_in[1];
  const float* conv3w = (const float*)d_in[2];
  const float* bn3g=(const float*)d_in[3], *bn3b=(const float*)d_in[4], *bn3m=(const float*)d_in[5], *bn3v=(const float*)d_in[6];
  const float* conv1w = (const float*)d_in[7];
  const float* bn1g=(const float*)d_in[8], *bn1b=(const float*)d_in[9], *bn1m=(const float*)d_in[10], *bn1v=(const float*)d_in[11];
  const float* fuseW=(const float*)d_in[12], *fuseB=(const float*)d_in[13];
  const float* lng=(const float*)d_in[14], *lnb=(const float*)d_in[15];
  const float* inpW=(const float*)d_in[16], *inpB=(const float*)d_in[17];
  const float* mlng=(const float*)d_in[18], *mlnb=(const float*)d_in[19];
  const float* minW=(const float*)d_in[20], *minB=(const float*)d_in[21];
  const float* cw=(const float*)d_in[22], *cb=(const float*)d_in[23];
  const float* alog=(const float*)d_in[24], *Dp=(const float*)d_in[25], *dtb=(const float*)d_in[26];
  const float* mng=(const float*)d_in[27];
  const float* moutW=(const float*)d_in[28], *moutB=(const float*)d_in[29];
  const float* outpW=(const float*)d_in[30], *outpB=(const float*)d_in[31];

  // ---- persistent layout ----
  char* ws = (char*)d_ws;
  size_t off = 0;
  auto alloc = [&](size_t bytes){ size_t o = off; off = (off + bytes + 1023) & ~(size_t)1023; return o; };
  const size_t O_WFUSE = alloc((size_t)256*256*2);
  const size_t O_WINP  = alloc((size_t)4*256*256*2);
  const size_t O_WMIN  = alloc((size_t)4*1288*256*2);
  const size_t O_WMOUT = alloc((size_t)4*256*512*2);
  const size_t O_WOUTP = alloc((size_t)4*256*256*2);
  const size_t O_WC3   = alloc((size_t)128*4608*2);
  const size_t O_WC1   = alloc((size_t)128*512*2);
  const size_t O_BNSS  = alloc(512*4);
  const size_t O_ZF    = alloc((size_t)16384*256*2);
  const size_t O_OUTS  = alloc((size_t)4*16384*256*2);
  const size_t O_P     = off;                 // per-phase region

  // per-dir sizes (bytes, all 1024-multiples)
  const size_t S0d  = (size_t)16384*256*2;    // 8.39MB
  const size_t XLNd = (size_t)16384*256*2;    // 8.39MB (S1 overlays)
  const size_t Yd   = (size_t)16384*512*2;    // 16.8MB (zgate aliases)
  const size_t XBCd = (size_t)16384*768*2;    // 25.2MB
  const size_t XCHd = (size_t)16384*256*2;    // 8.39MB (raw xBC column chunk)
  const size_t DTd  = (size_t)16384*8*4;      // 0.52MB
  const size_t perdir = S0d + XLNd + Yd + XBCd + XCHd + 2*DTd;

  int nd = 0;
  for (int cand = 4; cand >= 1; cand >>= 1)
    if (O_P + (size_t)cand*perdir <= ws_size) { nd = cand; break; }
  if (nd == 0) return;

  #define WP(o) ((u16*)(ws + (o)))
  #define FP(o) ((float*)(ws + (o)))

  // pre-phase transients live inside the phase region
  const size_t O_PAD = O_P;
  const size_t O_ZIN = O_PAD + (size_t)4*66*66*512*2;
  const size_t O_ZFT = O_ZIN + (size_t)16384*256*2;

  // 1. BN scale/shift + weight conversions
  bnssk<<<1, 256, 0, stream>>>(bn3g,bn3b,bn3m,bn3v, bn1g,bn1b,bn1m,bn1v, FP(O_BNSS));
  castk<<<(65536/4+255)/256, 256, 0, stream>>>(fuseW, WP(O_WFUSE), 65536);
  castk<<<(262144/4+255)/256, 256, 0, stream>>>(inpW, WP(O_WINP), 262144);
  castk<<<(1318912/4+255)/256, 256, 0, stream>>>(minW, WP(O_WMIN), 1318912);
  castk<<<(524288/4+255)/256, 256, 0, stream>>>(moutW, WP(O_WMOUT), 524288);
  castk<<<(262144/4+255)/256, 256, 0, stream>>>(outpW, WP(O_WOUTP), 262144);
  castk<<<(65536/4+255)/256, 256, 0, stream>>>(conv1w, WP(O_WC1), 65536);
  c3rep<<<2304, 256, 0, stream>>>(conv3w, WP(O_WC3));
  // 2. padded concat input (bf16)
  padk<<<4356, 256, 0, stream>>>(curr, prev, WP(O_PAD));

  GemmArgs a;
  // 3. conv3 -> zin[:,0:128]
  a = {}; a.pad = WP(O_PAD); a.Bw = WP(O_WC3); a.bZ = 0;
  a.scale = FP(O_BNSS); a.shift = FP(O_BNSS)+128;
  a.C = WP(O_ZIN); a.cZ = 0; a.ldc = 256; a.colOff = 0; a.K = 4608;
  gemm_bt<2,2><<<dim3(128,1,1), 256, 0, stream>>>(a);
  // 4. conv1 -> zin[:,128:256]
  a = {}; a.pad = WP(O_PAD); a.Bw = WP(O_WC1); a.bZ = 0;
  a.scale = FP(O_BNSS)+256; a.shift = FP(O_BNSS)+384;
  a.C = WP(O_ZIN); a.cZ = 0; a.ldc = 256; a.colOff = 128; a.K = 512;
  gemm_bt<3,2><<<dim3(128,1,1), 256, 0, stream>>>(a);
  // 5. fuse GEMM -> zft
  a = {}; a.A = WP(O_ZIN); a.aZ = 0; a.lda = 256; a.Bw = WP(O_WFUSE); a.bZ = 0;
  a.bias = fuseB; a.biasZ = 0; a.C = WP(O_ZFT); a.cZ = 0; a.ldc = 256; a.colOff = 0; a.K = 256;
  gemm_bt<0,0><<<dim3(128,2,1), 256, 0, stream>>>(a);
  // 6. LN -> zf (persistent)
  ln256<<<dim3(4096,1,1), 256, 0, stream>>>(WP(O_ZFT), 0, WP(O_ZF), 0, lng, lnb, 0);

  // ---- phases over directions ----
  for (int d0 = 0; d0 < 4; d0 += nd) {
    const size_t O_S0  = O_P;
    const size_t O_XLN = O_S0  + (size_t)nd*S0d;
    const size_t O_Y   = O_XLN + (size_t)nd*XLNd;   // zgate == Y
    const size_t O_XBC = O_Y   + (size_t)nd*Yd;
    const size_t O_XCH = O_XBC + (size_t)nd*XBCd;
    const size_t O_DT  = O_XCH + (size_t)nd*XCHd;
    const size_t O_DA  = O_DT  + (size_t)nd*DTd;
    const size_t O_S1  = O_XLN;                     // overlay (XLN dead after dtk)

    // 7. inp GEMM (permuted rows per dir) -> s0
    a = {}; a.A = WP(O_ZF); a.aZ = 0; a.lda = 256;
    a.Bw = WP(O_WINP) + (size_t)d0*65536; a.bZ = 65536;
    a.bias = inpB + d0*256; a.biasZ = 256;
    a.C = WP(O_S0); a.cZ = 4194304; a.ldc = 256; a.colOff = 0; a.K = 256; a.dirBase = d0;
    gemm_bt<1,0><<<dim3(128,2,nd), 256, 0, stream>>>(a);
    // 8. per-dir LN(s0) -> xln
    ln256<<<dim3(4096,1,nd), 256, 0, stream>>>(WP(O_S0), 4194304, WP(O_XLN), 4194304,
                                               mlng + d0*256, mlnb + d0*256, 256);
    // 9. z-gate GEMM -> Y region (cols 0..511)
    a = {}; a.A = WP(O_XLN); a.aZ = 4194304; a.lda = 256;
    a.Bw = WP(O_WMIN) + (size_t)d0*329728; a.bZ = 329728;
    a.bias = minB + d0*1288; a.biasZ = 1288;
    a.C = WP(O_Y); a.cZ = 8388608; a.ldc = 512; a.colOff = 0; a.K = 256;
    gemm_bt<0,0><<<dim3(128,4,nd), 256, 0, stream>>>(a);
    // 10. xBC GEMM in 3 column chunks of 256 + conv1d+silu per chunk -> xbcc
    for (int cc = 0; cc < 3; ++cc) {
      const int cbase = cc*256;
      a = {}; a.A = WP(O_XLN); a.aZ = 4194304; a.lda = 256;
      a.Bw = WP(O_WMIN) + (size_t)d0*329728 + (size_t)(512+cbase)*256; a.bZ = 329728;
      a.bias = minB + d0*1288 + 512 + cbase; a.biasZ = 1288;
      a.C = WP(O_XCH); a.cZ = 4194304; a.ldc = 256; a.colOff = 0; a.K = 256;
      gemm_bt<0,0><<<dim3(128,2,nd), 256, 0, stream>>>(a);
      convc<<<nd*2048, 256, 0, stream>>>(WP(O_XCH), WP(O_XBC), cw + d0*3072, cb + d0*768, cbase);
    }
    // 11. dt/dA (fp32)
    dtk<<<dim3(512,1,nd), 256, 0, stream>>>(WP(O_XLN), minW + (size_t)d0*329728,
                                            minB + d0*1288, dtb + d0*8, alog + d0*8,
                                            FP(O_DT), FP(O_DA));
    // 12. selective scan -> Y (gated, in-place over zgate)
    scank<<<nd*128, 256, 0, stream>>>(WP(O_XBC), WP(O_Y), FP(O_DT), FP(O_DA), Dp + d0*8, WP(O_Y));
    // 13. RMSNorm in-place on Y
    rms512<<<dim3(4096,1,nd), 256, 0, stream>>>(WP(O_Y), mng + d0*512);
    // 14. m_out GEMM + s0 residual -> s1 (overlays xln)
    a = {}; a.A = WP(O_Y); a.aZ = 8388608; a.lda = 512;
    a.Bw = WP(O_WMOUT) + (size_t)d0*131072; a.bZ = 131072;
    a.bias = moutB + d0*256; a.biasZ = 256;
    a.add = WP(O_S0); a.addZ = 4194304;
    a.C = WP(O_S1); a.cZ = 4194304; a.ldc = 256; a.colOff = 0; a.K = 512;
    gemm_bt<0,3><<<dim3(128,2,nd), 256, 0, stream>>>(a);
    // 15. outp GEMM -> outs (persistent)
    a = {}; a.A = WP(O_S1); a.aZ = 4194304; a.lda = 256;
    a.Bw = WP(O_WOUTP) + (size_t)d0*65536; a.bZ = 65536;
    a.bias = outpB + d0*256; a.biasZ = 256;
    a.C = WP(O_OUTS) + (size_t)d0*4194304; a.cZ = 4194304; a.ldc = 256; a.colOff = 0; a.K = 256;
    gemm_bt<0,0><<<dim3(128,2,nd), 256, 0, stream>>>(a);
  }

  // 16. final inverse-permute average + residual
  finalk<<<4096, 256, 0, stream>>>(curr, WP(O_OUTS), (float*)d_out);

  #undef WP
  #undef FP
}

// Round 3
// 1517.574 us; speedup vs baseline: 2.5478x; 2.5478x over previous
//
#include <hip/hip_runtime.h>
#include <hip/hip_bf16.h>
#include <cstdint>
#include <cstddef>

typedef unsigned short u16;
typedef unsigned int u32;
typedef __attribute__((ext_vector_type(8))) __bf16 bfx8;
typedef __attribute__((ext_vector_type(4))) float f32x4;

static __device__ __forceinline__ float bitf(u32 v){ float f; __builtin_memcpy(&f,&v,4); return f; }
static __device__ __forceinline__ float bf2f(u16 v){ return bitf(((u32)v)<<16); }
static __device__ __forceinline__ u16 f2bf(float f){ __bf16 b=(__bf16)f; u16 r; __builtin_memcpy(&r,&b,2); return r; }
static __device__ __forceinline__ u32 pk2(float a,float b){ return (u32)f2bf(a) | ((u32)f2bf(b)<<16); }
static __device__ __forceinline__ void unpk8(uint4 r, float* o){
  o[0]=bitf(r.x<<16); o[1]=bitf(r.x&0xffff0000u);
  o[2]=bitf(r.y<<16); o[3]=bitf(r.y&0xffff0000u);
  o[4]=bitf(r.z<<16); o[5]=bitf(r.z&0xffff0000u);
  o[6]=bitf(r.w<<16); o[7]=bitf(r.w&0xffff0000u);
}
static __device__ __forceinline__ void async16(void* lds, const void* g){
  __builtin_amdgcn_global_load_lds((const __attribute__((address_space(1))) u32*)g,
                                   (__attribute__((address_space(3))) u32*)lds, 16, 0, 0);
}

// ---------------- GEMM: C[M][N] = A[M][K] @ B[N][K]^T (+ epilogue) -----------
// AMODE: 0=linear, 1=dir-permuted rows, 2=conv3 implicit (padded in), 3=conv1
// EPI:   0=+bias->bf16, 2=BN(scale,shift)+ReLU->bf16, 3=+bias+addsrc->bf16
struct GemmArgs {
  const u16* A; long aZ; int lda;
  const u16* Bw; long bZ;
  const float* bias; int biasZ;
  const float* scale; const float* shift;
  const u16* add; long addZ;
  u16* C; long cZ; int ldc; int colOff;
  int K;
  const u16* pad;
  int dirBase;
};

template<int AMODE, int EPI>
__global__ __launch_bounds__(256)
void gemm_bt(GemmArgs g)
{
  __shared__ u16 smA[128*64];
  __shared__ u16 smB[128*64];
  const int tid = threadIdx.x;
  const int l = tid & 63;
  const int wv = tid >> 6;
  const int wr = wv >> 1, wc = wv & 1;
  const int z = blockIdx.z;
  const int r0 = blockIdx.x * 128;
  const int n0 = blockIdx.y * 128;

  const u16* Abase = g.A + (size_t)z * g.aZ;
  const u16* Bbase = g.Bw + (size_t)z * g.bZ;

  f32x4 acc[4][4];
  #pragma unroll
  for (int i=0;i<4;i++)
    #pragma unroll
    for (int j=0;j<4;j++) acc[i][j] = (f32x4){0.f,0.f,0.f,0.f};

  const int nkt = g.K >> 6;
  #pragma unroll 1
  for (int kt=0; kt<nkt; ++kt) {
    const int k0 = kt << 6;
    #pragma unroll
    for (int it=0; it<4; ++it) {
      const int s = it*256 + tid;
      const int row = s >> 3, ch = s & 7;
      const u16* ga;
      if (AMODE == 0) {
        ga = Abase + (size_t)(r0+row) * g.lda + k0 + ch*8;
      } else if (AMODE == 1) {
        int rr = r0 + row; int li = rr & 4095; int bb = rr >> 12;
        int dir = g.dirBase + z;
        int l2 = (dir & 2) ? (4095 - li) : li;
        int sl = (dir & 1) ? (((l2 & 63) << 6) | (l2 >> 6)) : l2;
        ga = Abase + (size_t)((bb << 12) | sl) * g.lda + k0 + ch*8;
      } else if (AMODE == 2) {
        int rr = r0 + row; int bb = rr >> 12; int li = rr & 4095;
        int yy = li >> 6, xx = li & 63;
        int tap = k0 >> 9, kin = k0 & 511;
        int dy = tap / 3 - 1, dx = tap % 3 - 1;
        ga = g.pad + (((size_t)(bb*66 + yy+dy+1))*66 + (xx+dx+1))*512 + kin + ch*8;
      } else {
        int rr = r0 + row; int bb = rr >> 12; int li = rr & 4095;
        int yy = li >> 6, xx = li & 63;
        ga = g.pad + (((size_t)(bb*66 + yy+1))*66 + (xx+1))*512 + k0 + ch*8;
      }
      async16(&smA[(size_t)(it*256 + (tid & ~63))*8], ga);
      const u16* gb = Bbase + (size_t)(n0+row) * g.K + k0 + ch*8;
      async16(&smB[(size_t)(it*256 + (tid & ~63))*8], gb);
    }
    __syncthreads();
    #pragma unroll
    for (int kk=0; kk<2; ++kk) {
      bfx8 av[4], bv[4];
      #pragma unroll
      for (int mi=0; mi<4; ++mi) {
        int ra = wr*64 + mi*16 + (l & 15);
        av[mi] = *(const bfx8*)&smA[ra*64 + kk*32 + (l>>4)*8];
      }
      #pragma unroll
      for (int ni=0; ni<4; ++ni) {
        int rb = wc*64 + ni*16 + (l & 15);
        bv[ni] = *(const bfx8*)&smB[rb*64 + kk*32 + (l>>4)*8];
      }
      #pragma unroll
      for (int mi=0; mi<4; ++mi)
        #pragma unroll
        for (int ni=0; ni<4; ++ni)
          acc[mi][ni] = __builtin_amdgcn_mfma_f32_16x16x32_bf16(av[mi], bv[ni], acc[mi][ni], 0, 0, 0);
    }
    __syncthreads();
  }

  const float* bias_d = (EPI != 2) ? g.bias + (size_t)z * g.biasZ : nullptr;
  const u16* add_d = (EPI == 3) ? g.add + (size_t)z * g.addZ : nullptr;
  u16* Cd = g.C + (size_t)z * g.cZ;
  #pragma unroll
  for (int mi=0; mi<4; ++mi) {
    #pragma unroll
    for (int ni=0; ni<4; ++ni) {
      f32x4 v = acc[mi][ni];
      const int gr = r0 + wr*64 + mi*16 + ((l >> 4) << 2);
      const int gc = n0 + wc*64 + ni*16 + (l & 15);
      #pragma unroll
      for (int q=0; q<4; ++q) {
        const int r = gr + q;
        float x = v[q];
        if (EPI == 2) {
          x = fmaxf(fmaf(x, g.scale[gc], g.shift[gc]), 0.f);
        } else if (EPI == 3) {
          x += bias_d[gc] + bf2f(add_d[(size_t)r * g.ldc + gc]);
        } else {
          x += bias_d[gc];
        }
        Cd[(size_t)r * g.ldc + g.colOff + gc] = f2bf(x);
      }
    }
  }
}

// ---------------- small utility kernels --------------------------------------
__global__ void castk(const float* __restrict__ s, u16* __restrict__ d, int n)
{
  int i = (blockIdx.x*256 + threadIdx.x)*4;
  if (i < n){
    float4 v = *(const float4*)(s+i);
    ushort4 o; o.x=f2bf(v.x); o.y=f2bf(v.y); o.z=f2bf(v.z); o.w=f2bf(v.w);
    *(ushort4*)(d+i) = o;
  }
}

__global__ void c3rep(const float* __restrict__ w, u16* __restrict__ o)
{
  int id = blockIdx.x*256 + threadIdx.x; // 128*4608
  int oc = id / 4608, rem = id % 4608;
  int tap = rem >> 9, ic = rem & 511;
  o[id] = f2bf(w[((size_t)oc*512 + ic)*9 + tap]);
}

__global__ void bnssk(const float* g3,const float* b3,const float* m3,const float* v3,
                      const float* g1,const float* b1,const float* m1,const float* v1,
                      float* out)
{
  int t = threadIdx.x; int i = t & 127;
  if (t < 128){ float sc = g3[i]*rsqrtf(v3[i]+1e-5f); out[i]=sc; out[128+i]=b3[i]-m3[i]*sc; }
  else        { float sc = g1[i]*rsqrtf(v1[i]+1e-5f); out[256+i]=sc; out[384+i]=b1[i]-m1[i]*sc; }
}

__global__ __launch_bounds__(256)
void padk(const float* __restrict__ curr, const float* __restrict__ prev, u16* __restrict__ pad)
{
  const int id = blockIdx.x*256 + threadIdx.x; // 4*66*66*64
  const int c8 = id & 63;
  int t = id >> 6;
  const int xx = t % 66; t /= 66;
  const int yy = t % 66; const int b = t / 66;
  const int c0 = c8*8;
  uint4 o;
  if (yy==0 || yy==65 || xx==0 || xx==65){ o.x=0;o.y=0;o.z=0;o.w=0; }
  else {
    const int l = (yy-1)*64 + (xx-1);
    const float* s = (c0 < 256) ? curr + ((size_t)b*4096 + l)*256 + c0
                                : prev + ((size_t)b*4096 + l)*256 + (c0-256);
    float4 a = *(const float4*)s, bb = *(const float4*)(s+4);
    o.x = pk2(a.x,a.y); o.y = pk2(a.z,a.w); o.z = pk2(bb.x,bb.y); o.w = pk2(bb.z,bb.w);
  }
  *(uint4*)(pad + (((size_t)b*66 + yy)*66 + xx)*512 + c0) = o;
}

__global__ __launch_bounds__(256)
void ln256(const u16* __restrict__ in, long inZ, u16* __restrict__ out, long outZ,
           const float* __restrict__ gw, const float* __restrict__ bw, int pz)
{
  const int z = blockIdx.z;
  const int row = blockIdx.x*4 + (threadIdx.x>>6);
  const int l = threadIdx.x & 63;
  const u16* ip = in + (size_t)z*inZ + (size_t)row*256 + l*4;
  ushort4 rr = *(const ushort4*)ip;
  float v0=bf2f(rr.x), v1=bf2f(rr.y), v2=bf2f(rr.z), v3=bf2f(rr.w);
  float s = v0+v1+v2+v3;
  float ss = v0*v0+v1*v1+v2*v2+v3*v3;
  #pragma unroll
  for(int m=1;m<64;m<<=1){ s += __shfl_xor(s,m); ss += __shfl_xor(ss,m); }
  float mu = s*(1.f/256.f);
  float var = ss*(1.f/256.f) - mu*mu;
  float rs = rsqrtf(var + 1e-5f);
  const float* g = gw + (size_t)z*pz; const float* b = bw + (size_t)z*pz;
  int c = l*4;
  u16* op = out + (size_t)z*outZ + (size_t)row*256 + c;
  ushort4 o; o.x=f2bf((v0-mu)*rs*g[c]+b[c]); o.y=f2bf((v1-mu)*rs*g[c+1]+b[c+1]);
  o.z=f2bf((v2-mu)*rs*g[c+2]+b[c+2]); o.w=f2bf((v3-mu)*rs*g[c+3]+b[c+3]);
  *(ushort4*)op = o;
}

__global__ __launch_bounds__(256)
void rms512(u16* __restrict__ Y, const float* __restrict__ gw)
{
  const int z = blockIdx.z;
  const int row = blockIdx.x*4 + (threadIdx.x>>6);
  const int l = threadIdx.x & 63;
  u16* p = Y + ((size_t)z*16384 + row)*512 + l*8;
  uint4 raw = *(const uint4*)p;
  float v[8]; unpk8(raw, v);
  float ss = 0.f;
  #pragma unroll
  for (int j=0;j<8;j++) ss += v[j]*v[j];
  #pragma unroll
  for (int m=1;m<64;m<<=1) ss += __shfl_xor(ss, m);
  const float sc = rsqrtf(ss*(1.f/512.f) + 1e-5f);
  const float* g = gw + (size_t)z*512 + l*8;
  uint4 o;
  o.x = pk2(v[0]*sc*g[0], v[1]*sc*g[1]);
  o.y = pk2(v[2]*sc*g[2], v[3]*sc*g[3]);
  o.z = pk2(v[4]*sc*g[4], v[5]*sc*g[5]);
  o.w = pk2(v[6]*sc*g[6], v[7]*sc*g[7]);
  *(uint4*)p = o;
}

// fp32 dt head: dt = softplus(xln.W_dt + b + dt_bias)
__global__ __launch_bounds__(256)
void dtk(const u16* __restrict__ xln, const float* __restrict__ minW,
         const float* __restrict__ minB, const float* __restrict__ dtb,
         float* __restrict__ DT)
{
  __shared__ float sx[32*257];
  const int z = blockIdx.z;
  const int r0 = blockIdx.x * 32;
  const int tid = threadIdx.x;
  {
    const int rr = tid >> 3, cc = (tid & 7) * 32;
    const u16* src = xln + ((size_t)z*16384 + r0 + rr)*256 + cc;
    #pragma unroll
    for (int q=0;q<4;q++){
      uint4 raw = *(const uint4*)(src + q*8);
      float v[8]; unpk8(raw, v);
      #pragma unroll
      for (int j=0;j<8;j++) sx[rr*257 + cc + q*8 + j] = v[j];
    }
  }
  __syncthreads();
  const int ri = tid >> 3, hv = tid & 7;
  const float* wrow = minW + ((size_t)z*1288 + 1280 + hv)*256;
  float acc = 0.f;
  #pragma unroll 4
  for (int k=0; k<256; k+=4){
    float4 wq = *(const float4*)(wrow + k);
    acc += sx[ri*257+k]*wq.x + sx[ri*257+k+1]*wq.y + sx[ri*257+k+2]*wq.z + sx[ri*257+k+3]*wq.w;
  }
  acc += minB[(size_t)z*1288 + 1280 + hv] + dtb[z*8 + hv];
  float dt = (acc > 20.f) ? acc : log1pf(expf(acc));
  DT[((size_t)z*16384 + r0 + ri)*8 + hv] = dt;
}

// chunk-local cumulative log-decay: CA[t] = -exp(A_log)*cumsum_incl(dt) per 64-chunk
__global__ __launch_bounds__(256)
void cak(const float* __restrict__ DT, float* __restrict__ CA,
         const float* __restrict__ alog, int dirBase)
{
  const int z = blockIdx.z;
  const int gidx = blockIdx.x*4 + (threadIdx.x>>6);   // 0..2047 chunk id
  const int lane = threadIdx.x & 63;
  const int c = gidx & 63, bh = gidx >> 6;
  const int b = bh >> 3, hh = bh & 7;
  const size_t row = (size_t)z*16384 + (size_t)b*4096 + c*64 + lane;
  float x = DT[row*8 + hh];
  #pragma unroll
  for (int m=1;m<64;m<<=1){ float o = __shfl_up(x, m); if (lane >= m) x += o; }
  float eA = expf(alog[(dirBase+z)*8 + hh]);
  CA[row*8 + hh] = -eA * x;
}

// causal depthwise conv1d (4 taps) + SiLU over a 256-column chunk of xBC
__global__ __launch_bounds__(256)
void convc(const u16* __restrict__ xch, u16* __restrict__ xbcc,
           const float* __restrict__ cw, const float* __restrict__ cb,
           int cbase, long xchZ)
{
  const int id = blockIdx.x*256 + threadIdx.x; // nd*16384*32
  const int c8 = id & 31;
  const int r = (id >> 5) & 16383;
  const int d = id >> 19;
  const int li = r & 4095;
  const int ch = cbase + c8*8;
  const u16* base = xch + (size_t)d*xchZ + (size_t)(r - li)*256 + c8*8;
  float acc[8];
  #pragma unroll
  for (int j=0;j<8;j++) acc[j] = cb[d*768 + ch + j];
  #pragma unroll
  for (int tap=0; tap<4; ++tap){
    int lt = li - 3 + tap;
    if (lt >= 0){
      uint4 raw = *(const uint4*)(base + (size_t)lt*256);
      float v[8]; unpk8(raw, v);
      #pragma unroll
      for (int j=0;j<8;j++)
        acc[j] = fmaf(v[j], cw[((size_t)d*768 + ch + j)*4 + tap], acc[j]);
    }
  }
  float s[8];
  #pragma unroll
  for (int j=0;j<8;j++) s[j] = acc[j] / (1.f + __expf(-acc[j]));
  uint4 o;
  o.x = pk2(s[0],s[1]); o.y = pk2(s[2],s[3]); o.z = pk2(s[4],s[5]); o.w = pk2(s[6],s[7]);
  *(uint4*)(xbcc + ((size_t)d*16384 + r)*768 + ch) = o;
}

#define BTS 72

// sequential (over 64 chunks) state recurrence, MFMA: h <- a*h + Bw@X ; H[c]=h (bf16)
// one block per (dir, b, h): grid nd*32
__global__ __launch_bounds__(256)
void statek(const u16* __restrict__ xbc, const float* __restrict__ DT,
            const float* __restrict__ CA, u16* __restrict__ H)
{
  __shared__ u16 Bt[128*BTS];   // [n][s] w-scaled
  __shared__ u16 Xt[64*BTS];    // [p][s]
  __shared__ float wS[64];
  __shared__ float aS;
  const int bx = blockIdx.x;
  const int z = bx >> 5, bh = bx & 31;
  const int b = bh >> 3, hh = bh & 7;
  const int tid = threadIdx.x;
  const int l = tid & 63, w = tid >> 6;

  const size_t rowb = (size_t)z*16384 + (size_t)b*4096;
  const u16* xc = xbc + rowb*768;
  const float* dtp = DT + rowb*8 + hh;
  const float* cap = CA + rowb*8 + hh;
  u16* Hd = H + (size_t)z*16777216 + (size_t)bh*524288;

  f32x4 acc[2][4];
  #pragma unroll
  for (int i=0;i<2;i++)
    #pragma unroll
    for (int j=0;j<4;j++) acc[i][j] = (f32x4){0.f,0.f,0.f,0.f};

  #pragma unroll 1
  for (int c=0; c<64; ++c) {
    if (tid < 64) {
      float cav = cap[(size_t)(c*64 + tid)*8];
      float ca63 = __shfl(cav, 63);
      float dtv = dtp[(size_t)(c*64 + tid)*8];
      wS[tid] = __expf(ca63 - cav) * dtv;
      if (tid == 63) aS = __expf(ca63);
    }
    __syncthreads();
    // stage Bt = w[s]*B[s][n] transposed, Xt = X[s][p] transposed
    #pragma unroll
    for (int u=0; u<4; ++u){
      int idx = u*256 + tid;              // 1024 units of 8
      int s = idx >> 4, seg = idx & 15;
      uint4 raw = *(const uint4*)(xc + (size_t)(c*64+s)*768 + 512 + seg*8);
      float v[8]; unpk8(raw, v);
      float wv = wS[s];
      u16* dst = &Bt[(seg*8)*BTS + s];
      #pragma unroll
      for (int j=0;j<8;j++) dst[j*BTS] = f2bf(v[j]*wv);
    }
    #pragma unroll
    for (int u=0; u<2; ++u){
      int idx = u*256 + tid;              // 512 units of 8
      int s = idx >> 3, seg = idx & 7;
      uint4 raw = *(const uint4*)(xc + (size_t)(c*64+s)*768 + hh*64 + seg*8);
      u16 t8[8]; *(uint4*)t8 = raw;
      u16* dst = &Xt[(seg*8)*BTS + s];
      #pragma unroll
      for (int j=0;j<8;j++) dst[j*BTS] = t8[j];
    }
    __syncthreads();
    // write H[c] (pre-update state), then scale by alpha
    const float al = aS;
    #pragma unroll
    for (int mi=0; mi<2; ++mi)
      #pragma unroll
      for (int pi=0; pi<4; ++pi){
        int n = (w*2+mi)*16 + (l>>4)*4;
        int p = pi*16 + (l&15);
        u32* hp = (u32*)&Hd[((size_t)c*64 + p)*128 + n];
        hp[0] = pk2(acc[mi][pi][0], acc[mi][pi][1]);
        hp[1] = pk2(acc[mi][pi][2], acc[mi][pi][3]);
        #pragma unroll
        for (int q=0;q<4;q++) acc[mi][pi][q] *= al;
      }
    // G MFMA: D[n][p] += sum_s Bw[n][s] X[s][p]
    #pragma unroll
    for (int kk=0; kk<2; ++kk){
      bfx8 a0 = *(const bfx8*)&Bt[((w*2+0)*16 + (l&15))*BTS + kk*32 + (l>>4)*8];
      bfx8 a1 = *(const bfx8*)&Bt[((w*2+1)*16 + (l&15))*BTS + kk*32 + (l>>4)*8];
      #pragma unroll
      for (int pi=0; pi<4; ++pi){
        bfx8 bv = *(const bfx8*)&Xt[(pi*16 + (l&15))*BTS + kk*32 + (l>>4)*8];
        acc[0][pi] = __builtin_amdgcn_mfma_f32_16x16x32_bf16(a0, bv, acc[0][pi], 0, 0, 0);
        acc[1][pi] = __builtin_amdgcn_mfma_f32_16x16x32_bf16(a1, bv, acc[1][pi], 0, 0, 0);
      }
    }
    __syncthreads();
  }
}

// per-chunk output: Y = (S_decayed @ X + diag(exp(ca)) * (C @ H[c]) + Dh*x) * silu(z)
// one block per (dir, b, h, c): grid (2048, 1, nd)
__global__ __launch_bounds__(256)
void yk(const u16* __restrict__ xbc, const float* __restrict__ DT,
        const float* __restrict__ CA, const u16* __restrict__ H,
        const float* __restrict__ Dp, u16* __restrict__ Y)
{
  __shared__ u16 Sm[64*BTS];    // [t][s] decayed scores
  __shared__ u16 Xt[64*BTS];    // [p][s]
  __shared__ float caL[64], dtL[64];
  const int bx = blockIdx.x;
  const int z = blockIdx.z;
  const int c = bx & 63, bh = bx >> 6;
  const int b = bh >> 3, hh = bh & 7;
  const int tid = threadIdx.x, l = tid & 63, w = tid >> 6;
  const size_t rowb = (size_t)z*16384 + (size_t)b*4096;
  const u16* xc = xbc + (rowb + c*64)*768;
  const float Dh = Dp[z*8 + hh];

  if (tid < 64){
    caL[tid] = CA[(rowb + c*64 + tid)*8 + hh];
    dtL[tid] = DT[(rowb + c*64 + tid)*8 + hh];
  }
  #pragma unroll
  for (int u=0; u<2; ++u){
    int idx = u*256 + tid; int s = idx >> 3, seg = idx & 7;
    uint4 raw = *(const uint4*)(xc + (size_t)s*768 + hh*64 + seg*8);
    u16 t8[8]; *(uint4*)t8 = raw;
    u16* dst = &Xt[(seg*8)*BTS + s];
    #pragma unroll
    for (int j=0;j<8;j++) dst[j*BTS] = t8[j];
  }
  __syncthreads();

  // S = C@B^T and acc2 = C@H[c]  (both K=128 over n)
  const u16* Hd = H + (size_t)z*16777216 + (size_t)bh*524288 + (size_t)c*8192;
  f32x4 sacc[4], acc2[4];
  #pragma unroll
  for (int i=0;i<4;i++){ sacc[i] = (f32x4){0.f,0.f,0.f,0.f}; acc2[i] = (f32x4){0.f,0.f,0.f,0.f}; }
  #pragma unroll
  for (int kk=0; kk<4; ++kk){
    bfx8 av = *(const bfx8*)(xc + (size_t)(w*16 + (l&15))*768 + 640 + kk*32 + (l>>4)*8);
    #pragma unroll
    for (int st=0; st<4; ++st){
      bfx8 bv = *(const bfx8*)(xc + (size_t)(st*16 + (l&15))*768 + 512 + kk*32 + (l>>4)*8);
      sacc[st] = __builtin_amdgcn_mfma_f32_16x16x32_bf16(av, bv, sacc[st], 0, 0, 0);
      bfx8 hv = *(const bfx8*)&Hd[(size_t)(st*16 + (l&15))*128 + kk*32 + (l>>4)*8];
      acc2[st] = __builtin_amdgcn_mfma_f32_16x16x32_bf16(av, hv, acc2[st], 0, 0, 0);
    }
  }
  // decay+mask scores -> Sm (bf16)
  #pragma unroll
  for (int st=0; st<4; ++st){
    #pragma unroll
    for (int q=0;q<4;q++){
      int t = w*16 + (l>>4)*4 + q;
      int s = st*16 + (l&15);
      float m = (s <= t) ? __expf(caL[t]-caL[s]) * dtL[s] : 0.f;
      Sm[t*BTS + s] = f2bf(sacc[st][q] * m);
    }
  }
  // scale inter part rows by exp(ca[t])
  #pragma unroll
  for (int pt=0; pt<4; ++pt)
    #pragma unroll
    for (int q=0;q<4;q++){
      int t = w*16 + (l>>4)*4 + q;
      acc2[pt][q] *= __expf(caL[t]);
    }
  __syncthreads();
  // acc2 += Sm @ Xt^T (K=64 over s)
  #pragma unroll
  for (int kk=0; kk<2; ++kk){
    bfx8 av = *(const bfx8*)&Sm[(w*16 + (l&15))*BTS + kk*32 + (l>>4)*8];
    #pragma unroll
    for (int pt=0; pt<4; ++pt){
      bfx8 bv = *(const bfx8*)&Xt[(pt*16 + (l&15))*BTS + kk*32 + (l>>4)*8];
      acc2[pt] = __builtin_amdgcn_mfma_f32_16x16x32_bf16(av, bv, acc2[pt], 0, 0, 0);
    }
  }
  // epilogue: +Dh*x, gate with silu(z), write Y in place of z
  u16* Yrow = Y + (rowb + c*64)*512 + hh*64;
  #pragma unroll
  for (int pt=0; pt<4; ++pt){
    #pragma unroll
    for (int q=0;q<4;q++){
      int t = w*16 + (l>>4)*4 + q;
      int p = pt*16 + (l&15);
      float xv = bf2f(Xt[p*BTS + t]);
      float zf = bf2f(Yrow[(size_t)t*512 + p]);
      float yv = (acc2[pt][q] + Dh*xv) * (zf/(1.f+__expf(-zf)));
      Yrow[(size_t)t*512 + p] = f2bf(yv);
    }
  }
}

__global__ __launch_bounds__(256)
void finalk(const float* __restrict__ curr, const u16* __restrict__ outs, float* __restrict__ o)
{
  const int row = blockIdx.x*4 + (threadIdx.x>>6);
  const int c4 = (threadIdx.x & 63)*4;
  const int b = row >> 12, li = row & 4095;
  const int T = ((li & 63) << 6) | (li >> 6);
  const size_t rb = (size_t)b*4096;
  const ushort4 a0 = *(const ushort4*)(outs + (size_t)0*4194304 + ((rb+li)*256 + c4));
  const ushort4 a1 = *(const ushort4*)(outs + (size_t)1*4194304 + ((rb+T)*256 + c4));
  const ushort4 a2 = *(const ushort4*)(outs + (size_t)2*4194304 + ((rb+4095-li)*256 + c4));
  const ushort4 a3 = *(const ushort4*)(outs + (size_t)3*4194304 + ((rb+4095-T)*256 + c4));
  float4 cv = *(const float4*)(curr + (size_t)row*256 + c4);
  float4 r;
  r.x = cv.x + 0.25f*(bf2f(a0.x)+bf2f(a1.x)+bf2f(a2.x)+bf2f(a3.x));
  r.y = cv.y + 0.25f*(bf2f(a0.y)+bf2f(a1.y)+bf2f(a2.y)+bf2f(a3.y));
  r.z = cv.z + 0.25f*(bf2f(a0.z)+bf2f(a1.z)+bf2f(a2.z)+bf2f(a3.z));
  r.w = cv.w + 0.25f*(bf2f(a0.w)+bf2f(a1.w)+bf2f(a2.w)+bf2f(a3.w));
  *(float4*)(o + (size_t)row*256 + c4) = r;
}

// ---------------------------------------------------------------------------
extern "C" void kernel_launch(void* const* d_in, const int* in_sizes, int n_in,
                              void* d_out, int out_size, void* d_ws, size_t ws_size,
                              hipStream_t stream)
{
  (void)in_sizes; (void)n_in; (void)out_size;
  const float* curr   = (const float*)d_in[0];
  const float* prev   = (const float*)d_in[1];
  const float* conv3w = (const float*)d_in[2];
  const float* bn3g=(const float*)d_in[3], *bn3b=(const float*)d_in[4], *bn3m=(const float*)d_in[5], *bn3v=(const float*)d_in[6];
  const float* conv1w = (const float*)d_in[7];
  const float* bn1g=(const float*)d_in[8], *bn1b=(const float*)d_in[9], *bn1m=(const float*)d_in[10], *bn1v=(const float*)d_in[11];
  const float* fuseW=(const float*)d_in[12], *fuseB=(const float*)d_in[13];
  const float* lng=(const float*)d_in[14], *lnb=(const float*)d_in[15];
  const float* inpW=(const float*)d_in[16], *inpB=(const float*)d_in[17];
  const float* mlng=(const float*)d_in[18], *mlnb=(const float*)d_in[19];
  const float* minW=(const float*)d_in[20], *minB=(const float*)d_in[21];
  const float* cw=(const float*)d_in[22], *cb=(const float*)d_in[23];
  const float* alog=(const float*)d_in[24], *Dp=(const float*)d_in[25], *dtb=(const float*)d_in[26];
  const float* mng=(const float*)d_in[27];
  const float* moutW=(const float*)d_in[28], *moutB=(const float*)d_in[29];
  const float* outpW=(const float*)d_in[30], *outpB=(const float*)d_in[31];

  // ---- persistent layout ----
  char* ws = (char*)d_ws;
  size_t off = 0;
  auto alloc = [&](size_t bytes){ size_t o = off; off = (off + bytes + 1023) & ~(size_t)1023; return o; };
  const size_t O_WFUSE = alloc((size_t)256*256*2);
  const size_t O_WINP  = alloc((size_t)4*256*256*2);
  const size_t O_WMIN  = alloc((size_t)4*1288*256*2);
  const size_t O_WMOUT = alloc((size_t)4*256*512*2);
  const size_t O_WOUTP = alloc((size_t)4*256*256*2);
  const size_t O_WC3   = alloc((size_t)128*4608*2);
  const size_t O_WC1   = alloc((size_t)128*512*2);
  const size_t O_BNSS  = alloc(512*4);
  const size_t O_ZF    = alloc((size_t)16384*256*2);
  const size_t O_OUTS  = alloc((size_t)4*16384*256*2);
  const size_t O_P     = off;                 // per-phase region

  // per-dir sizes (bytes)
  const size_t S0d  = (size_t)16384*256*2;    // 8.39MB
  const size_t XLNd = (size_t)16384*256*2;    // 8.39MB (S1 overlays)
  const size_t Yd   = (size_t)16384*512*2;    // 16.8MB (zgate + y; XCH overlays early)
  const size_t XBCd = (size_t)16384*768*2;    // 25.2MB
  const size_t DTd  = (size_t)16384*8*4;      // 0.52MB
  const size_t CAd  = (size_t)16384*8*4;      // 0.52MB
  const size_t Hd_  = (size_t)32*64*64*128*2; // 33.55MB  (b*h=32, c=64, p=64, n=128)
  const size_t perdir = S0d + XLNd + Yd + XBCd + DTd + CAd + Hd_;

  int nd = 0;
  for (int cand = 4; cand >= 1; cand >>= 1)
    if (O_P + (size_t)cand*perdir <= ws_size) { nd = cand; break; }
  if (nd == 0) return;

  #define WP(o) ((u16*)(ws + (o)))
  #define FP(o) ((float*)(ws + (o)))

  // pre-phase transients live inside the phase region
  const size_t O_PAD = O_P;
  const size_t O_ZIN = O_PAD + (size_t)4*66*66*512*2;
  const size_t O_ZFT = O_ZIN + (size_t)16384*256*2;

  // 1. BN scale/shift + weight conversions
  bnssk<<<1, 256, 0, stream>>>(bn3g,bn3b,bn3m,bn3v, bn1g,bn1b,bn1m,bn1v, FP(O_BNSS));
  castk<<<(65536/4+255)/256, 256, 0, stream>>>(fuseW, WP(O_WFUSE), 65536);
  castk<<<(262144/4+255)/256, 256, 0, stream>>>(inpW, WP(O_WINP), 262144);
  castk<<<(1318912/4+255)/256, 256, 0, stream>>>(minW, WP(O_WMIN), 1318912);
  castk<<<(524288/4+255)/256, 256, 0, stream>>>(moutW, WP(O_WMOUT), 524288);
  castk<<<(262144/4+255)/256, 256, 0, stream>>>(outpW, WP(O_WOUTP), 262144);
  castk<<<(65536/4+255)/256, 256, 0, stream>>>(conv1w, WP(O_WC1), 65536);
  c3rep<<<2304, 256, 0, stream>>>(conv3w, WP(O_WC3));
  // 2. padded concat input (bf16)
  padk<<<4356, 256, 0, stream>>>(curr, prev, WP(O_PAD));

  GemmArgs a;
  // 3. conv3 -> zin[:,0:128]
  a = {}; a.pad = WP(O_PAD); a.Bw = WP(O_WC3); a.bZ = 0;
  a.scale = FP(O_BNSS); a.shift = FP(O_BNSS)+128;
  a.C = WP(O_ZIN); a.cZ = 0; a.ldc = 256; a.colOff = 0; a.K = 4608;
  gemm_bt<2,2><<<dim3(128,1,1), 256, 0, stream>>>(a);
  // 4. conv1 -> zin[:,128:256]
  a = {}; a.pad = WP(O_PAD); a.Bw = WP(O_WC1); a.bZ = 0;
  a.scale = FP(O_BNSS)+256; a.shift = FP(O_BNSS)+384;
  a.C = WP(O_ZIN); a.cZ = 0; a.ldc = 256; a.colOff = 128; a.K = 512;
  gemm_bt<3,2><<<dim3(128,1,1), 256, 0, stream>>>(a);
  // 5. fuse GEMM -> zft
  a = {}; a.A = WP(O_ZIN); a.aZ = 0; a.lda = 256; a.Bw = WP(O_WFUSE); a.bZ = 0;
  a.bias = fuseB; a.biasZ = 0; a.C = WP(O_ZFT); a.cZ = 0; a.ldc = 256; a.colOff = 0; a.K = 256;
  gemm_bt<0,0><<<dim3(128,2,1), 256, 0, stream>>>(a);
  // 6. LN -> zf (persistent)
  ln256<<<dim3(4096,1,1), 256, 0, stream>>>(WP(O_ZFT), 0, WP(O_ZF), 0, lng, lnb, 0);

  // ---- phases over directions ----
  for (int d0 = 0; d0 < 4; d0 += nd) {
    const size_t O_S0  = O_P;
    const size_t O_XLN = O_S0  + (size_t)nd*S0d;
    const size_t O_Y   = O_XLN + (size_t)nd*XLNd;   // z-gate + y; XCH overlays first half early
    const size_t O_XBC = O_Y   + (size_t)nd*Yd;
    const size_t O_DT  = O_XBC + (size_t)nd*XBCd;
    const size_t O_CA  = O_DT  + (size_t)nd*DTd;
    const size_t O_H   = O_CA  + (size_t)nd*CAd;
    const size_t O_S1  = O_XLN;                     // overlay (XLN dead after zgate gemm)
    const size_t O_XCH = O_Y;                       // overlay (dead before zgate gemm)

    // 7. inp GEMM (permuted rows per dir) -> s0
    a = {}; a.A = WP(O_ZF); a.aZ = 0; a.lda = 256;
    a.Bw = WP(O_WINP) + (size_t)d0*65536; a.bZ = 65536;
    a.bias = inpB + d0*256; a.biasZ = 256;
    a.C = WP(O_S0); a.cZ = 4194304; a.ldc = 256; a.colOff = 0; a.K = 256; a.dirBase = d0;
    gemm_bt<1,0><<<dim3(128,2,nd), 256, 0, stream>>>(a);
    // 8. per-dir LN(s0) -> xln
    ln256<<<dim3(4096,1,nd), 256, 0, stream>>>(WP(O_S0), 4194304, WP(O_XLN), 4194304,
                                               mlng + d0*256, mlnb + d0*256, 256);
    // 9. xBC GEMM in 3 column chunks of 256 + conv1d+silu per chunk -> xbcc
    for (int cc = 0; cc < 3; ++cc) {
      const int cbase = cc*256;
      a = {}; a.A = WP(O_XLN); a.aZ = 4194304; a.lda = 256;
      a.Bw = WP(O_WMIN) + (size_t)d0*329728 + (size_t)(512+cbase)*256; a.bZ = 329728;
      a.bias = minB + d0*1288 + 512 + cbase; a.biasZ = 1288;
      a.C = WP(O_XCH); a.cZ = 8388608; a.ldc = 256; a.colOff = 0; a.K = 256;
      gemm_bt<0,0><<<dim3(128,2,nd), 256, 0, stream>>>(a);
      convc<<<nd*2048, 256, 0, stream>>>(WP(O_XCH), WP(O_XBC), cw + d0*3072, cb + d0*768,
                                         cbase, 8388608);
    }
    // 10. dt (fp32)
    dtk<<<dim3(512,1,nd), 256, 0, stream>>>(WP(O_XLN), minW + (size_t)d0*329728,
                                            minB + d0*1288, dtb + d0*8, FP(O_DT));
    // 11. chunk-local cumulative log-decay
    cak<<<dim3(512,1,nd), 256, 0, stream>>>(FP(O_DT), FP(O_CA), alog, d0);
    // 12. state recurrence (sequential over chunks) -> H
    statek<<<nd*32, 256, 0, stream>>>(WP(O_XBC), FP(O_DT), FP(O_CA), WP(O_H));
    // 13. z-gate GEMM -> Y region (clobbers XCH overlay; XLN still alive)
    a = {}; a.A = WP(O_XLN); a.aZ = 4194304; a.lda = 256;
    a.Bw = WP(O_WMIN) + (size_t)d0*329728; a.bZ = 329728;
    a.bias = minB + d0*1288; a.biasZ = 1288;
    a.C = WP(O_Y); a.cZ = 8388608; a.ldc = 512; a.colOff = 0; a.K = 256;
    gemm_bt<0,0><<<dim3(128,4,nd), 256, 0, stream>>>(a);
    // 14. per-chunk outputs (intra + inter + skip + gate) -> Y in place
    yk<<<dim3(2048,1,nd), 256, 0, stream>>>(WP(O_XBC), FP(O_DT), FP(O_CA), WP(O_H),
                                            Dp + d0*8, WP(O_Y));
    // 15. RMSNorm in-place on Y
    rms512<<<dim3(4096,1,nd), 256, 0, stream>>>(WP(O_Y), mng + d0*512);
    // 16. m_out GEMM + s0 residual -> s1 (overlays xln)
    a = {}; a.A = WP(O_Y); a.aZ = 8388608; a.lda = 512;
    a.Bw = WP(O_WMOUT) + (size_t)d0*131072; a.bZ = 131072;
    a.bias = moutB + d0*256; a.biasZ = 256;
    a.add = WP(O_S0); a.addZ = 4194304;
    a.C = WP(O_S1); a.cZ = 4194304; a.ldc = 256; a.colOff = 0; a.K = 512;
    gemm_bt<0,3><<<dim3(128,2,nd), 256, 0, stream>>>(a);
    // 17. outp GEMM -> outs (persistent)
    a = {}; a.A = WP(O_S1); a.aZ = 4194304; a.lda = 256;
    a.Bw = WP(O_WOUTP) + (size_t)d0*65536; a.bZ = 65536;
    a.bias = outpB + d0*256; a.biasZ = 256;
    a.C = WP(O_OUTS) + (size_t)d0*4194304; a.cZ = 4194304; a.ldc = 256; a.colOff = 0; a.K = 256;
    gemm_bt<0,0><<<dim3(128,2,nd), 256, 0, stream>>>(a);
  }

  // 18. final inverse-permute average + residual
  finalk<<<4096, 256, 0, stream>>>(curr, WP(O_OUTS), (float*)d_out);

  #undef WP
  #undef FP
}

// Round 4
// 1383.626 us; speedup vs baseline: 2.7945x; 1.0968x over previous
//
#include <hip/hip_runtime.h>
#include <hip/hip_bf16.h>
#include <cstdint>
#include <cstddef>

typedef unsigned short u16;
typedef unsigned int u32;
typedef __attribute__((ext_vector_type(8))) __bf16 bfx8;
typedef __attribute__((ext_vector_type(4))) float f32x4;

static __device__ __forceinline__ float bitf(u32 v){ float f; __builtin_memcpy(&f,&v,4); return f; }
static __device__ __forceinline__ float bf2f(u16 v){ return bitf(((u32)v)<<16); }
static __device__ __forceinline__ u16 f2bf(float f){ __bf16 b=(__bf16)f; u16 r; __builtin_memcpy(&r,&b,2); return r; }
static __device__ __forceinline__ u32 pk2(float a,float b){ return (u32)f2bf(a) | ((u32)f2bf(b)<<16); }
static __device__ __forceinline__ void unpk8(uint4 r, float* o){
  o[0]=bitf(r.x<<16); o[1]=bitf(r.x&0xffff0000u);
  o[2]=bitf(r.y<<16); o[3]=bitf(r.y&0xffff0000u);
  o[4]=bitf(r.z<<16); o[5]=bitf(r.z&0xffff0000u);
  o[6]=bitf(r.w<<16); o[7]=bitf(r.w&0xffff0000u);
}
static __device__ __forceinline__ void async16(void* lds, const void* g){
  __builtin_amdgcn_global_load_lds((const __attribute__((address_space(1))) u32*)g,
                                   (__attribute__((address_space(3))) u32*)lds, 16, 0, 0);
}

// ---------------- GEMM: C[M][N] = A[M][K] @ B[N][K]^T (+ epilogue) -----------
// AMODE: 0=linear, 1=dir-permuted rows, 2=conv3 implicit (padded in), 3=conv1
// EPI:   0=+bias->bf16, 2=BN(scale,shift)+ReLU->bf16, 3=+bias+addsrc->bf16
struct GemmArgs {
  const u16* A; long aZ; int lda;
  const u16* Bw; long bZ;
  const float* bias; int biasZ;
  const float* scale; const float* shift;
  const u16* add; long addZ;
  u16* C; long cZ; int ldc; int colOff;
  int K;
  const u16* pad;
  int dirBase;
};

template<int AMODE, int EPI>
__global__ __launch_bounds__(256)
void gemm_bt(GemmArgs g)
{
  __shared__ u16 smA[128*64];
  __shared__ u16 smB[128*64];
  const int tid = threadIdx.x;
  const int l = tid & 63;
  const int wv = tid >> 6;
  const int wr = wv >> 1, wc = wv & 1;
  const int z = blockIdx.z;
  const int r0 = blockIdx.x * 128;
  const int n0 = blockIdx.y * 128;

  const u16* Abase = g.A + (size_t)z * g.aZ;
  const u16* Bbase = g.Bw + (size_t)z * g.bZ;

  f32x4 acc[4][4];
  #pragma unroll
  for (int i=0;i<4;i++)
    #pragma unroll
    for (int j=0;j<4;j++) acc[i][j] = (f32x4){0.f,0.f,0.f,0.f};

  const int nkt = g.K >> 6;
  #pragma unroll 1
  for (int kt=0; kt<nkt; ++kt) {
    const int k0 = kt << 6;
    #pragma unroll
    for (int it=0; it<4; ++it) {
      const int s = it*256 + tid;
      const int row = s >> 3, ch = s & 7;
      const u16* ga;
      if (AMODE == 0) {
        ga = Abase + (size_t)(r0+row) * g.lda + k0 + ch*8;
      } else if (AMODE == 1) {
        int rr = r0 + row; int li = rr & 4095; int bb = rr >> 12;
        int dir = g.dirBase + z;
        int l2 = (dir & 2) ? (4095 - li) : li;
        int sl = (dir & 1) ? (((l2 & 63) << 6) | (l2 >> 6)) : l2;
        ga = Abase + (size_t)((bb << 12) | sl) * g.lda + k0 + ch*8;
      } else if (AMODE == 2) {
        int rr = r0 + row; int bb = rr >> 12; int li = rr & 4095;
        int yy = li >> 6, xx = li & 63;
        int tap = k0 >> 9, kin = k0 & 511;
        int dy = tap / 3 - 1, dx = tap % 3 - 1;
        ga = g.pad + (((size_t)(bb*66 + yy+dy+1))*66 + (xx+dx+1))*512 + kin + ch*8;
      } else {
        int rr = r0 + row; int bb = rr >> 12; int li = rr & 4095;
        int yy = li >> 6, xx = li & 63;
        ga = g.pad + (((size_t)(bb*66 + yy+1))*66 + (xx+1))*512 + k0 + ch*8;
      }
      async16(&smA[(size_t)(it*256 + (tid & ~63))*8], ga);
      const u16* gb = Bbase + (size_t)(n0+row) * g.K + k0 + ch*8;
      async16(&smB[(size_t)(it*256 + (tid & ~63))*8], gb);
    }
    __syncthreads();
    #pragma unroll
    for (int kk=0; kk<2; ++kk) {
      bfx8 av[4], bv[4];
      #pragma unroll
      for (int mi=0; mi<4; ++mi) {
        int ra = wr*64 + mi*16 + (l & 15);
        av[mi] = *(const bfx8*)&smA[ra*64 + kk*32 + (l>>4)*8];
      }
      #pragma unroll
      for (int ni=0; ni<4; ++ni) {
        int rb = wc*64 + ni*16 + (l & 15);
        bv[ni] = *(const bfx8*)&smB[rb*64 + kk*32 + (l>>4)*8];
      }
      #pragma unroll
      for (int mi=0; mi<4; ++mi)
        #pragma unroll
        for (int ni=0; ni<4; ++ni)
          acc[mi][ni] = __builtin_amdgcn_mfma_f32_16x16x32_bf16(av[mi], bv[ni], acc[mi][ni], 0, 0, 0);
    }
    __syncthreads();
  }

  const float* bias_d = (EPI != 2) ? g.bias + (size_t)z * g.biasZ : nullptr;
  const u16* add_d = (EPI == 3) ? g.add + (size_t)z * g.addZ : nullptr;
  u16* Cd = g.C + (size_t)z * g.cZ;
  #pragma unroll
  for (int mi=0; mi<4; ++mi) {
    #pragma unroll
    for (int ni=0; ni<4; ++ni) {
      f32x4 v = acc[mi][ni];
      const int gr = r0 + wr*64 + mi*16 + ((l >> 4) << 2);
      const int gc = n0 + wc*64 + ni*16 + (l & 15);
      #pragma unroll
      for (int q=0; q<4; ++q) {
        const int r = gr + q;
        float x = v[q];
        if (EPI == 2) {
          x = fmaxf(fmaf(x, g.scale[gc], g.shift[gc]), 0.f);
        } else if (EPI == 3) {
          x += bias_d[gc] + bf2f(add_d[(size_t)r * g.ldc + gc]);
        } else {
          x += bias_d[gc];
        }
        Cd[(size_t)r * g.ldc + g.colOff + gc] = f2bf(x);
      }
    }
  }
}

// ---------------- small utility kernels --------------------------------------
__global__ void castk(const float* __restrict__ s, u16* __restrict__ d, int n)
{
  int i = (blockIdx.x*256 + threadIdx.x)*4;
  if (i < n){
    float4 v = *(const float4*)(s+i);
    ushort4 o; o.x=f2bf(v.x); o.y=f2bf(v.y); o.z=f2bf(v.z); o.w=f2bf(v.w);
    *(ushort4*)(d+i) = o;
  }
}

__global__ void c3rep(const float* __restrict__ w, u16* __restrict__ o)
{
  int id = blockIdx.x*256 + threadIdx.x; // 128*4608
  int oc = id / 4608, rem = id % 4608;
  int tap = rem >> 9, ic = rem & 511;
  o[id] = f2bf(w[((size_t)oc*512 + ic)*9 + tap]);
}

__global__ void bnssk(const float* g3,const float* b3,const float* m3,const float* v3,
                      const float* g1,const float* b1,const float* m1,const float* v1,
                      float* out)
{
  int t = threadIdx.x; int i = t & 127;
  if (t < 128){ float sc = g3[i]*rsqrtf(v3[i]+1e-5f); out[i]=sc; out[128+i]=b3[i]-m3[i]*sc; }
  else        { float sc = g1[i]*rsqrtf(v1[i]+1e-5f); out[256+i]=sc; out[384+i]=b1[i]-m1[i]*sc; }
}

__global__ __launch_bounds__(256)
void padk(const float* __restrict__ curr, const float* __restrict__ prev, u16* __restrict__ pad)
{
  const int id = blockIdx.x*256 + threadIdx.x; // 4*66*66*64
  const int c8 = id & 63;
  int t = id >> 6;
  const int xx = t % 66; t /= 66;
  const int yy = t % 66; const int b = t / 66;
  const int c0 = c8*8;
  uint4 o;
  if (yy==0 || yy==65 || xx==0 || xx==65){ o.x=0;o.y=0;o.z=0;o.w=0; }
  else {
    const int l = (yy-1)*64 + (xx-1);
    const float* s = (c0 < 256) ? curr + ((size_t)b*4096 + l)*256 + c0
                                : prev + ((size_t)b*4096 + l)*256 + (c0-256);
    float4 a = *(const float4*)s, bb = *(const float4*)(s+4);
    o.x = pk2(a.x,a.y); o.y = pk2(a.z,a.w); o.z = pk2(bb.x,bb.y); o.w = pk2(bb.z,bb.w);
  }
  *(uint4*)(pad + (((size_t)b*66 + yy)*66 + xx)*512 + c0) = o;
}

__global__ __launch_bounds__(256)
void ln256(const u16* __restrict__ in, long inZ, u16* __restrict__ out, long outZ,
           const float* __restrict__ gw, const float* __restrict__ bw, int pz)
{
  const int z = blockIdx.z;
  const int row = blockIdx.x*4 + (threadIdx.x>>6);
  const int l = threadIdx.x & 63;
  const u16* ip = in + (size_t)z*inZ + (size_t)row*256 + l*4;
  ushort4 rr = *(const ushort4*)ip;
  float v0=bf2f(rr.x), v1=bf2f(rr.y), v2=bf2f(rr.z), v3=bf2f(rr.w);
  float s = v0+v1+v2+v3;
  float ss = v0*v0+v1*v1+v2*v2+v3*v3;
  #pragma unroll
  for(int m=1;m<64;m<<=1){ s += __shfl_xor(s,m); ss += __shfl_xor(ss,m); }
  float mu = s*(1.f/256.f);
  float var = ss*(1.f/256.f) - mu*mu;
  float rs = rsqrtf(var + 1e-5f);
  const float* g = gw + (size_t)z*pz; const float* b = bw + (size_t)z*pz;
  int c = l*4;
  u16* op = out + (size_t)z*outZ + (size_t)row*256 + c;
  ushort4 o; o.x=f2bf((v0-mu)*rs*g[c]+b[c]); o.y=f2bf((v1-mu)*rs*g[c+1]+b[c+1]);
  o.z=f2bf((v2-mu)*rs*g[c+2]+b[c+2]); o.w=f2bf((v3-mu)*rs*g[c+3]+b[c+3]);
  *(ushort4*)op = o;
}

__global__ __launch_bounds__(256)
void rms512(u16* __restrict__ Y, const float* __restrict__ gw)
{
  const int z = blockIdx.z;
  const int row = blockIdx.x*4 + (threadIdx.x>>6);
  const int l = threadIdx.x & 63;
  u16* p = Y + ((size_t)z*16384 + row)*512 + l*8;
  uint4 raw = *(const uint4*)p;
  float v[8]; unpk8(raw, v);
  float ss = 0.f;
  #pragma unroll
  for (int j=0;j<8;j++) ss += v[j]*v[j];
  #pragma unroll
  for (int m=1;m<64;m<<=1) ss += __shfl_xor(ss, m);
  const float sc = rsqrtf(ss*(1.f/512.f) + 1e-5f);
  const float* g = gw + (size_t)z*512 + l*8;
  uint4 o;
  o.x = pk2(v[0]*sc*g[0], v[1]*sc*g[1]);
  o.y = pk2(v[2]*sc*g[2], v[3]*sc*g[3]);
  o.z = pk2(v[4]*sc*g[4], v[5]*sc*g[5]);
  o.w = pk2(v[6]*sc*g[6], v[7]*sc*g[7]);
  *(uint4*)p = o;
}

// fp32 dt head: dt = softplus(xln.W_dt + b + dt_bias)
__global__ __launch_bounds__(256)
void dtk(const u16* __restrict__ xln, const float* __restrict__ minW,
         const float* __restrict__ minB, const float* __restrict__ dtb,
         float* __restrict__ DT)
{
  __shared__ float sx[32*257];
  const int z = blockIdx.z;
  const int r0 = blockIdx.x * 32;
  const int tid = threadIdx.x;
  {
    const int rr = tid >> 3, cc = (tid & 7) * 32;
    const u16* src = xln + ((size_t)z*16384 + r0 + rr)*256 + cc;
    #pragma unroll
    for (int q=0;q<4;q++){
      uint4 raw = *(const uint4*)(src + q*8);
      float v[8]; unpk8(raw, v);
      #pragma unroll
      for (int j=0;j<8;j++) sx[rr*257 + cc + q*8 + j] = v[j];
    }
  }
  __syncthreads();
  const int ri = tid >> 3, hv = tid & 7;
  const float* wrow = minW + ((size_t)z*1288 + 1280 + hv)*256;
  float acc = 0.f;
  #pragma unroll 4
  for (int k=0; k<256; k+=4){
    float4 wq = *(const float4*)(wrow + k);
    acc += sx[ri*257+k]*wq.x + sx[ri*257+k+1]*wq.y + sx[ri*257+k+2]*wq.z + sx[ri*257+k+3]*wq.w;
  }
  acc += minB[(size_t)z*1288 + 1280 + hv] + dtb[z*8 + hv];
  float dt = (acc > 20.f) ? acc : log1pf(expf(acc));
  DT[((size_t)z*16384 + r0 + ri)*8 + hv] = dt;
}

// chunk-local cumulative log-decay: CA[t] = -exp(A_log)*cumsum_incl(dt) per 64-chunk
__global__ __launch_bounds__(256)
void cak(const float* __restrict__ DT, float* __restrict__ CA,
         const float* __restrict__ alog, int dirBase)
{
  const int z = blockIdx.z;
  const int gidx = blockIdx.x*4 + (threadIdx.x>>6);   // 0..2047 chunk id
  const int lane = threadIdx.x & 63;
  const int c = gidx & 63, bh = gidx >> 6;
  const int b = bh >> 3, hh = bh & 7;
  const size_t row = (size_t)z*16384 + (size_t)b*4096 + c*64 + lane;
  float x = DT[row*8 + hh];
  #pragma unroll
  for (int m=1;m<64;m<<=1){ float o = __shfl_up(x, m); if (lane >= m) x += o; }
  float eA = expf(alog[(dirBase+z)*8 + hh]);
  CA[row*8 + hh] = -eA * x;
}

// causal depthwise conv1d (4 taps) + SiLU over a 256-column chunk of xBC
__global__ __launch_bounds__(256)
void convc(const u16* __restrict__ xch, u16* __restrict__ xbcc,
           const float* __restrict__ cw, const float* __restrict__ cb,
           int cbase, long xchZ)
{
  const int id = blockIdx.x*256 + threadIdx.x; // nd*16384*32
  const int c8 = id & 31;
  const int r = (id >> 5) & 16383;
  const int d = id >> 19;
  const int li = r & 4095;
  const int ch = cbase + c8*8;
  const u16* base = xch + (size_t)d*xchZ + (size_t)(r - li)*256 + c8*8;
  float acc[8];
  #pragma unroll
  for (int j=0;j<8;j++) acc[j] = cb[d*768 + ch + j];
  #pragma unroll
  for (int tap=0; tap<4; ++tap){
    int lt = li - 3 + tap;
    if (lt >= 0){
      uint4 raw = *(const uint4*)(base + (size_t)lt*256);
      float v[8]; unpk8(raw, v);
      #pragma unroll
      for (int j=0;j<8;j++)
        acc[j] = fmaf(v[j], cw[((size_t)d*768 + ch + j)*4 + tap], acc[j]);
    }
  }
  float s[8];
  #pragma unroll
  for (int j=0;j<8;j++) s[j] = acc[j] / (1.f + __expf(-acc[j]));
  uint4 o;
  o.x = pk2(s[0],s[1]); o.y = pk2(s[2],s[3]); o.z = pk2(s[4],s[5]); o.w = pk2(s[6],s[7]);
  *(uint4*)(xbcc + ((size_t)d*16384 + r)*768 + ch) = o;
}

#define BTS 72

// per-chunk outer-product sums (fully parallel): CS[c] = sum_s w[s]*B[s] (x) X[s]
// one block per (dir, bh, c): grid (2048, 1, nd)
__global__ __launch_bounds__(256)
void chunkk(const u16* __restrict__ xbc, const float* __restrict__ DT,
            const float* __restrict__ CA, u16* __restrict__ CS)
{
  __shared__ u16 Bt[128*BTS];   // [n][s] w-scaled
  __shared__ u16 Xt[64*BTS];    // [p][s]
  __shared__ float wS[64];
  const int bx = blockIdx.x;
  const int z = blockIdx.z;
  const int c = bx & 63, bh = bx >> 6;
  const int b = bh >> 3, hh = bh & 7;
  const int tid = threadIdx.x;
  const int l = tid & 63, w = tid >> 6;

  const size_t rowb = (size_t)z*16384 + (size_t)b*4096;
  const u16* xc = xbc + (rowb + c*64)*768;

  if (tid < 64) {
    float cav = CA[(rowb + c*64 + tid)*8 + hh];
    float ca63 = __shfl(cav, 63);
    float dtv = DT[(rowb + c*64 + tid)*8 + hh];
    wS[tid] = __expf(ca63 - cav) * dtv;
  }
  __syncthreads();
  // stage Bt = w[s]*B[s][n] transposed, Xt = X[s][p] transposed
  #pragma unroll
  for (int u=0; u<4; ++u){
    int idx = u*256 + tid;              // 1024 units of 8
    int s = idx >> 4, seg = idx & 15;
    uint4 raw = *(const uint4*)(xc + (size_t)s*768 + 512 + seg*8);
    float v[8]; unpk8(raw, v);
    float wv = wS[s];
    u16* dst = &Bt[(seg*8)*BTS + s];
    #pragma unroll
    for (int j=0;j<8;j++) dst[j*BTS] = f2bf(v[j]*wv);
  }
  #pragma unroll
  for (int u=0; u<2; ++u){
    int idx = u*256 + tid;              // 512 units of 8
    int s = idx >> 3, seg = idx & 7;
    uint4 raw = *(const uint4*)(xc + (size_t)s*768 + hh*64 + seg*8);
    u16 t8[8]; *(uint4*)t8 = raw;
    u16* dst = &Xt[(seg*8)*BTS + s];
    #pragma unroll
    for (int j=0;j<8;j++) dst[j*BTS] = t8[j];
  }
  __syncthreads();

  f32x4 acc[2][4];
  #pragma unroll
  for (int i=0;i<2;i++)
    #pragma unroll
    for (int j=0;j<4;j++) acc[i][j] = (f32x4){0.f,0.f,0.f,0.f};
  #pragma unroll
  for (int kk=0; kk<2; ++kk){
    bfx8 a0 = *(const bfx8*)&Bt[((w*2+0)*16 + (l&15))*BTS + kk*32 + (l>>4)*8];
    bfx8 a1 = *(const bfx8*)&Bt[((w*2+1)*16 + (l&15))*BTS + kk*32 + (l>>4)*8];
    #pragma unroll
    for (int pi=0; pi<4; ++pi){
      bfx8 bv = *(const bfx8*)&Xt[(pi*16 + (l&15))*BTS + kk*32 + (l>>4)*8];
      acc[0][pi] = __builtin_amdgcn_mfma_f32_16x16x32_bf16(a0, bv, acc[0][pi], 0, 0, 0);
      acc[1][pi] = __builtin_amdgcn_mfma_f32_16x16x32_bf16(a1, bv, acc[1][pi], 0, 0, 0);
    }
  }
  // write CS[bh][c][p][n]
  u16* Cd = CS + (size_t)z*16777216 + (size_t)bh*524288 + (size_t)c*8192;
  #pragma unroll
  for (int mi=0; mi<2; ++mi)
    #pragma unroll
    for (int pi=0; pi<4; ++pi){
      int n = (w*2+mi)*16 + (l>>4)*4;
      int p = pi*16 + (l&15);
      u32* cp = (u32*)&Cd[(size_t)p*128 + n];
      cp[0] = pk2(acc[mi][pi][0], acc[mi][pi][1]);
      cp[1] = pk2(acc[mi][pi][2], acc[mi][pi][3]);
    }
}

// sequential 64-step combine (elementwise): H[c] = h; h = a[c]*h + CS[c]
// grid (128, 1, nd): block per (bh, 16-row p-group)
__global__ __launch_bounds__(256)
void combk(const u16* __restrict__ CS, const float* __restrict__ CA,
           u16* __restrict__ H)
{
  __shared__ float aL[64];
  const int bx = blockIdx.x;
  const int z = blockIdx.z;
  const int pg = bx & 3, bh = bx >> 2;
  const int b = bh >> 3, hh = bh & 7;
  const int tid = threadIdx.x;
  const int p = pg*16 + (tid >> 4), n = (tid & 15)*8;
  const size_t rowb = (size_t)z*16384 + (size_t)b*4096;
  if (tid < 64) aL[tid] = __expf(CA[(rowb + tid*64 + 63)*8 + hh]);
  __syncthreads();
  const u16* Cs = CS + (size_t)z*16777216 + (size_t)bh*524288 + (size_t)p*128 + n;
  u16* Hd = H + (size_t)z*16777216 + (size_t)bh*524288 + (size_t)p*128 + n;
  float h[8];
  #pragma unroll
  for (int j=0;j<8;j++) h[j]=0.f;
  uint4 pf = *(const uint4*)Cs;
  #pragma unroll 1
  for (int c=0; c<64; ++c){
    uint4 cur = pf;
    if (c < 63) pf = *(const uint4*)(Cs + (size_t)(c+1)*8192);
    uint4 o;
    o.x = pk2(h[0],h[1]); o.y = pk2(h[2],h[3]);
    o.z = pk2(h[4],h[5]); o.w = pk2(h[6],h[7]);
    *(uint4*)(Hd + (size_t)c*8192) = o;
    float v[8]; unpk8(cur, v);
    const float a = aL[c];
    #pragma unroll
    for (int j=0;j<8;j++) h[j] = fmaf(h[j], a, v[j]);
  }
}

// per-chunk output: Y = (S_decayed @ X + diag(exp(ca)) * (C @ H[c]) + Dh*x) * silu(z)
// one block per (dir, b, h, c): grid (2048, 1, nd)
__global__ __launch_bounds__(256)
void yk(const u16* __restrict__ xbc, const float* __restrict__ DT,
        const float* __restrict__ CA, const u16* __restrict__ H,
        const float* __restrict__ Dp, u16* __restrict__ Y)
{
  __shared__ u16 Sm[64*BTS];    // [t][s] decayed scores
  __shared__ u16 Xt[64*BTS];    // [p][s]
  __shared__ float caL[64], dtL[64];
  const int bx = blockIdx.x;
  const int z = blockIdx.z;
  const int c = bx & 63, bh = bx >> 6;
  const int b = bh >> 3, hh = bh & 7;
  const int tid = threadIdx.x, l = tid & 63, w = tid >> 6;
  const size_t rowb = (size_t)z*16384 + (size_t)b*4096;
  const u16* xc = xbc + (rowb + c*64)*768;
  const float Dh = Dp[z*8 + hh];

  if (tid < 64){
    caL[tid] = CA[(rowb + c*64 + tid)*8 + hh];
    dtL[tid] = DT[(rowb + c*64 + tid)*8 + hh];
  }
  #pragma unroll
  for (int u=0; u<2; ++u){
    int idx = u*256 + tid; int s = idx >> 3, seg = idx & 7;
    uint4 raw = *(const uint4*)(xc + (size_t)s*768 + hh*64 + seg*8);
    u16 t8[8]; *(uint4*)t8 = raw;
    u16* dst = &Xt[(seg*8)*BTS + s];
    #pragma unroll
    for (int j=0;j<8;j++) dst[j*BTS] = t8[j];
  }
  __syncthreads();

  // S = C@B^T and acc2 = C@H[c]  (both K=128 over n)
  const u16* Hd = H + (size_t)z*16777216 + (size_t)bh*524288 + (size_t)c*8192;
  f32x4 sacc[4], acc2[4];
  #pragma unroll
  for (int i=0;i<4;i++){ sacc[i] = (f32x4){0.f,0.f,0.f,0.f}; acc2[i] = (f32x4){0.f,0.f,0.f,0.f}; }
  #pragma unroll
  for (int kk=0; kk<4; ++kk){
    bfx8 av = *(const bfx8*)(xc + (size_t)(w*16 + (l&15))*768 + 640 + kk*32 + (l>>4)*8);
    #pragma unroll
    for (int st=0; st<4; ++st){
      bfx8 bv = *(const bfx8*)(xc + (size_t)(st*16 + (l&15))*768 + 512 + kk*32 + (l>>4)*8);
      sacc[st] = __builtin_amdgcn_mfma_f32_16x16x32_bf16(av, bv, sacc[st], 0, 0, 0);
      bfx8 hv = *(const bfx8*)&Hd[(size_t)(st*16 + (l&15))*128 + kk*32 + (l>>4)*8];
      acc2[st] = __builtin_amdgcn_mfma_f32_16x16x32_bf16(av, hv, acc2[st], 0, 0, 0);
    }
  }
  // decay+mask scores -> Sm (bf16)
  #pragma unroll
  for (int st=0; st<4; ++st){
    #pragma unroll
    for (int q=0;q<4;q++){
      int t = w*16 + (l>>4)*4 + q;
      int s = st*16 + (l&15);
      float m = (s <= t) ? __expf(caL[t]-caL[s]) * dtL[s] : 0.f;
      Sm[t*BTS + s] = f2bf(sacc[st][q] * m);
    }
  }
  // scale inter part rows by exp(ca[t])
  #pragma unroll
  for (int pt=0; pt<4; ++pt)
    #pragma unroll
    for (int q=0;q<4;q++){
      int t = w*16 + (l>>4)*4 + q;
      acc2[pt][q] *= __expf(caL[t]);
    }
  __syncthreads();
  // acc2 += Sm @ Xt^T (K=64 over s)
  #pragma unroll
  for (int kk=0; kk<2; ++kk){
    bfx8 av = *(const bfx8*)&Sm[(w*16 + (l&15))*BTS + kk*32 + (l>>4)*8];
    #pragma unroll
    for (int pt=0; pt<4; ++pt){
      bfx8 bv = *(const bfx8*)&Xt[(pt*16 + (l&15))*BTS + kk*32 + (l>>4)*8];
      acc2[pt] = __builtin_amdgcn_mfma_f32_16x16x32_bf16(av, bv, acc2[pt], 0, 0, 0);
    }
  }
  // epilogue: +Dh*x, gate with silu(z), write Y in place of z
  u16* Yrow = Y + (rowb + c*64)*512 + hh*64;
  #pragma unroll
  for (int pt=0; pt<4; ++pt){
    #pragma unroll
    for (int q=0;q<4;q++){
      int t = w*16 + (l>>4)*4 + q;
      int p = pt*16 + (l&15);
      float xv = bf2f(Xt[p*BTS + t]);
      float zf = bf2f(Yrow[(size_t)t*512 + p]);
      float yv = (acc2[pt][q] + Dh*xv) * (zf/(1.f+__expf(-zf)));
      Yrow[(size_t)t*512 + p] = f2bf(yv);
    }
  }
}

__global__ __launch_bounds__(256)
void finalk(const float* __restrict__ curr, const u16* __restrict__ outs, float* __restrict__ o)
{
  const int row = blockIdx.x*4 + (threadIdx.x>>6);
  const int c4 = (threadIdx.x & 63)*4;
  const int b = row >> 12, li = row & 4095;
  const int T = ((li & 63) << 6) | (li >> 6);
  const size_t rb = (size_t)b*4096;
  const ushort4 a0 = *(const ushort4*)(outs + (size_t)0*4194304 + ((rb+li)*256 + c4));
  const ushort4 a1 = *(const ushort4*)(outs + (size_t)1*4194304 + ((rb+T)*256 + c4));
  const ushort4 a2 = *(const ushort4*)(outs + (size_t)2*4194304 + ((rb+4095-li)*256 + c4));
  const ushort4 a3 = *(const ushort4*)(outs + (size_t)3*4194304 + ((rb+4095-T)*256 + c4));
  float4 cv = *(const float4*)(curr + (size_t)row*256 + c4);
  float4 r;
  r.x = cv.x + 0.25f*(bf2f(a0.x)+bf2f(a1.x)+bf2f(a2.x)+bf2f(a3.x));
  r.y = cv.y + 0.25f*(bf2f(a0.y)+bf2f(a1.y)+bf2f(a2.y)+bf2f(a3.y));
  r.z = cv.z + 0.25f*(bf2f(a0.z)+bf2f(a1.z)+bf2f(a2.z)+bf2f(a3.z));
  r.w = cv.w + 0.25f*(bf2f(a0.w)+bf2f(a1.w)+bf2f(a2.w)+bf2f(a3.w));
  *(float4*)(o + (size_t)row*256 + c4) = r;
}

// ---------------------------------------------------------------------------
extern "C" void kernel_launch(void* const* d_in, const int* in_sizes, int n_in,
                              void* d_out, int out_size, void* d_ws, size_t ws_size,
                              hipStream_t stream)
{
  (void)in_sizes; (void)n_in; (void)out_size;
  const float* curr   = (const float*)d_in[0];
  const float* prev   = (const float*)d_in[1];
  const float* conv3w = (const float*)d_in[2];
  const float* bn3g=(const float*)d_in[3], *bn3b=(const float*)d_in[4], *bn3m=(const float*)d_in[5], *bn3v=(const float*)d_in[6];
  const float* conv1w = (const float*)d_in[7];
  const float* bn1g=(const float*)d_in[8], *bn1b=(const float*)d_in[9], *bn1m=(const float*)d_in[10], *bn1v=(const float*)d_in[11];
  const float* fuseW=(const float*)d_in[12], *fuseB=(const float*)d_in[13];
  const float* lng=(const float*)d_in[14], *lnb=(const float*)d_in[15];
  const float* inpW=(const float*)d_in[16], *inpB=(const float*)d_in[17];
  const float* mlng=(const float*)d_in[18], *mlnb=(const float*)d_in[19];
  const float* minW=(const float*)d_in[20], *minB=(const float*)d_in[21];
  const float* cw=(const float*)d_in[22], *cb=(const float*)d_in[23];
  const float* alog=(const float*)d_in[24], *Dp=(const float*)d_in[25], *dtb=(const float*)d_in[26];
  const float* mng=(const float*)d_in[27];
  const float* moutW=(const float*)d_in[28], *moutB=(const float*)d_in[29];
  const float* outpW=(const float*)d_in[30], *outpB=(const float*)d_in[31];

  // ---- persistent layout ----
  char* ws = (char*)d_ws;
  size_t off = 0;
  auto alloc = [&](size_t bytes){ size_t o = off; off = (off + bytes + 1023) & ~(size_t)1023; return o; };
  const size_t O_WFUSE = alloc((size_t)256*256*2);
  const size_t O_WINP  = alloc((size_t)4*256*256*2);
  const size_t O_WMIN  = alloc((size_t)4*1288*256*2);
  const size_t O_WMOUT = alloc((size_t)4*256*512*2);
  const size_t O_WOUTP = alloc((size_t)4*256*256*2);
  const size_t O_WC3   = alloc((size_t)128*4608*2);
  const size_t O_WC1   = alloc((size_t)128*512*2);
  const size_t O_BNSS  = alloc(512*4);
  const size_t O_ZF    = alloc((size_t)16384*256*2);
  const size_t O_OUTS  = alloc((size_t)4*16384*256*2);
  const size_t O_P     = off;                 // per-phase region

  // per-dir sizes (bytes)
  const size_t S0d  = (size_t)16384*256*2;    // 8.39MB
  const size_t XLNd = (size_t)16384*256*2;    // 8.39MB (S1 overlays)
  const size_t Yd   = (size_t)16384*512*2;    // 16.8MB (zgate + y; XCH overlays early)
  const size_t XBCd = (size_t)16384*768*2;    // 25.2MB
  const size_t DTd  = (size_t)16384*8*4;      // 0.52MB
  const size_t CAd  = (size_t)16384*8*4;      // 0.52MB
  const size_t Hd_  = (size_t)32*64*64*128*2; // 33.55MB
  const size_t CSd  = (size_t)32*64*64*128*2; // 33.55MB
  const size_t perdir = S0d + XLNd + Yd + XBCd + DTd + CAd + Hd_ + CSd;

  int nd = 0;
  for (int cand = 4; cand >= 1; cand >>= 1)
    if (O_P + (size_t)cand*perdir <= ws_size) { nd = cand; break; }
  if (nd == 0) return;

  #define WP(o) ((u16*)(ws + (o)))
  #define FP(o) ((float*)(ws + (o)))

  // pre-phase transients live inside the phase region
  const size_t O_PAD = O_P;
  const size_t O_ZIN = O_PAD + (size_t)4*66*66*512*2;
  const size_t O_ZFT = O_ZIN + (size_t)16384*256*2;

  // 1. BN scale/shift + weight conversions
  bnssk<<<1, 256, 0, stream>>>(bn3g,bn3b,bn3m,bn3v, bn1g,bn1b,bn1m,bn1v, FP(O_BNSS));
  castk<<<(65536/4+255)/256, 256, 0, stream>>>(fuseW, WP(O_WFUSE), 65536);
  castk<<<(262144/4+255)/256, 256, 0, stream>>>(inpW, WP(O_WINP), 262144);
  castk<<<(1318912/4+255)/256, 256, 0, stream>>>(minW, WP(O_WMIN), 1318912);
  castk<<<(524288/4+255)/256, 256, 0, stream>>>(moutW, WP(O_WMOUT), 524288);
  castk<<<(262144/4+255)/256, 256, 0, stream>>>(outpW, WP(O_WOUTP), 262144);
  castk<<<(65536/4+255)/256, 256, 0, stream>>>(conv1w, WP(O_WC1), 65536);
  c3rep<<<2304, 256, 0, stream>>>(conv3w, WP(O_WC3));
  // 2. padded concat input (bf16)
  padk<<<4356, 256, 0, stream>>>(curr, prev, WP(O_PAD));

  GemmArgs a;
  // 3. conv3 -> zin[:,0:128]
  a = {}; a.pad = WP(O_PAD); a.Bw = WP(O_WC3); a.bZ = 0;
  a.scale = FP(O_BNSS); a.shift = FP(O_BNSS)+128;
  a.C = WP(O_ZIN); a.cZ = 0; a.ldc = 256; a.colOff = 0; a.K = 4608;
  gemm_bt<2,2><<<dim3(128,1,1), 256, 0, stream>>>(a);
  // 4. conv1 -> zin[:,128:256]
  a = {}; a.pad = WP(O_PAD); a.Bw = WP(O_WC1); a.bZ = 0;
  a.scale = FP(O_BNSS)+256; a.shift = FP(O_BNSS)+384;
  a.C = WP(O_ZIN); a.cZ = 0; a.ldc = 256; a.colOff = 128; a.K = 512;
  gemm_bt<3,2><<<dim3(128,1,1), 256, 0, stream>>>(a);
  // 5. fuse GEMM -> zft
  a = {}; a.A = WP(O_ZIN); a.aZ = 0; a.lda = 256; a.Bw = WP(O_WFUSE); a.bZ = 0;
  a.bias = fuseB; a.biasZ = 0; a.C = WP(O_ZFT); a.cZ = 0; a.ldc = 256; a.colOff = 0; a.K = 256;
  gemm_bt<0,0><<<dim3(128,2,1), 256, 0, stream>>>(a);
  // 6. LN -> zf (persistent)
  ln256<<<dim3(4096,1,1), 256, 0, stream>>>(WP(O_ZFT), 0, WP(O_ZF), 0, lng, lnb, 0);

  // ---- phases over directions ----
  for (int d0 = 0; d0 < 4; d0 += nd) {
    const size_t O_S0  = O_P;
    const size_t O_XLN = O_S0  + (size_t)nd*S0d;
    const size_t O_Y   = O_XLN + (size_t)nd*XLNd;   // z-gate + y; XCH overlays first half early
    const size_t O_XBC = O_Y   + (size_t)nd*Yd;
    const size_t O_DT  = O_XBC + (size_t)nd*XBCd;
    const size_t O_CA  = O_DT  + (size_t)nd*DTd;
    const size_t O_H   = O_CA  + (size_t)nd*CAd;
    const size_t O_CS  = O_H   + (size_t)nd*Hd_;
    const size_t O_S1  = O_XLN;                     // overlay (XLN dead after zgate gemm)
    const size_t O_XCH = O_Y;                       // overlay (dead before zgate gemm)

    // 7. inp GEMM (permuted rows per dir) -> s0
    a = {}; a.A = WP(O_ZF); a.aZ = 0; a.lda = 256;
    a.Bw = WP(O_WINP) + (size_t)d0*65536; a.bZ = 65536;
    a.bias = inpB + d0*256; a.biasZ = 256;
    a.C = WP(O_S0); a.cZ = 4194304; a.ldc = 256; a.colOff = 0; a.K = 256; a.dirBase = d0;
    gemm_bt<1,0><<<dim3(128,2,nd), 256, 0, stream>>>(a);
    // 8. per-dir LN(s0) -> xln
    ln256<<<dim3(4096,1,nd), 256, 0, stream>>>(WP(O_S0), 4194304, WP(O_XLN), 4194304,
                                               mlng + d0*256, mlnb + d0*256, 256);
    // 9. xBC GEMM in 3 column chunks of 256 + conv1d+silu per chunk -> xbcc
    for (int cc = 0; cc < 3; ++cc) {
      const int cbase = cc*256;
      a = {}; a.A = WP(O_XLN); a.aZ = 4194304; a.lda = 256;
      a.Bw = WP(O_WMIN) + (size_t)d0*329728 + (size_t)(512+cbase)*256; a.bZ = 329728;
      a.bias = minB + d0*1288 + 512 + cbase; a.biasZ = 1288;
      a.C = WP(O_XCH); a.cZ = 8388608; a.ldc = 256; a.colOff = 0; a.K = 256;
      gemm_bt<0,0><<<dim3(128,2,nd), 256, 0, stream>>>(a);
      convc<<<nd*2048, 256, 0, stream>>>(WP(O_XCH), WP(O_XBC), cw + d0*3072, cb + d0*768,
                                         cbase, 8388608);
    }
    // 10. dt (fp32)
    dtk<<<dim3(512,1,nd), 256, 0, stream>>>(WP(O_XLN), minW + (size_t)d0*329728,
                                            minB + d0*1288, dtb + d0*8, FP(O_DT));
    // 11. chunk-local cumulative log-decay
    cak<<<dim3(512,1,nd), 256, 0, stream>>>(FP(O_DT), FP(O_CA), alog, d0);
    // 12a. per-chunk outer-product sums (parallel) -> CS
    chunkk<<<dim3(2048,1,nd), 256, 0, stream>>>(WP(O_XBC), FP(O_DT), FP(O_CA), WP(O_CS));
    // 12b. 64-step elementwise combine -> H
    combk<<<dim3(128,1,nd), 256, 0, stream>>>(WP(O_CS), FP(O_CA), WP(O_H));
    // 13. z-gate GEMM -> Y region (clobbers XCH overlay; XLN still alive)
    a = {}; a.A = WP(O_XLN); a.aZ = 4194304; a.lda = 256;
    a.Bw = WP(O_WMIN) + (size_t)d0*329728; a.bZ = 329728;
    a.bias = minB + d0*1288; a.biasZ = 1288;
    a.C = WP(O_Y); a.cZ = 8388608; a.ldc = 512; a.colOff = 0; a.K = 256;
    gemm_bt<0,0><<<dim3(128,4,nd), 256, 0, stream>>>(a);
    // 14. per-chunk outputs (intra + inter + skip + gate) -> Y in place
    yk<<<dim3(2048,1,nd), 256, 0, stream>>>(WP(O_XBC), FP(O_DT), FP(O_CA), WP(O_H),
                                            Dp + d0*8, WP(O_Y));
    // 15. RMSNorm in-place on Y
    rms512<<<dim3(4096,1,nd), 256, 0, stream>>>(WP(O_Y), mng + d0*512);
    // 16. m_out GEMM + s0 residual -> s1 (overlays xln)
    a = {}; a.A = WP(O_Y); a.aZ = 8388608; a.lda = 512;
    a.Bw = WP(O_WMOUT) + (size_t)d0*131072; a.bZ = 131072;
    a.bias = moutB + d0*256; a.biasZ = 256;
    a.add = WP(O_S0); a.addZ = 4194304;
    a.C = WP(O_S1); a.cZ = 4194304; a.ldc = 256; a.colOff = 0; a.K = 512;
    gemm_bt<0,3><<<dim3(128,2,nd), 256, 0, stream>>>(a);
    // 17. outp GEMM -> outs (persistent)
    a = {}; a.A = WP(O_S1); a.aZ = 4194304; a.lda = 256;
    a.Bw = WP(O_WOUTP) + (size_t)d0*65536; a.bZ = 65536;
    a.bias = outpB + d0*256; a.biasZ = 256;
    a.C = WP(O_OUTS) + (size_t)d0*4194304; a.cZ = 4194304; a.ldc = 256; a.colOff = 0; a.K = 256;
    gemm_bt<0,0><<<dim3(128,2,nd), 256, 0, stream>>>(a);
  }

  // 18. final inverse-permute average + residual
  finalk<<<4096, 256, 0, stream>>>(curr, WP(O_OUTS), (float*)d_out);

  #undef WP
  #undef FP
}

// Round 5
// 904.410 us; speedup vs baseline: 4.2752x; 1.5299x over previous
//
#include <hip/hip_runtime.h>
#include <hip/hip_bf16.h>
#include <cstdint>
#include <cstddef>

typedef unsigned short u16;
typedef unsigned int u32;
typedef __attribute__((ext_vector_type(8))) __bf16 bfx8;
typedef __attribute__((ext_vector_type(4))) float f32x4;

static __device__ __forceinline__ float bitf(u32 v){ float f; __builtin_memcpy(&f,&v,4); return f; }
static __device__ __forceinline__ float bf2f(u16 v){ return bitf(((u32)v)<<16); }
static __device__ __forceinline__ u16 f2bf(float f){ __bf16 b=(__bf16)f; u16 r; __builtin_memcpy(&r,&b,2); return r; }
static __device__ __forceinline__ u32 pk2(float a,float b){ return (u32)f2bf(a) | ((u32)f2bf(b)<<16); }
static __device__ __forceinline__ void unpk8(uint4 r, float* o){
  o[0]=bitf(r.x<<16); o[1]=bitf(r.x&0xffff0000u);
  o[2]=bitf(r.y<<16); o[3]=bitf(r.y&0xffff0000u);
  o[4]=bitf(r.z<<16); o[5]=bitf(r.z&0xffff0000u);
  o[6]=bitf(r.w<<16); o[7]=bitf(r.w&0xffff0000u);
}
static __device__ __forceinline__ void async16(void* lds, const void* g){
  __builtin_amdgcn_global_load_lds((const __attribute__((address_space(1))) u32*)g,
                                   (__attribute__((address_space(3))) u32*)lds, 16, 0, 0);
}

// ---------------- GEMM: C[M][N] = A[M][K] @ B[N][K]^T (+ epilogue) -----------
// AMODE: 0=linear, 1=dir-permuted rows, 2=conv3 implicit split-K (tap=z), 3=conv1
// EPI:   0=+bias->bf16, 2=BN(scale,shift)+ReLU->bf16, 3=+bias+addsrc->bf16, 4=raw fp32
struct GemmArgs {
  const u16* A; long aZ; int lda;
  const u16* Bw; long bZ; int ldb;
  const float* bias; int biasZ;
  const float* scale; const float* shift;
  const u16* add; long addZ;
  u16* C; long cZ; int ldc; int colOff;
  int K;
  const u16* pad;
  int dirBase;
};

template<int AMODE, int EPI>
__global__ __launch_bounds__(256)
void gemm_bt(GemmArgs g)
{
  __shared__ u16 smA[128*64];
  __shared__ u16 smB[128*64];
  const int tid = threadIdx.x;
  const int l = tid & 63;
  const int wv = tid >> 6;
  const int wr = wv >> 1, wc = wv & 1;
  const int z = blockIdx.z;
  const int r0 = blockIdx.x * 128;
  const int n0 = blockIdx.y * 128;

  const u16* Abase = g.A + (size_t)z * g.aZ;
  const u16* Bbase = g.Bw + (size_t)z * g.bZ;
  const int ldb = g.ldb ? g.ldb : g.K;

  f32x4 acc[4][4];
  #pragma unroll
  for (int i=0;i<4;i++)
    #pragma unroll
    for (int j=0;j<4;j++) acc[i][j] = (f32x4){0.f,0.f,0.f,0.f};

  const int nkt = g.K >> 6;
  #pragma unroll 1
  for (int kt=0; kt<nkt; ++kt) {
    const int k0 = kt << 6;
    #pragma unroll
    for (int it=0; it<4; ++it) {
      const int s = it*256 + tid;
      const int row = s >> 3, ch = s & 7;
      const u16* ga;
      if (AMODE == 0) {
        ga = Abase + (size_t)(r0+row) * g.lda + k0 + ch*8;
      } else if (AMODE == 1) {
        int rr = r0 + row; int li = rr & 4095; int bb = rr >> 12;
        int dir = g.dirBase + z;
        int l2 = (dir & 2) ? (4095 - li) : li;
        int sl = (dir & 1) ? (((l2 & 63) << 6) | (l2 >> 6)) : l2;
        ga = Abase + (size_t)((bb << 12) | sl) * g.lda + k0 + ch*8;
      } else if (AMODE == 2) {
        int rr = r0 + row; int bb = rr >> 12; int li = rr & 4095;
        int yy = li >> 6, xx = li & 63;
        int tap = z, kin = k0;
        int dy = tap / 3 - 1, dx = tap % 3 - 1;
        ga = g.pad + (((size_t)(bb*66 + yy+dy+1))*66 + (xx+dx+1))*512 + kin + ch*8;
      } else {
        int rr = r0 + row; int bb = rr >> 12; int li = rr & 4095;
        int yy = li >> 6, xx = li & 63;
        ga = g.pad + (((size_t)(bb*66 + yy+1))*66 + (xx+1))*512 + k0 + ch*8;
      }
      async16(&smA[(size_t)(it*256 + (tid & ~63))*8], ga);
      const u16* gb = Bbase + (size_t)(n0+row) * ldb + k0 + ch*8;
      async16(&smB[(size_t)(it*256 + (tid & ~63))*8], gb);
    }
    __syncthreads();
    #pragma unroll
    for (int kk=0; kk<2; ++kk) {
      bfx8 av[4], bv[4];
      #pragma unroll
      for (int mi=0; mi<4; ++mi) {
        int ra = wr*64 + mi*16 + (l & 15);
        av[mi] = *(const bfx8*)&smA[ra*64 + kk*32 + (l>>4)*8];
      }
      #pragma unroll
      for (int ni=0; ni<4; ++ni) {
        int rb = wc*64 + ni*16 + (l & 15);
        bv[ni] = *(const bfx8*)&smB[rb*64 + kk*32 + (l>>4)*8];
      }
      #pragma unroll
      for (int mi=0; mi<4; ++mi)
        #pragma unroll
        for (int ni=0; ni<4; ++ni)
          acc[mi][ni] = __builtin_amdgcn_mfma_f32_16x16x32_bf16(av[mi], bv[ni], acc[mi][ni], 0, 0, 0);
    }
    __syncthreads();
  }

  const float* bias_d = (EPI == 0 || EPI == 3) ? g.bias + (size_t)z * g.biasZ : nullptr;
  const u16* add_d = (EPI == 3) ? g.add + (size_t)z * g.addZ : nullptr;
  u16* Cd = g.C + (size_t)z * g.cZ;
  float* Cf = (float*)g.C + (size_t)z * g.cZ;
  #pragma unroll
  for (int mi=0; mi<4; ++mi) {
    #pragma unroll
    for (int ni=0; ni<4; ++ni) {
      f32x4 v = acc[mi][ni];
      const int gr = r0 + wr*64 + mi*16 + ((l >> 4) << 2);
      const int gc = n0 + wc*64 + ni*16 + (l & 15);
      #pragma unroll
      for (int q=0; q<4; ++q) {
        const int r = gr + q;
        float x = v[q];
        if (EPI == 2) {
          x = fmaxf(fmaf(x, g.scale[gc], g.shift[gc]), 0.f);
          Cd[(size_t)r * g.ldc + g.colOff + gc] = f2bf(x);
        } else if (EPI == 3) {
          x += bias_d[gc] + bf2f(add_d[(size_t)r * g.ldc + gc]);
          Cd[(size_t)r * g.ldc + g.colOff + gc] = f2bf(x);
        } else if (EPI == 4) {
          Cf[(size_t)r * g.ldc + g.colOff + gc] = x;
        } else {
          x += bias_d[gc];
          Cd[(size_t)r * g.ldc + g.colOff + gc] = f2bf(x);
        }
      }
    }
  }
}

// ---------------- small utility kernels --------------------------------------
__global__ void castk(const float* __restrict__ s, u16* __restrict__ d, int n)
{
  int i = (blockIdx.x*256 + threadIdx.x)*4;
  if (i < n){
    float4 v = *(const float4*)(s+i);
    ushort4 o; o.x=f2bf(v.x); o.y=f2bf(v.y); o.z=f2bf(v.z); o.w=f2bf(v.w);
    *(ushort4*)(d+i) = o;
  }
}

__global__ void c3rep(const float* __restrict__ w, u16* __restrict__ o)
{
  int id = blockIdx.x*256 + threadIdx.x; // 128*4608
  int oc = id / 4608, rem = id % 4608;
  int tap = rem >> 9, ic = rem & 511;
  o[id] = f2bf(w[((size_t)oc*512 + ic)*9 + tap]);
}

__global__ void bnssk(const float* g3,const float* b3,const float* m3,const float* v3,
                      const float* g1,const float* b1,const float* m1,const float* v1,
                      float* out)
{
  int t = threadIdx.x; int i = t & 127;
  if (t < 128){ float sc = g3[i]*rsqrtf(v3[i]+1e-5f); out[i]=sc; out[128+i]=b3[i]-m3[i]*sc; }
  else        { float sc = g1[i]*rsqrtf(v1[i]+1e-5f); out[256+i]=sc; out[384+i]=b1[i]-m1[i]*sc; }
}

// reduce 9 fp32 partials -> BN+ReLU -> bf16 into zin cols 0..127
__global__ __launch_bounds__(256)
void c3red(const float* __restrict__ P, const float* __restrict__ bnss, u16* __restrict__ zin)
{
  const int id = blockIdx.x*256 + threadIdx.x;   // 524288 units of 4
  const size_t base = (size_t)id * 4;
  const int r = (int)(base >> 7), c = (int)(base & 127);
  float4 s = {0.f,0.f,0.f,0.f};
  #pragma unroll
  for (int z=0; z<9; ++z){
    float4 v = *(const float4*)(P + (size_t)z*2097152 + base);
    s.x += v.x; s.y += v.y; s.z += v.z; s.w += v.w;
  }
  float4 sc = *(const float4*)(bnss + c);
  float4 sh = *(const float4*)(bnss + 128 + c);
  ushort4 o;
  o.x = f2bf(fmaxf(fmaf(s.x, sc.x, sh.x), 0.f));
  o.y = f2bf(fmaxf(fmaf(s.y, sc.y, sh.y), 0.f));
  o.z = f2bf(fmaxf(fmaf(s.z, sc.z, sh.z), 0.f));
  o.w = f2bf(fmaxf(fmaf(s.w, sc.w, sh.w), 0.f));
  *(ushort4*)(zin + (size_t)r*256 + c) = o;
}

__global__ __launch_bounds__(256)
void padk(const float* __restrict__ curr, const float* __restrict__ prev, u16* __restrict__ pad)
{
  const int id = blockIdx.x*256 + threadIdx.x; // 4*66*66*64
  const int c8 = id & 63;
  int t = id >> 6;
  const int xx = t % 66; t /= 66;
  const int yy = t % 66; const int b = t / 66;
  const int c0 = c8*8;
  uint4 o;
  if (yy==0 || yy==65 || xx==0 || xx==65){ o.x=0;o.y=0;o.z=0;o.w=0; }
  else {
    const int l = (yy-1)*64 + (xx-1);
    const float* s = (c0 < 256) ? curr + ((size_t)b*4096 + l)*256 + c0
                                : prev + ((size_t)b*4096 + l)*256 + (c0-256);
    float4 a = *(const float4*)s, bb = *(const float4*)(s+4);
    o.x = pk2(a.x,a.y); o.y = pk2(a.z,a.w); o.z = pk2(bb.x,bb.y); o.w = pk2(bb.z,bb.w);
  }
  *(uint4*)(pad + (((size_t)b*66 + yy)*66 + xx)*512 + c0) = o;
}

__global__ __launch_bounds__(256)
void ln256(const u16* __restrict__ in, long inZ, u16* __restrict__ out, long outZ,
           const float* __restrict__ gw, const float* __restrict__ bw, int pz)
{
  const int z = blockIdx.z;
  const int row = blockIdx.x*4 + (threadIdx.x>>6);
  const int l = threadIdx.x & 63;
  const u16* ip = in + (size_t)z*inZ + (size_t)row*256 + l*4;
  ushort4 rr = *(const ushort4*)ip;
  float v0=bf2f(rr.x), v1=bf2f(rr.y), v2=bf2f(rr.z), v3=bf2f(rr.w);
  float s = v0+v1+v2+v3;
  float ss = v0*v0+v1*v1+v2*v2+v3*v3;
  #pragma unroll
  for(int m=1;m<64;m<<=1){ s += __shfl_xor(s,m); ss += __shfl_xor(ss,m); }
  float mu = s*(1.f/256.f);
  float var = ss*(1.f/256.f) - mu*mu;
  float rs = rsqrtf(var + 1e-5f);
  const float* g = gw + (size_t)z*pz; const float* b = bw + (size_t)z*pz;
  int c = l*4;
  u16* op = out + (size_t)z*outZ + (size_t)row*256 + c;
  ushort4 o; o.x=f2bf((v0-mu)*rs*g[c]+b[c]); o.y=f2bf((v1-mu)*rs*g[c+1]+b[c+1]);
  o.z=f2bf((v2-mu)*rs*g[c+2]+b[c+2]); o.w=f2bf((v3-mu)*rs*g[c+3]+b[c+3]);
  *(ushort4*)op = o;
}

__global__ __launch_bounds__(256)
void rms512(u16* __restrict__ Y, const float* __restrict__ gw)
{
  const int z = blockIdx.z;
  const int row = blockIdx.x*4 + (threadIdx.x>>6);
  const int l = threadIdx.x & 63;
  u16* p = Y + ((size_t)z*16384 + row)*512 + l*8;
  uint4 raw = *(const uint4*)p;
  float v[8]; unpk8(raw, v);
  float ss = 0.f;
  #pragma unroll
  for (int j=0;j<8;j++) ss += v[j]*v[j];
  #pragma unroll
  for (int m=1;m<64;m<<=1) ss += __shfl_xor(ss, m);
  const float sc = rsqrtf(ss*(1.f/512.f) + 1e-5f);
  const float* g = gw + (size_t)z*512 + l*8;
  uint4 o;
  o.x = pk2(v[0]*sc*g[0], v[1]*sc*g[1]);
  o.y = pk2(v[2]*sc*g[2], v[3]*sc*g[3]);
  o.z = pk2(v[4]*sc*g[4], v[5]*sc*g[5]);
  o.w = pk2(v[6]*sc*g[6], v[7]*sc*g[7]);
  *(uint4*)p = o;
}

// fp32 dt head: dt = softplus(xln.W_dt + b + dt_bias)
__global__ __launch_bounds__(256)
void dtk(const u16* __restrict__ xln, const float* __restrict__ minW,
         const float* __restrict__ minB, const float* __restrict__ dtb,
         float* __restrict__ DT)
{
  __shared__ float sx[32*257];
  const int z = blockIdx.z;
  const int r0 = blockIdx.x * 32;
  const int tid = threadIdx.x;
  {
    const int rr = tid >> 3, cc = (tid & 7) * 32;
    const u16* src = xln + ((size_t)z*16384 + r0 + rr)*256 + cc;
    #pragma unroll
    for (int q=0;q<4;q++){
      uint4 raw = *(const uint4*)(src + q*8);
      float v[8]; unpk8(raw, v);
      #pragma unroll
      for (int j=0;j<8;j++) sx[rr*257 + cc + q*8 + j] = v[j];
    }
  }
  __syncthreads();
  const int ri = tid >> 3, hv = tid & 7;
  const float* wrow = minW + ((size_t)z*1288 + 1280 + hv)*256;
  float acc = 0.f;
  #pragma unroll 4
  for (int k=0; k<256; k+=4){
    float4 wq = *(const float4*)(wrow + k);
    acc += sx[ri*257+k]*wq.x + sx[ri*257+k+1]*wq.y + sx[ri*257+k+2]*wq.z + sx[ri*257+k+3]*wq.w;
  }
  acc += minB[(size_t)z*1288 + 1280 + hv] + dtb[z*8 + hv];
  float dt = (acc > 20.f) ? acc : log1pf(expf(acc));
  DT[((size_t)z*16384 + r0 + ri)*8 + hv] = dt;
}

// chunk-local cumulative log-decay
__global__ __launch_bounds__(256)
void cak(const float* __restrict__ DT, float* __restrict__ CA,
         const float* __restrict__ alog, int dirBase)
{
  const int z = blockIdx.z;
  const int gidx = blockIdx.x*4 + (threadIdx.x>>6);
  const int lane = threadIdx.x & 63;
  const int c = gidx & 63, bh = gidx >> 6;
  const int b = bh >> 3, hh = bh & 7;
  const size_t row = (size_t)z*16384 + (size_t)b*4096 + c*64 + lane;
  float x = DT[row*8 + hh];
  #pragma unroll
  for (int m=1;m<64;m<<=1){ float o = __shfl_up(x, m); if (lane >= m) x += o; }
  float eA = expf(alog[(dirBase+z)*8 + hh]);
  CA[row*8 + hh] = -eA * x;
}

// causal conv1d(4)+SiLU over the B/C columns (raw cols 512..767) -> BCC[row][256]
__global__ __launch_bounds__(256)
void convbc(const u16* __restrict__ xbcr, u16* __restrict__ bcc,
            const float* __restrict__ cw, const float* __restrict__ cb)
{
  const int id = blockIdx.x*256 + threadIdx.x; // nd*16384*32
  const int c8 = id & 31;
  const int r = (id >> 5) & 16383;
  const int d = id >> 19;
  const int li = r & 4095;
  const int col = 512 + c8*8;
  const u16* base = xbcr + ((size_t)d*16384 + (size_t)(r - li))*768 + col;
  float acc[8];
  #pragma unroll
  for (int j=0;j<8;j++) acc[j] = cb[d*768 + col + j];
  #pragma unroll
  for (int tap=0; tap<4; ++tap){
    int lt = li - 3 + tap;
    if (lt >= 0){
      uint4 raw = *(const uint4*)(base + (size_t)lt*768);
      float v[8]; unpk8(raw, v);
      #pragma unroll
      for (int j=0;j<8;j++)
        acc[j] = fmaf(v[j], cw[((size_t)d*768 + col + j)*4 + tap], acc[j]);
    }
  }
  uint4 o;
  float s[8];
  #pragma unroll
  for (int j=0;j<8;j++) s[j] = acc[j] / (1.f + __expf(-acc[j]));
  o.x = pk2(s[0],s[1]); o.y = pk2(s[2],s[3]); o.z = pk2(s[4],s[5]); o.w = pk2(s[6],s[7]);
  *(uint4*)(bcc + ((size_t)d*16384 + r)*256 + c8*8) = o;
}

#define BTS 72

// per-chunk outer-product sums: CS[c] = sum_s w[s]*convB[s] (x) convX[s]
// grid (2048, 1, nd); X-head conv'd on the fly from raw
__global__ __launch_bounds__(256)
void chunkk(const u16* __restrict__ bcc, const u16* __restrict__ xbcr,
            const float* __restrict__ DT, const float* __restrict__ CA,
            const float* __restrict__ cw, const float* __restrict__ cb,
            u16* __restrict__ CS)
{
  __shared__ u16 Bt[128*BTS];   // [n][s] w-scaled
  __shared__ u16 Xt[64*BTS];    // [p][s]
  __shared__ float wS[64];
  __shared__ float cwXs[4][64];
  __shared__ float cbX[64];
  const int bx = blockIdx.x;
  const int z = blockIdx.z;
  const int c = bx & 63, bh = bx >> 6;
  const int b = bh >> 3, hh = bh & 7;
  const int tid = threadIdx.x;
  const int l = tid & 63, w = tid >> 6;

  const size_t rowb = (size_t)z*16384 + (size_t)b*4096;
  const u16* xb = xbcr + rowb*768;           // raw rows of this (dir,b)
  const u16* bc = bcc + (rowb + c*64)*256;   // conv'd B/C rows of this chunk

  if (tid < 64) {
    float cav = CA[(rowb + c*64 + tid)*8 + hh];
    float ca63 = __shfl(cav, 63);
    float dtv = DT[(rowb + c*64 + tid)*8 + hh];
    wS[tid] = __expf(ca63 - cav) * dtv;
    float4 w4 = *(const float4*)(cw + (size_t)z*3072 + (hh*64 + tid)*4);
    cwXs[0][tid]=w4.x; cwXs[1][tid]=w4.y; cwXs[2][tid]=w4.z; cwXs[3][tid]=w4.w;
    cbX[tid] = cb[z*768 + hh*64 + tid];
  }
  __syncthreads();
  // stage Bt = w[s]*B[s][n] transposed (from BCC)
  #pragma unroll
  for (int u=0; u<4; ++u){
    int idx = u*256 + tid;              // 1024 units
    int s = idx >> 4, seg = idx & 15;
    uint4 raw = *(const uint4*)(bc + (size_t)s*256 + seg*8);
    float v[8]; unpk8(raw, v);
    float wv = wS[s];
    u16* dst = &Bt[(seg*8)*BTS + s];
    #pragma unroll
    for (int j=0;j<8;j++) dst[j*BTS] = f2bf(v[j]*wv);
  }
  // stage Xt transposed, conv+silu on the fly from raw
  #pragma unroll
  for (int u=0; u<2; ++u){
    int idx = u*256 + tid;              // 512 units
    int s = idx >> 3, seg = idx & 7;
    int li = c*64 + s;
    float acc[8];
    #pragma unroll
    for (int j=0;j<8;j++) acc[j] = cbX[seg*8+j];
    #pragma unroll
    for (int tap=0; tap<4; ++tap){
      int lt = li - 3 + tap;
      if (lt >= 0){
        uint4 raw = *(const uint4*)(xb + (size_t)lt*768 + hh*64 + seg*8);
        float v[8]; unpk8(raw, v);
        #pragma unroll
        for (int j=0;j<8;j++) acc[j] = fmaf(v[j], cwXs[tap][seg*8+j], acc[j]);
      }
    }
    u16* dst = &Xt[(seg*8)*BTS + s];
    #pragma unroll
    for (int j=0;j<8;j++) dst[j*BTS] = f2bf(acc[j] / (1.f + __expf(-acc[j])));
  }
  __syncthreads();

  f32x4 acc[2][4];
  #pragma unroll
  for (int i=0;i<2;i++)
    #pragma unroll
    for (int j=0;j<4;j++) acc[i][j] = (f32x4){0.f,0.f,0.f,0.f};
  #pragma unroll
  for (int kk=0; kk<2; ++kk){
    bfx8 a0 = *(const bfx8*)&Bt[((w*2+0)*16 + (l&15))*BTS + kk*32 + (l>>4)*8];
    bfx8 a1 = *(const bfx8*)&Bt[((w*2+1)*16 + (l&15))*BTS + kk*32 + (l>>4)*8];
    #pragma unroll
    for (int pi=0; pi<4; ++pi){
      bfx8 bv = *(const bfx8*)&Xt[(pi*16 + (l&15))*BTS + kk*32 + (l>>4)*8];
      acc[0][pi] = __builtin_amdgcn_mfma_f32_16x16x32_bf16(a0, bv, acc[0][pi], 0, 0, 0);
      acc[1][pi] = __builtin_amdgcn_mfma_f32_16x16x32_bf16(a1, bv, acc[1][pi], 0, 0, 0);
    }
  }
  u16* Cd = CS + (size_t)z*16777216 + (size_t)bh*524288 + (size_t)c*8192;
  #pragma unroll
  for (int mi=0; mi<2; ++mi)
    #pragma unroll
    for (int pi=0; pi<4; ++pi){
      int n = (w*2+mi)*16 + (l>>4)*4;
      int p = pi*16 + (l&15);
      u32* cp = (u32*)&Cd[(size_t)p*128 + n];
      cp[0] = pk2(acc[mi][pi][0], acc[mi][pi][1]);
      cp[1] = pk2(acc[mi][pi][2], acc[mi][pi][3]);
    }
}

// sequential 64-step combine IN PLACE (H aliases CS): H[c] = h; h = a[c]*h + CS[c]
__global__ __launch_bounds__(256)
void combk(const u16* __restrict__ CS, const float* __restrict__ CA,
           u16* __restrict__ H)
{
  __shared__ float aL[64];
  const int bx = blockIdx.x;
  const int z = blockIdx.z;
  const int pg = bx & 3, bh = bx >> 2;
  const int b = bh >> 3, hh = bh & 7;
  const int tid = threadIdx.x;
  const int p = pg*16 + (tid >> 4), n = (tid & 15)*8;
  const size_t rowb = (size_t)z*16384 + (size_t)b*4096;
  if (tid < 64) aL[tid] = __expf(CA[(rowb + tid*64 + 63)*8 + hh]);
  __syncthreads();
  const u16* Cs = CS + (size_t)z*16777216 + (size_t)bh*524288 + (size_t)p*128 + n;
  u16* Hd = H + (size_t)z*16777216 + (size_t)bh*524288 + (size_t)p*128 + n;
  float h[8];
  #pragma unroll
  for (int j=0;j<8;j++) h[j]=0.f;
  uint4 pf = *(const uint4*)Cs;
  #pragma unroll 1
  for (int c=0; c<64; ++c){
    uint4 cur = pf;
    if (c < 63) pf = *(const uint4*)(Cs + (size_t)(c+1)*8192);
    uint4 o;
    o.x = pk2(h[0],h[1]); o.y = pk2(h[2],h[3]);
    o.z = pk2(h[4],h[5]); o.w = pk2(h[6],h[7]);
    *(uint4*)(Hd + (size_t)c*8192) = o;
    float v[8]; unpk8(cur, v);
    const float a = aL[c];
    #pragma unroll
    for (int j=0;j<8;j++) h[j] = fmaf(h[j], a, v[j]);
  }
}

// per-chunk output: Y = (S_decayed @ X + diag(exp(ca)) * (C @ H[c]) + Dh*x) * silu(z)
__global__ __launch_bounds__(256)
void yk(const u16* __restrict__ bcc, const u16* __restrict__ xbcr,
        const float* __restrict__ DT, const float* __restrict__ CA,
        const u16* __restrict__ H, const float* __restrict__ Dp,
        const float* __restrict__ cw, const float* __restrict__ cb,
        u16* __restrict__ Y)
{
  __shared__ u16 Sm[64*BTS];    // [t][s] decayed scores
  __shared__ u16 Xt[64*BTS];    // [p][s]
  __shared__ float caL[64], dtL[64];
  __shared__ float cwXs[4][64];
  __shared__ float cbX[64];
  const int bx = blockIdx.x;
  const int z = blockIdx.z;
  const int c = bx & 63, bh = bx >> 6;
  const int b = bh >> 3, hh = bh & 7;
  const int tid = threadIdx.x, l = tid & 63, w = tid >> 6;
  const size_t rowb = (size_t)z*16384 + (size_t)b*4096;
  const u16* xb = xbcr + rowb*768;
  const u16* bc = bcc + (rowb + c*64)*256;
  const float Dh = Dp[z*8 + hh];

  if (tid < 64){
    caL[tid] = CA[(rowb + c*64 + tid)*8 + hh];
    dtL[tid] = DT[(rowb + c*64 + tid)*8 + hh];
    float4 w4 = *(const float4*)(cw + (size_t)z*3072 + (hh*64 + tid)*4);
    cwXs[0][tid]=w4.x; cwXs[1][tid]=w4.y; cwXs[2][tid]=w4.z; cwXs[3][tid]=w4.w;
    cbX[tid] = cb[z*768 + hh*64 + tid];
  }
  __syncthreads();
  // stage Xt transposed, conv+silu on the fly
  #pragma unroll
  for (int u=0; u<2; ++u){
    int idx = u*256 + tid; int s = idx >> 3, seg = idx & 7;
    int li = c*64 + s;
    float acc[8];
    #pragma unroll
    for (int j=0;j<8;j++) acc[j] = cbX[seg*8+j];
    #pragma unroll
    for (int tap=0; tap<4; ++tap){
      int lt = li - 3 + tap;
      if (lt >= 0){
        uint4 raw = *(const uint4*)(xb + (size_t)lt*768 + hh*64 + seg*8);
        float v[8]; unpk8(raw, v);
        #pragma unroll
        for (int j=0;j<8;j++) acc[j] = fmaf(v[j], cwXs[tap][seg*8+j], acc[j]);
      }
    }
    u16* dst = &Xt[(seg*8)*BTS + s];
    #pragma unroll
    for (int j=0;j<8;j++) dst[j*BTS] = f2bf(acc[j] / (1.f + __expf(-acc[j])));
  }
  __syncthreads();

  // S = C@B^T and acc2 = C@H[c]  (K=128 over n); B/C read from BCC global
  const u16* Hd = H + (size_t)z*16777216 + (size_t)bh*524288 + (size_t)c*8192;
  f32x4 sacc[4], acc2[4];
  #pragma unroll
  for (int i=0;i<4;i++){ sacc[i] = (f32x4){0.f,0.f,0.f,0.f}; acc2[i] = (f32x4){0.f,0.f,0.f,0.f}; }
  #pragma unroll
  for (int kk=0; kk<4; ++kk){
    bfx8 av = *(const bfx8*)(bc + (size_t)(w*16 + (l&15))*256 + 128 + kk*32 + (l>>4)*8);
    #pragma unroll
    for (int st=0; st<4; ++st){
      bfx8 bv = *(const bfx8*)(bc + (size_t)(st*16 + (l&15))*256 + kk*32 + (l>>4)*8);
      sacc[st] = __builtin_amdgcn_mfma_f32_16x16x32_bf16(av, bv, sacc[st], 0, 0, 0);
      bfx8 hv = *(const bfx8*)&Hd[(size_t)(st*16 + (l&15))*128 + kk*32 + (l>>4)*8];
      acc2[st] = __builtin_amdgcn_mfma_f32_16x16x32_bf16(av, hv, acc2[st], 0, 0, 0);
    }
  }
  #pragma unroll
  for (int st=0; st<4; ++st){
    #pragma unroll
    for (int q=0;q<4;q++){
      int t = w*16 + (l>>4)*4 + q;
      int s = st*16 + (l&15);
      float m = (s <= t) ? __expf(caL[t]-caL[s]) * dtL[s] : 0.f;
      Sm[t*BTS + s] = f2bf(sacc[st][q] * m);
    }
  }
  #pragma unroll
  for (int pt=0; pt<4; ++pt)
    #pragma unroll
    for (int q=0;q<4;q++){
      int t = w*16 + (l>>4)*4 + q;
      acc2[pt][q] *= __expf(caL[t]);
    }
  __syncthreads();
  #pragma unroll
  for (int kk=0; kk<2; ++kk){
    bfx8 av = *(const bfx8*)&Sm[(w*16 + (l&15))*BTS + kk*32 + (l>>4)*8];
    #pragma unroll
    for (int pt=0; pt<4; ++pt){
      bfx8 bv = *(const bfx8*)&Xt[(pt*16 + (l&15))*BTS + kk*32 + (l>>4)*8];
      acc2[pt] = __builtin_amdgcn_mfma_f32_16x16x32_bf16(av, bv, acc2[pt], 0, 0, 0);
    }
  }
  u16* Yrow = Y + (rowb + c*64)*512 + hh*64;
  #pragma unroll
  for (int pt=0; pt<4; ++pt){
    #pragma unroll
    for (int q=0;q<4;q++){
      int t = w*16 + (l>>4)*4 + q;
      int p = pt*16 + (l&15);
      float xv = bf2f(Xt[p*BTS + t]);
      float zf = bf2f(Yrow[(size_t)t*512 + p]);
      float yv = (acc2[pt][q] + Dh*xv) * (zf/(1.f+__expf(-zf)));
      Yrow[(size_t)t*512 + p] = f2bf(yv);
    }
  }
}

__global__ __launch_bounds__(256)
void finalk(const float* __restrict__ curr, const u16* __restrict__ outs, float* __restrict__ o)
{
  const int row = blockIdx.x*4 + (threadIdx.x>>6);
  const int c4 = (threadIdx.x & 63)*4;
  const int b = row >> 12, li = row & 4095;
  const int T = ((li & 63) << 6) | (li >> 6);
  const size_t rb = (size_t)b*4096;
  const ushort4 a0 = *(const ushort4*)(outs + (size_t)0*4194304 + ((rb+li)*256 + c4));
  const ushort4 a1 = *(const ushort4*)(outs + (size_t)1*4194304 + ((rb+T)*256 + c4));
  const ushort4 a2 = *(const ushort4*)(outs + (size_t)2*4194304 + ((rb+4095-li)*256 + c4));
  const ushort4 a3 = *(const ushort4*)(outs + (size_t)3*4194304 + ((rb+4095-T)*256 + c4));
  float4 cv = *(const float4*)(curr + (size_t)row*256 + c4);
  float4 r;
  r.x = cv.x + 0.25f*(bf2f(a0.x)+bf2f(a1.x)+bf2f(a2.x)+bf2f(a3.x));
  r.y = cv.y + 0.25f*(bf2f(a0.y)+bf2f(a1.y)+bf2f(a2.y)+bf2f(a3.y));
  r.z = cv.z + 0.25f*(bf2f(a0.z)+bf2f(a1.z)+bf2f(a2.z)+bf2f(a3.z));
  r.w = cv.w + 0.25f*(bf2f(a0.w)+bf2f(a1.w)+bf2f(a2.w)+bf2f(a3.w));
  *(float4*)(o + (size_t)row*256 + c4) = r;
}

// ---------------------------------------------------------------------------
extern "C" void kernel_launch(void* const* d_in, const int* in_sizes, int n_in,
                              void* d_out, int out_size, void* d_ws, size_t ws_size,
                              hipStream_t stream)
{
  (void)in_sizes; (void)n_in; (void)out_size;
  const float* curr   = (const float*)d_in[0];
  const float* prev   = (const float*)d_in[1];
  const float* conv3w = (const float*)d_in[2];
  const float* bn3g=(const float*)d_in[3], *bn3b=(const float*)d_in[4], *bn3m=(const float*)d_in[5], *bn3v=(const float*)d_in[6];
  const float* conv1w = (const float*)d_in[7];
  const float* bn1g=(const float*)d_in[8], *bn1b=(const float*)d_in[9], *bn1m=(const float*)d_in[10], *bn1v=(const float*)d_in[11];
  const float* fuseW=(const float*)d_in[12], *fuseB=(const float*)d_in[13];
  const float* lng=(const float*)d_in[14], *lnb=(const float*)d_in[15];
  const float* inpW=(const float*)d_in[16], *inpB=(const float*)d_in[17];
  const float* mlng=(const float*)d_in[18], *mlnb=(const float*)d_in[19];
  const float* minW=(const float*)d_in[20], *minB=(const float*)d_in[21];
  const float* cw=(const float*)d_in[22], *cb=(const float*)d_in[23];
  const float* alog=(const float*)d_in[24], *Dp=(const float*)d_in[25], *dtb=(const float*)d_in[26];
  const float* mng=(const float*)d_in[27];
  const float* moutW=(const float*)d_in[28], *moutB=(const float*)d_in[29];
  const float* outpW=(const float*)d_in[30], *outpB=(const float*)d_in[31];

  // ---- persistent layout ----
  char* ws = (char*)d_ws;
  size_t off = 0;
  auto alloc = [&](size_t bytes){ size_t o = off; off = (off + bytes + 1023) & ~(size_t)1023; return o; };
  const size_t O_WFUSE = alloc((size_t)256*256*2);
  const size_t O_WINP  = alloc((size_t)4*256*256*2);
  const size_t O_WMIN  = alloc((size_t)4*1288*256*2);
  const size_t O_WMOUT = alloc((size_t)4*256*512*2);
  const size_t O_WOUTP = alloc((size_t)4*256*256*2);
  const size_t O_WC3   = alloc((size_t)128*4608*2);
  const size_t O_WC1   = alloc((size_t)128*512*2);
  const size_t O_BNSS  = alloc(512*4);
  const size_t O_ZF    = alloc((size_t)16384*256*2);
  const size_t O_OUTS  = alloc((size_t)4*16384*256*2);
  const size_t O_P     = off;                 // per-phase region

  // per-dir sizes (bytes)
  const size_t S0d  = (size_t)16384*256*2;    // 8.39MB
  const size_t XLNd = (size_t)16384*256*2;    // 8.39MB (BCC and S1 overlay)
  const size_t Yd   = (size_t)16384*512*2;    // 16.8MB (z-gate then y)
  const size_t XBCd = (size_t)16384*768*2;    // 25.2MB (raw xBC)
  const size_t DTd  = (size_t)16384*8*4;
  const size_t CAd  = (size_t)16384*8*4;
  const size_t Hd_  = (size_t)32*64*64*128*2; // 33.55MB (CS==H)
  const size_t perdir = S0d + XLNd + Yd + XBCd + DTd + CAd + Hd_;

  // pre-phase transient footprint (pad + 9 fp32 conv3 partials + zin + zft)
  const size_t PADsz = (size_t)4*66*66*512*2;
  const size_t CPsz  = (size_t)9*16384*128*4;
  const size_t PREsz = PADsz + CPsz + (size_t)16384*256*2*2 + 4096;

  int nd = 0;
  for (int cand = 4; cand >= 1; cand >>= 1) {
    size_t need = (size_t)cand*perdir; if (need < PREsz) need = PREsz;
    if (O_P + need <= ws_size) { nd = cand; break; }
  }
  if (nd == 0) return;

  #define WP(o) ((u16*)(ws + (o)))
  #define FP(o) ((float*)(ws + (o)))

  const size_t O_PAD = O_P;
  const size_t O_CP  = O_PAD + PADsz;         // conv3 partials (fp32)
  const size_t O_ZIN = O_CP + CPsz;
  const size_t O_ZFT = O_ZIN + (size_t)16384*256*2;

  // 1. BN scale/shift + weight conversions
  bnssk<<<1, 256, 0, stream>>>(bn3g,bn3b,bn3m,bn3v, bn1g,bn1b,bn1m,bn1v, FP(O_BNSS));
  castk<<<64, 256, 0, stream>>>(fuseW, WP(O_WFUSE), 65536);
  castk<<<256, 256, 0, stream>>>(inpW, WP(O_WINP), 262144);
  castk<<<1288, 256, 0, stream>>>(minW, WP(O_WMIN), 1318912);
  castk<<<512, 256, 0, stream>>>(moutW, WP(O_WMOUT), 524288);
  castk<<<256, 256, 0, stream>>>(outpW, WP(O_WOUTP), 262144);
  castk<<<64, 256, 0, stream>>>(conv1w, WP(O_WC1), 65536);
  c3rep<<<2304, 256, 0, stream>>>(conv3w, WP(O_WC3));
  // 2. padded concat input (bf16)
  padk<<<4356, 256, 0, stream>>>(curr, prev, WP(O_PAD));

  GemmArgs a;
  // 3. conv3 split-K over 9 taps -> fp32 partials, then reduce+BN+ReLU
  a = {}; a.A = WP(O_PAD); a.pad = WP(O_PAD);
  a.Bw = WP(O_WC3); a.bZ = 512; a.ldb = 4608;
  a.C = WP(O_CP); a.cZ = 2097152; a.ldc = 128; a.colOff = 0; a.K = 512;
  gemm_bt<2,4><<<dim3(128,1,9), 256, 0, stream>>>(a);
  c3red<<<2048, 256, 0, stream>>>(FP(O_CP), FP(O_BNSS), WP(O_ZIN));
  // 4. conv1 -> zin[:,128:256]
  a = {}; a.A = WP(O_PAD); a.pad = WP(O_PAD); a.Bw = WP(O_WC1); a.bZ = 0; a.ldb = 512;
  a.scale = FP(O_BNSS)+256; a.shift = FP(O_BNSS)+384;
  a.C = WP(O_ZIN); a.cZ = 0; a.ldc = 256; a.colOff = 128; a.K = 512;
  gemm_bt<3,2><<<dim3(128,1,1), 256, 0, stream>>>(a);
  // 5. fuse GEMM -> zft
  a = {}; a.A = WP(O_ZIN); a.aZ = 0; a.lda = 256; a.Bw = WP(O_WFUSE); a.bZ = 0; a.ldb = 256;
  a.bias = fuseB; a.biasZ = 0; a.C = WP(O_ZFT); a.cZ = 0; a.ldc = 256; a.colOff = 0; a.K = 256;
  gemm_bt<0,0><<<dim3(128,2,1), 256, 0, stream>>>(a);
  // 6. LN -> zf (persistent)
  ln256<<<dim3(4096,1,1), 256, 0, stream>>>(WP(O_ZFT), 0, WP(O_ZF), 0, lng, lnb, 0);

  // ---- phases over directions ----
  for (int d0 = 0; d0 < 4; d0 += nd) {
    const size_t O_S0  = O_P;
    const size_t O_XLN = O_S0  + (size_t)nd*S0d;
    const size_t O_Y   = O_XLN + (size_t)nd*XLNd;
    const size_t O_XBC = O_Y   + (size_t)nd*Yd;
    const size_t O_DT  = O_XBC + (size_t)nd*XBCd;
    const size_t O_CA  = O_DT  + (size_t)nd*DTd;
    const size_t O_H   = O_CA  + (size_t)nd*CAd;   // CS == H
    const size_t O_BCC = O_XLN;                    // overlay (XLN dead after xbc gemm)
    const size_t O_S1  = O_XLN;                    // overlay (BCC dead after yk)

    // 7. inp GEMM (permuted rows per dir) -> s0
    a = {}; a.A = WP(O_ZF); a.aZ = 0; a.lda = 256;
    a.Bw = WP(O_WINP) + (size_t)d0*65536; a.bZ = 65536; a.ldb = 256;
    a.bias = inpB + d0*256; a.biasZ = 256;
    a.C = WP(O_S0); a.cZ = 4194304; a.ldc = 256; a.colOff = 0; a.K = 256; a.dirBase = d0;
    gemm_bt<1,0><<<dim3(128,2,nd), 256, 0, stream>>>(a);
    // 8. per-dir LN(s0) -> xln
    ln256<<<dim3(4096,1,nd), 256, 0, stream>>>(WP(O_S0), 4194304, WP(O_XLN), 4194304,
                                               mlng + d0*256, mlnb + d0*256, 256);
    // 9. dt (fp32), chunk log-decay
    dtk<<<dim3(512,1,nd), 256, 0, stream>>>(WP(O_XLN), minW + (size_t)d0*329728,
                                            minB + d0*1288, dtb + d0*8, FP(O_DT));
    cak<<<dim3(512,1,nd), 256, 0, stream>>>(FP(O_DT), FP(O_CA), alog, d0);
    // 10. z-gate GEMM -> Y (cols as z)
    a = {}; a.A = WP(O_XLN); a.aZ = 4194304; a.lda = 256;
    a.Bw = WP(O_WMIN) + (size_t)d0*329728; a.bZ = 329728; a.ldb = 256;
    a.bias = minB + d0*1288; a.biasZ = 1288;
    a.C = WP(O_Y); a.cZ = 8388608; a.ldc = 512; a.colOff = 0; a.K = 256;
    gemm_bt<0,0><<<dim3(128,4,nd), 256, 0, stream>>>(a);
    // 11. xBC GEMM (raw, single launch) -> xbcr    [last reader of XLN]
    a = {}; a.A = WP(O_XLN); a.aZ = 4194304; a.lda = 256;
    a.Bw = WP(O_WMIN) + (size_t)d0*329728 + (size_t)512*256; a.bZ = 329728; a.ldb = 256;
    a.bias = minB + d0*1288 + 512; a.biasZ = 1288;
    a.C = WP(O_XBC); a.cZ = 12582912; a.ldc = 768; a.colOff = 0; a.K = 256;
    gemm_bt<0,0><<<dim3(128,6,nd), 256, 0, stream>>>(a);
    // 12. conv1d+SiLU on B/C columns -> BCC (overlays XLN)
    convbc<<<nd*2048, 256, 0, stream>>>(WP(O_XBC), WP(O_BCC), cw + d0*3072, cb + d0*768);
    // 13. per-chunk outer products -> CS(=H)
    chunkk<<<dim3(2048,1,nd), 256, 0, stream>>>(WP(O_BCC), WP(O_XBC), FP(O_DT), FP(O_CA),
                                                cw + d0*3072, cb + d0*768, WP(O_H));
    // 14. 64-step combine in place -> H
    combk<<<dim3(128,1,nd), 256, 0, stream>>>(WP(O_H), FP(O_CA), WP(O_H));
    // 15. per-chunk outputs -> Y in place
    yk<<<dim3(2048,1,nd), 256, 0, stream>>>(WP(O_BCC), WP(O_XBC), FP(O_DT), FP(O_CA),
                                            WP(O_H), Dp + d0*8, cw + d0*3072, cb + d0*768,
                                            WP(O_Y));
    // 16. RMSNorm in-place on Y
    rms512<<<dim3(4096,1,nd), 256, 0, stream>>>(WP(O_Y), mng + d0*512);
    // 17. m_out GEMM + s0 residual -> s1 (overlays BCC/XLN)
    a = {}; a.A = WP(O_Y); a.aZ = 8388608; a.lda = 512;
    a.Bw = WP(O_WMOUT) + (size_t)d0*131072; a.bZ = 131072; a.ldb = 512;
    a.bias = moutB + d0*256; a.biasZ = 256;
    a.add = WP(O_S0); a.addZ = 4194304;
    a.C = WP(O_S1); a.cZ = 4194304; a.ldc = 256; a.colOff = 0; a.K = 512;
    gemm_bt<0,3><<<dim3(128,2,nd), 256, 0, stream>>>(a);
    // 18. outp GEMM -> outs (persistent)
    a = {}; a.A = WP(O_S1); a.aZ = 4194304; a.lda = 256;
    a.Bw = WP(O_WOUTP) + (size_t)d0*65536; a.bZ = 65536; a.ldb = 256;
    a.bias = outpB + d0*256; a.biasZ = 256;
    a.C = WP(O_OUTS) + (size_t)d0*4194304; a.cZ = 4194304; a.ldc = 256; a.colOff = 0; a.K = 256;
    gemm_bt<0,0><<<dim3(128,2,nd), 256, 0, stream>>>(a);
  }

  // 19. final inverse-permute average + residual
  finalk<<<4096, 256, 0, stream>>>(curr, WP(O_OUTS), (float*)d_out);

  #undef WP
  #undef FP
}

// Round 6
// 857.009 us; speedup vs baseline: 4.5116x; 1.0553x over previous
//
#include <hip/hip_runtime.h>
#include <hip/hip_bf16.h>
#include <cstdint>
#include <cstddef>

typedef unsigned short u16;
typedef unsigned int u32;
typedef __attribute__((ext_vector_type(8))) __bf16 bfx8;
typedef __attribute__((ext_vector_type(4))) float f32x4;

static __device__ __forceinline__ float bitf(u32 v){ float f; __builtin_memcpy(&f,&v,4); return f; }
static __device__ __forceinline__ float bf2f(u16 v){ return bitf(((u32)v)<<16); }
static __device__ __forceinline__ u16 f2bf(float f){ __bf16 b=(__bf16)f; u16 r; __builtin_memcpy(&r,&b,2); return r; }
static __device__ __forceinline__ u32 pk2(float a,float b){ return (u32)f2bf(a) | ((u32)f2bf(b)<<16); }
static __device__ __forceinline__ void unpk8(uint4 r, float* o){
  o[0]=bitf(r.x<<16); o[1]=bitf(r.x&0xffff0000u);
  o[2]=bitf(r.y<<16); o[3]=bitf(r.y&0xffff0000u);
  o[4]=bitf(r.z<<16); o[5]=bitf(r.z&0xffff0000u);
  o[6]=bitf(r.w<<16); o[7]=bitf(r.w&0xffff0000u);
}
static __device__ __forceinline__ void async16(void* lds, const void* g){
  __builtin_amdgcn_global_load_lds((const __attribute__((address_space(1))) u32*)g,
                                   (__attribute__((address_space(3))) u32*)lds, 16, 0, 0);
}

// ---------------- GEMM: C[M][N] = A[M][K] @ B[N][K]^T (+ epilogue) -----------
struct GemmArgs {
  const u16* A; long aZ; int lda;
  const u16* Bw; long bZ; int ldb;
  const float* bias; int biasZ;
  const float* scale; const float* shift;
  const u16* add; long addZ;
  u16* C; long cZ; int ldc; int colOff;
  int K;
  const u16* pad;
  int dirBase;
};

template<int AMODE, int EPI>
__global__ __launch_bounds__(256)
void gemm_bt(GemmArgs g)
{
  __shared__ u16 smA[128*64];
  __shared__ u16 smB[128*64];
  const int tid = threadIdx.x;
  const int l = tid & 63;
  const int wv = tid >> 6;
  const int wr = wv >> 1, wc = wv & 1;
  const int z = blockIdx.z;
  const int r0 = blockIdx.x * 128;
  const int n0 = blockIdx.y * 128;

  const u16* Abase = g.A + (size_t)z * g.aZ;
  const u16* Bbase = g.Bw + (size_t)z * g.bZ;
  const int ldb = g.ldb ? g.ldb : g.K;

  f32x4 acc[4][4];
  #pragma unroll
  for (int i=0;i<4;i++)
    #pragma unroll
    for (int j=0;j<4;j++) acc[i][j] = (f32x4){0.f,0.f,0.f,0.f};

  const int nkt = g.K >> 6;
  #pragma unroll 1
  for (int kt=0; kt<nkt; ++kt) {
    const int k0 = kt << 6;
    #pragma unroll
    for (int it=0; it<4; ++it) {
      const int s = it*256 + tid;
      const int row = s >> 3, ch = s & 7;
      const u16* ga;
      if (AMODE == 0) {
        ga = Abase + (size_t)(r0+row) * g.lda + k0 + ch*8;
      } else if (AMODE == 1) {
        int rr = r0 + row; int li = rr & 4095; int bb = rr >> 12;
        int dir = g.dirBase + z;
        int l2 = (dir & 2) ? (4095 - li) : li;
        int sl = (dir & 1) ? (((l2 & 63) << 6) | (l2 >> 6)) : l2;
        ga = Abase + (size_t)((bb << 12) | sl) * g.lda + k0 + ch*8;
      } else if (AMODE == 2) {
        int rr = r0 + row; int bb = rr >> 12; int li = rr & 4095;
        int yy = li >> 6, xx = li & 63;
        int tap = z, kin = k0;
        int dy = tap / 3 - 1, dx = tap % 3 - 1;
        ga = g.pad + (((size_t)(bb*66 + yy+dy+1))*66 + (xx+dx+1))*512 + kin + ch*8;
      } else {
        int rr = r0 + row; int bb = rr >> 12; int li = rr & 4095;
        int yy = li >> 6, xx = li & 63;
        ga = g.pad + (((size_t)(bb*66 + yy+1))*66 + (xx+1))*512 + k0 + ch*8;
      }
      async16(&smA[(size_t)(it*256 + (tid & ~63))*8], ga);
      const u16* gb = Bbase + (size_t)(n0+row) * ldb + k0 + ch*8;
      async16(&smB[(size_t)(it*256 + (tid & ~63))*8], gb);
    }
    __syncthreads();
    #pragma unroll
    for (int kk=0; kk<2; ++kk) {
      bfx8 av[4], bv[4];
      #pragma unroll
      for (int mi=0; mi<4; ++mi) {
        int ra = wr*64 + mi*16 + (l & 15);
        av[mi] = *(const bfx8*)&smA[ra*64 + kk*32 + (l>>4)*8];
      }
      #pragma unroll
      for (int ni=0; ni<4; ++ni) {
        int rb = wc*64 + ni*16 + (l & 15);
        bv[ni] = *(const bfx8*)&smB[rb*64 + kk*32 + (l>>4)*8];
      }
      #pragma unroll
      for (int mi=0; mi<4; ++mi)
        #pragma unroll
        for (int ni=0; ni<4; ++ni)
          acc[mi][ni] = __builtin_amdgcn_mfma_f32_16x16x32_bf16(av[mi], bv[ni], acc[mi][ni], 0, 0, 0);
    }
    __syncthreads();
  }

  const float* bias_d = (EPI == 0 || EPI == 3) ? g.bias + (size_t)z * g.biasZ : nullptr;
  const u16* add_d = (EPI == 3) ? g.add + (size_t)z * g.addZ : nullptr;
  u16* Cd = g.C + (size_t)z * g.cZ;
  float* Cf = (float*)g.C + (size_t)z * g.cZ;
  #pragma unroll
  for (int mi=0; mi<4; ++mi) {
    #pragma unroll
    for (int ni=0; ni<4; ++ni) {
      f32x4 v = acc[mi][ni];
      const int gr = r0 + wr*64 + mi*16 + ((l >> 4) << 2);
      const int gc = n0 + wc*64 + ni*16 + (l & 15);
      #pragma unroll
      for (int q=0; q<4; ++q) {
        const int r = gr + q;
        float x = v[q];
        if (EPI == 2) {
          x = fmaxf(fmaf(x, g.scale[gc], g.shift[gc]), 0.f);
          Cd[(size_t)r * g.ldc + g.colOff + gc] = f2bf(x);
        } else if (EPI == 3) {
          x += bias_d[gc] + bf2f(add_d[(size_t)r * g.ldc + gc]);
          Cd[(size_t)r * g.ldc + g.colOff + gc] = f2bf(x);
        } else if (EPI == 4) {
          Cf[(size_t)r * g.ldc + g.colOff + gc] = x;
        } else {
          x += bias_d[gc];
          Cd[(size_t)r * g.ldc + g.colOff + gc] = f2bf(x);
        }
      }
    }
  }
}

// ---------------- small utility kernels --------------------------------------
__global__ void castk(const float* __restrict__ s, u16* __restrict__ d, int n)
{
  int i = (blockIdx.x*256 + threadIdx.x)*4;
  if (i < n){
    float4 v = *(const float4*)(s+i);
    ushort4 o; o.x=f2bf(v.x); o.y=f2bf(v.y); o.z=f2bf(v.z); o.w=f2bf(v.w);
    *(ushort4*)(d+i) = o;
  }
}

__global__ void c3rep(const float* __restrict__ w, u16* __restrict__ o)
{
  int id = blockIdx.x*256 + threadIdx.x; // 128*4608
  int oc = id / 4608, rem = id % 4608;
  int tap = rem >> 9, ic = rem & 511;
  o[id] = f2bf(w[((size_t)oc*512 + ic)*9 + tap]);
}

__global__ void bnssk(const float* g3,const float* b3,const float* m3,const float* v3,
                      const float* g1,const float* b1,const float* m1,const float* v1,
                      float* out)
{
  int t = threadIdx.x; int i = t & 127;
  if (t < 128){ float sc = g3[i]*rsqrtf(v3[i]+1e-5f); out[i]=sc; out[128+i]=b3[i]-m3[i]*sc; }
  else        { float sc = g1[i]*rsqrtf(v1[i]+1e-5f); out[256+i]=sc; out[384+i]=b1[i]-m1[i]*sc; }
}

// reduce 9 fp32 partials -> BN+ReLU -> bf16 into zin cols 0..127
__global__ __launch_bounds__(256)
void c3red(const float* __restrict__ P, const float* __restrict__ bnss, u16* __restrict__ zin)
{
  const int id = blockIdx.x*256 + threadIdx.x;
  const size_t base = (size_t)id * 4;
  const int r = (int)(base >> 7), c = (int)(base & 127);
  float4 s = {0.f,0.f,0.f,0.f};
  #pragma unroll
  for (int z=0; z<9; ++z){
    float4 v = *(const float4*)(P + (size_t)z*2097152 + base);
    s.x += v.x; s.y += v.y; s.z += v.z; s.w += v.w;
  }
  float4 sc = *(const float4*)(bnss + c);
  float4 sh = *(const float4*)(bnss + 128 + c);
  ushort4 o;
  o.x = f2bf(fmaxf(fmaf(s.x, sc.x, sh.x), 0.f));
  o.y = f2bf(fmaxf(fmaf(s.y, sc.y, sh.y), 0.f));
  o.z = f2bf(fmaxf(fmaf(s.z, sc.z, sh.z), 0.f));
  o.w = f2bf(fmaxf(fmaf(s.w, sc.w, sh.w), 0.f));
  *(ushort4*)(zin + (size_t)r*256 + c) = o;
}

__global__ __launch_bounds__(256)
void padk(const float* __restrict__ curr, const float* __restrict__ prev, u16* __restrict__ pad)
{
  const int id = blockIdx.x*256 + threadIdx.x;
  const int c8 = id & 63;
  int t = id >> 6;
  const int xx = t % 66; t /= 66;
  const int yy = t % 66; const int b = t / 66;
  const int c0 = c8*8;
  uint4 o;
  if (yy==0 || yy==65 || xx==0 || xx==65){ o.x=0;o.y=0;o.z=0;o.w=0; }
  else {
    const int l = (yy-1)*64 + (xx-1);
    const float* s = (c0 < 256) ? curr + ((size_t)b*4096 + l)*256 + c0
                                : prev + ((size_t)b*4096 + l)*256 + (c0-256);
    float4 a = *(const float4*)s, bb = *(const float4*)(s+4);
    o.x = pk2(a.x,a.y); o.y = pk2(a.z,a.w); o.z = pk2(bb.x,bb.y); o.w = pk2(bb.z,bb.w);
  }
  *(uint4*)(pad + (((size_t)b*66 + yy)*66 + xx)*512 + c0) = o;
}

__global__ __launch_bounds__(256)
void ln256(const u16* __restrict__ in, long inZ, u16* __restrict__ out, long outZ,
           const float* __restrict__ gw, const float* __restrict__ bw, int pz)
{
  const int z = blockIdx.z;
  const int row = blockIdx.x*4 + (threadIdx.x>>6);
  const int l = threadIdx.x & 63;
  const u16* ip = in + (size_t)z*inZ + (size_t)row*256 + l*4;
  ushort4 rr = *(const ushort4*)ip;
  float v0=bf2f(rr.x), v1=bf2f(rr.y), v2=bf2f(rr.z), v3=bf2f(rr.w);
  float s = v0+v1+v2+v3;
  float ss = v0*v0+v1*v1+v2*v2+v3*v3;
  #pragma unroll
  for(int m=1;m<64;m<<=1){ s += __shfl_xor(s,m); ss += __shfl_xor(ss,m); }
  float mu = s*(1.f/256.f);
  float var = ss*(1.f/256.f) - mu*mu;
  float rs = rsqrtf(var + 1e-5f);
  const float* g = gw + (size_t)z*pz; const float* b = bw + (size_t)z*pz;
  int c = l*4;
  u16* op = out + (size_t)z*outZ + (size_t)row*256 + c;
  ushort4 o; o.x=f2bf((v0-mu)*rs*g[c]+b[c]); o.y=f2bf((v1-mu)*rs*g[c+1]+b[c+1]);
  o.z=f2bf((v2-mu)*rs*g[c+2]+b[c+2]); o.w=f2bf((v3-mu)*rs*g[c+3]+b[c+3]);
  *(ushort4*)op = o;
}

__global__ __launch_bounds__(256)
void rms512(u16* __restrict__ Y, const float* __restrict__ gw)
{
  const int z = blockIdx.z;
  const int row = blockIdx.x*4 + (threadIdx.x>>6);
  const int l = threadIdx.x & 63;
  u16* p = Y + ((size_t)z*16384 + row)*512 + l*8;
  uint4 raw = *(const uint4*)p;
  float v[8]; unpk8(raw, v);
  float ss = 0.f;
  #pragma unroll
  for (int j=0;j<8;j++) ss += v[j]*v[j];
  #pragma unroll
  for (int m=1;m<64;m<<=1) ss += __shfl_xor(ss, m);
  const float sc = rsqrtf(ss*(1.f/512.f) + 1e-5f);
  const float* g = gw + (size_t)z*512 + l*8;
  uint4 o;
  o.x = pk2(v[0]*sc*g[0], v[1]*sc*g[1]);
  o.y = pk2(v[2]*sc*g[2], v[3]*sc*g[3]);
  o.z = pk2(v[4]*sc*g[4], v[5]*sc*g[5]);
  o.w = pk2(v[6]*sc*g[6], v[7]*sc*g[7]);
  *(uint4*)p = o;
}

// fp32 dt head: dt = softplus(xln.W_dt + b + dt_bias)
__global__ __launch_bounds__(256)
void dtk(const u16* __restrict__ xln, const float* __restrict__ minW,
         const float* __restrict__ minB, const float* __restrict__ dtb,
         float* __restrict__ DT)
{
  __shared__ float sx[32*257];
  const int z = blockIdx.z;
  const int r0 = blockIdx.x * 32;
  const int tid = threadIdx.x;
  {
    const int rr = tid >> 3, cc = (tid & 7) * 32;
    const u16* src = xln + ((size_t)z*16384 + r0 + rr)*256 + cc;
    #pragma unroll
    for (int q=0;q<4;q++){
      uint4 raw = *(const uint4*)(src + q*8);
      float v[8]; unpk8(raw, v);
      #pragma unroll
      for (int j=0;j<8;j++) sx[rr*257 + cc + q*8 + j] = v[j];
    }
  }
  __syncthreads();
  const int ri = tid >> 3, hv = tid & 7;
  const float* wrow = minW + ((size_t)z*1288 + 1280 + hv)*256;
  float acc = 0.f;
  #pragma unroll 4
  for (int k=0; k<256; k+=4){
    float4 wq = *(const float4*)(wrow + k);
    acc += sx[ri*257+k]*wq.x + sx[ri*257+k+1]*wq.y + sx[ri*257+k+2]*wq.z + sx[ri*257+k+3]*wq.w;
  }
  acc += minB[(size_t)z*1288 + 1280 + hv] + dtb[z*8 + hv];
  float dt = (acc > 20.f) ? acc : log1pf(expf(acc));
  DT[((size_t)z*16384 + r0 + ri)*8 + hv] = dt;
}

// chunk-local cumulative log-decay
__global__ __launch_bounds__(256)
void cak(const float* __restrict__ DT, float* __restrict__ CA,
         const float* __restrict__ alog, int dirBase)
{
  const int z = blockIdx.z;
  const int gidx = blockIdx.x*4 + (threadIdx.x>>6);
  const int lane = threadIdx.x & 63;
  const int c = gidx & 63, bh = gidx >> 6;
  const int b = bh >> 3, hh = bh & 7;
  const size_t row = (size_t)z*16384 + (size_t)b*4096 + c*64 + lane;
  float x = DT[row*8 + hh];
  #pragma unroll
  for (int m=1;m<64;m<<=1){ float o = __shfl_up(x, m); if (lane >= m) x += o; }
  float eA = expf(alog[(dirBase+z)*8 + hh]);
  CA[row*8 + hh] = -eA * x;
}

// causal conv1d(4)+SiLU over the B/C columns (raw cols 512..767) -> BCC[row][256]
__global__ __launch_bounds__(256)
void convbc(const u16* __restrict__ xbcr, u16* __restrict__ bcc,
            const float* __restrict__ cw, const float* __restrict__ cb)
{
  const int id = blockIdx.x*256 + threadIdx.x;
  const int c8 = id & 31;
  const int r = (id >> 5) & 16383;
  const int d = id >> 19;
  const int li = r & 4095;
  const int col = 512 + c8*8;
  const u16* base = xbcr + (size_t)d*16777216 + (size_t)(r - li)*768 + col;
  float acc[8];
  #pragma unroll
  for (int j=0;j<8;j++) acc[j] = cb[d*768 + col + j];
  #pragma unroll
  for (int tap=0; tap<4; ++tap){
    int lt = li - 3 + tap;
    if (lt >= 0){
      uint4 raw = *(const uint4*)(base + (size_t)lt*768);
      float v[8]; unpk8(raw, v);
      #pragma unroll
      for (int j=0;j<8;j++)
        acc[j] = fmaf(v[j], cw[((size_t)d*768 + col + j)*4 + tap], acc[j]);
    }
  }
  uint4 o;
  float s[8];
  #pragma unroll
  for (int j=0;j<8;j++) s[j] = acc[j] / (1.f + __expf(-acc[j]));
  o.x = pk2(s[0],s[1]); o.y = pk2(s[2],s[3]); o.z = pk2(s[4],s[5]); o.w = pk2(s[6],s[7]);
  *(uint4*)(bcc + ((size_t)d*16384 + r)*256 + c8*8) = o;
}

// conv1d(4)+SiLU on X cols (raw 0..511) + transpose -> XCT[p][g]
// grid (1024, 1, nd): tile = 64 rows (c) x 128 cols (pq)
__global__ __launch_bounds__(256)
void convx(const u16* __restrict__ xbcr, u16* __restrict__ xct,
           const float* __restrict__ cw, const float* __restrict__ cb)
{
  __shared__ u16 T[128*72];
  __shared__ float cwX[4][128];
  __shared__ float cbX[128];
  const int bx = blockIdx.x, z = blockIdx.z;
  const int pq = bx & 3, c = (bx>>2) & 63, b = bx >> 8;
  const int tid = threadIdx.x;
  const u16* xb = xbcr + (size_t)z*16777216 + (size_t)b*4096*768;
  if (tid < 128){
    float4 w4 = *(const float4*)(cw + (size_t)z*3072 + (pq*128+tid)*4);
    cwX[0][tid]=w4.x; cwX[1][tid]=w4.y; cwX[2][tid]=w4.z; cwX[3][tid]=w4.w;
    cbX[tid] = cb[z*768 + pq*128 + tid];
  }
  __syncthreads();
  #pragma unroll
  for (int u=0; u<4; ++u){
    int idx = u*256 + tid;
    int s = idx >> 4, seg = idx & 15;
    int li = c*64 + s;
    int col = pq*128 + seg*8;
    float acc[8];
    #pragma unroll
    for (int j=0;j<8;j++) acc[j] = cbX[seg*8+j];
    #pragma unroll
    for (int tap=0; tap<4; ++tap){
      int lt = li - 3 + tap;
      if (lt >= 0){
        uint4 raw = *(const uint4*)(xb + (size_t)lt*768 + col);
        float v[8]; unpk8(raw, v);
        #pragma unroll
        for (int j=0;j<8;j++) acc[j] = fmaf(v[j], cwX[tap][seg*8+j], acc[j]);
      }
    }
    #pragma unroll
    for (int j=0;j<8;j++)
      T[(seg*8+j)*72 + s] = f2bf(acc[j] / (1.f + __expf(-acc[j])));
  }
  __syncthreads();
  #pragma unroll
  for (int u=0; u<4; ++u){
    int idx = u*256 + tid;
    int pl = idx >> 3, sg = idx & 7;
    uint4 v = *(const uint4*)&T[pl*72 + sg*8];
    *(uint4*)(xct + (size_t)z*8388608 + (size_t)(pq*128+pl)*16384 + b*4096 + c*64 + sg*8) = v;
  }
}

// transpose conv'd B (BCC cols 0..127) -> BT[n][g]; grid (256,1,nd)
__global__ __launch_bounds__(256)
void btk(const u16* __restrict__ bcc, u16* __restrict__ bt)
{
  __shared__ u16 T[128*72];
  const int bx = blockIdx.x, z = blockIdx.z;
  const int c = bx & 63, b = bx >> 6;
  const int tid = threadIdx.x;
  const u16* src = bcc + ((size_t)z*16384 + (size_t)b*4096 + c*64)*256;
  #pragma unroll
  for (int u=0; u<4; ++u){
    int idx = u*256 + tid;
    int s = idx >> 4, seg = idx & 15;
    uint4 raw = *(const uint4*)(src + (size_t)s*256 + seg*8);
    u16 t8[8]; *(uint4*)t8 = raw;
    #pragma unroll
    for (int j=0;j<8;j++) T[(seg*8+j)*72 + s] = t8[j];
  }
  __syncthreads();
  #pragma unroll
  for (int u=0; u<4; ++u){
    int idx = u*256 + tid;
    int n = idx >> 3, sg = idx & 7;
    uint4 v = *(const uint4*)&T[n*72 + sg*8];
    *(uint4*)(bt + (size_t)z*2097152 + (size_t)n*16384 + b*4096 + c*64 + sg*8) = v;
  }
}

// per-chunk outer products, all heads fused: CS[p][n] = sum_s (w[s,h]*X^T[p][s])*B^T[n][s]
// grid (512, 1, nd): block = (b, c, p-half)
__global__ __launch_bounds__(256)
void csk(const u16* __restrict__ xct, const u16* __restrict__ bt,
         const float* __restrict__ DT, const float* __restrict__ CA,
         u16* __restrict__ CS)
{
  __shared__ u16 Xw[256*72];
  __shared__ u16 Bt[128*72];
  __shared__ float wS[64*8];
  const int bx = blockIdx.x, z = blockIdx.z;
  const int ph = bx & 1, c = (bx>>1) & 63, b = bx >> 7;
  const int tid = threadIdx.x, l = tid & 63, w = tid >> 6;
  const size_t rowb = (size_t)z*16384 + (size_t)b*4096;
  const int p0 = ph*256;
  {
    int s = tid & 63, h0 = tid >> 6;
    #pragma unroll
    for (int hh=h0; hh<8; hh+=4){
      float ca63 = CA[(rowb + c*64 + 63)*8 + hh];
      float cav  = CA[(rowb + c*64 + s)*8 + hh];
      float dtv  = DT[(rowb + c*64 + s)*8 + hh];
      wS[s*8+hh] = __expf(ca63 - cav) * dtv;
    }
  }
  __syncthreads();
  #pragma unroll
  for (int u=0; u<8; ++u){
    int idx = u*256 + tid;
    int pl = idx >> 3, sg = idx & 7;
    int gp = p0 + pl; int hh = gp >> 6;
    uint4 raw = *(const uint4*)(xct + (size_t)z*8388608 + (size_t)gp*16384 + b*4096 + c*64 + sg*8);
    float v[8]; unpk8(raw, v);
    uint4 o;
    o.x = pk2(v[0]*wS[(sg*8+0)*8+hh], v[1]*wS[(sg*8+1)*8+hh]);
    o.y = pk2(v[2]*wS[(sg*8+2)*8+hh], v[3]*wS[(sg*8+3)*8+hh]);
    o.z = pk2(v[4]*wS[(sg*8+4)*8+hh], v[5]*wS[(sg*8+5)*8+hh]);
    o.w = pk2(v[6]*wS[(sg*8+6)*8+hh], v[7]*wS[(sg*8+7)*8+hh]);
    *(uint4*)&Xw[pl*72 + sg*8] = o;
  }
  #pragma unroll
  for (int u=0; u<4; ++u){
    int idx = u*256 + tid;
    int n = idx >> 3, sg = idx & 7;
    *(uint4*)&Bt[n*72 + sg*8] =
      *(const uint4*)(bt + (size_t)z*2097152 + (size_t)n*16384 + b*4096 + c*64 + sg*8);
  }
  __syncthreads();
  // D[n][p]: A = Bt rows n (M=128), B-op = Xw cols p (wave w covers 64 p)
  f32x4 acc[8][4];
  #pragma unroll
  for (int i=0;i<8;i++)
    #pragma unroll
    for (int j=0;j<4;j++) acc[i][j] = (f32x4){0.f,0.f,0.f,0.f};
  #pragma unroll
  for (int kk=0; kk<2; ++kk){
    bfx8 bvp[4];
    #pragma unroll
    for (int ni=0; ni<4; ++ni)
      bvp[ni] = *(const bfx8*)&Xw[(w*64 + ni*16 + (l&15))*72 + kk*32 + (l>>4)*8];
    #pragma unroll
    for (int mi=0; mi<8; ++mi){
      bfx8 av = *(const bfx8*)&Bt[(mi*16 + (l&15))*72 + kk*32 + (l>>4)*8];
      #pragma unroll
      for (int ni=0; ni<4; ++ni)
        acc[mi][ni] = __builtin_amdgcn_mfma_f32_16x16x32_bf16(av, bvp[ni], acc[mi][ni], 0, 0, 0);
    }
  }
  // write CS[bh][c][p&63][n]: n = mi*16 + (l>>4)*4 + q, p = p0 + w*64 + ni*16 + (l&15)
  #pragma unroll
  for (int mi=0; mi<8; ++mi){
    #pragma unroll
    for (int ni=0; ni<4; ++ni){
      int gp = p0 + w*64 + ni*16 + (l&15);
      int bhx = b*8 + (gp>>6); int pin = gp & 63;
      int n0 = mi*16 + ((l>>4)<<2);
      u32* cp = (u32*)&CS[(size_t)z*16777216 + (size_t)bhx*524288 + (size_t)c*8192 + (size_t)pin*128 + n0];
      cp[0] = pk2(acc[mi][ni][0], acc[mi][ni][1]);
      cp[1] = pk2(acc[mi][ni][2], acc[mi][ni][3]);
    }
  }
}

// sequential 64-step combine IN PLACE (H aliases CS)
__global__ __launch_bounds__(256)
void combk(const u16* __restrict__ CS, const float* __restrict__ CA,
           u16* __restrict__ H)
{
  __shared__ float aL[64];
  const int bx = blockIdx.x;
  const int z = blockIdx.z;
  const int pg = bx & 3, bh = bx >> 2;
  const int b = bh >> 3, hh = bh & 7;
  const int tid = threadIdx.x;
  const int p = pg*16 + (tid >> 4), n = (tid & 15)*8;
  const size_t rowb = (size_t)z*16384 + (size_t)b*4096;
  if (tid < 64) aL[tid] = __expf(CA[(rowb + tid*64 + 63)*8 + hh]);
  __syncthreads();
  const u16* Cs = CS + (size_t)z*16777216 + (size_t)bh*524288 + (size_t)p*128 + n;
  u16* Hd = H + (size_t)z*16777216 + (size_t)bh*524288 + (size_t)p*128 + n;
  float h[8];
  #pragma unroll
  for (int j=0;j<8;j++) h[j]=0.f;
  uint4 pf = *(const uint4*)Cs;
  #pragma unroll 1
  for (int c=0; c<64; ++c){
    uint4 cur = pf;
    if (c < 63) pf = *(const uint4*)(Cs + (size_t)(c+1)*8192);
    uint4 o;
    o.x = pk2(h[0],h[1]); o.y = pk2(h[2],h[3]);
    o.z = pk2(h[4],h[5]); o.w = pk2(h[6],h[7]);
    *(uint4*)(Hd + (size_t)c*8192) = o;
    float v[8]; unpk8(cur, v);
    const float a = aL[c];
    #pragma unroll
    for (int j=0;j<8;j++) h[j] = fmaf(h[j], a, v[j]);
  }
}

// per-chunk output: Y = (S_decayed @ X + diag(exp(ca)) * (C @ H[c]) + Dh*x) * silu(z)
// grid (2048, 1, nd) per (bh, c); all-LDS staged
__global__ __launch_bounds__(256)
void yk2(const u16* __restrict__ bcc, const u16* __restrict__ xct,
         const float* __restrict__ DT, const float* __restrict__ CA,
         const u16* __restrict__ H, const float* __restrict__ Dp,
         u16* __restrict__ Y)
{
  __shared__ u16 Bc[64*264];    // [s][B:0..127, C:128..255]
  __shared__ u16 Hs[64*136];    // [p][n]
  __shared__ u16 Xt[64*72];     // [p][s]
  __shared__ u16 Sm[64*72];     // [t][s]
  __shared__ float caL[64], dtL[64];
  const int bx = blockIdx.x, z = blockIdx.z;
  const int c = bx & 63, bh = bx >> 6;
  const int b = bh >> 3, hh = bh & 7;
  const int tid = threadIdx.x, l = tid & 63, w = tid >> 6;
  const size_t rowb = (size_t)z*16384 + (size_t)b*4096;
  const u16* bcp = bcc + (rowb + c*64)*256;
  const u16* Hd = H + (size_t)z*16777216 + (size_t)bh*524288 + (size_t)c*8192;
  const u16* xcp = xct + (size_t)z*8388608 + (size_t)(hh*64)*16384 + b*4096 + c*64;
  const float Dh = Dp[z*8 + hh];
  if (tid < 64){
    caL[tid] = CA[(rowb + c*64 + tid)*8 + hh];
    dtL[tid] = DT[(rowb + c*64 + tid)*8 + hh];
  }
  #pragma unroll
  for (int u=0; u<8; ++u){
    int idx = u*256 + tid; int s = idx >> 5, sg = idx & 31;
    *(uint4*)&Bc[s*264 + sg*8] = *(const uint4*)(bcp + (size_t)s*256 + sg*8);
  }
  #pragma unroll
  for (int u=0; u<4; ++u){
    int idx = u*256 + tid; int p = idx >> 4, sg = idx & 15;
    *(uint4*)&Hs[p*136 + sg*8] = *(const uint4*)(Hd + (size_t)p*128 + sg*8);
  }
  #pragma unroll
  for (int u=0; u<2; ++u){
    int idx = u*256 + tid; int p = idx >> 3, sg = idx & 7;
    *(uint4*)&Xt[p*72 + sg*8] = *(const uint4*)(xcp + (size_t)p*16384 + sg*8);
  }
  __syncthreads();

  f32x4 sacc[4], acc2[4];
  #pragma unroll
  for (int i=0;i<4;i++){ sacc[i] = (f32x4){0.f,0.f,0.f,0.f}; acc2[i] = (f32x4){0.f,0.f,0.f,0.f}; }
  #pragma unroll
  for (int kk=0; kk<4; ++kk){
    bfx8 av = *(const bfx8*)&Bc[(w*16 + (l&15))*264 + 128 + kk*32 + (l>>4)*8];
    #pragma unroll
    for (int st=0; st<4; ++st){
      bfx8 bv = *(const bfx8*)&Bc[(st*16 + (l&15))*264 + kk*32 + (l>>4)*8];
      sacc[st] = __builtin_amdgcn_mfma_f32_16x16x32_bf16(av, bv, sacc[st], 0, 0, 0);
      bfx8 hv = *(const bfx8*)&Hs[(st*16 + (l&15))*136 + kk*32 + (l>>4)*8];
      acc2[st] = __builtin_amdgcn_mfma_f32_16x16x32_bf16(av, hv, acc2[st], 0, 0, 0);
    }
  }
  #pragma unroll
  for (int st=0; st<4; ++st){
    #pragma unroll
    for (int q=0;q<4;q++){
      int t = w*16 + (l>>4)*4 + q;
      int s = st*16 + (l&15);
      float m = (s <= t) ? __expf(caL[t]-caL[s]) * dtL[s] : 0.f;
      Sm[t*72 + s] = f2bf(sacc[st][q] * m);
    }
  }
  #pragma unroll
  for (int pt=0; pt<4; ++pt)
    #pragma unroll
    for (int q=0;q<4;q++){
      int t = w*16 + (l>>4)*4 + q;
      acc2[pt][q] *= __expf(caL[t]);
    }
  __syncthreads();
  #pragma unroll
  for (int kk=0; kk<2; ++kk){
    bfx8 av = *(const bfx8*)&Sm[(w*16 + (l&15))*72 + kk*32 + (l>>4)*8];
    #pragma unroll
    for (int pt=0; pt<4; ++pt){
      bfx8 bv = *(const bfx8*)&Xt[(pt*16 + (l&15))*72 + kk*32 + (l>>4)*8];
      acc2[pt] = __builtin_amdgcn_mfma_f32_16x16x32_bf16(av, bv, acc2[pt], 0, 0, 0);
    }
  }
  u16* Yrow = Y + (rowb + c*64)*512 + hh*64;
  #pragma unroll
  for (int pt=0; pt<4; ++pt){
    #pragma unroll
    for (int q=0;q<4;q++){
      int t = w*16 + (l>>4)*4 + q;
      int p = pt*16 + (l&15);
      float xv = bf2f(Xt[p*72 + t]);
      float zf = bf2f(Yrow[(size_t)t*512 + p]);
      float yv = (acc2[pt][q] + Dh*xv) * (zf/(1.f+__expf(-zf)));
      Yrow[(size_t)t*512 + p] = f2bf(yv);
    }
  }
}

__global__ __launch_bounds__(256)
void finalk(const float* __restrict__ curr, const u16* __restrict__ outs, float* __restrict__ o)
{
  const int row = blockIdx.x*4 + (threadIdx.x>>6);
  const int c4 = (threadIdx.x & 63)*4;
  const int b = row >> 12, li = row & 4095;
  const int T = ((li & 63) << 6) | (li >> 6);
  const size_t rb = (size_t)b*4096;
  const ushort4 a0 = *(const ushort4*)(outs + (size_t)0*4194304 + ((rb+li)*256 + c4));
  const ushort4 a1 = *(const ushort4*)(outs + (size_t)1*4194304 + ((rb+T)*256 + c4));
  const ushort4 a2 = *(const ushort4*)(outs + (size_t)2*4194304 + ((rb+4095-li)*256 + c4));
  const ushort4 a3 = *(const ushort4*)(outs + (size_t)3*4194304 + ((rb+4095-T)*256 + c4));
  float4 cv = *(const float4*)(curr + (size_t)row*256 + c4);
  float4 r;
  r.x = cv.x + 0.25f*(bf2f(a0.x)+bf2f(a1.x)+bf2f(a2.x)+bf2f(a3.x));
  r.y = cv.y + 0.25f*(bf2f(a0.y)+bf2f(a1.y)+bf2f(a2.y)+bf2f(a3.y));
  r.z = cv.z + 0.25f*(bf2f(a0.z)+bf2f(a1.z)+bf2f(a2.z)+bf2f(a3.z));
  r.w = cv.w + 0.25f*(bf2f(a0.w)+bf2f(a1.w)+bf2f(a2.w)+bf2f(a3.w));
  *(float4*)(o + (size_t)row*256 + c4) = r;
}

// ---------------------------------------------------------------------------
extern "C" void kernel_launch(void* const* d_in, const int* in_sizes, int n_in,
                              void* d_out, int out_size, void* d_ws, size_t ws_size,
                              hipStream_t stream)
{
  (void)in_sizes; (void)n_in; (void)out_size;
  const float* curr   = (const float*)d_in[0];
  const float* prev   = (const float*)d_in[1];
  const float* conv3w = (const float*)d_in[2];
  const float* bn3g=(const float*)d_in[3], *bn3b=(const float*)d_in[4], *bn3m=(const float*)d_in[5], *bn3v=(const float*)d_in[6];
  const float* conv1w = (const float*)d_in[7];
  const float* bn1g=(const float*)d_in[8], *bn1b=(const float*)d_in[9], *bn1m=(const float*)d_in[10], *bn1v=(const float*)d_in[11];
  const float* fuseW=(const float*)d_in[12], *fuseB=(const float*)d_in[13];
  const float* lng=(const float*)d_in[14], *lnb=(const float*)d_in[15];
  const float* inpW=(const float*)d_in[16], *inpB=(const float*)d_in[17];
  const float* mlng=(const float*)d_in[18], *mlnb=(const float*)d_in[19];
  const float* minW=(const float*)d_in[20], *minB=(const float*)d_in[21];
  const float* cw=(const float*)d_in[22], *cb=(const float*)d_in[23];
  const float* alog=(const float*)d_in[24], *Dp=(const float*)d_in[25], *dtb=(const float*)d_in[26];
  const float* mng=(const float*)d_in[27];
  const float* moutW=(const float*)d_in[28], *moutB=(const float*)d_in[29];
  const float* outpW=(const float*)d_in[30], *outpB=(const float*)d_in[31];

  // ---- persistent layout ----
  char* ws = (char*)d_ws;
  size_t off = 0;
  auto alloc = [&](size_t bytes){ size_t o = off; off = (off + bytes + 1023) & ~(size_t)1023; return o; };
  const size_t O_WFUSE = alloc((size_t)256*256*2);
  const size_t O_WINP  = alloc((size_t)4*256*256*2);
  const size_t O_WMIN  = alloc((size_t)4*1288*256*2);
  const size_t O_WMOUT = alloc((size_t)4*256*512*2);
  const size_t O_WOUTP = alloc((size_t)4*256*256*2);
  const size_t O_WC3   = alloc((size_t)128*4608*2);
  const size_t O_WC1   = alloc((size_t)128*512*2);
  const size_t O_BNSS  = alloc(512*4);
  const size_t O_ZF    = alloc((size_t)16384*256*2);
  const size_t O_OUTS  = alloc((size_t)4*16384*256*2);
  const size_t O_P     = off;

  // per-dir sizes (bytes)
  const size_t S0d  = (size_t)16384*256*2;    // 8.39MB
  const size_t XLNd = (size_t)16384*256*2;    // 8.39MB (BCC / S1 overlay)
  const size_t Yd   = (size_t)16384*512*2;    // 16.8MB (z then y)
  const size_t XCTd = (size_t)512*16384*2;    // 16.8MB (conv'd X transposed)
  const size_t BTd  = (size_t)128*16384*2;    // 4.19MB (conv'd B transposed)
  const size_t DTd  = (size_t)16384*8*4;
  const size_t CAd  = (size_t)16384*8*4;
  const size_t XHd  = (size_t)16777216*2;     // 33.55MB union: raw xBC (25.2) then CS==H
  const size_t perdir = S0d + XLNd + Yd + XCTd + BTd + DTd + CAd + XHd;

  const size_t PADsz = (size_t)4*66*66*512*2;
  const size_t CPsz  = (size_t)9*16384*128*4;
  const size_t PREsz = PADsz + CPsz + (size_t)16384*256*2*2 + 4096;

  int nd = 0;
  for (int cand = 4; cand >= 1; cand >>= 1) {
    size_t need = (size_t)cand*perdir; if (need < PREsz) need = PREsz;
    if (O_P + need <= ws_size) { nd = cand; break; }
  }
  if (nd == 0) return;

  #define WP(o) ((u16*)(ws + (o)))
  #define FP(o) ((float*)(ws + (o)))

  const size_t O_PAD = O_P;
  const size_t O_CP  = O_PAD + PADsz;
  const size_t O_ZIN = O_CP + CPsz;
  const size_t O_ZFT = O_ZIN + (size_t)16384*256*2;

  // 1. BN scale/shift + weight conversions
  bnssk<<<1, 256, 0, stream>>>(bn3g,bn3b,bn3m,bn3v, bn1g,bn1b,bn1m,bn1v, FP(O_BNSS));
  castk<<<64, 256, 0, stream>>>(fuseW, WP(O_WFUSE), 65536);
  castk<<<256, 256, 0, stream>>>(inpW, WP(O_WINP), 262144);
  castk<<<1288, 256, 0, stream>>>(minW, WP(O_WMIN), 1318912);
  castk<<<512, 256, 0, stream>>>(moutW, WP(O_WMOUT), 524288);
  castk<<<256, 256, 0, stream>>>(outpW, WP(O_WOUTP), 262144);
  castk<<<64, 256, 0, stream>>>(conv1w, WP(O_WC1), 65536);
  c3rep<<<2304, 256, 0, stream>>>(conv3w, WP(O_WC3));
  // 2. padded concat input (bf16)
  padk<<<4356, 256, 0, stream>>>(curr, prev, WP(O_PAD));

  GemmArgs a;
  // 3. conv3 split-K over 9 taps -> fp32 partials -> reduce+BN+ReLU
  a = {}; a.A = WP(O_PAD); a.pad = WP(O_PAD);
  a.Bw = WP(O_WC3); a.bZ = 512; a.ldb = 4608;
  a.C = WP(O_CP); a.cZ = 2097152; a.ldc = 128; a.colOff = 0; a.K = 512;
  gemm_bt<2,4><<<dim3(128,1,9), 256, 0, stream>>>(a);
  c3red<<<2048, 256, 0, stream>>>(FP(O_CP), FP(O_BNSS), WP(O_ZIN));
  // 4. conv1 -> zin[:,128:256]
  a = {}; a.A = WP(O_PAD); a.pad = WP(O_PAD); a.Bw = WP(O_WC1); a.bZ = 0; a.ldb = 512;
  a.scale = FP(O_BNSS)+256; a.shift = FP(O_BNSS)+384;
  a.C = WP(O_ZIN); a.cZ = 0; a.ldc = 256; a.colOff = 128; a.K = 512;
  gemm_bt<3,2><<<dim3(128,1,1), 256, 0, stream>>>(a);
  // 5. fuse GEMM -> zft
  a = {}; a.A = WP(O_ZIN); a.aZ = 0; a.lda = 256; a.Bw = WP(O_WFUSE); a.bZ = 0; a.ldb = 256;
  a.bias = fuseB; a.biasZ = 0; a.C = WP(O_ZFT); a.cZ = 0; a.ldc = 256; a.colOff = 0; a.K = 256;
  gemm_bt<0,0><<<dim3(128,2,1), 256, 0, stream>>>(a);
  // 6. LN -> zf (persistent)
  ln256<<<dim3(4096,1,1), 256, 0, stream>>>(WP(O_ZFT), 0, WP(O_ZF), 0, lng, lnb, 0);

  // ---- phases over directions ----
  for (int d0 = 0; d0 < 4; d0 += nd) {
    size_t o = O_P;
    const size_t O_S0  = o; o += (size_t)nd*S0d;
    const size_t O_XLN = o; o += (size_t)nd*XLNd;
    const size_t O_Y   = o; o += (size_t)nd*Yd;
    const size_t O_XCT = o; o += (size_t)nd*XCTd;
    const size_t O_BT  = o; o += (size_t)nd*BTd;
    const size_t O_DT  = o; o += (size_t)nd*DTd;
    const size_t O_CA  = o; o += (size_t)nd*CAd;
    const size_t O_XH  = o;                     // raw xBC (padded stride), then CS==H
    const size_t O_BCC = O_XLN;                 // overlay (XLN dead after xbc gemm)
    const size_t O_S1  = O_XLN;                 // overlay (BCC dead after yk2)

    // 7. inp GEMM (permuted rows per dir) -> s0
    a = {}; a.A = WP(O_ZF); a.aZ = 0; a.lda = 256;
    a.Bw = WP(O_WINP) + (size_t)d0*65536; a.bZ = 65536; a.ldb = 256;
    a.bias = inpB + d0*256; a.biasZ = 256;
    a.C = WP(O_S0); a.cZ = 4194304; a.ldc = 256; a.colOff = 0; a.K = 256; a.dirBase = d0;
    gemm_bt<1,0><<<dim3(128,2,nd), 256, 0, stream>>>(a);
    // 8. per-dir LN(s0) -> xln
    ln256<<<dim3(4096,1,nd), 256, 0, stream>>>(WP(O_S0), 4194304, WP(O_XLN), 4194304,
                                               mlng + d0*256, mlnb + d0*256, 256);
    // 9. dt, chunk log-decay
    dtk<<<dim3(512,1,nd), 256, 0, stream>>>(WP(O_XLN), minW + (size_t)d0*329728,
                                            minB + d0*1288, dtb + d0*8, FP(O_DT));
    cak<<<dim3(512,1,nd), 256, 0, stream>>>(FP(O_DT), FP(O_CA), alog, d0);
    // 10. z-gate GEMM -> Y
    a = {}; a.A = WP(O_XLN); a.aZ = 4194304; a.lda = 256;
    a.Bw = WP(O_WMIN) + (size_t)d0*329728; a.bZ = 329728; a.ldb = 256;
    a.bias = minB + d0*1288; a.biasZ = 1288;
    a.C = WP(O_Y); a.cZ = 8388608; a.ldc = 512; a.colOff = 0; a.K = 256;
    gemm_bt<0,0><<<dim3(128,4,nd), 256, 0, stream>>>(a);
    // 11. xBC GEMM -> raw xbc (padded per-dir stride)   [last reader of XLN]
    a = {}; a.A = WP(O_XLN); a.aZ = 4194304; a.lda = 256;
    a.Bw = WP(O_WMIN) + (size_t)d0*329728 + (size_t)512*256; a.bZ = 329728; a.ldb = 256;
    a.bias = minB + d0*1288 + 512; a.biasZ = 1288;
    a.C = WP(O_XH); a.cZ = 16777216; a.ldc = 768; a.colOff = 0; a.K = 256;
    gemm_bt<0,0><<<dim3(128,6,nd), 256, 0, stream>>>(a);
    // 12. conv1d+SiLU on B/C -> BCC (overlays XLN)
    convbc<<<nd*2048, 256, 0, stream>>>(WP(O_XH), WP(O_BCC), cw + d0*3072, cb + d0*768);
    // 13. conv1d+SiLU+transpose X -> XCT
    convx<<<dim3(1024,1,nd), 256, 0, stream>>>(WP(O_XH), WP(O_XCT), cw + d0*3072, cb + d0*768);
    // 14. transpose conv'd B -> BT
    btk<<<dim3(256,1,nd), 256, 0, stream>>>(WP(O_BCC), WP(O_BT));
    // 15. per-chunk outer products (all heads) -> CS (overlays raw xbc)
    csk<<<dim3(512,1,nd), 256, 0, stream>>>(WP(O_XCT), WP(O_BT), FP(O_DT), FP(O_CA), WP(O_XH));
    // 16. 64-step combine in place -> H
    combk<<<dim3(128,1,nd), 256, 0, stream>>>(WP(O_XH), FP(O_CA), WP(O_XH));
    // 17. per-chunk outputs -> Y in place
    yk2<<<dim3(2048,1,nd), 256, 0, stream>>>(WP(O_BCC), WP(O_XCT), FP(O_DT), FP(O_CA),
                                             WP(O_XH), Dp + d0*8, WP(O_Y));
    // 18. RMSNorm in-place on Y
    rms512<<<dim3(4096,1,nd), 256, 0, stream>>>(WP(O_Y), mng + d0*512);
    // 19. m_out GEMM + s0 residual -> s1 (overlays BCC/XLN)
    a = {}; a.A = WP(O_Y); a.aZ = 8388608; a.lda = 512;
    a.Bw = WP(O_WMOUT) + (size_t)d0*131072; a.bZ = 131072; a.ldb = 512;
    a.bias = moutB + d0*256; a.biasZ = 256;
    a.add = WP(O_S0); a.addZ = 4194304;
    a.C = WP(O_S1); a.cZ = 4194304; a.ldc = 256; a.colOff = 0; a.K = 512;
    gemm_bt<0,3><<<dim3(128,2,nd), 256, 0, stream>>>(a);
    // 20. outp GEMM -> outs (persistent)
    a = {}; a.A = WP(O_S1); a.aZ = 4194304; a.lda = 256;
    a.Bw = WP(O_WOUTP) + (size_t)d0*65536; a.bZ = 65536; a.ldb = 256;
    a.bias = outpB + d0*256; a.biasZ = 256;
    a.C = WP(O_OUTS) + (size_t)d0*4194304; a.cZ = 4194304; a.ldc = 256; a.colOff = 0; a.K = 256;
    gemm_bt<0,0><<<dim3(128,2,nd), 256, 0, stream>>>(a);
  }

  // 21. final inverse-permute average + residual
  finalk<<<4096, 256, 0, stream>>>(curr, WP(O_OUTS), (float*)d_out);

  #undef WP
  #undef FP
}

// Round 7
// 757.428 us; speedup vs baseline: 5.1048x; 1.1315x over previous
//
#include <hip/hip_runtime.h>
#include <hip/hip_bf16.h>
#include <cstdint>
#include <cstddef>

typedef unsigned short u16;
typedef unsigned int u32;
typedef __attribute__((ext_vector_type(8))) __bf16 bfx8;
typedef __attribute__((ext_vector_type(4))) float f32x4;

static __device__ __forceinline__ float bitf(u32 v){ float f; __builtin_memcpy(&f,&v,4); return f; }
static __device__ __forceinline__ float bf2f(u16 v){ return bitf(((u32)v)<<16); }
static __device__ __forceinline__ u16 f2bf(float f){ __bf16 b=(__bf16)f; u16 r; __builtin_memcpy(&r,&b,2); return r; }
static __device__ __forceinline__ u32 pk2(float a,float b){ return (u32)f2bf(a) | ((u32)f2bf(b)<<16); }
static __device__ __forceinline__ void unpk8(uint4 r, float* o){
  o[0]=bitf(r.x<<16); o[1]=bitf(r.x&0xffff0000u);
  o[2]=bitf(r.y<<16); o[3]=bitf(r.y&0xffff0000u);
  o[4]=bitf(r.z<<16); o[5]=bitf(r.z&0xffff0000u);
  o[6]=bitf(r.w<<16); o[7]=bitf(r.w&0xffff0000u);
}
static __device__ __forceinline__ void unpk4(uint2 r, float* o){
  o[0]=bitf(r.x<<16); o[1]=bitf(r.x&0xffff0000u);
  o[2]=bitf(r.y<<16); o[3]=bitf(r.y&0xffff0000u);
}
static __device__ __forceinline__ void async16(void* lds, const void* g){
  __builtin_amdgcn_global_load_lds((const __attribute__((address_space(1))) u32*)g,
                                   (__attribute__((address_space(3))) u32*)lds, 16, 0, 0);
}

// ---------------- GEMM: C[M][N] = A[M][K] @ B[N][K]^T (+ epilogue) -----------
struct GemmArgs {
  const u16* A; long aZ; int lda;
  const u16* Bw; long bZ; int ldb;
  const float* bias; int biasZ;
  const float* scale; const float* shift;
  const u16* add; long addZ;
  u16* C; long cZ; int ldc; int colOff;
  int K;
  const u16* pad;
  int dirBase;
};

template<int AMODE, int EPI>
__global__ __launch_bounds__(256)
void gemm_bt(GemmArgs g)
{
  __shared__ u16 smA[128*64];
  __shared__ u16 smB[128*64];
  const int tid = threadIdx.x;
  const int l = tid & 63;
  const int wv = tid >> 6;
  const int wr = wv >> 1, wc = wv & 1;
  const int z = blockIdx.z;
  const int r0 = blockIdx.x * 128;
  const int n0 = blockIdx.y * 128;

  const u16* Abase = g.A + (size_t)z * g.aZ;
  const u16* Bbase = g.Bw + (size_t)z * g.bZ;
  const int ldb = g.ldb ? g.ldb : g.K;

  f32x4 acc[4][4];
  #pragma unroll
  for (int i=0;i<4;i++)
    #pragma unroll
    for (int j=0;j<4;j++) acc[i][j] = (f32x4){0.f,0.f,0.f,0.f};

  const int nkt = g.K >> 6;
  #pragma unroll 1
  for (int kt=0; kt<nkt; ++kt) {
    const int k0 = kt << 6;
    #pragma unroll
    for (int it=0; it<4; ++it) {
      const int s = it*256 + tid;
      const int row = s >> 3, ch = s & 7;
      const u16* ga;
      if (AMODE == 0) {
        ga = Abase + (size_t)(r0+row) * g.lda + k0 + ch*8;
      } else if (AMODE == 1) {
        int rr = r0 + row; int li = rr & 4095; int bb = rr >> 12;
        int dir = g.dirBase + z;
        int l2 = (dir & 2) ? (4095 - li) : li;
        int sl = (dir & 1) ? (((l2 & 63) << 6) | (l2 >> 6)) : l2;
        ga = Abase + (size_t)((bb << 12) | sl) * g.lda + k0 + ch*8;
      } else if (AMODE == 2) {
        int rr = r0 + row; int bb = rr >> 12; int li = rr & 4095;
        int yy = li >> 6, xx = li & 63;
        int tap = z, kin = k0;
        int dy = tap / 3 - 1, dx = tap % 3 - 1;
        ga = g.pad + (((size_t)(bb*66 + yy+dy+1))*66 + (xx+dx+1))*512 + kin + ch*8;
      } else {
        int rr = r0 + row; int bb = rr >> 12; int li = rr & 4095;
        int yy = li >> 6, xx = li & 63;
        ga = g.pad + (((size_t)(bb*66 + yy+1))*66 + (xx+1))*512 + k0 + ch*8;
      }
      async16(&smA[(size_t)(it*256 + (tid & ~63))*8], ga);
      const u16* gb = Bbase + (size_t)(n0+row) * ldb + k0 + ch*8;
      async16(&smB[(size_t)(it*256 + (tid & ~63))*8], gb);
    }
    __syncthreads();
    #pragma unroll
    for (int kk=0; kk<2; ++kk) {
      bfx8 av[4], bv[4];
      #pragma unroll
      for (int mi=0; mi<4; ++mi) {
        int ra = wr*64 + mi*16 + (l & 15);
        av[mi] = *(const bfx8*)&smA[ra*64 + kk*32 + (l>>4)*8];
      }
      #pragma unroll
      for (int ni=0; ni<4; ++ni) {
        int rb = wc*64 + ni*16 + (l & 15);
        bv[ni] = *(const bfx8*)&smB[rb*64 + kk*32 + (l>>4)*8];
      }
      #pragma unroll
      for (int mi=0; mi<4; ++mi)
        #pragma unroll
        for (int ni=0; ni<4; ++ni)
          acc[mi][ni] = __builtin_amdgcn_mfma_f32_16x16x32_bf16(av[mi], bv[ni], acc[mi][ni], 0, 0, 0);
    }
    __syncthreads();
  }

  const float* bias_d = (EPI == 0 || EPI == 3) ? g.bias + (size_t)z * g.biasZ : nullptr;
  const u16* add_d = (EPI == 3) ? g.add + (size_t)z * g.addZ : nullptr;
  u16* Cd = g.C + (size_t)z * g.cZ;
  float* Cf = (float*)g.C + (size_t)z * g.cZ;
  #pragma unroll
  for (int mi=0; mi<4; ++mi) {
    #pragma unroll
    for (int ni=0; ni<4; ++ni) {
      f32x4 v = acc[mi][ni];
      const int gr = r0 + wr*64 + mi*16 + ((l >> 4) << 2);
      const int gc = n0 + wc*64 + ni*16 + (l & 15);
      #pragma unroll
      for (int q=0; q<4; ++q) {
        const int r = gr + q;
        float x = v[q];
        if (EPI == 2) {
          x = fmaxf(fmaf(x, g.scale[gc], g.shift[gc]), 0.f);
          Cd[(size_t)r * g.ldc + g.colOff + gc] = f2bf(x);
        } else if (EPI == 3) {
          x += bias_d[gc] + bf2f(add_d[(size_t)r * g.ldc + gc]);
          Cd[(size_t)r * g.ldc + g.colOff + gc] = f2bf(x);
        } else if (EPI == 4) {
          Cf[(size_t)r * g.ldc + g.colOff + gc] = x;
        } else {
          x += bias_d[gc];
          Cd[(size_t)r * g.ldc + g.colOff + gc] = f2bf(x);
        }
      }
    }
  }
}

// ---------------- small utility kernels --------------------------------------
__global__ void castk(const float* __restrict__ s, u16* __restrict__ d, int n)
{
  int i = (blockIdx.x*256 + threadIdx.x)*4;
  if (i < n){
    float4 v = *(const float4*)(s+i);
    ushort4 o; o.x=f2bf(v.x); o.y=f2bf(v.y); o.z=f2bf(v.z); o.w=f2bf(v.w);
    *(ushort4*)(d+i) = o;
  }
}

__global__ void c3rep(const float* __restrict__ w, u16* __restrict__ o)
{
  int id = blockIdx.x*256 + threadIdx.x; // 128*4608
  int oc = id / 4608, rem = id % 4608;
  int tap = rem >> 9, ic = rem & 511;
  o[id] = f2bf(w[((size_t)oc*512 + ic)*9 + tap]);
}

__global__ void bnssk(const float* g3,const float* b3,const float* m3,const float* v3,
                      const float* g1,const float* b1,const float* m1,const float* v1,
                      float* out)
{
  int t = threadIdx.x; int i = t & 127;
  if (t < 128){ float sc = g3[i]*rsqrtf(v3[i]+1e-5f); out[i]=sc; out[128+i]=b3[i]-m3[i]*sc; }
  else        { float sc = g1[i]*rsqrtf(v1[i]+1e-5f); out[256+i]=sc; out[384+i]=b1[i]-m1[i]*sc; }
}

// reduce 9 fp32 partials -> BN+ReLU -> bf16 into zin cols 0..127
__global__ __launch_bounds__(256)
void c3red(const float* __restrict__ P, const float* __restrict__ bnss, u16* __restrict__ zin)
{
  const int id = blockIdx.x*256 + threadIdx.x;
  const size_t base = (size_t)id * 4;
  const int r = (int)(base >> 7), c = (int)(base & 127);
  float4 s = {0.f,0.f,0.f,0.f};
  #pragma unroll
  for (int z=0; z<9; ++z){
    float4 v = *(const float4*)(P + (size_t)z*2097152 + base);
    s.x += v.x; s.y += v.y; s.z += v.z; s.w += v.w;
  }
  float4 sc = *(const float4*)(bnss + c);
  float4 sh = *(const float4*)(bnss + 128 + c);
  ushort4 o;
  o.x = f2bf(fmaxf(fmaf(s.x, sc.x, sh.x), 0.f));
  o.y = f2bf(fmaxf(fmaf(s.y, sc.y, sh.y), 0.f));
  o.z = f2bf(fmaxf(fmaf(s.z, sc.z, sh.z), 0.f));
  o.w = f2bf(fmaxf(fmaf(s.w, sc.w, sh.w), 0.f));
  *(ushort4*)(zin + (size_t)r*256 + c) = o;
}

__global__ __launch_bounds__(256)
void padk(const float* __restrict__ curr, const float* __restrict__ prev, u16* __restrict__ pad)
{
  const int id = blockIdx.x*256 + threadIdx.x;
  const int c8 = id & 63;
  int t = id >> 6;
  const int xx = t % 66; t /= 66;
  const int yy = t % 66; const int b = t / 66;
  const int c0 = c8*8;
  uint4 o;
  if (yy==0 || yy==65 || xx==0 || xx==65){ o.x=0;o.y=0;o.z=0;o.w=0; }
  else {
    const int l = (yy-1)*64 + (xx-1);
    const float* s = (c0 < 256) ? curr + ((size_t)b*4096 + l)*256 + c0
                                : prev + ((size_t)b*4096 + l)*256 + (c0-256);
    float4 a = *(const float4*)s, bb = *(const float4*)(s+4);
    o.x = pk2(a.x,a.y); o.y = pk2(a.z,a.w); o.z = pk2(bb.x,bb.y); o.w = pk2(bb.z,bb.w);
  }
  *(uint4*)(pad + (((size_t)b*66 + yy)*66 + xx)*512 + c0) = o;
}

__global__ __launch_bounds__(256)
void ln256(const u16* __restrict__ in, long inZ, u16* __restrict__ out, long outZ,
           const float* __restrict__ gw, const float* __restrict__ bw, int pz)
{
  const int z = blockIdx.z;
  const int row = blockIdx.x*4 + (threadIdx.x>>6);
  const int l = threadIdx.x & 63;
  const u16* ip = in + (size_t)z*inZ + (size_t)row*256 + l*4;
  ushort4 rr = *(const ushort4*)ip;
  float v0=bf2f(rr.x), v1=bf2f(rr.y), v2=bf2f(rr.z), v3=bf2f(rr.w);
  float s = v0+v1+v2+v3;
  float ss = v0*v0+v1*v1+v2*v2+v3*v3;
  #pragma unroll
  for(int m=1;m<64;m<<=1){ s += __shfl_xor(s,m); ss += __shfl_xor(ss,m); }
  float mu = s*(1.f/256.f);
  float var = ss*(1.f/256.f) - mu*mu;
  float rs = rsqrtf(var + 1e-5f);
  const float* g = gw + (size_t)z*pz; const float* b = bw + (size_t)z*pz;
  int c = l*4;
  u16* op = out + (size_t)z*outZ + (size_t)row*256 + c;
  ushort4 o; o.x=f2bf((v0-mu)*rs*g[c]+b[c]); o.y=f2bf((v1-mu)*rs*g[c+1]+b[c+1]);
  o.z=f2bf((v2-mu)*rs*g[c+2]+b[c+2]); o.w=f2bf((v3-mu)*rs*g[c+3]+b[c+3]);
  *(ushort4*)op = o;
}

__global__ __launch_bounds__(256)
void rms512(u16* __restrict__ Y, const float* __restrict__ gw)
{
  const int z = blockIdx.z;
  const int row = blockIdx.x*4 + (threadIdx.x>>6);
  const int l = threadIdx.x & 63;
  u16* p = Y + ((size_t)z*16384 + row)*512 + l*8;
  uint4 raw = *(const uint4*)p;
  float v[8]; unpk8(raw, v);
  float ss = 0.f;
  #pragma unroll
  for (int j=0;j<8;j++) ss += v[j]*v[j];
  #pragma unroll
  for (int m=1;m<64;m<<=1) ss += __shfl_xor(ss, m);
  const float sc = rsqrtf(ss*(1.f/512.f) + 1e-5f);
  const float* g = gw + (size_t)z*512 + l*8;
  uint4 o;
  o.x = pk2(v[0]*sc*g[0], v[1]*sc*g[1]);
  o.y = pk2(v[2]*sc*g[2], v[3]*sc*g[3]);
  o.z = pk2(v[4]*sc*g[4], v[5]*sc*g[5]);
  o.w = pk2(v[6]*sc*g[6], v[7]*sc*g[7]);
  *(uint4*)p = o;
}

// fp32 dt head: dt = softplus(xln.W_dt + b + dt_bias)
__global__ __launch_bounds__(256)
void dtk(const u16* __restrict__ xln, const float* __restrict__ minW,
         const float* __restrict__ minB, const float* __restrict__ dtb,
         float* __restrict__ DT)
{
  __shared__ float sx[32*257];
  const int z = blockIdx.z;
  const int r0 = blockIdx.x * 32;
  const int tid = threadIdx.x;
  {
    const int rr = tid >> 3, cc = (tid & 7) * 32;
    const u16* src = xln + ((size_t)z*16384 + r0 + rr)*256 + cc;
    #pragma unroll
    for (int q=0;q<4;q++){
      uint4 raw = *(const uint4*)(src + q*8);
      float v[8]; unpk8(raw, v);
      #pragma unroll
      for (int j=0;j<8;j++) sx[rr*257 + cc + q*8 + j] = v[j];
    }
  }
  __syncthreads();
  const int ri = tid >> 3, hv = tid & 7;
  const float* wrow = minW + ((size_t)z*1288 + 1280 + hv)*256;
  float acc = 0.f;
  #pragma unroll 4
  for (int k=0; k<256; k+=4){
    float4 wq = *(const float4*)(wrow + k);
    acc += sx[ri*257+k]*wq.x + sx[ri*257+k+1]*wq.y + sx[ri*257+k+2]*wq.z + sx[ri*257+k+3]*wq.w;
  }
  acc += minB[(size_t)z*1288 + 1280 + hv] + dtb[z*8 + hv];
  float dt = (acc > 20.f) ? acc : log1pf(expf(acc));
  DT[((size_t)z*16384 + r0 + ri)*8 + hv] = dt;
}

// chunk-local cumulative log-decay
__global__ __launch_bounds__(256)
void cak(const float* __restrict__ DT, float* __restrict__ CA,
         const float* __restrict__ alog, int dirBase)
{
  const int z = blockIdx.z;
  const int gidx = blockIdx.x*4 + (threadIdx.x>>6);
  const int lane = threadIdx.x & 63;
  const int c = gidx & 63, bh = gidx >> 6;
  const int b = bh >> 3, hh = bh & 7;
  const size_t row = (size_t)z*16384 + (size_t)b*4096 + c*64 + lane;
  float x = DT[row*8 + hh];
  #pragma unroll
  for (int m=1;m<64;m<<=1){ float o = __shfl_up(x, m); if (lane >= m) x += o; }
  float eA = expf(alog[(dirBase+z)*8 + hh]);
  CA[row*8 + hh] = -eA * x;
}

// causal conv1d(4)+SiLU over the B/C columns (raw cols 512..767) -> BCC[row][256]
// weights staged in LDS (global per-element gathers were the R6 bottleneck)
__global__ __launch_bounds__(256)
void convbc(const u16* __restrict__ xbcr, u16* __restrict__ bcc,
            const float* __restrict__ cw, const float* __restrict__ cb)
{
  __shared__ float cwS[4][256];
  __shared__ float cbS[256];
  const int tid = threadIdx.x;
  const int id = blockIdx.x*256 + tid;
  const int c8 = id & 31;
  const int r = (id >> 5) & 16383;
  const int d = id >> 19;
  {
    float4 w4 = *(const float4*)(cw + ((size_t)d*768 + 512 + tid)*4);
    cwS[0][tid]=w4.x; cwS[1][tid]=w4.y; cwS[2][tid]=w4.z; cwS[3][tid]=w4.w;
    cbS[tid] = cb[(size_t)d*768 + 512 + tid];
  }
  __syncthreads();
  const int li = r & 4095;
  const int col = 512 + c8*8;
  const u16* base = xbcr + (size_t)d*16777216 + (size_t)(r - li)*768 + col;
  float acc[8];
  #pragma unroll
  for (int j=0;j<8;j++) acc[j] = cbS[c8*8+j];
  #pragma unroll
  for (int tap=0; tap<4; ++tap){
    int lt = li - 3 + tap;
    if (lt >= 0){
      uint4 raw = *(const uint4*)(base + (size_t)lt*768);
      float v[8]; unpk8(raw, v);
      #pragma unroll
      for (int j=0;j<8;j++)
        acc[j] = fmaf(v[j], cwS[tap][c8*8+j], acc[j]);
    }
  }
  uint4 o;
  float s[8];
  #pragma unroll
  for (int j=0;j<8;j++) s[j] = acc[j] / (1.f + __expf(-acc[j]));
  o.x = pk2(s[0],s[1]); o.y = pk2(s[2],s[3]); o.z = pk2(s[4],s[5]); o.w = pk2(s[6],s[7]);
  *(uint4*)(bcc + ((size_t)d*16384 + r)*256 + c8*8) = o;
}

// conv1d(4)+SiLU on X cols (raw 0..511) + transpose -> XCT[p][g]
__global__ __launch_bounds__(256)
void convx(const u16* __restrict__ xbcr, u16* __restrict__ xct,
           const float* __restrict__ cw, const float* __restrict__ cb)
{
  __shared__ u16 T[128*72];
  __shared__ float cwX[4][128];
  __shared__ float cbX[128];
  const int bx = blockIdx.x, z = blockIdx.z;
  const int pq = bx & 3, c = (bx>>2) & 63, b = bx >> 8;
  const int tid = threadIdx.x;
  const u16* xb = xbcr + (size_t)z*16777216 + (size_t)b*4096*768;
  if (tid < 128){
    float4 w4 = *(const float4*)(cw + (size_t)z*3072 + (pq*128+tid)*4);
    cwX[0][tid]=w4.x; cwX[1][tid]=w4.y; cwX[2][tid]=w4.z; cwX[3][tid]=w4.w;
    cbX[tid] = cb[z*768 + pq*128 + tid];
  }
  __syncthreads();
  #pragma unroll
  for (int u=0; u<4; ++u){
    int idx = u*256 + tid;
    int s = idx >> 4, seg = idx & 15;
    int li = c*64 + s;
    int col = pq*128 + seg*8;
    float acc[8];
    #pragma unroll
    for (int j=0;j<8;j++) acc[j] = cbX[seg*8+j];
    #pragma unroll
    for (int tap=0; tap<4; ++tap){
      int lt = li - 3 + tap;
      if (lt >= 0){
        uint4 raw = *(const uint4*)(xb + (size_t)lt*768 + col);
        float v[8]; unpk8(raw, v);
        #pragma unroll
        for (int j=0;j<8;j++) acc[j] = fmaf(v[j], cwX[tap][seg*8+j], acc[j]);
      }
    }
    #pragma unroll
    for (int j=0;j<8;j++)
      T[(seg*8+j)*72 + s] = f2bf(acc[j] / (1.f + __expf(-acc[j])));
  }
  __syncthreads();
  #pragma unroll
  for (int u=0; u<4; ++u){
    int idx = u*256 + tid;
    int pl = idx >> 3, sg = idx & 7;
    uint4 v = *(const uint4*)&T[pl*72 + sg*8];
    *(uint4*)(xct + (size_t)z*8388608 + (size_t)(pq*128+pl)*16384 + b*4096 + c*64 + sg*8) = v;
  }
}

// transpose conv'd B (BCC cols 0..127) -> BT[n][g]; grid (256,1,nd)
__global__ __launch_bounds__(256)
void btk(const u16* __restrict__ bcc, u16* __restrict__ bt)
{
  __shared__ u16 T[128*72];
  const int bx = blockIdx.x, z = blockIdx.z;
  const int c = bx & 63, b = bx >> 6;
  const int tid = threadIdx.x;
  const u16* src = bcc + ((size_t)z*16384 + (size_t)b*4096 + c*64)*256;
  #pragma unroll
  for (int u=0; u<4; ++u){
    int idx = u*256 + tid;
    int s = idx >> 4, seg = idx & 15;
    uint4 raw = *(const uint4*)(src + (size_t)s*256 + seg*8);
    u16 t8[8]; *(uint4*)t8 = raw;
    #pragma unroll
    for (int j=0;j<8;j++) T[(seg*8+j)*72 + s] = t8[j];
  }
  __syncthreads();
  #pragma unroll
  for (int u=0; u<4; ++u){
    int idx = u*256 + tid;
    int n = idx >> 3, sg = idx & 7;
    uint4 v = *(const uint4*)&T[n*72 + sg*8];
    *(uint4*)(bt + (size_t)z*2097152 + (size_t)n*16384 + b*4096 + c*64 + sg*8) = v;
  }
}

// per-chunk outer products, all heads fused: CS[p][n] = sum_s (w[s,h]*X^T[p][s])*B^T[n][s]
__global__ __launch_bounds__(256)
void csk(const u16* __restrict__ xct, const u16* __restrict__ bt,
         const float* __restrict__ DT, const float* __restrict__ CA,
         u16* __restrict__ CS)
{
  __shared__ u16 Xw[256*72];
  __shared__ u16 Bt[128*72];
  __shared__ float wS[64*8];
  const int bx = blockIdx.x, z = blockIdx.z;
  const int ph = bx & 1, c = (bx>>1) & 63, b = bx >> 7;
  const int tid = threadIdx.x, l = tid & 63, w = tid >> 6;
  const size_t rowb = (size_t)z*16384 + (size_t)b*4096;
  const int p0 = ph*256;
  {
    int s = tid & 63, h0 = tid >> 6;
    #pragma unroll
    for (int hh=h0; hh<8; hh+=4){
      float ca63 = CA[(rowb + c*64 + 63)*8 + hh];
      float cav  = CA[(rowb + c*64 + s)*8 + hh];
      float dtv  = DT[(rowb + c*64 + s)*8 + hh];
      wS[s*8+hh] = __expf(ca63 - cav) * dtv;
    }
  }
  __syncthreads();
  #pragma unroll
  for (int u=0; u<8; ++u){
    int idx = u*256 + tid;
    int pl = idx >> 3, sg = idx & 7;
    int gp = p0 + pl; int hh = gp >> 6;
    uint4 raw = *(const uint4*)(xct + (size_t)z*8388608 + (size_t)gp*16384 + b*4096 + c*64 + sg*8);
    float v[8]; unpk8(raw, v);
    uint4 o;
    o.x = pk2(v[0]*wS[(sg*8+0)*8+hh], v[1]*wS[(sg*8+1)*8+hh]);
    o.y = pk2(v[2]*wS[(sg*8+2)*8+hh], v[3]*wS[(sg*8+3)*8+hh]);
    o.z = pk2(v[4]*wS[(sg*8+4)*8+hh], v[5]*wS[(sg*8+5)*8+hh]);
    o.w = pk2(v[6]*wS[(sg*8+6)*8+hh], v[7]*wS[(sg*8+7)*8+hh]);
    *(uint4*)&Xw[pl*72 + sg*8] = o;
  }
  #pragma unroll
  for (int u=0; u<4; ++u){
    int idx = u*256 + tid;
    int n = idx >> 3, sg = idx & 7;
    *(uint4*)&Bt[n*72 + sg*8] =
      *(const uint4*)(bt + (size_t)z*2097152 + (size_t)n*16384 + b*4096 + c*64 + sg*8);
  }
  __syncthreads();
  f32x4 acc[8][4];
  #pragma unroll
  for (int i=0;i<8;i++)
    #pragma unroll
    for (int j=0;j<4;j++) acc[i][j] = (f32x4){0.f,0.f,0.f,0.f};
  #pragma unroll
  for (int kk=0; kk<2; ++kk){
    bfx8 bvp[4];
    #pragma unroll
    for (int ni=0; ni<4; ++ni)
      bvp[ni] = *(const bfx8*)&Xw[(w*64 + ni*16 + (l&15))*72 + kk*32 + (l>>4)*8];
    #pragma unroll
    for (int mi=0; mi<8; ++mi){
      bfx8 av = *(const bfx8*)&Bt[(mi*16 + (l&15))*72 + kk*32 + (l>>4)*8];
      #pragma unroll
      for (int ni=0; ni<4; ++ni)
        acc[mi][ni] = __builtin_amdgcn_mfma_f32_16x16x32_bf16(av, bvp[ni], acc[mi][ni], 0, 0, 0);
    }
  }
  #pragma unroll
  for (int mi=0; mi<8; ++mi){
    #pragma unroll
    for (int ni=0; ni<4; ++ni){
      int gp = p0 + w*64 + ni*16 + (l&15);
      int bhx = b*8 + (gp>>6); int pin = gp & 63;
      int n0 = mi*16 + ((l>>4)<<2);
      u32* cp = (u32*)&CS[(size_t)z*16777216 + (size_t)bhx*524288 + (size_t)c*8192 + (size_t)pin*128 + n0];
      cp[0] = pk2(acc[mi][ni][0], acc[mi][ni][1]);
      cp[1] = pk2(acc[mi][ni][2], acc[mi][ni][3]);
    }
  }
}

// sequential 64-step combine IN PLACE (H aliases CS); 2x n-split for occupancy
// grid (256, 1, nd)
__global__ __launch_bounds__(256)
void combk(const u16* __restrict__ CS, const float* __restrict__ CA,
           u16* __restrict__ H)
{
  __shared__ float aL[64];
  const int bx = blockIdx.x;
  const int z = blockIdx.z;
  const int nh = bx & 1, pg = (bx >> 1) & 3, bh = bx >> 3;
  const int b = bh >> 3, hh = bh & 7;
  const int tid = threadIdx.x;
  const int p = pg*16 + (tid >> 4), n = nh*64 + (tid & 15)*4;
  const size_t rowb = (size_t)z*16384 + (size_t)b*4096;
  if (tid < 64) aL[tid] = __expf(CA[(rowb + tid*64 + 63)*8 + hh]);
  __syncthreads();
  const u16* Cs = CS + (size_t)z*16777216 + (size_t)bh*524288 + (size_t)p*128 + n;
  u16* Hd = H + (size_t)z*16777216 + (size_t)bh*524288 + (size_t)p*128 + n;
  float h[4];
  #pragma unroll
  for (int j=0;j<4;j++) h[j]=0.f;
  uint2 pf = *(const uint2*)Cs;
  #pragma unroll 1
  for (int c=0; c<64; ++c){
    uint2 cur = pf;
    if (c < 63) pf = *(const uint2*)(Cs + (size_t)(c+1)*8192);
    uint2 o;
    o.x = pk2(h[0],h[1]); o.y = pk2(h[2],h[3]);
    *(uint2*)(Hd + (size_t)c*8192) = o;
    float v[4]; unpk4(cur, v);
    const float a = aL[c];
    #pragma unroll
    for (int j=0;j<4;j++) h[j] = fmaf(h[j], a, v[j]);
  }
}

// per-chunk output: Y = (S_decayed @ X + diag(exp(ca)) * (C @ H[c]) + Dh*x) * silu(z)
__global__ __launch_bounds__(256)
void yk2(const u16* __restrict__ bcc, const u16* __restrict__ xct,
         const float* __restrict__ DT, const float* __restrict__ CA,
         const u16* __restrict__ H, const float* __restrict__ Dp,
         u16* __restrict__ Y)
{
  __shared__ u16 Bc[64*264];
  __shared__ u16 Hs[64*136];
  __shared__ u16 Xt[64*72];
  __shared__ u16 Sm[64*72];
  __shared__ float caL[64], dtL[64];
  const int bx = blockIdx.x, z = blockIdx.z;
  const int c = bx & 63, bh = bx >> 6;
  const int b = bh >> 3, hh = bh & 7;
  const int tid = threadIdx.x, l = tid & 63, w = tid >> 6;
  const size_t rowb = (size_t)z*16384 + (size_t)b*4096;
  const u16* bcp = bcc + (rowb + c*64)*256;
  const u16* Hd = H + (size_t)z*16777216 + (size_t)bh*524288 + (size_t)c*8192;
  const u16* xcp = xct + (size_t)z*8388608 + (size_t)(hh*64)*16384 + b*4096 + c*64;
  const float Dh = Dp[z*8 + hh];
  if (tid < 64){
    caL[tid] = CA[(rowb + c*64 + tid)*8 + hh];
    dtL[tid] = DT[(rowb + c*64 + tid)*8 + hh];
  }
  #pragma unroll
  for (int u=0; u<8; ++u){
    int idx = u*256 + tid; int s = idx >> 5, sg = idx & 31;
    *(uint4*)&Bc[s*264 + sg*8] = *(const uint4*)(bcp + (size_t)s*256 + sg*8);
  }
  #pragma unroll
  for (int u=0; u<4; ++u){
    int idx = u*256 + tid; int p = idx >> 4, sg = idx & 15;
    *(uint4*)&Hs[p*136 + sg*8] = *(const uint4*)(Hd + (size_t)p*128 + sg*8);
  }
  #pragma unroll
  for (int u=0; u<2; ++u){
    int idx = u*256 + tid; int p = idx >> 3, sg = idx & 7;
    *(uint4*)&Xt[p*72 + sg*8] = *(const uint4*)(xcp + (size_t)p*16384 + sg*8);
  }
  __syncthreads();

  f32x4 sacc[4], acc2[4];
  #pragma unroll
  for (int i=0;i<4;i++){ sacc[i] = (f32x4){0.f,0.f,0.f,0.f}; acc2[i] = (f32x4){0.f,0.f,0.f,0.f}; }
  #pragma unroll
  for (int kk=0; kk<4; ++kk){
    bfx8 av = *(const bfx8*)&Bc[(w*16 + (l&15))*264 + 128 + kk*32 + (l>>4)*8];
    #pragma unroll
    for (int st=0; st<4; ++st){
      bfx8 bv = *(const bfx8*)&Bc[(st*16 + (l&15))*264 + kk*32 + (l>>4)*8];
      sacc[st] = __builtin_amdgcn_mfma_f32_16x16x32_bf16(av, bv, sacc[st], 0, 0, 0);
      bfx8 hv = *(const bfx8*)&Hs[(st*16 + (l&15))*136 + kk*32 + (l>>4)*8];
      acc2[st] = __builtin_amdgcn_mfma_f32_16x16x32_bf16(av, hv, acc2[st], 0, 0, 0);
    }
  }
  #pragma unroll
  for (int st=0; st<4; ++st){
    #pragma unroll
    for (int q=0;q<4;q++){
      int t = w*16 + (l>>4)*4 + q;
      int s = st*16 + (l&15);
      float m = (s <= t) ? __expf(caL[t]-caL[s]) * dtL[s] : 0.f;
      Sm[t*72 + s] = f2bf(sacc[st][q] * m);
    }
  }
  #pragma unroll
  for (int pt=0; pt<4; ++pt)
    #pragma unroll
    for (int q=0;q<4;q++){
      int t = w*16 + (l>>4)*4 + q;
      acc2[pt][q] *= __expf(caL[t]);
    }
  __syncthreads();
  #pragma unroll
  for (int kk=0; kk<2; ++kk){
    bfx8 av = *(const bfx8*)&Sm[(w*16 + (l&15))*72 + kk*32 + (l>>4)*8];
    #pragma unroll
    for (int pt=0; pt<4; ++pt){
      bfx8 bv = *(const bfx8*)&Xt[(pt*16 + (l&15))*72 + kk*32 + (l>>4)*8];
      acc2[pt] = __builtin_amdgcn_mfma_f32_16x16x32_bf16(av, bv, acc2[pt], 0, 0, 0);
    }
  }
  u16* Yrow = Y + (rowb + c*64)*512 + hh*64;
  #pragma unroll
  for (int pt=0; pt<4; ++pt){
    #pragma unroll
    for (int q=0;q<4;q++){
      int t = w*16 + (l>>4)*4 + q;
      int p = pt*16 + (l&15);
      float xv = bf2f(Xt[p*72 + t]);
      float zf = bf2f(Yrow[(size_t)t*512 + p]);
      float yv = (acc2[pt][q] + Dh*xv) * (zf/(1.f+__expf(-zf)));
      Yrow[(size_t)t*512 + p] = f2bf(yv);
    }
  }
}

__global__ __launch_bounds__(256)
void finalk(const float* __restrict__ curr, const u16* __restrict__ outs, float* __restrict__ o)
{
  const int row = blockIdx.x*4 + (threadIdx.x>>6);
  const int c4 = (threadIdx.x & 63)*4;
  const int b = row >> 12, li = row & 4095;
  const int T = ((li & 63) << 6) | (li >> 6);
  const size_t rb = (size_t)b*4096;
  const ushort4 a0 = *(const ushort4*)(outs + (size_t)0*4194304 + ((rb+li)*256 + c4));
  const ushort4 a1 = *(const ushort4*)(outs + (size_t)1*4194304 + ((rb+T)*256 + c4));
  const ushort4 a2 = *(const ushort4*)(outs + (size_t)2*4194304 + ((rb+4095-li)*256 + c4));
  const ushort4 a3 = *(const ushort4*)(outs + (size_t)3*4194304 + ((rb+4095-T)*256 + c4));
  float4 cv = *(const float4*)(curr + (size_t)row*256 + c4);
  float4 r;
  r.x = cv.x + 0.25f*(bf2f(a0.x)+bf2f(a1.x)+bf2f(a2.x)+bf2f(a3.x));
  r.y = cv.y + 0.25f*(bf2f(a0.y)+bf2f(a1.y)+bf2f(a2.y)+bf2f(a3.y));
  r.z = cv.z + 0.25f*(bf2f(a0.z)+bf2f(a1.z)+bf2f(a2.z)+bf2f(a3.z));
  r.w = cv.w + 0.25f*(bf2f(a0.w)+bf2f(a1.w)+bf2f(a2.w)+bf2f(a3.w));
  *(float4*)(o + (size_t)row*256 + c4) = r;
}

// ---------------------------------------------------------------------------
extern "C" void kernel_launch(void* const* d_in, const int* in_sizes, int n_in,
                              void* d_out, int out_size, void* d_ws, size_t ws_size,
                              hipStream_t stream)
{
  (void)in_sizes; (void)n_in; (void)out_size;
  const float* curr   = (const float*)d_in[0];
  const float* prev   = (const float*)d_in[1];
  const float* conv3w = (const float*)d_in[2];
  const float* bn3g=(const float*)d_in[3], *bn3b=(const float*)d_in[4], *bn3m=(const float*)d_in[5], *bn3v=(const float*)d_in[6];
  const float* conv1w = (const float*)d_in[7];
  const float* bn1g=(const float*)d_in[8], *bn1b=(const float*)d_in[9], *bn1m=(const float*)d_in[10], *bn1v=(const float*)d_in[11];
  const float* fuseW=(const float*)d_in[12], *fuseB=(const float*)d_in[13];
  const float* lng=(const float*)d_in[14], *lnb=(const float*)d_in[15];
  const float* inpW=(const float*)d_in[16], *inpB=(const float*)d_in[17];
  const float* mlng=(const float*)d_in[18], *mlnb=(const float*)d_in[19];
  const float* minW=(const float*)d_in[20], *minB=(const float*)d_in[21];
  const float* cw=(const float*)d_in[22], *cb=(const float*)d_in[23];
  const float* alog=(const float*)d_in[24], *Dp=(const float*)d_in[25], *dtb=(const float*)d_in[26];
  const float* mng=(const float*)d_in[27];
  const float* moutW=(const float*)d_in[28], *moutB=(const float*)d_in[29];
  const float* outpW=(const float*)d_in[30], *outpB=(const float*)d_in[31];

  // ---- persistent layout ----
  char* ws = (char*)d_ws;
  size_t off = 0;
  auto alloc = [&](size_t bytes){ size_t o = off; off = (off + bytes + 1023) & ~(size_t)1023; return o; };
  const size_t O_WFUSE = alloc((size_t)256*256*2);
  const size_t O_WINP  = alloc((size_t)4*256*256*2);
  const size_t O_WMIN  = alloc((size_t)4*1288*256*2);
  const size_t O_WMOUT = alloc((size_t)4*256*512*2);
  const size_t O_WOUTP = alloc((size_t)4*256*256*2);
  const size_t O_WC3   = alloc((size_t)128*4608*2);
  const size_t O_WC1   = alloc((size_t)128*512*2);
  const size_t O_BNSS  = alloc(512*4);
  const size_t O_ZF    = alloc((size_t)16384*256*2);
  const size_t O_OUTS  = alloc((size_t)4*16384*256*2);
  const size_t O_P     = off;

  // per-dir sizes (bytes)
  const size_t S0d  = (size_t)16384*256*2;
  const size_t XLNd = (size_t)16384*256*2;
  const size_t Yd   = (size_t)16384*512*2;
  const size_t XCTd = (size_t)512*16384*2;
  const size_t BTd  = (size_t)128*16384*2;
  const size_t DTd  = (size_t)16384*8*4;
  const size_t CAd  = (size_t)16384*8*4;
  const size_t XHd  = (size_t)16777216*2;
  const size_t perdir = S0d + XLNd + Yd + XCTd + BTd + DTd + CAd + XHd;

  const size_t PADsz = (size_t)4*66*66*512*2;
  const size_t CPsz  = (size_t)9*16384*128*4;
  const size_t PREsz = PADsz + CPsz + (size_t)16384*256*2*2 + 4096;

  int nd = 0;
  for (int cand = 4; cand >= 1; cand >>= 1) {
    size_t need = (size_t)cand*perdir; if (need < PREsz) need = PREsz;
    if (O_P + need <= ws_size) { nd = cand; break; }
  }
  if (nd == 0) return;

  #define WP(o) ((u16*)(ws + (o)))
  #define FP(o) ((float*)(ws + (o)))

  const size_t O_PAD = O_P;
  const size_t O_CP  = O_PAD + PADsz;
  const size_t O_ZIN = O_CP + CPsz;
  const size_t O_ZFT = O_ZIN + (size_t)16384*256*2;

  // 1. BN scale/shift + weight conversions
  bnssk<<<1, 256, 0, stream>>>(bn3g,bn3b,bn3m,bn3v, bn1g,bn1b,bn1m,bn1v, FP(O_BNSS));
  castk<<<64, 256, 0, stream>>>(fuseW, WP(O_WFUSE), 65536);
  castk<<<256, 256, 0, stream>>>(inpW, WP(O_WINP), 262144);
  castk<<<1288, 256, 0, stream>>>(minW, WP(O_WMIN), 1318912);
  castk<<<512, 256, 0, stream>>>(moutW, WP(O_WMOUT), 524288);
  castk<<<256, 256, 0, stream>>>(outpW, WP(O_WOUTP), 262144);
  castk<<<64, 256, 0, stream>>>(conv1w, WP(O_WC1), 65536);
  c3rep<<<2304, 256, 0, stream>>>(conv3w, WP(O_WC3));
  // 2. padded concat input (bf16)
  padk<<<4356, 256, 0, stream>>>(curr, prev, WP(O_PAD));

  GemmArgs a;
  // 3. conv3 split-K over 9 taps -> fp32 partials -> reduce+BN+ReLU
  a = {}; a.A = WP(O_PAD); a.pad = WP(O_PAD);
  a.Bw = WP(O_WC3); a.bZ = 512; a.ldb = 4608;
  a.C = WP(O_CP); a.cZ = 2097152; a.ldc = 128; a.colOff = 0; a.K = 512;
  gemm_bt<2,4><<<dim3(128,1,9), 256, 0, stream>>>(a);
  c3red<<<2048, 256, 0, stream>>>(FP(O_CP), FP(O_BNSS), WP(O_ZIN));
  // 4. conv1 -> zin[:,128:256]
  a = {}; a.A = WP(O_PAD); a.pad = WP(O_PAD); a.Bw = WP(O_WC1); a.bZ = 0; a.ldb = 512;
  a.scale = FP(O_BNSS)+256; a.shift = FP(O_BNSS)+384;
  a.C = WP(O_ZIN); a.cZ = 0; a.ldc = 256; a.colOff = 128; a.K = 512;
  gemm_bt<3,2><<<dim3(128,1,1), 256, 0, stream>>>(a);
  // 5. fuse GEMM -> zft
  a = {}; a.A = WP(O_ZIN); a.aZ = 0; a.lda = 256; a.Bw = WP(O_WFUSE); a.bZ = 0; a.ldb = 256;
  a.bias = fuseB; a.biasZ = 0; a.C = WP(O_ZFT); a.cZ = 0; a.ldc = 256; a.colOff = 0; a.K = 256;
  gemm_bt<0,0><<<dim3(128,2,1), 256, 0, stream>>>(a);
  // 6. LN -> zf (persistent)
  ln256<<<dim3(4096,1,1), 256, 0, stream>>>(WP(O_ZFT), 0, WP(O_ZF), 0, lng, lnb, 0);

  // ---- phases over directions ----
  for (int d0 = 0; d0 < 4; d0 += nd) {
    size_t o = O_P;
    const size_t O_S0  = o; o += (size_t)nd*S0d;
    const size_t O_XLN = o; o += (size_t)nd*XLNd;
    const size_t O_Y   = o; o += (size_t)nd*Yd;
    const size_t O_XCT = o; o += (size_t)nd*XCTd;
    const size_t O_BT  = o; o += (size_t)nd*BTd;
    const size_t O_DT  = o; o += (size_t)nd*DTd;
    const size_t O_CA  = o; o += (size_t)nd*CAd;
    const size_t O_XH  = o;
    const size_t O_BCC = O_XLN;
    const size_t O_S1  = O_XLN;

    // 7. inp GEMM (permuted rows per dir) -> s0
    a = {}; a.A = WP(O_ZF); a.aZ = 0; a.lda = 256;
    a.Bw = WP(O_WINP) + (size_t)d0*65536; a.bZ = 65536; a.ldb = 256;
    a.bias = inpB + d0*256; a.biasZ = 256;
    a.C = WP(O_S0); a.cZ = 4194304; a.ldc = 256; a.colOff = 0; a.K = 256; a.dirBase = d0;
    gemm_bt<1,0><<<dim3(128,2,nd), 256, 0, stream>>>(a);
    // 8. per-dir LN(s0) -> xln
    ln256<<<dim3(4096,1,nd), 256, 0, stream>>>(WP(O_S0), 4194304, WP(O_XLN), 4194304,
                                               mlng + d0*256, mlnb + d0*256, 256);
    // 9. dt, chunk log-decay
    dtk<<<dim3(512,1,nd), 256, 0, stream>>>(WP(O_XLN), minW + (size_t)d0*329728,
                                            minB + d0*1288, dtb + d0*8, FP(O_DT));
    cak<<<dim3(512,1,nd), 256, 0, stream>>>(FP(O_DT), FP(O_CA), alog, d0);
    // 10. z-gate GEMM -> Y
    a = {}; a.A = WP(O_XLN); a.aZ = 4194304; a.lda = 256;
    a.Bw = WP(O_WMIN) + (size_t)d0*329728; a.bZ = 329728; a.ldb = 256;
    a.bias = minB + d0*1288; a.biasZ = 1288;
    a.C = WP(O_Y); a.cZ = 8388608; a.ldc = 512; a.colOff = 0; a.K = 256;
    gemm_bt<0,0><<<dim3(128,4,nd), 256, 0, stream>>>(a);
    // 11. xBC GEMM -> raw xbc (padded per-dir stride)   [last reader of XLN]
    a = {}; a.A = WP(O_XLN); a.aZ = 4194304; a.lda = 256;
    a.Bw = WP(O_WMIN) + (size_t)d0*329728 + (size_t)512*256; a.bZ = 329728; a.ldb = 256;
    a.bias = minB + d0*1288 + 512; a.biasZ = 1288;
    a.C = WP(O_XH); a.cZ = 16777216; a.ldc = 768; a.colOff = 0; a.K = 256;
    gemm_bt<0,0><<<dim3(128,6,nd), 256, 0, stream>>>(a);
    // 12. conv1d+SiLU on B/C -> BCC (overlays XLN)
    convbc<<<nd*2048, 256, 0, stream>>>(WP(O_XH), WP(O_BCC), cw + d0*3072, cb + d0*768);
    // 13. conv1d+SiLU+transpose X -> XCT
    convx<<<dim3(1024,1,nd), 256, 0, stream>>>(WP(O_XH), WP(O_XCT), cw + d0*3072, cb + d0*768);
    // 14. transpose conv'd B -> BT
    btk<<<dim3(256,1,nd), 256, 0, stream>>>(WP(O_BCC), WP(O_BT));
    // 15. per-chunk outer products (all heads) -> CS (overlays raw xbc)
    csk<<<dim3(512,1,nd), 256, 0, stream>>>(WP(O_XCT), WP(O_BT), FP(O_DT), FP(O_CA), WP(O_XH));
    // 16. 64-step combine in place -> H
    combk<<<dim3(256,1,nd), 256, 0, stream>>>(WP(O_XH), FP(O_CA), WP(O_XH));
    // 17. per-chunk outputs -> Y in place
    yk2<<<dim3(2048,1,nd), 256, 0, stream>>>(WP(O_BCC), WP(O_XCT), FP(O_DT), FP(O_CA),
                                             WP(O_XH), Dp + d0*8, WP(O_Y));
    // 18. RMSNorm in-place on Y
    rms512<<<dim3(4096,1,nd), 256, 0, stream>>>(WP(O_Y), mng + d0*512);
    // 19. m_out GEMM + s0 residual -> s1 (overlays BCC/XLN)
    a = {}; a.A = WP(O_Y); a.aZ = 8388608; a.lda = 512;
    a.Bw = WP(O_WMOUT) + (size_t)d0*131072; a.bZ = 131072; a.ldb = 512;
    a.bias = moutB + d0*256; a.biasZ = 256;
    a.add = WP(O_S0); a.addZ = 4194304;
    a.C = WP(O_S1); a.cZ = 4194304; a.ldc = 256; a.colOff = 0; a.K = 512;
    gemm_bt<0,3><<<dim3(128,2,nd), 256, 0, stream>>>(a);
    // 20. outp GEMM -> outs (persistent)
    a = {}; a.A = WP(O_S1); a.aZ = 4194304; a.lda = 256;
    a.Bw = WP(O_WOUTP) + (size_t)d0*65536; a.bZ = 65536; a.ldb = 256;
    a.bias = outpB + d0*256; a.biasZ = 256;
    a.C = WP(O_OUTS) + (size_t)d0*4194304; a.cZ = 4194304; a.ldc = 256; a.colOff = 0; a.K = 256;
    gemm_bt<0,0><<<dim3(128,2,nd), 256, 0, stream>>>(a);
  }

  // 21. final inverse-permute average + residual
  finalk<<<4096, 256, 0, stream>>>(curr, WP(O_OUTS), (float*)d_out);

  #undef WP
  #undef FP
}

// Round 8
// 730.710 us; speedup vs baseline: 5.2914x; 1.0366x over previous
//
#include <hip/hip_runtime.h>
#include <hip/hip_bf16.h>
#include <cstdint>
#include <cstddef>

typedef unsigned short u16;
typedef unsigned int u32;
typedef __attribute__((ext_vector_type(8))) __bf16 bfx8;
typedef __attribute__((ext_vector_type(4))) float f32x4;

static __device__ __forceinline__ float bitf(u32 v){ float f; __builtin_memcpy(&f,&v,4); return f; }
static __device__ __forceinline__ float bf2f(u16 v){ return bitf(((u32)v)<<16); }
static __device__ __forceinline__ u16 f2bf(float f){ __bf16 b=(__bf16)f; u16 r; __builtin_memcpy(&r,&b,2); return r; }
static __device__ __forceinline__ u32 pk2(float a,float b){ return (u32)f2bf(a) | ((u32)f2bf(b)<<16); }
static __device__ __forceinline__ void unpk8(uint4 r, float* o){
  o[0]=bitf(r.x<<16); o[1]=bitf(r.x&0xffff0000u);
  o[2]=bitf(r.y<<16); o[3]=bitf(r.y&0xffff0000u);
  o[4]=bitf(r.z<<16); o[5]=bitf(r.z&0xffff0000u);
  o[6]=bitf(r.w<<16); o[7]=bitf(r.w&0xffff0000u);
}
static __device__ __forceinline__ void unpk4(uint2 r, float* o){
  o[0]=bitf(r.x<<16); o[1]=bitf(r.x&0xffff0000u);
  o[2]=bitf(r.y<<16); o[3]=bitf(r.y&0xffff0000u);
}
static __device__ __forceinline__ void async16(void* lds, const void* g){
  __builtin_amdgcn_global_load_lds((const __attribute__((address_space(1))) u32*)g,
                                   (__attribute__((address_space(3))) u32*)lds, 16, 0, 0);
}

// ---------------- GEMM: C[M][N] = A[M][K] @ B[N][K]^T (+ epilogue) -----------
struct GemmArgs {
  const u16* A; long aZ; int lda;
  const u16* Bw; long bZ; int ldb;
  const float* bias; int biasZ;
  const float* scale; const float* shift;
  const u16* add; long addZ;
  u16* C; long cZ; int ldc; int colOff;
  int K;
  const u16* pad;
  int dirBase;
};

template<int AMODE, int EPI>
__global__ __launch_bounds__(256)
void gemm_bt(GemmArgs g)
{
  __shared__ u16 smA[128*64];
  __shared__ u16 smB[128*64];
  const int tid = threadIdx.x;
  const int l = tid & 63;
  const int wv = tid >> 6;
  const int wr = wv >> 1, wc = wv & 1;
  const int z = blockIdx.z;
  const int r0 = blockIdx.x * 128;
  const int n0 = blockIdx.y * 128;

  const u16* Abase = g.A + (size_t)z * g.aZ;
  const u16* Bbase = g.Bw + (size_t)z * g.bZ;
  const int ldb = g.ldb ? g.ldb : g.K;

  f32x4 acc[4][4];
  #pragma unroll
  for (int i=0;i<4;i++)
    #pragma unroll
    for (int j=0;j<4;j++) acc[i][j] = (f32x4){0.f,0.f,0.f,0.f};

  const int nkt = g.K >> 6;
  #pragma unroll 1
  for (int kt=0; kt<nkt; ++kt) {
    const int k0 = kt << 6;
    #pragma unroll
    for (int it=0; it<4; ++it) {
      const int s = it*256 + tid;
      const int row = s >> 3, ch = s & 7;
      const u16* ga;
      if (AMODE == 0) {
        ga = Abase + (size_t)(r0+row) * g.lda + k0 + ch*8;
      } else if (AMODE == 1) {
        int rr = r0 + row; int li = rr & 4095; int bb = rr >> 12;
        int dir = g.dirBase + z;
        int l2 = (dir & 2) ? (4095 - li) : li;
        int sl = (dir & 1) ? (((l2 & 63) << 6) | (l2 >> 6)) : l2;
        ga = Abase + (size_t)((bb << 12) | sl) * g.lda + k0 + ch*8;
      } else if (AMODE == 2) {
        int rr = r0 + row; int bb = rr >> 12; int li = rr & 4095;
        int yy = li >> 6, xx = li & 63;
        int tap = z, kin = k0;
        int dy = tap / 3 - 1, dx = tap % 3 - 1;
        ga = g.pad + (((size_t)(bb*66 + yy+dy+1))*66 + (xx+dx+1))*512 + kin + ch*8;
      } else {
        int rr = r0 + row; int bb = rr >> 12; int li = rr & 4095;
        int yy = li >> 6, xx = li & 63;
        ga = g.pad + (((size_t)(bb*66 + yy+1))*66 + (xx+1))*512 + k0 + ch*8;
      }
      async16(&smA[(size_t)(it*256 + (tid & ~63))*8], ga);
      const u16* gb = Bbase + (size_t)(n0+row) * ldb + k0 + ch*8;
      async16(&smB[(size_t)(it*256 + (tid & ~63))*8], gb);
    }
    __syncthreads();
    #pragma unroll
    for (int kk=0; kk<2; ++kk) {
      bfx8 av[4], bv[4];
      #pragma unroll
      for (int mi=0; mi<4; ++mi) {
        int ra = wr*64 + mi*16 + (l & 15);
        av[mi] = *(const bfx8*)&smA[ra*64 + kk*32 + (l>>4)*8];
      }
      #pragma unroll
      for (int ni=0; ni<4; ++ni) {
        int rb = wc*64 + ni*16 + (l & 15);
        bv[ni] = *(const bfx8*)&smB[rb*64 + kk*32 + (l>>4)*8];
      }
      #pragma unroll
      for (int mi=0; mi<4; ++mi)
        #pragma unroll
        for (int ni=0; ni<4; ++ni)
          acc[mi][ni] = __builtin_amdgcn_mfma_f32_16x16x32_bf16(av[mi], bv[ni], acc[mi][ni], 0, 0, 0);
    }
    __syncthreads();
  }

  const float* bias_d = (EPI == 0 || EPI == 3) ? g.bias + (size_t)z * g.biasZ : nullptr;
  const u16* add_d = (EPI == 3) ? g.add + (size_t)z * g.addZ : nullptr;
  u16* Cd = g.C + (size_t)z * g.cZ;
  float* Cf = (float*)g.C + (size_t)z * g.cZ;
  #pragma unroll
  for (int mi=0; mi<4; ++mi) {
    #pragma unroll
    for (int ni=0; ni<4; ++ni) {
      f32x4 v = acc[mi][ni];
      const int gr = r0 + wr*64 + mi*16 + ((l >> 4) << 2);
      const int gc = n0 + wc*64 + ni*16 + (l & 15);
      #pragma unroll
      for (int q=0; q<4; ++q) {
        const int r = gr + q;
        float x = v[q];
        if (EPI == 2) {
          x = fmaxf(fmaf(x, g.scale[gc], g.shift[gc]), 0.f);
          Cd[(size_t)r * g.ldc + g.colOff + gc] = f2bf(x);
        } else if (EPI == 3) {
          x += bias_d[gc] + bf2f(add_d[(size_t)r * g.ldc + gc]);
          Cd[(size_t)r * g.ldc + g.colOff + gc] = f2bf(x);
        } else if (EPI == 4) {
          Cf[(size_t)r * g.ldc + g.colOff + gc] = x;
        } else {
          x += bias_d[gc];
          Cd[(size_t)r * g.ldc + g.colOff + gc] = f2bf(x);
        }
      }
    }
  }
}

// ---------------- small utility kernels --------------------------------------
__global__ void castk(const float* __restrict__ s, u16* __restrict__ d, int n)
{
  int i = (blockIdx.x*256 + threadIdx.x)*4;
  if (i < n){
    float4 v = *(const float4*)(s+i);
    ushort4 o; o.x=f2bf(v.x); o.y=f2bf(v.y); o.z=f2bf(v.z); o.w=f2bf(v.w);
    *(ushort4*)(d+i) = o;
  }
}

__global__ void c3rep(const float* __restrict__ w, u16* __restrict__ o)
{
  int id = blockIdx.x*256 + threadIdx.x; // 128*4608
  int oc = id / 4608, rem = id % 4608;
  int tap = rem >> 9, ic = rem & 511;
  o[id] = f2bf(w[((size_t)oc*512 + ic)*9 + tap]);
}

__global__ void bnssk(const float* g3,const float* b3,const float* m3,const float* v3,
                      const float* g1,const float* b1,const float* m1,const float* v1,
                      float* out)
{
  int t = threadIdx.x; int i = t & 127;
  if (t < 128){ float sc = g3[i]*rsqrtf(v3[i]+1e-5f); out[i]=sc; out[128+i]=b3[i]-m3[i]*sc; }
  else        { float sc = g1[i]*rsqrtf(v1[i]+1e-5f); out[256+i]=sc; out[384+i]=b1[i]-m1[i]*sc; }
}

// reduce 9 fp32 partials -> BN+ReLU -> bf16 into zin cols 0..127
__global__ __launch_bounds__(256)
void c3red(const float* __restrict__ P, const float* __restrict__ bnss, u16* __restrict__ zin)
{
  const int id = blockIdx.x*256 + threadIdx.x;
  const size_t base = (size_t)id * 4;
  const int r = (int)(base >> 7), c = (int)(base & 127);
  float4 s = {0.f,0.f,0.f,0.f};
  #pragma unroll
  for (int z=0; z<9; ++z){
    float4 v = *(const float4*)(P + (size_t)z*2097152 + base);
    s.x += v.x; s.y += v.y; s.z += v.z; s.w += v.w;
  }
  float4 sc = *(const float4*)(bnss + c);
  float4 sh = *(const float4*)(bnss + 128 + c);
  ushort4 o;
  o.x = f2bf(fmaxf(fmaf(s.x, sc.x, sh.x), 0.f));
  o.y = f2bf(fmaxf(fmaf(s.y, sc.y, sh.y), 0.f));
  o.z = f2bf(fmaxf(fmaf(s.z, sc.z, sh.z), 0.f));
  o.w = f2bf(fmaxf(fmaf(s.w, sc.w, sh.w), 0.f));
  *(ushort4*)(zin + (size_t)r*256 + c) = o;
}

__global__ __launch_bounds__(256)
void padk(const float* __restrict__ curr, const float* __restrict__ prev, u16* __restrict__ pad)
{
  const int id = blockIdx.x*256 + threadIdx.x;
  const int c8 = id & 63;
  int t = id >> 6;
  const int xx = t % 66; t /= 66;
  const int yy = t % 66; const int b = t / 66;
  const int c0 = c8*8;
  uint4 o;
  if (yy==0 || yy==65 || xx==0 || xx==65){ o.x=0;o.y=0;o.z=0;o.w=0; }
  else {
    const int l = (yy-1)*64 + (xx-1);
    const float* s = (c0 < 256) ? curr + ((size_t)b*4096 + l)*256 + c0
                                : prev + ((size_t)b*4096 + l)*256 + (c0-256);
    float4 a = *(const float4*)s, bb = *(const float4*)(s+4);
    o.x = pk2(a.x,a.y); o.y = pk2(a.z,a.w); o.z = pk2(bb.x,bb.y); o.w = pk2(bb.z,bb.w);
  }
  *(uint4*)(pad + (((size_t)b*66 + yy)*66 + xx)*512 + c0) = o;
}

__global__ __launch_bounds__(256)
void ln256(const u16* __restrict__ in, long inZ, u16* __restrict__ out, long outZ,
           const float* __restrict__ gw, const float* __restrict__ bw, int pz)
{
  const int z = blockIdx.z;
  const int row = blockIdx.x*4 + (threadIdx.x>>6);
  const int l = threadIdx.x & 63;
  const u16* ip = in + (size_t)z*inZ + (size_t)row*256 + l*4;
  ushort4 rr = *(const ushort4*)ip;
  float v0=bf2f(rr.x), v1=bf2f(rr.y), v2=bf2f(rr.z), v3=bf2f(rr.w);
  float s = v0+v1+v2+v3;
  float ss = v0*v0+v1*v1+v2*v2+v3*v3;
  #pragma unroll
  for(int m=1;m<64;m<<=1){ s += __shfl_xor(s,m); ss += __shfl_xor(ss,m); }
  float mu = s*(1.f/256.f);
  float var = ss*(1.f/256.f) - mu*mu;
  float rs = rsqrtf(var + 1e-5f);
  const float* g = gw + (size_t)z*pz; const float* b = bw + (size_t)z*pz;
  int c = l*4;
  u16* op = out + (size_t)z*outZ + (size_t)row*256 + c;
  ushort4 o; o.x=f2bf((v0-mu)*rs*g[c]+b[c]); o.y=f2bf((v1-mu)*rs*g[c+1]+b[c+1]);
  o.z=f2bf((v2-mu)*rs*g[c+2]+b[c+2]); o.w=f2bf((v3-mu)*rs*g[c+3]+b[c+3]);
  *(ushort4*)op = o;
}

__global__ __launch_bounds__(256)
void rms512(u16* __restrict__ Y, const float* __restrict__ gw)
{
  const int z = blockIdx.z;
  const int row = blockIdx.x*4 + (threadIdx.x>>6);
  const int l = threadIdx.x & 63;
  u16* p = Y + ((size_t)z*16384 + row)*512 + l*8;
  uint4 raw = *(const uint4*)p;
  float v[8]; unpk8(raw, v);
  float ss = 0.f;
  #pragma unroll
  for (int j=0;j<8;j++) ss += v[j]*v[j];
  #pragma unroll
  for (int m=1;m<64;m<<=1) ss += __shfl_xor(ss, m);
  const float sc = rsqrtf(ss*(1.f/512.f) + 1e-5f);
  const float* g = gw + (size_t)z*512 + l*8;
  uint4 o;
  o.x = pk2(v[0]*sc*g[0], v[1]*sc*g[1]);
  o.y = pk2(v[2]*sc*g[2], v[3]*sc*g[3]);
  o.z = pk2(v[4]*sc*g[4], v[5]*sc*g[5]);
  o.w = pk2(v[6]*sc*g[6], v[7]*sc*g[7]);
  *(uint4*)p = o;
}

// fp32 dt head: dt = softplus(xln.W_dt + b + dt_bias)
__global__ __launch_bounds__(256)
void dtk(const u16* __restrict__ xln, const float* __restrict__ minW,
         const float* __restrict__ minB, const float* __restrict__ dtb,
         float* __restrict__ DT)
{
  __shared__ float sx[32*257];
  const int z = blockIdx.z;
  const int r0 = blockIdx.x * 32;
  const int tid = threadIdx.x;
  {
    const int rr = tid >> 3, cc = (tid & 7) * 32;
    const u16* src = xln + ((size_t)z*16384 + r0 + rr)*256 + cc;
    #pragma unroll
    for (int q=0;q<4;q++){
      uint4 raw = *(const uint4*)(src + q*8);
      float v[8]; unpk8(raw, v);
      #pragma unroll
      for (int j=0;j<8;j++) sx[rr*257 + cc + q*8 + j] = v[j];
    }
  }
  __syncthreads();
  const int ri = tid >> 3, hv = tid & 7;
  const float* wrow = minW + ((size_t)z*1288 + 1280 + hv)*256;
  float acc = 0.f;
  #pragma unroll 4
  for (int k=0; k<256; k+=4){
    float4 wq = *(const float4*)(wrow + k);
    acc += sx[ri*257+k]*wq.x + sx[ri*257+k+1]*wq.y + sx[ri*257+k+2]*wq.z + sx[ri*257+k+3]*wq.w;
  }
  acc += minB[(size_t)z*1288 + 1280 + hv] + dtb[z*8 + hv];
  float dt = (acc > 20.f) ? acc : log1pf(expf(acc));
  DT[((size_t)z*16384 + r0 + ri)*8 + hv] = dt;
}

// chunk-local cumulative log-decay
__global__ __launch_bounds__(256)
void cak(const float* __restrict__ DT, float* __restrict__ CA,
         const float* __restrict__ alog, int dirBase)
{
  const int z = blockIdx.z;
  const int gidx = blockIdx.x*4 + (threadIdx.x>>6);
  const int lane = threadIdx.x & 63;
  const int c = gidx & 63, bh = gidx >> 6;
  const int b = bh >> 3, hh = bh & 7;
  const size_t row = (size_t)z*16384 + (size_t)b*4096 + c*64 + lane;
  float x = DT[row*8 + hh];
  #pragma unroll
  for (int m=1;m<64;m<<=1){ float o = __shfl_up(x, m); if (lane >= m) x += o; }
  float eA = expf(alog[(dirBase+z)*8 + hh]);
  CA[row*8 + hh] = -eA * x;
}

// causal conv1d(4)+SiLU over the B/C columns (raw cols 512..767) -> BCC[row][256]
__global__ __launch_bounds__(256)
void convbc(const u16* __restrict__ xbcr, u16* __restrict__ bcc,
            const float* __restrict__ cw, const float* __restrict__ cb)
{
  __shared__ float cwS[4][256];
  __shared__ float cbS[256];
  const int tid = threadIdx.x;
  const int id = blockIdx.x*256 + tid;
  const int c8 = id & 31;
  const int r = (id >> 5) & 16383;
  const int d = id >> 19;
  {
    float4 w4 = *(const float4*)(cw + ((size_t)d*768 + 512 + tid)*4);
    cwS[0][tid]=w4.x; cwS[1][tid]=w4.y; cwS[2][tid]=w4.z; cwS[3][tid]=w4.w;
    cbS[tid] = cb[(size_t)d*768 + 512 + tid];
  }
  __syncthreads();
  const int li = r & 4095;
  const int col = 512 + c8*8;
  const u16* base = xbcr + (size_t)d*16777216 + (size_t)(r - li)*768 + col;
  float acc[8];
  #pragma unroll
  for (int j=0;j<8;j++) acc[j] = cbS[c8*8+j];
  #pragma unroll
  for (int tap=0; tap<4; ++tap){
    int lt = li - 3 + tap;
    if (lt >= 0){
      uint4 raw = *(const uint4*)(base + (size_t)lt*768);
      float v[8]; unpk8(raw, v);
      #pragma unroll
      for (int j=0;j<8;j++)
        acc[j] = fmaf(v[j], cwS[tap][c8*8+j], acc[j]);
    }
  }
  uint4 o;
  float s[8];
  #pragma unroll
  for (int j=0;j<8;j++) s[j] = acc[j] / (1.f + __expf(-acc[j]));
  o.x = pk2(s[0],s[1]); o.y = pk2(s[2],s[3]); o.z = pk2(s[4],s[5]); o.w = pk2(s[6],s[7]);
  *(uint4*)(bcc + ((size_t)d*16384 + r)*256 + c8*8) = o;
}

// conv1d(4)+SiLU on X cols (raw 0..511) + transpose -> XCT[p][g]
__global__ __launch_bounds__(256)
void convx(const u16* __restrict__ xbcr, u16* __restrict__ xct,
           const float* __restrict__ cw, const float* __restrict__ cb)
{
  __shared__ u16 T[128*72];
  __shared__ float cwX[4][128];
  __shared__ float cbX[128];
  const int bx = blockIdx.x, z = blockIdx.z;
  const int pq = bx & 3, c = (bx>>2) & 63, b = bx >> 8;
  const int tid = threadIdx.x;
  const u16* xb = xbcr + (size_t)z*16777216 + (size_t)b*4096*768;
  if (tid < 128){
    float4 w4 = *(const float4*)(cw + (size_t)z*3072 + (pq*128+tid)*4);
    cwX[0][tid]=w4.x; cwX[1][tid]=w4.y; cwX[2][tid]=w4.z; cwX[3][tid]=w4.w;
    cbX[tid] = cb[z*768 + pq*128 + tid];
  }
  __syncthreads();
  #pragma unroll
  for (int u=0; u<4; ++u){
    int idx = u*256 + tid;
    int s = idx >> 4, seg = idx & 15;
    int li = c*64 + s;
    int col = pq*128 + seg*8;
    float acc[8];
    #pragma unroll
    for (int j=0;j<8;j++) acc[j] = cbX[seg*8+j];
    #pragma unroll
    for (int tap=0; tap<4; ++tap){
      int lt = li - 3 + tap;
      if (lt >= 0){
        uint4 raw = *(const uint4*)(xb + (size_t)lt*768 + col);
        float v[8]; unpk8(raw, v);
        #pragma unroll
        for (int j=0;j<8;j++) acc[j] = fmaf(v[j], cwX[tap][seg*8+j], acc[j]);
      }
    }
    #pragma unroll
    for (int j=0;j<8;j++)
      T[(seg*8+j)*72 + s] = f2bf(acc[j] / (1.f + __expf(-acc[j])));
  }
  __syncthreads();
  #pragma unroll
  for (int u=0; u<4; ++u){
    int idx = u*256 + tid;
    int pl = idx >> 3, sg = idx & 7;
    uint4 v = *(const uint4*)&T[pl*72 + sg*8];
    *(uint4*)(xct + (size_t)z*8388608 + (size_t)(pq*128+pl)*16384 + b*4096 + c*64 + sg*8) = v;
  }
}

// transpose conv'd B (BCC cols 0..127) -> BT[n][g]; grid (256,1,nd)
__global__ __launch_bounds__(256)
void btk(const u16* __restrict__ bcc, u16* __restrict__ bt)
{
  __shared__ u16 T[128*72];
  const int bx = blockIdx.x, z = blockIdx.z;
  const int c = bx & 63, b = bx >> 6;
  const int tid = threadIdx.x;
  const u16* src = bcc + ((size_t)z*16384 + (size_t)b*4096 + c*64)*256;
  #pragma unroll
  for (int u=0; u<4; ++u){
    int idx = u*256 + tid;
    int s = idx >> 4, seg = idx & 15;
    uint4 raw = *(const uint4*)(src + (size_t)s*256 + seg*8);
    u16 t8[8]; *(uint4*)t8 = raw;
    #pragma unroll
    for (int j=0;j<8;j++) T[(seg*8+j)*72 + s] = t8[j];
  }
  __syncthreads();
  #pragma unroll
  for (int u=0; u<4; ++u){
    int idx = u*256 + tid;
    int n = idx >> 3, sg = idx & 7;
    uint4 v = *(const uint4*)&T[n*72 + sg*8];
    *(uint4*)(bt + (size_t)z*2097152 + (size_t)n*16384 + b*4096 + c*64 + sg*8) = v;
  }
}

// per-chunk outer products, heads fused, p-quarter per block:
// CS[p][n] = sum_s (w[s,h]*X^T[p][s])*B^T[n][s];  grid (1024, 1, nd)
__global__ __launch_bounds__(256)
void csk(const u16* __restrict__ xct, const u16* __restrict__ bt,
         const float* __restrict__ DT, const float* __restrict__ CA,
         u16* __restrict__ CS)
{
  __shared__ u16 Xw[128*72];
  __shared__ u16 Bt[128*72];
  __shared__ float wS[64*2];
  const int bx = blockIdx.x, z = blockIdx.z;
  const int pq = bx & 3, c = (bx>>2) & 63, b = bx >> 8;
  const int tid = threadIdx.x, l = tid & 63, w = tid >> 6;
  const size_t rowb = (size_t)z*16384 + (size_t)b*4096;
  const int p0 = pq*128;
  if (tid < 128){
    int s = tid & 63, hi = tid >> 6;
    int hh = pq*2 + hi;
    float ca63 = CA[(rowb + c*64 + 63)*8 + hh];
    float cav  = CA[(rowb + c*64 + s)*8 + hh];
    float dtv  = DT[(rowb + c*64 + s)*8 + hh];
    wS[s*2+hi] = __expf(ca63 - cav) * dtv;
  }
  __syncthreads();
  #pragma unroll
  for (int u=0; u<4; ++u){
    int idx = u*256 + tid;
    int pl = idx >> 3, sg = idx & 7;
    int hi = pl >> 6;
    uint4 raw = *(const uint4*)(xct + (size_t)z*8388608 + (size_t)(p0+pl)*16384 + b*4096 + c*64 + sg*8);
    float v[8]; unpk8(raw, v);
    uint4 o;
    o.x = pk2(v[0]*wS[(sg*8+0)*2+hi], v[1]*wS[(sg*8+1)*2+hi]);
    o.y = pk2(v[2]*wS[(sg*8+2)*2+hi], v[3]*wS[(sg*8+3)*2+hi]);
    o.z = pk2(v[4]*wS[(sg*8+4)*2+hi], v[5]*wS[(sg*8+5)*2+hi]);
    o.w = pk2(v[6]*wS[(sg*8+6)*2+hi], v[7]*wS[(sg*8+7)*2+hi]);
    *(uint4*)&Xw[pl*72 + sg*8] = o;
  }
  #pragma unroll
  for (int u=0; u<4; ++u){
    int idx = u*256 + tid;
    int n = idx >> 3, sg = idx & 7;
    *(uint4*)&Bt[n*72 + sg*8] =
      *(const uint4*)(bt + (size_t)z*2097152 + (size_t)n*16384 + b*4096 + c*64 + sg*8);
  }
  __syncthreads();
  f32x4 acc[8][2];
  #pragma unroll
  for (int i=0;i<8;i++)
    #pragma unroll
    for (int j=0;j<2;j++) acc[i][j] = (f32x4){0.f,0.f,0.f,0.f};
  #pragma unroll
  for (int kk=0; kk<2; ++kk){
    bfx8 bvp[2];
    #pragma unroll
    for (int ni=0; ni<2; ++ni)
      bvp[ni] = *(const bfx8*)&Xw[(w*32 + ni*16 + (l&15))*72 + kk*32 + (l>>4)*8];
    #pragma unroll
    for (int mi=0; mi<8; ++mi){
      bfx8 av = *(const bfx8*)&Bt[(mi*16 + (l&15))*72 + kk*32 + (l>>4)*8];
      #pragma unroll
      for (int ni=0; ni<2; ++ni)
        acc[mi][ni] = __builtin_amdgcn_mfma_f32_16x16x32_bf16(av, bvp[ni], acc[mi][ni], 0, 0, 0);
    }
  }
  #pragma unroll
  for (int mi=0; mi<8; ++mi){
    #pragma unroll
    for (int ni=0; ni<2; ++ni){
      int gp = p0 + w*32 + ni*16 + (l&15);
      int bhx = b*8 + (gp>>6); int pin = gp & 63;
      int n0 = mi*16 + ((l>>4)<<2);
      u32* cp = (u32*)&CS[(size_t)z*16777216 + (size_t)bhx*524288 + (size_t)c*8192 + (size_t)pin*128 + n0];
      cp[0] = pk2(acc[mi][ni][0], acc[mi][ni][1]);
      cp[1] = pk2(acc[mi][ni][2], acc[mi][ni][3]);
    }
  }
}

// sequential 64-step combine IN PLACE (H aliases CS); 2x n-split
__global__ __launch_bounds__(256)
void combk(const u16* __restrict__ CS, const float* __restrict__ CA,
           u16* __restrict__ H)
{
  __shared__ float aL[64];
  const int bx = blockIdx.x;
  const int z = blockIdx.z;
  const int nh = bx & 1, pg = (bx >> 1) & 3, bh = bx >> 3;
  const int b = bh >> 3, hh = bh & 7;
  const int tid = threadIdx.x;
  const int p = pg*16 + (tid >> 4), n = nh*64 + (tid & 15)*4;
  const size_t rowb = (size_t)z*16384 + (size_t)b*4096;
  if (tid < 64) aL[tid] = __expf(CA[(rowb + tid*64 + 63)*8 + hh]);
  __syncthreads();
  const u16* Cs = CS + (size_t)z*16777216 + (size_t)bh*524288 + (size_t)p*128 + n;
  u16* Hd = H + (size_t)z*16777216 + (size_t)bh*524288 + (size_t)p*128 + n;
  float h[4];
  #pragma unroll
  for (int j=0;j<4;j++) h[j]=0.f;
  uint2 pf = *(const uint2*)Cs;
  #pragma unroll 1
  for (int c=0; c<64; ++c){
    uint2 cur = pf;
    if (c < 63) pf = *(const uint2*)(Cs + (size_t)(c+1)*8192);
    uint2 o;
    o.x = pk2(h[0],h[1]); o.y = pk2(h[2],h[3]);
    *(uint2*)(Hd + (size_t)c*8192) = o;
    float v[4]; unpk4(cur, v);
    const float a = aL[c];
    #pragma unroll
    for (int j=0;j<4;j++) h[j] = fmaf(h[j], a, v[j]);
  }
}

// per-chunk output: Y = (S_decayed @ X + diag(exp(ca)) * (C @ H[c]) + Dh*x) * silu(z)
// B staged in LDS; C-operand loaded direct to registers (LDS diet -> 3 blocks/CU)
__global__ __launch_bounds__(256)
void yk2(const u16* __restrict__ bcc, const u16* __restrict__ xct,
         const float* __restrict__ DT, const float* __restrict__ CA,
         const u16* __restrict__ H, const float* __restrict__ Dp,
         u16* __restrict__ Y)
{
  __shared__ u16 Bs[64*136];    // [s][n]  (B only)
  __shared__ u16 Hs[64*136];    // [p][n]
  __shared__ u16 Xt[64*72];     // [p][s]
  __shared__ u16 Sm[64*72];     // [t][s]
  __shared__ float caL[64], dtL[64];
  const int bx = blockIdx.x, z = blockIdx.z;
  const int c = bx & 63, bh = bx >> 6;
  const int b = bh >> 3, hh = bh & 7;
  const int tid = threadIdx.x, l = tid & 63, w = tid >> 6;
  const size_t rowb = (size_t)z*16384 + (size_t)b*4096;
  const u16* bcp = bcc + (rowb + c*64)*256;
  const u16* Hd = H + (size_t)z*16777216 + (size_t)bh*524288 + (size_t)c*8192;
  const u16* xcp = xct + (size_t)z*8388608 + (size_t)(hh*64)*16384 + b*4096 + c*64;
  const float Dh = Dp[z*8 + hh];

  // C-operand fragments direct from global (issued first, overlap staging)
  bfx8 av[4];
  #pragma unroll
  for (int kk=0; kk<4; ++kk)
    av[kk] = *(const bfx8*)(bcp + (size_t)(w*16 + (l&15))*256 + 128 + kk*32 + (l>>4)*8);

  if (tid < 64){
    caL[tid] = CA[(rowb + c*64 + tid)*8 + hh];
    dtL[tid] = DT[(rowb + c*64 + tid)*8 + hh];
  }
  #pragma unroll
  for (int u=0; u<4; ++u){
    int idx = u*256 + tid; int s = idx >> 4, sg = idx & 15;
    *(uint4*)&Bs[s*136 + sg*8] = *(const uint4*)(bcp + (size_t)s*256 + sg*8);
  }
  #pragma unroll
  for (int u=0; u<4; ++u){
    int idx = u*256 + tid; int p = idx >> 4, sg = idx & 15;
    *(uint4*)&Hs[p*136 + sg*8] = *(const uint4*)(Hd + (size_t)p*128 + sg*8);
  }
  #pragma unroll
  for (int u=0; u<2; ++u){
    int idx = u*256 + tid; int p = idx >> 3, sg = idx & 7;
    *(uint4*)&Xt[p*72 + sg*8] = *(const uint4*)(xcp + (size_t)p*16384 + sg*8);
  }
  __syncthreads();

  f32x4 sacc[4], acc2[4];
  #pragma unroll
  for (int i=0;i<4;i++){ sacc[i] = (f32x4){0.f,0.f,0.f,0.f}; acc2[i] = (f32x4){0.f,0.f,0.f,0.f}; }
  #pragma unroll
  for (int kk=0; kk<4; ++kk){
    #pragma unroll
    for (int st=0; st<4; ++st){
      bfx8 bv = *(const bfx8*)&Bs[(st*16 + (l&15))*136 + kk*32 + (l>>4)*8];
      sacc[st] = __builtin_amdgcn_mfma_f32_16x16x32_bf16(av[kk], bv, sacc[st], 0, 0, 0);
      bfx8 hv = *(const bfx8*)&Hs[(st*16 + (l&15))*136 + kk*32 + (l>>4)*8];
      acc2[st] = __builtin_amdgcn_mfma_f32_16x16x32_bf16(av[kk], hv, acc2[st], 0, 0, 0);
    }
  }
  #pragma unroll
  for (int st=0; st<4; ++st){
    #pragma unroll
    for (int q=0;q<4;q++){
      int t = w*16 + (l>>4)*4 + q;
      int s = st*16 + (l&15);
      float m = (s <= t) ? __expf(caL[t]-caL[s]) * dtL[s] : 0.f;
      Sm[t*72 + s] = f2bf(sacc[st][q] * m);
    }
  }
  #pragma unroll
  for (int pt=0; pt<4; ++pt)
    #pragma unroll
    for (int q=0;q<4;q++){
      int t = w*16 + (l>>4)*4 + q;
      acc2[pt][q] *= __expf(caL[t]);
    }
  __syncthreads();
  #pragma unroll
  for (int kk=0; kk<2; ++kk){
    bfx8 sv = *(const bfx8*)&Sm[(w*16 + (l&15))*72 + kk*32 + (l>>4)*8];
    #pragma unroll
    for (int pt=0; pt<4; ++pt){
      bfx8 bv = *(const bfx8*)&Xt[(pt*16 + (l&15))*72 + kk*32 + (l>>4)*8];
      acc2[pt] = __builtin_amdgcn_mfma_f32_16x16x32_bf16(sv, bv, acc2[pt], 0, 0, 0);
    }
  }
  u16* Yrow = Y + (rowb + c*64)*512 + hh*64;
  #pragma unroll
  for (int pt=0; pt<4; ++pt){
    #pragma unroll
    for (int q=0;q<4;q++){
      int t = w*16 + (l>>4)*4 + q;
      int p = pt*16 + (l&15);
      float xv = bf2f(Xt[p*72 + t]);
      float zf = bf2f(Yrow[(size_t)t*512 + p]);
      float yv = (acc2[pt][q] + Dh*xv) * (zf/(1.f+__expf(-zf)));
      Yrow[(size_t)t*512 + p] = f2bf(yv);
    }
  }
}

__global__ __launch_bounds__(256)
void finalk(const float* __restrict__ curr, const u16* __restrict__ outs, float* __restrict__ o)
{
  const int row = blockIdx.x*4 + (threadIdx.x>>6);
  const int c4 = (threadIdx.x & 63)*4;
  const int b = row >> 12, li = row & 4095;
  const int T = ((li & 63) << 6) | (li >> 6);
  const size_t rb = (size_t)b*4096;
  const ushort4 a0 = *(const ushort4*)(outs + (size_t)0*4194304 + ((rb+li)*256 + c4));
  const ushort4 a1 = *(const ushort4*)(outs + (size_t)1*4194304 + ((rb+T)*256 + c4));
  const ushort4 a2 = *(const ushort4*)(outs + (size_t)2*4194304 + ((rb+4095-li)*256 + c4));
  const ushort4 a3 = *(const ushort4*)(outs + (size_t)3*4194304 + ((rb+4095-T)*256 + c4));
  float4 cv = *(const float4*)(curr + (size_t)row*256 + c4);
  float4 r;
  r.x = cv.x + 0.25f*(bf2f(a0.x)+bf2f(a1.x)+bf2f(a2.x)+bf2f(a3.x));
  r.y = cv.y + 0.25f*(bf2f(a0.y)+bf2f(a1.y)+bf2f(a2.y)+bf2f(a3.y));
  r.z = cv.z + 0.25f*(bf2f(a0.z)+bf2f(a1.z)+bf2f(a2.z)+bf2f(a3.z));
  r.w = cv.w + 0.25f*(bf2f(a0.w)+bf2f(a1.w)+bf2f(a2.w)+bf2f(a3.w));
  *(float4*)(o + (size_t)row*256 + c4) = r;
}

// ---------------------------------------------------------------------------
extern "C" void kernel_launch(void* const* d_in, const int* in_sizes, int n_in,
                              void* d_out, int out_size, void* d_ws, size_t ws_size,
                              hipStream_t stream)
{
  (void)in_sizes; (void)n_in; (void)out_size;
  const float* curr   = (const float*)d_in[0];
  const float* prev   = (const float*)d_in[1];
  const float* conv3w = (const float*)d_in[2];
  const float* bn3g=(const float*)d_in[3], *bn3b=(const float*)d_in[4], *bn3m=(const float*)d_in[5], *bn3v=(const float*)d_in[6];
  const float* conv1w = (const float*)d_in[7];
  const float* bn1g=(const float*)d_in[8], *bn1b=(const float*)d_in[9], *bn1m=(const float*)d_in[10], *bn1v=(const float*)d_in[11];
  const float* fuseW=(const float*)d_in[12], *fuseB=(const float*)d_in[13];
  const float* lng=(const float*)d_in[14], *lnb=(const float*)d_in[15];
  const float* inpW=(const float*)d_in[16], *inpB=(const float*)d_in[17];
  const float* mlng=(const float*)d_in[18], *mlnb=(const float*)d_in[19];
  const float* minW=(const float*)d_in[20], *minB=(const float*)d_in[21];
  const float* cw=(const float*)d_in[22], *cb=(const float*)d_in[23];
  const float* alog=(const float*)d_in[24], *Dp=(const float*)d_in[25], *dtb=(const float*)d_in[26];
  const float* mng=(const float*)d_in[27];
  const float* moutW=(const float*)d_in[28], *moutB=(const float*)d_in[29];
  const float* outpW=(const float*)d_in[30], *outpB=(const float*)d_in[31];

  // ---- persistent layout ----
  char* ws = (char*)d_ws;
  size_t off = 0;
  auto alloc = [&](size_t bytes){ size_t o = off; off = (off + bytes + 1023) & ~(size_t)1023; return o; };
  const size_t O_WFUSE = alloc((size_t)256*256*2);
  const size_t O_WINP  = alloc((size_t)4*256*256*2);
  const size_t O_WMIN  = alloc((size_t)4*1288*256*2);
  const size_t O_WMOUT = alloc((size_t)4*256*512*2);
  const size_t O_WOUTP = alloc((size_t)4*256*256*2);
  const size_t O_WC3   = alloc((size_t)128*4608*2);
  const size_t O_WC1   = alloc((size_t)128*512*2);
  const size_t O_BNSS  = alloc(512*4);
  const size_t O_ZF    = alloc((size_t)16384*256*2);
  const size_t O_OUTS  = alloc((size_t)4*16384*256*2);
  const size_t O_P     = off;

  // per-dir sizes (bytes)
  const size_t S0d  = (size_t)16384*256*2;
  const size_t XLNd = (size_t)16384*256*2;
  const size_t Yd   = (size_t)16384*512*2;
  const size_t XCTd = (size_t)512*16384*2;
  const size_t BTd  = (size_t)128*16384*2;
  const size_t DTd  = (size_t)16384*8*4;
  const size_t CAd  = (size_t)16384*8*4;
  const size_t XHd  = (size_t)16777216*2;
  const size_t perdir = S0d + XLNd + Yd + XCTd + BTd + DTd + CAd + XHd;

  const size_t PADsz = (size_t)4*66*66*512*2;
  const size_t CPsz  = (size_t)9*16384*128*4;
  const size_t PREsz = PADsz + CPsz + (size_t)16384*256*2*2 + 4096;

  int nd = 0;
  for (int cand = 4; cand >= 1; cand >>= 1) {
    size_t need = (size_t)cand*perdir; if (need < PREsz) need = PREsz;
    if (O_P + need <= ws_size) { nd = cand; break; }
  }
  if (nd == 0) return;

  #define WP(o) ((u16*)(ws + (o)))
  #define FP(o) ((float*)(ws + (o)))

  const size_t O_PAD = O_P;
  const size_t O_CP  = O_PAD + PADsz;
  const size_t O_ZIN = O_CP + CPsz;
  const size_t O_ZFT = O_ZIN + (size_t)16384*256*2;

  // 1. BN scale/shift + weight conversions
  bnssk<<<1, 256, 0, stream>>>(bn3g,bn3b,bn3m,bn3v, bn1g,bn1b,bn1m,bn1v, FP(O_BNSS));
  castk<<<64, 256, 0, stream>>>(fuseW, WP(O_WFUSE), 65536);
  castk<<<256, 256, 0, stream>>>(inpW, WP(O_WINP), 262144);
  castk<<<1288, 256, 0, stream>>>(minW, WP(O_WMIN), 1318912);
  castk<<<512, 256, 0, stream>>>(moutW, WP(O_WMOUT), 524288);
  castk<<<256, 256, 0, stream>>>(outpW, WP(O_WOUTP), 262144);
  castk<<<64, 256, 0, stream>>>(conv1w, WP(O_WC1), 65536);
  c3rep<<<2304, 256, 0, stream>>>(conv3w, WP(O_WC3));
  // 2. padded concat input (bf16)
  padk<<<4356, 256, 0, stream>>>(curr, prev, WP(O_PAD));

  GemmArgs a;
  // 3. conv3 split-K over 9 taps -> fp32 partials -> reduce+BN+ReLU
  a = {}; a.A = WP(O_PAD); a.pad = WP(O_PAD);
  a.Bw = WP(O_WC3); a.bZ = 512; a.ldb = 4608;
  a.C = WP(O_CP); a.cZ = 2097152; a.ldc = 128; a.colOff = 0; a.K = 512;
  gemm_bt<2,4><<<dim3(128,1,9), 256, 0, stream>>>(a);
  c3red<<<2048, 256, 0, stream>>>(FP(O_CP), FP(O_BNSS), WP(O_ZIN));
  // 4. conv1 -> zin[:,128:256]
  a = {}; a.A = WP(O_PAD); a.pad = WP(O_PAD); a.Bw = WP(O_WC1); a.bZ = 0; a.ldb = 512;
  a.scale = FP(O_BNSS)+256; a.shift = FP(O_BNSS)+384;
  a.C = WP(O_ZIN); a.cZ = 0; a.ldc = 256; a.colOff = 128; a.K = 512;
  gemm_bt<3,2><<<dim3(128,1,1), 256, 0, stream>>>(a);
  // 5. fuse GEMM -> zft
  a = {}; a.A = WP(O_ZIN); a.aZ = 0; a.lda = 256; a.Bw = WP(O_WFUSE); a.bZ = 0; a.ldb = 256;
  a.bias = fuseB; a.biasZ = 0; a.C = WP(O_ZFT); a.cZ = 0; a.ldc = 256; a.colOff = 0; a.K = 256;
  gemm_bt<0,0><<<dim3(128,2,1), 256, 0, stream>>>(a);
  // 6. LN -> zf (persistent)
  ln256<<<dim3(4096,1,1), 256, 0, stream>>>(WP(O_ZFT), 0, WP(O_ZF), 0, lng, lnb, 0);

  // ---- phases over directions ----
  for (int d0 = 0; d0 < 4; d0 += nd) {
    size_t o = O_P;
    const size_t O_S0  = o; o += (size_t)nd*S0d;
    const size_t O_XLN = o; o += (size_t)nd*XLNd;
    const size_t O_Y   = o; o += (size_t)nd*Yd;
    const size_t O_XCT = o; o += (size_t)nd*XCTd;
    const size_t O_BT  = o; o += (size_t)nd*BTd;
    const size_t O_DT  = o; o += (size_t)nd*DTd;
    const size_t O_CA  = o; o += (size_t)nd*CAd;
    const size_t O_XH  = o;
    const size_t O_BCC = O_XLN;
    const size_t O_S1  = O_XLN;

    // 7. inp GEMM (permuted rows per dir) -> s0
    a = {}; a.A = WP(O_ZF); a.aZ = 0; a.lda = 256;
    a.Bw = WP(O_WINP) + (size_t)d0*65536; a.bZ = 65536; a.ldb = 256;
    a.bias = inpB + d0*256; a.biasZ = 256;
    a.C = WP(O_S0); a.cZ = 4194304; a.ldc = 256; a.colOff = 0; a.K = 256; a.dirBase = d0;
    gemm_bt<1,0><<<dim3(128,2,nd), 256, 0, stream>>>(a);
    // 8. per-dir LN(s0) -> xln
    ln256<<<dim3(4096,1,nd), 256, 0, stream>>>(WP(O_S0), 4194304, WP(O_XLN), 4194304,
                                               mlng + d0*256, mlnb + d0*256, 256);
    // 9. dt, chunk log-decay
    dtk<<<dim3(512,1,nd), 256, 0, stream>>>(WP(O_XLN), minW + (size_t)d0*329728,
                                            minB + d0*1288, dtb + d0*8, FP(O_DT));
    cak<<<dim3(512,1,nd), 256, 0, stream>>>(FP(O_DT), FP(O_CA), alog, d0);
    // 10. z-gate GEMM -> Y
    a = {}; a.A = WP(O_XLN); a.aZ = 4194304; a.lda = 256;
    a.Bw = WP(O_WMIN) + (size_t)d0*329728; a.bZ = 329728; a.ldb = 256;
    a.bias = minB + d0*1288; a.biasZ = 1288;
    a.C = WP(O_Y); a.cZ = 8388608; a.ldc = 512; a.colOff = 0; a.K = 256;
    gemm_bt<0,0><<<dim3(128,4,nd), 256, 0, stream>>>(a);
    // 11. xBC GEMM -> raw xbc (padded per-dir stride)   [last reader of XLN]
    a = {}; a.A = WP(O_XLN); a.aZ = 4194304; a.lda = 256;
    a.Bw = WP(O_WMIN) + (size_t)d0*329728 + (size_t)512*256; a.bZ = 329728; a.ldb = 256;
    a.bias = minB + d0*1288 + 512; a.biasZ = 1288;
    a.C = WP(O_XH); a.cZ = 16777216; a.ldc = 768; a.colOff = 0; a.K = 256;
    gemm_bt<0,0><<<dim3(128,6,nd), 256, 0, stream>>>(a);
    // 12. conv1d+SiLU on B/C -> BCC (overlays XLN)
    convbc<<<nd*2048, 256, 0, stream>>>(WP(O_XH), WP(O_BCC), cw + d0*3072, cb + d0*768);
    // 13. conv1d+SiLU+transpose X -> XCT
    convx<<<dim3(1024,1,nd), 256, 0, stream>>>(WP(O_XH), WP(O_XCT), cw + d0*3072, cb + d0*768);
    // 14. transpose conv'd B -> BT
    btk<<<dim3(256,1,nd), 256, 0, stream>>>(WP(O_BCC), WP(O_BT));
    // 15. per-chunk outer products (p-quarter blocks) -> CS (overlays raw xbc)
    csk<<<dim3(1024,1,nd), 256, 0, stream>>>(WP(O_XCT), WP(O_BT), FP(O_DT), FP(O_CA), WP(O_XH));
    // 16. 64-step combine in place -> H
    combk<<<dim3(256,1,nd), 256, 0, stream>>>(WP(O_XH), FP(O_CA), WP(O_XH));
    // 17. per-chunk outputs -> Y in place
    yk2<<<dim3(2048,1,nd), 256, 0, stream>>>(WP(O_BCC), WP(O_XCT), FP(O_DT), FP(O_CA),
                                             WP(O_XH), Dp + d0*8, WP(O_Y));
    // 18. RMSNorm in-place on Y
    rms512<<<dim3(4096,1,nd), 256, 0, stream>>>(WP(O_Y), mng + d0*512);
    // 19. m_out GEMM + s0 residual -> s1 (overlays BCC/XLN)
    a = {}; a.A = WP(O_Y); a.aZ = 8388608; a.lda = 512;
    a.Bw = WP(O_WMOUT) + (size_t)d0*131072; a.bZ = 131072; a.ldb = 512;
    a.bias = moutB + d0*256; a.biasZ = 256;
    a.add = WP(O_S0); a.addZ = 4194304;
    a.C = WP(O_S1); a.cZ = 4194304; a.ldc = 256; a.colOff = 0; a.K = 512;
    gemm_bt<0,3><<<dim3(128,2,nd), 256, 0, stream>>>(a);
    // 20. outp GEMM -> outs (persistent)
    a = {}; a.A = WP(O_S1); a.aZ = 4194304; a.lda = 256;
    a.Bw = WP(O_WOUTP) + (size_t)d0*65536; a.bZ = 65536; a.ldb = 256;
    a.bias = outpB + d0*256; a.biasZ = 256;
    a.C = WP(O_OUTS) + (size_t)d0*4194304; a.cZ = 4194304; a.ldc = 256; a.colOff = 0; a.K = 256;
    gemm_bt<0,0><<<dim3(128,2,nd), 256, 0, stream>>>(a);
  }

  // 21. final inverse-permute average + residual
  finalk<<<4096, 256, 0, stream>>>(curr, WP(O_OUTS), (float*)d_out);

  #undef WP
  #undef FP
}

// Round 9
// 729.419 us; speedup vs baseline: 5.3008x; 1.0018x over previous
//
#include <hip/hip_runtime.h>
#include <hip/hip_bf16.h>
#include <cstdint>
#include <cstddef>

typedef unsigned short u16;
typedef unsigned int u32;
typedef __attribute__((ext_vector_type(8))) __bf16 bfx8;
typedef __attribute__((ext_vector_type(4))) float f32x4;

static __device__ __forceinline__ float bitf(u32 v){ float f; __builtin_memcpy(&f,&v,4); return f; }
static __device__ __forceinline__ float bf2f(u16 v){ return bitf(((u32)v)<<16); }
static __device__ __forceinline__ u16 f2bf(float f){ __bf16 b=(__bf16)f; u16 r; __builtin_memcpy(&r,&b,2); return r; }
static __device__ __forceinline__ u32 pk2(float a,float b){ return (u32)f2bf(a) | ((u32)f2bf(b)<<16); }
static __device__ __forceinline__ void unpk8(uint4 r, float* o){
  o[0]=bitf(r.x<<16); o[1]=bitf(r.x&0xffff0000u);
  o[2]=bitf(r.y<<16); o[3]=bitf(r.y&0xffff0000u);
  o[4]=bitf(r.z<<16); o[5]=bitf(r.z&0xffff0000u);
  o[6]=bitf(r.w<<16); o[7]=bitf(r.w&0xffff0000u);
}
static __device__ __forceinline__ void unpk4(uint2 r, float* o){
  o[0]=bitf(r.x<<16); o[1]=bitf(r.x&0xffff0000u);
  o[2]=bitf(r.y<<16); o[3]=bitf(r.y&0xffff0000u);
}
static __device__ __forceinline__ void async16(void* lds, const void* g){
  __builtin_amdgcn_global_load_lds((const __attribute__((address_space(1))) u32*)g,
                                   (__attribute__((address_space(3))) u32*)lds, 16, 0, 0);
}

// ---------------- GEMM: C[M][N] = A[M][K] @ B[N][K]^T (+ epilogue) -----------
// EPI: 0=+bias, 2=BN+ReLU, 3=+bias+add, 4=raw fp32, 5=*rowsc+bias+add
struct GemmArgs {
  const u16* A; long aZ; int lda;
  const u16* Bw; long bZ; int ldb;
  const float* bias; int biasZ;
  const float* scale; const float* shift;
  const u16* add; long addZ;
  const float* rowsc; long rowscZ;
  u16* C; long cZ; int ldc; int colOff;
  int K;
  const u16* pad;
  int dirBase;
};

template<int AMODE, int EPI>
__global__ __launch_bounds__(256)
void gemm_bt(GemmArgs g)
{
  __shared__ u16 smA[128*64];
  __shared__ u16 smB[128*64];
  const int tid = threadIdx.x;
  const int l = tid & 63;
  const int wv = tid >> 6;
  const int wr = wv >> 1, wc = wv & 1;
  const int z = blockIdx.z;
  const int r0 = blockIdx.x * 128;
  const int n0 = blockIdx.y * 128;

  const u16* Abase = g.A + (size_t)z * g.aZ;
  const u16* Bbase = g.Bw + (size_t)z * g.bZ;
  const int ldb = g.ldb ? g.ldb : g.K;

  f32x4 acc[4][4];
  #pragma unroll
  for (int i=0;i<4;i++)
    #pragma unroll
    for (int j=0;j<4;j++) acc[i][j] = (f32x4){0.f,0.f,0.f,0.f};

  const int nkt = g.K >> 6;
  #pragma unroll 1
  for (int kt=0; kt<nkt; ++kt) {
    const int k0 = kt << 6;
    #pragma unroll
    for (int it=0; it<4; ++it) {
      const int s = it*256 + tid;
      const int row = s >> 3, ch = s & 7;
      const u16* ga;
      if (AMODE == 0) {
        ga = Abase + (size_t)(r0+row) * g.lda + k0 + ch*8;
      } else if (AMODE == 1) {
        int rr = r0 + row; int li = rr & 4095; int bb = rr >> 12;
        int dir = g.dirBase + z;
        int l2 = (dir & 2) ? (4095 - li) : li;
        int sl = (dir & 1) ? (((l2 & 63) << 6) | (l2 >> 6)) : l2;
        ga = Abase + (size_t)((bb << 12) | sl) * g.lda + k0 + ch*8;
      } else if (AMODE == 2) {
        int rr = r0 + row; int bb = rr >> 12; int li = rr & 4095;
        int yy = li >> 6, xx = li & 63;
        int tap = z, kin = k0;
        int dy = tap / 3 - 1, dx = tap % 3 - 1;
        ga = g.pad + (((size_t)(bb*66 + yy+dy+1))*66 + (xx+dx+1))*512 + kin + ch*8;
      } else {
        int rr = r0 + row; int bb = rr >> 12; int li = rr & 4095;
        int yy = li >> 6, xx = li & 63;
        ga = g.pad + (((size_t)(bb*66 + yy+1))*66 + (xx+1))*512 + k0 + ch*8;
      }
      async16(&smA[(size_t)(it*256 + (tid & ~63))*8], ga);
      const u16* gb = Bbase + (size_t)(n0+row) * ldb + k0 + ch*8;
      async16(&smB[(size_t)(it*256 + (tid & ~63))*8], gb);
    }
    __syncthreads();
    #pragma unroll
    for (int kk=0; kk<2; ++kk) {
      bfx8 av[4], bv[4];
      #pragma unroll
      for (int mi=0; mi<4; ++mi) {
        int ra = wr*64 + mi*16 + (l & 15);
        av[mi] = *(const bfx8*)&smA[ra*64 + kk*32 + (l>>4)*8];
      }
      #pragma unroll
      for (int ni=0; ni<4; ++ni) {
        int rb = wc*64 + ni*16 + (l & 15);
        bv[ni] = *(const bfx8*)&smB[rb*64 + kk*32 + (l>>4)*8];
      }
      #pragma unroll
      for (int mi=0; mi<4; ++mi)
        #pragma unroll
        for (int ni=0; ni<4; ++ni)
          acc[mi][ni] = __builtin_amdgcn_mfma_f32_16x16x32_bf16(av[mi], bv[ni], acc[mi][ni], 0, 0, 0);
    }
    __syncthreads();
  }

  const float* bias_d = (EPI == 0 || EPI == 3 || EPI == 5) ? g.bias + (size_t)z * g.biasZ : nullptr;
  const u16* add_d = (EPI == 3 || EPI == 5) ? g.add + (size_t)z * g.addZ : nullptr;
  const float* rowsc_d = (EPI == 5) ? g.rowsc + (size_t)z * g.rowscZ : nullptr;
  u16* Cd = g.C + (size_t)z * g.cZ;
  float* Cf = (float*)g.C + (size_t)z * g.cZ;
  #pragma unroll
  for (int mi=0; mi<4; ++mi) {
    #pragma unroll
    for (int ni=0; ni<4; ++ni) {
      f32x4 v = acc[mi][ni];
      const int gr = r0 + wr*64 + mi*16 + ((l >> 4) << 2);
      const int gc = n0 + wc*64 + ni*16 + (l & 15);
      #pragma unroll
      for (int q=0; q<4; ++q) {
        const int r = gr + q;
        float x = v[q];
        if (EPI == 2) {
          x = fmaxf(fmaf(x, g.scale[gc], g.shift[gc]), 0.f);
          Cd[(size_t)r * g.ldc + g.colOff + gc] = f2bf(x);
        } else if (EPI == 3) {
          x += bias_d[gc] + bf2f(add_d[(size_t)r * g.ldc + gc]);
          Cd[(size_t)r * g.ldc + g.colOff + gc] = f2bf(x);
        } else if (EPI == 5) {
          x = x * rowsc_d[r] + bias_d[gc] + bf2f(add_d[(size_t)r * g.ldc + gc]);
          Cd[(size_t)r * g.ldc + g.colOff + gc] = f2bf(x);
        } else if (EPI == 4) {
          Cf[(size_t)r * g.ldc + g.colOff + gc] = x;
        } else {
          x += bias_d[gc];
          Cd[(size_t)r * g.ldc + g.colOff + gc] = f2bf(x);
        }
      }
    }
  }
}

// ---------------- small utility kernels --------------------------------------
__global__ void castk(const float* __restrict__ s, u16* __restrict__ d, int n)
{
  int i = (blockIdx.x*256 + threadIdx.x)*4;
  if (i < n){
    float4 v = *(const float4*)(s+i);
    ushort4 o; o.x=f2bf(v.x); o.y=f2bf(v.y); o.z=f2bf(v.z); o.w=f2bf(v.w);
    *(ushort4*)(d+i) = o;
  }
}

// cast m_out W with norm gain folded in: W'[d][j][k] = W[d][j][k]*g[d][k]
__global__ void castg(const float* __restrict__ s, const float* __restrict__ gw,
                      u16* __restrict__ d)
{
  int i = (blockIdx.x*256 + threadIdx.x)*4;   // 524288 total
  int dd = i >> 17, k = i & 511;
  float4 v = *(const float4*)(s+i);
  float4 g4 = *(const float4*)(gw + dd*512 + k);
  ushort4 o; o.x=f2bf(v.x*g4.x); o.y=f2bf(v.y*g4.y); o.z=f2bf(v.z*g4.z); o.w=f2bf(v.w*g4.w);
  *(ushort4*)(d+i) = o;
}

__global__ void c3rep(const float* __restrict__ w, u16* __restrict__ o)
{
  int id = blockIdx.x*256 + threadIdx.x; // 128*4608
  int oc = id / 4608, rem = id % 4608;
  int tap = rem >> 9, ic = rem & 511;
  o[id] = f2bf(w[((size_t)oc*512 + ic)*9 + tap]);
}

__global__ void bnssk(const float* g3,const float* b3,const float* m3,const float* v3,
                      const float* g1,const float* b1,const float* m1,const float* v1,
                      float* out)
{
  int t = threadIdx.x; int i = t & 127;
  if (t < 128){ float sc = g3[i]*rsqrtf(v3[i]+1e-5f); out[i]=sc; out[128+i]=b3[i]-m3[i]*sc; }
  else        { float sc = g1[i]*rsqrtf(v1[i]+1e-5f); out[256+i]=sc; out[384+i]=b1[i]-m1[i]*sc; }
}

// reduce 9 fp32 partials -> BN+ReLU -> bf16 into zin cols 0..127
__global__ __launch_bounds__(256)
void c3red(const float* __restrict__ P, const float* __restrict__ bnss, u16* __restrict__ zin)
{
  const int id = blockIdx.x*256 + threadIdx.x;
  const size_t base = (size_t)id * 4;
  const int r = (int)(base >> 7), c = (int)(base & 127);
  float4 s = {0.f,0.f,0.f,0.f};
  #pragma unroll
  for (int z=0; z<9; ++z){
    float4 v = *(const float4*)(P + (size_t)z*2097152 + base);
    s.x += v.x; s.y += v.y; s.z += v.z; s.w += v.w;
  }
  float4 sc = *(const float4*)(bnss + c);
  float4 sh = *(const float4*)(bnss + 128 + c);
  ushort4 o;
  o.x = f2bf(fmaxf(fmaf(s.x, sc.x, sh.x), 0.f));
  o.y = f2bf(fmaxf(fmaf(s.y, sc.y, sh.y), 0.f));
  o.z = f2bf(fmaxf(fmaf(s.z, sc.z, sh.z), 0.f));
  o.w = f2bf(fmaxf(fmaf(s.w, sc.w, sh.w), 0.f));
  *(ushort4*)(zin + (size_t)r*256 + c) = o;
}

__global__ __launch_bounds__(256)
void padk(const float* __restrict__ curr, const float* __restrict__ prev, u16* __restrict__ pad)
{
  const int id = blockIdx.x*256 + threadIdx.x;
  const int c8 = id & 63;
  int t = id >> 6;
  const int xx = t % 66; t /= 66;
  const int yy = t % 66; const int b = t / 66;
  const int c0 = c8*8;
  uint4 o;
  if (yy==0 || yy==65 || xx==0 || xx==65){ o.x=0;o.y=0;o.z=0;o.w=0; }
  else {
    const int l = (yy-1)*64 + (xx-1);
    const float* s = (c0 < 256) ? curr + ((size_t)b*4096 + l)*256 + c0
                                : prev + ((size_t)b*4096 + l)*256 + (c0-256);
    float4 a = *(const float4*)s, bb = *(const float4*)(s+4);
    o.x = pk2(a.x,a.y); o.y = pk2(a.z,a.w); o.z = pk2(bb.x,bb.y); o.w = pk2(bb.z,bb.w);
  }
  *(uint4*)(pad + (((size_t)b*66 + yy)*66 + xx)*512 + c0) = o;
}

__global__ __launch_bounds__(256)
void ln256(const u16* __restrict__ in, long inZ, u16* __restrict__ out, long outZ,
           const float* __restrict__ gw, const float* __restrict__ bw, int pz)
{
  const int z = blockIdx.z;
  const int row = blockIdx.x*4 + (threadIdx.x>>6);
  const int l = threadIdx.x & 63;
  const u16* ip = in + (size_t)z*inZ + (size_t)row*256 + l*4;
  ushort4 rr = *(const ushort4*)ip;
  float v0=bf2f(rr.x), v1=bf2f(rr.y), v2=bf2f(rr.z), v3=bf2f(rr.w);
  float s = v0+v1+v2+v3;
  float ss = v0*v0+v1*v1+v2*v2+v3*v3;
  #pragma unroll
  for(int m=1;m<64;m<<=1){ s += __shfl_xor(s,m); ss += __shfl_xor(ss,m); }
  float mu = s*(1.f/256.f);
  float var = ss*(1.f/256.f) - mu*mu;
  float rs = rsqrtf(var + 1e-5f);
  const float* g = gw + (size_t)z*pz; const float* b = bw + (size_t)z*pz;
  int c = l*4;
  u16* op = out + (size_t)z*outZ + (size_t)row*256 + c;
  ushort4 o; o.x=f2bf((v0-mu)*rs*g[c]+b[c]); o.y=f2bf((v1-mu)*rs*g[c+1]+b[c+1]);
  o.z=f2bf((v2-mu)*rs*g[c+2]+b[c+2]); o.w=f2bf((v3-mu)*rs*g[c+3]+b[c+3]);
  *(ushort4*)op = o;
}

// per-row inverse-RMS of gated y (512 wide) -> RS[row]  (fp32)
__global__ __launch_bounds__(256)
void rnormk(const u16* __restrict__ Y, float* __restrict__ RS)
{
  const int z = blockIdx.z;
  const int row = blockIdx.x*4 + (threadIdx.x>>6);
  const int l = threadIdx.x & 63;
  const u16* p = Y + ((size_t)z*16384 + row)*512 + l*8;
  uint4 raw = *(const uint4*)p;
  float v[8]; unpk8(raw, v);
  float ss = 0.f;
  #pragma unroll
  for (int j=0;j<8;j++) ss += v[j]*v[j];
  #pragma unroll
  for (int m=1;m<64;m<<=1) ss += __shfl_xor(ss, m);
  if (l == 0) RS[(size_t)z*16384 + row] = rsqrtf(ss*(1.f/512.f) + 1e-5f);
}

// fp32 dt head: dt = softplus(xln.W_dt + b + dt_bias)
__global__ __launch_bounds__(256)
void dtk(const u16* __restrict__ xln, const float* __restrict__ minW,
         const float* __restrict__ minB, const float* __restrict__ dtb,
         float* __restrict__ DT)
{
  __shared__ float sx[32*257];
  const int z = blockIdx.z;
  const int r0 = blockIdx.x * 32;
  const int tid = threadIdx.x;
  {
    const int rr = tid >> 3, cc = (tid & 7) * 32;
    const u16* src = xln + ((size_t)z*16384 + r0 + rr)*256 + cc;
    #pragma unroll
    for (int q=0;q<4;q++){
      uint4 raw = *(const uint4*)(src + q*8);
      float v[8]; unpk8(raw, v);
      #pragma unroll
      for (int j=0;j<8;j++) sx[rr*257 + cc + q*8 + j] = v[j];
    }
  }
  __syncthreads();
  const int ri = tid >> 3, hv = tid & 7;
  const float* wrow = minW + ((size_t)z*1288 + 1280 + hv)*256;
  float acc = 0.f;
  #pragma unroll 4
  for (int k=0; k<256; k+=4){
    float4 wq = *(const float4*)(wrow + k);
    acc += sx[ri*257+k]*wq.x + sx[ri*257+k+1]*wq.y + sx[ri*257+k+2]*wq.z + sx[ri*257+k+3]*wq.w;
  }
  acc += minB[(size_t)z*1288 + 1280 + hv] + dtb[z*8 + hv];
  float dt = (acc > 20.f) ? acc : log1pf(expf(acc));
  DT[((size_t)z*16384 + r0 + ri)*8 + hv] = dt;
}

// chunk-local cumulative log-decay
__global__ __launch_bounds__(256)
void cak(const float* __restrict__ DT, float* __restrict__ CA,
         const float* __restrict__ alog, int dirBase)
{
  const int z = blockIdx.z;
  const int gidx = blockIdx.x*4 + (threadIdx.x>>6);
  const int lane = threadIdx.x & 63;
  const int c = gidx & 63, bh = gidx >> 6;
  const int b = bh >> 3, hh = bh & 7;
  const size_t row = (size_t)z*16384 + (size_t)b*4096 + c*64 + lane;
  float x = DT[row*8 + hh];
  #pragma unroll
  for (int m=1;m<64;m<<=1){ float o = __shfl_up(x, m); if (lane >= m) x += o; }
  float eA = expf(alog[(dirBase+z)*8 + hh]);
  CA[row*8 + hh] = -eA * x;
}

// causal conv1d(4)+SiLU over the B/C columns (raw cols 512..767) -> BCC[row][256]
__global__ __launch_bounds__(256)
void convbc(const u16* __restrict__ xbcr, u16* __restrict__ bcc,
            const float* __restrict__ cw, const float* __restrict__ cb)
{
  __shared__ float cwS[4][256];
  __shared__ float cbS[256];
  const int tid = threadIdx.x;
  const int id = blockIdx.x*256 + tid;
  const int c8 = id & 31;
  const int r = (id >> 5) & 16383;
  const int d = id >> 19;
  {
    float4 w4 = *(const float4*)(cw + ((size_t)d*768 + 512 + tid)*4);
    cwS[0][tid]=w4.x; cwS[1][tid]=w4.y; cwS[2][tid]=w4.z; cwS[3][tid]=w4.w;
    cbS[tid] = cb[(size_t)d*768 + 512 + tid];
  }
  __syncthreads();
  const int li = r & 4095;
  const int col = 512 + c8*8;
  const u16* base = xbcr + (size_t)d*16777216 + (size_t)(r - li)*768 + col;
  float acc[8];
  #pragma unroll
  for (int j=0;j<8;j++) acc[j] = cbS[c8*8+j];
  #pragma unroll
  for (int tap=0; tap<4; ++tap){
    int lt = li - 3 + tap;
    if (lt >= 0){
      uint4 raw = *(const uint4*)(base + (size_t)lt*768);
      float v[8]; unpk8(raw, v);
      #pragma unroll
      for (int j=0;j<8;j++)
        acc[j] = fmaf(v[j], cwS[tap][c8*8+j], acc[j]);
    }
  }
  uint4 o;
  float s[8];
  #pragma unroll
  for (int j=0;j<8;j++) s[j] = acc[j] / (1.f + __expf(-acc[j]));
  o.x = pk2(s[0],s[1]); o.y = pk2(s[2],s[3]); o.z = pk2(s[4],s[5]); o.w = pk2(s[6],s[7]);
  *(uint4*)(bcc + ((size_t)d*16384 + r)*256 + c8*8) = o;
}

// conv1d(4)+SiLU on X cols (raw 0..511) + transpose -> XCT[p][g]
__global__ __launch_bounds__(256)
void convx(const u16* __restrict__ xbcr, u16* __restrict__ xct,
           const float* __restrict__ cw, const float* __restrict__ cb)
{
  __shared__ u16 T[128*72];
  __shared__ float cwX[4][128];
  __shared__ float cbX[128];
  const int bx = blockIdx.x, z = blockIdx.z;
  const int pq = bx & 3, c = (bx>>2) & 63, b = bx >> 8;
  const int tid = threadIdx.x;
  const u16* xb = xbcr + (size_t)z*16777216 + (size_t)b*4096*768;
  if (tid < 128){
    float4 w4 = *(const float4*)(cw + (size_t)z*3072 + (pq*128+tid)*4);
    cwX[0][tid]=w4.x; cwX[1][tid]=w4.y; cwX[2][tid]=w4.z; cwX[3][tid]=w4.w;
    cbX[tid] = cb[z*768 + pq*128 + tid];
  }
  __syncthreads();
  #pragma unroll
  for (int u=0; u<4; ++u){
    int idx = u*256 + tid;
    int s = idx >> 4, seg = idx & 15;
    int li = c*64 + s;
    int col = pq*128 + seg*8;
    float acc[8];
    #pragma unroll
    for (int j=0;j<8;j++) acc[j] = cbX[seg*8+j];
    #pragma unroll
    for (int tap=0; tap<4; ++tap){
      int lt = li - 3 + tap;
      if (lt >= 0){
        uint4 raw = *(const uint4*)(xb + (size_t)lt*768 + col);
        float v[8]; unpk8(raw, v);
        #pragma unroll
        for (int j=0;j<8;j++) acc[j] = fmaf(v[j], cwX[tap][seg*8+j], acc[j]);
      }
    }
    #pragma unroll
    for (int j=0;j<8;j++)
      T[(seg*8+j)*72 + s] = f2bf(acc[j] / (1.f + __expf(-acc[j])));
  }
  __syncthreads();
  #pragma unroll
  for (int u=0; u<4; ++u){
    int idx = u*256 + tid;
    int pl = idx >> 3, sg = idx & 7;
    uint4 v = *(const uint4*)&T[pl*72 + sg*8];
    *(uint4*)(xct + (size_t)z*8388608 + (size_t)(pq*128+pl)*16384 + b*4096 + c*64 + sg*8) = v;
  }
}

// transpose conv'd B (BCC cols 0..127) -> BT[n][g]; grid (256,1,nd)
__global__ __launch_bounds__(256)
void btk(const u16* __restrict__ bcc, u16* __restrict__ bt)
{
  __shared__ u16 T[128*72];
  const int bx = blockIdx.x, z = blockIdx.z;
  const int c = bx & 63, b = bx >> 6;
  const int tid = threadIdx.x;
  const u16* src = bcc + ((size_t)z*16384 + (size_t)b*4096 + c*64)*256;
  #pragma unroll
  for (int u=0; u<4; ++u){
    int idx = u*256 + tid;
    int s = idx >> 4, seg = idx & 15;
    uint4 raw = *(const uint4*)(src + (size_t)s*256 + seg*8);
    u16 t8[8]; *(uint4*)t8 = raw;
    #pragma unroll
    for (int j=0;j<8;j++) T[(seg*8+j)*72 + s] = t8[j];
  }
  __syncthreads();
  #pragma unroll
  for (int u=0; u<4; ++u){
    int idx = u*256 + tid;
    int n = idx >> 3, sg = idx & 7;
    uint4 v = *(const uint4*)&T[n*72 + sg*8];
    *(uint4*)(bt + (size_t)z*2097152 + (size_t)n*16384 + b*4096 + c*64 + sg*8) = v;
  }
}

// raw head-shared scores: ST[s][t] = sum_n C[t][n]B[s][n]  per (b,c); grid (256,1,nd)
__global__ __launch_bounds__(256)
void sk(const u16* __restrict__ bcc, u16* __restrict__ SR)
{
  __shared__ u16 Bs[64*136];
  const int bx = blockIdx.x, z = blockIdx.z;
  const int c = bx & 63, b = bx >> 6;
  const int tid = threadIdx.x, l = tid & 63, w = tid >> 6;
  const u16* bcp = bcc + ((size_t)z*16384 + (size_t)b*4096 + c*64)*256;
  bfx8 av[4];
  #pragma unroll
  for (int kk=0; kk<4; ++kk)
    av[kk] = *(const bfx8*)(bcp + (size_t)(w*16 + (l&15))*256 + 128 + kk*32 + (l>>4)*8);
  #pragma unroll
  for (int u=0; u<4; ++u){
    int idx = u*256 + tid; int s = idx >> 4, sg = idx & 15;
    *(uint4*)&Bs[s*136 + sg*8] = *(const uint4*)(bcp + (size_t)s*256 + sg*8);
  }
  __syncthreads();
  f32x4 sacc[4];
  #pragma unroll
  for (int i=0;i<4;i++) sacc[i] = (f32x4){0.f,0.f,0.f,0.f};
  #pragma unroll
  for (int kk=0; kk<4; ++kk)
    #pragma unroll
    for (int st=0; st<4; ++st){
      bfx8 bv = *(const bfx8*)&Bs[(st*16 + (l&15))*136 + kk*32 + (l>>4)*8];
      sacc[st] = __builtin_amdgcn_mfma_f32_16x16x32_bf16(av[kk], bv, sacc[st], 0, 0, 0);
    }
  // write transposed: ST[s][t], t-pairs contiguous
  u16* Sd = SR + ((size_t)z*4 + b)*524288 + (size_t)c*4096;
  const int t0 = w*16 + ((l>>4)<<2);
  #pragma unroll
  for (int st=0; st<4; ++st){
    int s = st*16 + (l&15);
    u32* cp = (u32*)&Sd[(size_t)s*64 + t0];
    cp[0] = pk2(sacc[st][0], sacc[st][1]);
    cp[1] = pk2(sacc[st][2], sacc[st][3]);
  }
}

// per-chunk outer products, heads fused, p-quarter per block:
// CS[p][n] = sum_s (w[s,h]*X^T[p][s])*B^T[n][s];  grid (1024, 1, nd)
__global__ __launch_bounds__(256)
void csk(const u16* __restrict__ xct, const u16* __restrict__ bt,
         const float* __restrict__ DT, const float* __restrict__ CA,
         u16* __restrict__ CS)
{
  __shared__ u16 Xw[128*72];
  __shared__ u16 Bt[128*72];
  __shared__ float wS[64*2];
  const int bx = blockIdx.x, z = blockIdx.z;
  const int pq = bx & 3, c = (bx>>2) & 63, b = bx >> 8;
  const int tid = threadIdx.x, l = tid & 63, w = tid >> 6;
  const size_t rowb = (size_t)z*16384 + (size_t)b*4096;
  const int p0 = pq*128;
  if (tid < 128){
    int s = tid & 63, hi = tid >> 6;
    int hh = pq*2 + hi;
    float ca63 = CA[(rowb + c*64 + 63)*8 + hh];
    float cav  = CA[(rowb + c*64 + s)*8 + hh];
    float dtv  = DT[(rowb + c*64 + s)*8 + hh];
    wS[s*2+hi] = __expf(ca63 - cav) * dtv;
  }
  __syncthreads();
  #pragma unroll
  for (int u=0; u<4; ++u){
    int idx = u*256 + tid;
    int pl = idx >> 3, sg = idx & 7;
    int hi = pl >> 6;
    uint4 raw = *(const uint4*)(xct + (size_t)z*8388608 + (size_t)(p0+pl)*16384 + b*4096 + c*64 + sg*8);
    float v[8]; unpk8(raw, v);
    uint4 o;
    o.x = pk2(v[0]*wS[(sg*8+0)*2+hi], v[1]*wS[(sg*8+1)*2+hi]);
    o.y = pk2(v[2]*wS[(sg*8+2)*2+hi], v[3]*wS[(sg*8+3)*2+hi]);
    o.z = pk2(v[4]*wS[(sg*8+4)*2+hi], v[5]*wS[(sg*8+5)*2+hi]);
    o.w = pk2(v[6]*wS[(sg*8+6)*2+hi], v[7]*wS[(sg*8+7)*2+hi]);
    *(uint4*)&Xw[pl*72 + sg*8] = o;
  }
  #pragma unroll
  for (int u=0; u<4; ++u){
    int idx = u*256 + tid;
    int n = idx >> 3, sg = idx & 7;
    *(uint4*)&Bt[n*72 + sg*8] =
      *(const uint4*)(bt + (size_t)z*2097152 + (size_t)n*16384 + b*4096 + c*64 + sg*8);
  }
  __syncthreads();
  f32x4 acc[8][2];
  #pragma unroll
  for (int i=0;i<8;i++)
    #pragma unroll
    for (int j=0;j<2;j++) acc[i][j] = (f32x4){0.f,0.f,0.f,0.f};
  #pragma unroll
  for (int kk=0; kk<2; ++kk){
    bfx8 bvp[2];
    #pragma unroll
    for (int ni=0; ni<2; ++ni)
      bvp[ni] = *(const bfx8*)&Xw[(w*32 + ni*16 + (l&15))*72 + kk*32 + (l>>4)*8];
    #pragma unroll
    for (int mi=0; mi<8; ++mi){
      bfx8 av = *(const bfx8*)&Bt[(mi*16 + (l&15))*72 + kk*32 + (l>>4)*8];
      #pragma unroll
      for (int ni=0; ni<2; ++ni)
        acc[mi][ni] = __builtin_amdgcn_mfma_f32_16x16x32_bf16(av, bvp[ni], acc[mi][ni], 0, 0, 0);
    }
  }
  #pragma unroll
  for (int mi=0; mi<8; ++mi){
    #pragma unroll
    for (int ni=0; ni<2; ++ni){
      int gp = p0 + w*32 + ni*16 + (l&15);
      int bhx = b*8 + (gp>>6); int pin = gp & 63;
      int n0 = mi*16 + ((l>>4)<<2);
      u32* cp = (u32*)&CS[(size_t)z*16777216 + (size_t)bhx*524288 + (size_t)c*8192 + (size_t)pin*128 + n0];
      cp[0] = pk2(acc[mi][ni][0], acc[mi][ni][1]);
      cp[1] = pk2(acc[mi][ni][2], acc[mi][ni][3]);
    }
  }
}

// sequential 64-step combine IN PLACE (H aliases CS); 2x n-split
__global__ __launch_bounds__(256)
void combk(const u16* __restrict__ CS, const float* __restrict__ CA,
           u16* __restrict__ H)
{
  __shared__ float aL[64];
  const int bx = blockIdx.x;
  const int z = blockIdx.z;
  const int nh = bx & 1, pg = (bx >> 1) & 3, bh = bx >> 3;
  const int b = bh >> 3, hh = bh & 7;
  const int tid = threadIdx.x;
  const int p = pg*16 + (tid >> 4), n = nh*64 + (tid & 15)*4;
  const size_t rowb = (size_t)z*16384 + (size_t)b*4096;
  if (tid < 64) aL[tid] = __expf(CA[(rowb + tid*64 + 63)*8 + hh]);
  __syncthreads();
  const u16* Cs = CS + (size_t)z*16777216 + (size_t)bh*524288 + (size_t)p*128 + n;
  u16* Hd = H + (size_t)z*16777216 + (size_t)bh*524288 + (size_t)p*128 + n;
  float h[4];
  #pragma unroll
  for (int j=0;j<4;j++) h[j]=0.f;
  uint2 pf = *(const uint2*)Cs;
  #pragma unroll 1
  for (int c=0; c<64; ++c){
    uint2 cur = pf;
    if (c < 63) pf = *(const uint2*)(Cs + (size_t)(c+1)*8192);
    uint2 o;
    o.x = pk2(h[0],h[1]); o.y = pk2(h[2],h[3]);
    *(uint2*)(Hd + (size_t)c*8192) = o;
    float v[4]; unpk4(cur, v);
    const float a = aL[c];
    #pragma unroll
    for (int j=0;j<4;j++) h[j] = fmaf(h[j], a, v[j]);
  }
}

// per-chunk output: Y = (S_decayed @ X + diag(exp(ca)) * (C @ H[c]) + Dh*x) * silu(z)
// S precomputed head-shared (sk); C-operand direct to regs; 45.6KB LDS -> 3 blk/CU
__global__ __launch_bounds__(256)
void yk2(const u16* __restrict__ bcc, const u16* __restrict__ xct,
         const u16* __restrict__ SR,
         const float* __restrict__ DT, const float* __restrict__ CA,
         const u16* __restrict__ H, const float* __restrict__ Dp,
         u16* __restrict__ Y)
{
  __shared__ u16 Ss[64*72];     // [s][t] raw scores
  __shared__ u16 Hs[64*136];    // [p][n]
  __shared__ u16 Xt[64*72];     // [p][s]
  __shared__ u16 Sm[64*72];     // [t][s] decayed
  __shared__ float caL[64], dtL[64];
  const int bx = blockIdx.x, z = blockIdx.z;
  const int c = bx & 63, bh = bx >> 6;
  const int b = bh >> 3, hh = bh & 7;
  const int tid = threadIdx.x, l = tid & 63, w = tid >> 6;
  const size_t rowb = (size_t)z*16384 + (size_t)b*4096;
  const u16* bcp = bcc + (rowb + c*64)*256;
  const u16* Hd = H + (size_t)z*16777216 + (size_t)bh*524288 + (size_t)c*8192;
  const u16* xcp = xct + (size_t)z*8388608 + (size_t)(hh*64)*16384 + b*4096 + c*64;
  const u16* Sd = SR + ((size_t)z*4 + b)*524288 + (size_t)c*4096;
  const float Dh = Dp[z*8 + hh];

  // C-operand fragments direct from global
  bfx8 av[4];
  #pragma unroll
  for (int kk=0; kk<4; ++kk)
    av[kk] = *(const bfx8*)(bcp + (size_t)(w*16 + (l&15))*256 + 128 + kk*32 + (l>>4)*8);

  if (tid < 64){
    caL[tid] = CA[(rowb + c*64 + tid)*8 + hh];
    dtL[tid] = DT[(rowb + c*64 + tid)*8 + hh];
  }
  #pragma unroll
  for (int u=0; u<2; ++u){
    int idx = u*256 + tid; int s = idx >> 3, sg = idx & 7;
    *(uint4*)&Ss[s*72 + sg*8] = *(const uint4*)(Sd + (size_t)s*64 + sg*8);
  }
  #pragma unroll
  for (int u=0; u<4; ++u){
    int idx = u*256 + tid; int p = idx >> 4, sg = idx & 15;
    *(uint4*)&Hs[p*136 + sg*8] = *(const uint4*)(Hd + (size_t)p*128 + sg*8);
  }
  #pragma unroll
  for (int u=0; u<2; ++u){
    int idx = u*256 + tid; int p = idx >> 3, sg = idx & 7;
    *(uint4*)&Xt[p*72 + sg*8] = *(const uint4*)(xcp + (size_t)p*16384 + sg*8);
  }
  __syncthreads();

  // inter part: acc2 = C @ H[c]
  f32x4 acc2[4];
  #pragma unroll
  for (int i=0;i<4;i++) acc2[i] = (f32x4){0.f,0.f,0.f,0.f};
  #pragma unroll
  for (int kk=0; kk<4; ++kk)
    #pragma unroll
    for (int st=0; st<4; ++st){
      bfx8 hv = *(const bfx8*)&Hs[(st*16 + (l&15))*136 + kk*32 + (l>>4)*8];
      acc2[st] = __builtin_amdgcn_mfma_f32_16x16x32_bf16(av[kk], hv, acc2[st], 0, 0, 0);
    }
  // decay+mask precomputed scores -> Sm
  #pragma unroll
  for (int st=0; st<4; ++st){
    #pragma unroll
    for (int q=0;q<4;q++){
      int t = w*16 + (l>>4)*4 + q;
      int s = st*16 + (l&15);
      float m = (s <= t) ? __expf(caL[t]-caL[s]) * dtL[s] : 0.f;
      Sm[t*72 + s] = f2bf(bf2f(Ss[s*72 + t]) * m);
    }
  }
  #pragma unroll
  for (int pt=0; pt<4; ++pt)
    #pragma unroll
    for (int q=0;q<4;q++){
      int t = w*16 + (l>>4)*4 + q;
      acc2[pt][q] *= __expf(caL[t]);
    }
  __syncthreads();
  #pragma unroll
  for (int kk=0; kk<2; ++kk){
    bfx8 sv = *(const bfx8*)&Sm[(w*16 + (l&15))*72 + kk*32 + (l>>4)*8];
    #pragma unroll
    for (int pt=0; pt<4; ++pt){
      bfx8 bv = *(const bfx8*)&Xt[(pt*16 + (l&15))*72 + kk*32 + (l>>4)*8];
      acc2[pt] = __builtin_amdgcn_mfma_f32_16x16x32_bf16(sv, bv, acc2[pt], 0, 0, 0);
    }
  }
  u16* Yrow = Y + (rowb + c*64)*512 + hh*64;
  #pragma unroll
  for (int pt=0; pt<4; ++pt){
    #pragma unroll
    for (int q=0;q<4;q++){
      int t = w*16 + (l>>4)*4 + q;
      int p = pt*16 + (l&15);
      float xv = bf2f(Xt[p*72 + t]);
      float zf = bf2f(Yrow[(size_t)t*512 + p]);
      float yv = (acc2[pt][q] + Dh*xv) * (zf/(1.f+__expf(-zf)));
      Yrow[(size_t)t*512 + p] = f2bf(yv);
    }
  }
}

__global__ __launch_bounds__(256)
void finalk(const float* __restrict__ curr, const u16* __restrict__ outs, float* __restrict__ o)
{
  const int row = blockIdx.x*4 + (threadIdx.x>>6);
  const int c4 = (threadIdx.x & 63)*4;
  const int b = row >> 12, li = row & 4095;
  const int T = ((li & 63) << 6) | (li >> 6);
  const size_t rb = (size_t)b*4096;
  const ushort4 a0 = *(const ushort4*)(outs + (size_t)0*4194304 + ((rb+li)*256 + c4));
  const ushort4 a1 = *(const ushort4*)(outs + (size_t)1*4194304 + ((rb+T)*256 + c4));
  const ushort4 a2 = *(const ushort4*)(outs + (size_t)2*4194304 + ((rb+4095-li)*256 + c4));
  const ushort4 a3 = *(const ushort4*)(outs + (size_t)3*4194304 + ((rb+4095-T)*256 + c4));
  float4 cv = *(const float4*)(curr + (size_t)row*256 + c4);
  float4 r;
  r.x = cv.x + 0.25f*(bf2f(a0.x)+bf2f(a1.x)+bf2f(a2.x)+bf2f(a3.x));
  r.y = cv.y + 0.25f*(bf2f(a0.y)+bf2f(a1.y)+bf2f(a2.y)+bf2f(a3.y));
  r.z = cv.z + 0.25f*(bf2f(a0.z)+bf2f(a1.z)+bf2f(a2.z)+bf2f(a3.z));
  r.w = cv.w + 0.25f*(bf2f(a0.w)+bf2f(a1.w)+bf2f(a2.w)+bf2f(a3.w));
  *(float4*)(o + (size_t)row*256 + c4) = r;
}

// ---------------------------------------------------------------------------
extern "C" void kernel_launch(void* const* d_in, const int* in_sizes, int n_in,
                              void* d_out, int out_size, void* d_ws, size_t ws_size,
                              hipStream_t stream)
{
  (void)in_sizes; (void)n_in; (void)out_size;
  const float* curr   = (const float*)d_in[0];
  const float* prev   = (const float*)d_in[1];
  const float* conv3w = (const float*)d_in[2];
  const float* bn3g=(const float*)d_in[3], *bn3b=(const float*)d_in[4], *bn3m=(const float*)d_in[5], *bn3v=(const float*)d_in[6];
  const float* conv1w = (const float*)d_in[7];
  const float* bn1g=(const float*)d_in[8], *bn1b=(const float*)d_in[9], *bn1m=(const float*)d_in[10], *bn1v=(const float*)d_in[11];
  const float* fuseW=(const float*)d_in[12], *fuseB=(const float*)d_in[13];
  const float* lng=(const float*)d_in[14], *lnb=(const float*)d_in[15];
  const float* inpW=(const float*)d_in[16], *inpB=(const float*)d_in[17];
  const float* mlng=(const float*)d_in[18], *mlnb=(const float*)d_in[19];
  const float* minW=(const float*)d_in[20], *minB=(const float*)d_in[21];
  const float* cw=(const float*)d_in[22], *cb=(const float*)d_in[23];
  const float* alog=(const float*)d_in[24], *Dp=(const float*)d_in[25], *dtb=(const float*)d_in[26];
  const float* mng=(const float*)d_in[27];
  const float* moutW=(const float*)d_in[28], *moutB=(const float*)d_in[29];
  const float* outpW=(const float*)d_in[30], *outpB=(const float*)d_in[31];

  // ---- persistent layout ----
  char* ws = (char*)d_ws;
  size_t off = 0;
  auto alloc = [&](size_t bytes){ size_t o = off; off = (off + bytes + 1023) & ~(size_t)1023; return o; };
  const size_t O_WFUSE = alloc((size_t)256*256*2);
  const size_t O_WINP  = alloc((size_t)4*256*256*2);
  const size_t O_WMIN  = alloc((size_t)4*1288*256*2);
  const size_t O_WMOUT = alloc((size_t)4*256*512*2);
  const size_t O_WOUTP = alloc((size_t)4*256*256*2);
  const size_t O_WC3   = alloc((size_t)128*4608*2);
  const size_t O_WC1   = alloc((size_t)128*512*2);
  const size_t O_BNSS  = alloc(512*4);
  const size_t O_ZF    = alloc((size_t)16384*256*2);
  const size_t O_OUTS  = alloc((size_t)4*16384*256*2);
  const size_t O_P     = off;

  // per-dir sizes (bytes)
  const size_t S0d  = (size_t)16384*256*2;
  const size_t XLNd = (size_t)16384*256*2;
  const size_t Yd   = (size_t)16384*512*2;
  const size_t XCTd = (size_t)512*16384*2;
  const size_t BTd  = (size_t)128*16384*2;
  const size_t DTd  = (size_t)16384*8*4;
  const size_t CAd  = (size_t)16384*8*4;
  const size_t SRd  = (size_t)4*64*4096*2;    // 2.10MB head-shared scores
  const size_t RSd  = (size_t)16384*4;        // row inv-rms
  const size_t XHd  = (size_t)16777216*2;
  const size_t perdir = S0d + XLNd + Yd + XCTd + BTd + DTd + CAd + SRd + RSd + XHd;

  const size_t PADsz = (size_t)4*66*66*512*2;
  const size_t CPsz  = (size_t)9*16384*128*4;
  const size_t PREsz = PADsz + CPsz + (size_t)16384*256*2*2 + 4096;

  int nd = 0;
  for (int cand = 4; cand >= 1; cand >>= 1) {
    size_t need = (size_t)cand*perdir; if (need < PREsz) need = PREsz;
    if (O_P + need <= ws_size) { nd = cand; break; }
  }
  if (nd == 0) return;

  #define WP(o) ((u16*)(ws + (o)))
  #define FP(o) ((float*)(ws + (o)))

  const size_t O_PAD = O_P;
  const size_t O_CP  = O_PAD + PADsz;
  const size_t O_ZIN = O_CP + CPsz;
  const size_t O_ZFT = O_ZIN + (size_t)16384*256*2;

  // 1. BN scale/shift + weight conversions
  bnssk<<<1, 256, 0, stream>>>(bn3g,bn3b,bn3m,bn3v, bn1g,bn1b,bn1m,bn1v, FP(O_BNSS));
  castk<<<64, 256, 0, stream>>>(fuseW, WP(O_WFUSE), 65536);
  castk<<<256, 256, 0, stream>>>(inpW, WP(O_WINP), 262144);
  castk<<<1288, 256, 0, stream>>>(minW, WP(O_WMIN), 1318912);
  castg<<<512, 256, 0, stream>>>(moutW, mng, WP(O_WMOUT));
  castk<<<256, 256, 0, stream>>>(outpW, WP(O_WOUTP), 262144);
  castk<<<64, 256, 0, stream>>>(conv1w, WP(O_WC1), 65536);
  c3rep<<<2304, 256, 0, stream>>>(conv3w, WP(O_WC3));
  // 2. padded concat input (bf16)
  padk<<<4356, 256, 0, stream>>>(curr, prev, WP(O_PAD));

  GemmArgs a;
  // 3. conv3 split-K over 9 taps -> fp32 partials -> reduce+BN+ReLU
  a = {}; a.A = WP(O_PAD); a.pad = WP(O_PAD);
  a.Bw = WP(O_WC3); a.bZ = 512; a.ldb = 4608;
  a.C = WP(O_CP); a.cZ = 2097152; a.ldc = 128; a.colOff = 0; a.K = 512;
  gemm_bt<2,4><<<dim3(128,1,9), 256, 0, stream>>>(a);
  c3red<<<2048, 256, 0, stream>>>(FP(O_CP), FP(O_BNSS), WP(O_ZIN));
  // 4. conv1 -> zin[:,128:256]
  a = {}; a.A = WP(O_PAD); a.pad = WP(O_PAD); a.Bw = WP(O_WC1); a.bZ = 0; a.ldb = 512;
  a.scale = FP(O_BNSS)+256; a.shift = FP(O_BNSS)+384;
  a.C = WP(O_ZIN); a.cZ = 0; a.ldc = 256; a.colOff = 128; a.K = 512;
  gemm_bt<3,2><<<dim3(128,1,1), 256, 0, stream>>>(a);
  // 5. fuse GEMM -> zft
  a = {}; a.A = WP(O_ZIN); a.aZ = 0; a.lda = 256; a.Bw = WP(O_WFUSE); a.bZ = 0; a.ldb = 256;
  a.bias = fuseB; a.biasZ = 0; a.C = WP(O_ZFT); a.cZ = 0; a.ldc = 256; a.colOff = 0; a.K = 256;
  gemm_bt<0,0><<<dim3(128,2,1), 256, 0, stream>>>(a);
  // 6. LN -> zf (persistent)
  ln256<<<dim3(4096,1,1), 256, 0, stream>>>(WP(O_ZFT), 0, WP(O_ZF), 0, lng, lnb, 0);

  // ---- phases over directions ----
  for (int d0 = 0; d0 < 4; d0 += nd) {
    size_t o = O_P;
    const size_t O_S0  = o; o += (size_t)nd*S0d;
    const size_t O_XLN = o; o += (size_t)nd*XLNd;
    const size_t O_Y   = o; o += (size_t)nd*Yd;
    const size_t O_XCT = o; o += (size_t)nd*XCTd;
    const size_t O_BT  = o; o += (size_t)nd*BTd;
    const size_t O_DT  = o; o += (size_t)nd*DTd;
    const size_t O_CA  = o; o += (size_t)nd*CAd;
    const size_t O_SR  = o; o += (size_t)nd*SRd;
    const size_t O_RS  = o; o += (size_t)nd*RSd;
    const size_t O_XH  = o;
    const size_t O_BCC = O_XLN;
    const size_t O_S1  = O_XLN;

    // 7. inp GEMM (permuted rows per dir) -> s0
    a = {}; a.A = WP(O_ZF); a.aZ = 0; a.lda = 256;
    a.Bw = WP(O_WINP) + (size_t)d0*65536; a.bZ = 65536; a.ldb = 256;
    a.bias = inpB + d0*256; a.biasZ = 256;
    a.C = WP(O_S0); a.cZ = 4194304; a.ldc = 256; a.colOff = 0; a.K = 256; a.dirBase = d0;
    gemm_bt<1,0><<<dim3(128,2,nd), 256, 0, stream>>>(a);
    // 8. per-dir LN(s0) -> xln
    ln256<<<dim3(4096,1,nd), 256, 0, stream>>>(WP(O_S0), 4194304, WP(O_XLN), 4194304,
                                               mlng + d0*256, mlnb + d0*256, 256);
    // 9. dt, chunk log-decay
    dtk<<<dim3(512,1,nd), 256, 0, stream>>>(WP(O_XLN), minW + (size_t)d0*329728,
                                            minB + d0*1288, dtb + d0*8, FP(O_DT));
    cak<<<dim3(512,1,nd), 256, 0, stream>>>(FP(O_DT), FP(O_CA), alog, d0);
    // 10. z-gate GEMM -> Y
    a = {}; a.A = WP(O_XLN); a.aZ = 4194304; a.lda = 256;
    a.Bw = WP(O_WMIN) + (size_t)d0*329728; a.bZ = 329728; a.ldb = 256;
    a.bias = minB + d0*1288; a.biasZ = 1288;
    a.C = WP(O_Y); a.cZ = 8388608; a.ldc = 512; a.colOff = 0; a.K = 256;
    gemm_bt<0,0><<<dim3(128,4,nd), 256, 0, stream>>>(a);
    // 11. xBC GEMM -> raw xbc   [last reader of XLN]
    a = {}; a.A = WP(O_XLN); a.aZ = 4194304; a.lda = 256;
    a.Bw = WP(O_WMIN) + (size_t)d0*329728 + (size_t)512*256; a.bZ = 329728; a.ldb = 256;
    a.bias = minB + d0*1288 + 512; a.biasZ = 1288;
    a.C = WP(O_XH); a.cZ = 16777216; a.ldc = 768; a.colOff = 0; a.K = 256;
    gemm_bt<0,0><<<dim3(128,6,nd), 256, 0, stream>>>(a);
    // 12. conv1d+SiLU on B/C -> BCC (overlays XLN)
    convbc<<<nd*2048, 256, 0, stream>>>(WP(O_XH), WP(O_BCC), cw + d0*3072, cb + d0*768);
    // 13. conv1d+SiLU+transpose X -> XCT
    convx<<<dim3(1024,1,nd), 256, 0, stream>>>(WP(O_XH), WP(O_XCT), cw + d0*3072, cb + d0*768);
    // 14. transpose conv'd B -> BT
    btk<<<dim3(256,1,nd), 256, 0, stream>>>(WP(O_BCC), WP(O_BT));
    // 15. head-shared raw scores -> SR
    sk<<<dim3(256,1,nd), 256, 0, stream>>>(WP(O_BCC), WP(O_SR));
    // 16. per-chunk outer products -> CS (overlays raw xbc)
    csk<<<dim3(1024,1,nd), 256, 0, stream>>>(WP(O_XCT), WP(O_BT), FP(O_DT), FP(O_CA), WP(O_XH));
    // 17. 64-step combine in place -> H
    combk<<<dim3(256,1,nd), 256, 0, stream>>>(WP(O_XH), FP(O_CA), WP(O_XH));
    // 18. per-chunk outputs -> Y in place
    yk2<<<dim3(2048,1,nd), 256, 0, stream>>>(WP(O_BCC), WP(O_XCT), WP(O_SR),
                                             FP(O_DT), FP(O_CA), WP(O_XH), Dp + d0*8, WP(O_Y));
    // 19. per-row inv-RMS of Y -> RS
    rnormk<<<dim3(4096,1,nd), 256, 0, stream>>>(WP(O_Y), FP(O_RS));
    // 20. m_out GEMM (norm fused: *rowsc, W pre-scaled by mng) + s0 residual -> s1
    a = {}; a.A = WP(O_Y); a.aZ = 8388608; a.lda = 512;
    a.Bw = WP(O_WMOUT) + (size_t)d0*131072; a.bZ = 131072; a.ldb = 512;
    a.bias = moutB + d0*256; a.biasZ = 256;
    a.add = WP(O_S0); a.addZ = 4194304;
    a.rowsc = FP(O_RS); a.rowscZ = 16384;
    a.C = WP(O_S1); a.cZ = 4194304; a.ldc = 256; a.colOff = 0; a.K = 512;
    gemm_bt<0,5><<<dim3(128,2,nd), 256, 0, stream>>>(a);
    // 21. outp GEMM -> outs (persistent)
    a = {}; a.A = WP(O_S1); a.aZ = 4194304; a.lda = 256;
    a.Bw = WP(O_WOUTP) + (size_t)d0*65536; a.bZ = 65536; a.ldb = 256;
    a.bias = outpB + d0*256; a.biasZ = 256;
    a.C = WP(O_OUTS) + (size_t)d0*4194304; a.cZ = 4194304; a.ldc = 256; a.colOff = 0; a.K = 256;
    gemm_bt<0,0><<<dim3(128,2,nd), 256, 0, stream>>>(a);
  }

  // 22. final inverse-permute average + residual
  finalk<<<4096, 256, 0, stream>>>(curr, WP(O_OUTS), (float*)d_out);

  #undef WP
  #undef FP
}

// Round 11
// 711.658 us; speedup vs baseline: 5.4331x; 1.0250x over previous
//
#include <hip/hip_runtime.h>
#include <hip/hip_bf16.h>
#include <cstdint>
#include <cstddef>

typedef unsigned short u16;
typedef unsigned int u32;
typedef __attribute__((ext_vector_type(8))) __bf16 bfx8;
typedef __attribute__((ext_vector_type(4))) float f32x4;

static __device__ __forceinline__ float bitf(u32 v){ float f; __builtin_memcpy(&f,&v,4); return f; }
static __device__ __forceinline__ float bf2f(u16 v){ return bitf(((u32)v)<<16); }
static __device__ __forceinline__ u16 f2bf(float f){ __bf16 b=(__bf16)f; u16 r; __builtin_memcpy(&r,&b,2); return r; }
static __device__ __forceinline__ u32 pk2(float a,float b){ return (u32)f2bf(a) | ((u32)f2bf(b)<<16); }
static __device__ __forceinline__ void unpk8(uint4 r, float* o){
  o[0]=bitf(r.x<<16); o[1]=bitf(r.x&0xffff0000u);
  o[2]=bitf(r.y<<16); o[3]=bitf(r.y&0xffff0000u);
  o[4]=bitf(r.z<<16); o[5]=bitf(r.z&0xffff0000u);
  o[6]=bitf(r.w<<16); o[7]=bitf(r.w&0xffff0000u);
}
static __device__ __forceinline__ void unpk4(uint2 r, float* o){
  o[0]=bitf(r.x<<16); o[1]=bitf(r.x&0xffff0000u);
  o[2]=bitf(r.y<<16); o[3]=bitf(r.y&0xffff0000u);
}
static __device__ __forceinline__ void async16(void* lds, const void* g){
  __builtin_amdgcn_global_load_lds((const __attribute__((address_space(1))) u32*)g,
                                   (__attribute__((address_space(3))) u32*)lds, 16, 0, 0);
}

// ---------------- GEMM: C[M][N] = A[M][K] @ B[N][K]^T (+ epilogue) -----------
// EPI: 0=+bias, 2=BN+ReLU, 3=+bias+add, 4=raw fp32, 5=*rowsc+bias+add, 6=raw bf16
struct GemmArgs {
  const u16* A; long aZ; int lda;
  const u16* Bw; long bZ; int ldb;
  const float* bias; int biasZ;
  const float* scale; const float* shift;
  const u16* add; long addZ;
  const float* rowsc; long rowscZ;
  u16* C; long cZ; int ldc; int colOff;
  int K;
  const u16* pad;
  int dirBase;
};

template<int AMODE, int EPI>
__global__ __launch_bounds__(256)
void gemm_bt(GemmArgs g)
{
  __shared__ u16 smA[128*64];
  __shared__ u16 smB[128*64];
  const int tid = threadIdx.x;
  const int l = tid & 63;
  const int wv = tid >> 6;
  const int wr = wv >> 1, wc = wv & 1;
  const int z = blockIdx.z;
  const int r0 = blockIdx.x * 128;
  const int n0 = blockIdx.y * 128;

  const u16* Abase = g.A + (size_t)z * g.aZ;
  const u16* Bbase = g.Bw + (size_t)z * g.bZ;
  const int ldb = g.ldb ? g.ldb : g.K;

  f32x4 acc[4][4];
  #pragma unroll
  for (int i=0;i<4;i++)
    #pragma unroll
    for (int j=0;j<4;j++) acc[i][j] = (f32x4){0.f,0.f,0.f,0.f};

  const int nkt = g.K >> 6;
  #pragma unroll 1
  for (int kt=0; kt<nkt; ++kt) {
    const int k0 = kt << 6;
    #pragma unroll
    for (int it=0; it<4; ++it) {
      const int s = it*256 + tid;
      const int row = s >> 3, ch = s & 7;
      const u16* ga;
      if (AMODE == 0) {
        ga = Abase + (size_t)(r0+row) * g.lda + k0 + ch*8;
      } else if (AMODE == 1) {
        int rr = r0 + row; int li = rr & 4095; int bb = rr >> 12;
        int dir = g.dirBase + z;
        int l2 = (dir & 2) ? (4095 - li) : li;
        int sl = (dir & 1) ? (((l2 & 63) << 6) | (l2 >> 6)) : l2;
        ga = Abase + (size_t)((bb << 12) | sl) * g.lda + k0 + ch*8;
      } else if (AMODE == 2) {
        int rr = r0 + row; int bb = rr >> 12; int li = rr & 4095;
        int yy = li >> 6, xx = li & 63;
        int tap = z, kin = k0;
        int dy = tap / 3 - 1, dx = tap % 3 - 1;
        ga = g.pad + (((size_t)(bb*66 + yy+dy+1))*66 + (xx+dx+1))*512 + kin + ch*8;
      } else {
        int rr = r0 + row; int bb = rr >> 12; int li = rr & 4095;
        int yy = li >> 6, xx = li & 63;
        ga = g.pad + (((size_t)(bb*66 + yy+1))*66 + (xx+1))*512 + k0 + ch*8;
      }
      async16(&smA[(size_t)(it*256 + (tid & ~63))*8], ga);
      const u16* gb = Bbase + (size_t)(n0+row) * ldb + k0 + ch*8;
      async16(&smB[(size_t)(it*256 + (tid & ~63))*8], gb);
    }
    __syncthreads();
    #pragma unroll
    for (int kk=0; kk<2; ++kk) {
      bfx8 av[4], bv[4];
      #pragma unroll
      for (int mi=0; mi<4; ++mi) {
        int ra = wr*64 + mi*16 + (l & 15);
        av[mi] = *(const bfx8*)&smA[ra*64 + kk*32 + (l>>4)*8];
      }
      #pragma unroll
      for (int ni=0; ni<4; ++ni) {
        int rb = wc*64 + ni*16 + (l & 15);
        bv[ni] = *(const bfx8*)&smB[rb*64 + kk*32 + (l>>4)*8];
      }
      #pragma unroll
      for (int mi=0; mi<4; ++mi)
        #pragma unroll
        for (int ni=0; ni<4; ++ni)
          acc[mi][ni] = __builtin_amdgcn_mfma_f32_16x16x32_bf16(av[mi], bv[ni], acc[mi][ni], 0, 0, 0);
    }
    __syncthreads();
  }

  const float* bias_d = (EPI == 0 || EPI == 3 || EPI == 5) ? g.bias + (size_t)z * g.biasZ : nullptr;
  const u16* add_d = (EPI == 3 || EPI == 5) ? g.add + (size_t)z * g.addZ : nullptr;
  const float* rowsc_d = (EPI == 5) ? g.rowsc + (size_t)z * g.rowscZ : nullptr;
  u16* Cd = g.C + (size_t)z * g.cZ;
  float* Cf = (float*)g.C + (size_t)z * g.cZ;
  #pragma unroll
  for (int mi=0; mi<4; ++mi) {
    #pragma unroll
    for (int ni=0; ni<4; ++ni) {
      f32x4 v = acc[mi][ni];
      const int gr = r0 + wr*64 + mi*16 + ((l >> 4) << 2);
      const int gc = n0 + wc*64 + ni*16 + (l & 15);
      #pragma unroll
      for (int q=0; q<4; ++q) {
        const int r = gr + q;
        float x = v[q];
        if (EPI == 2) {
          x = fmaxf(fmaf(x, g.scale[gc], g.shift[gc]), 0.f);
          Cd[(size_t)r * g.ldc + g.colOff + gc] = f2bf(x);
        } else if (EPI == 3) {
          x += bias_d[gc] + bf2f(add_d[(size_t)r * g.ldc + gc]);
          Cd[(size_t)r * g.ldc + g.colOff + gc] = f2bf(x);
        } else if (EPI == 5) {
          x = x * rowsc_d[r] + bias_d[gc] + bf2f(add_d[(size_t)r * g.ldc + gc]);
          Cd[(size_t)r * g.ldc + g.colOff + gc] = f2bf(x);
        } else if (EPI == 4) {
          Cf[(size_t)r * g.ldc + g.colOff + gc] = x;
        } else if (EPI == 6) {
          Cd[(size_t)r * g.ldc + g.colOff + gc] = f2bf(x);
        } else {
          x += bias_d[gc];
          Cd[(size_t)r * g.ldc + g.colOff + gc] = f2bf(x);
        }
      }
    }
  }
}

// ---------------- small utility kernels --------------------------------------
__global__ void castk(const float* __restrict__ s, u16* __restrict__ d, int n)
{
  int i = (blockIdx.x*256 + threadIdx.x)*4;
  if (i < n){
    float4 v = *(const float4*)(s+i);
    ushort4 o; o.x=f2bf(v.x); o.y=f2bf(v.y); o.z=f2bf(v.z); o.w=f2bf(v.w);
    *(ushort4*)(d+i) = o;
  }
}

// cast m_out W with norm gain folded in
__global__ void castg(const float* __restrict__ s, const float* __restrict__ gw,
                      u16* __restrict__ d)
{
  int i = (blockIdx.x*256 + threadIdx.x)*4;
  int dd = i >> 17, k = i & 511;
  float4 v = *(const float4*)(s+i);
  float4 g4 = *(const float4*)(gw + dd*512 + k);
  ushort4 o; o.x=f2bf(v.x*g4.x); o.y=f2bf(v.y*g4.y); o.z=f2bf(v.z*g4.z); o.w=f2bf(v.w*g4.w);
  *(ushort4*)(d+i) = o;
}

__global__ void c3rep(const float* __restrict__ w, u16* __restrict__ o)
{
  int id = blockIdx.x*256 + threadIdx.x;
  int oc = id / 4608, rem = id % 4608;
  int tap = rem >> 9, ic = rem & 511;
  o[id] = f2bf(w[((size_t)oc*512 + ic)*9 + tap]);
}

__global__ void bnssk(const float* g3,const float* b3,const float* m3,const float* v3,
                      const float* g1,const float* b1,const float* m1,const float* v1,
                      float* out)
{
  int t = threadIdx.x; int i = t & 127;
  if (t < 128){ float sc = g3[i]*rsqrtf(v3[i]+1e-5f); out[i]=sc; out[128+i]=b3[i]-m3[i]*sc; }
  else        { float sc = g1[i]*rsqrtf(v1[i]+1e-5f); out[256+i]=sc; out[384+i]=b1[i]-m1[i]*sc; }
}

// reduce 9 bf16 partials -> BN+ReLU -> bf16 into zin cols 0..127
__global__ __launch_bounds__(256)
void c3red(const u16* __restrict__ P, const float* __restrict__ bnss, u16* __restrict__ zin)
{
  const int id = blockIdx.x*256 + threadIdx.x;   // 262144 units of 8
  const size_t base = (size_t)id * 8;
  const int r = (int)(base >> 7), c = (int)(base & 127);
  float s[8] = {0,0,0,0,0,0,0,0};
  #pragma unroll
  for (int z=0; z<9; ++z){
    uint4 raw = *(const uint4*)(P + (size_t)z*2097152 + base);
    float v[8]; unpk8(raw, v);
    #pragma unroll
    for (int j=0;j<8;j++) s[j] += v[j];
  }
  uint4 o;
  float r8[8];
  #pragma unroll
  for (int j=0;j<8;j++)
    r8[j] = fmaxf(fmaf(s[j], bnss[c+j], bnss[128+c+j]), 0.f);
  o.x = pk2(r8[0],r8[1]); o.y = pk2(r8[2],r8[3]);
  o.z = pk2(r8[4],r8[5]); o.w = pk2(r8[6],r8[7]);
  *(uint4*)(zin + (size_t)r*256 + c) = o;
}

__global__ __launch_bounds__(256)
void padk(const float* __restrict__ curr, const float* __restrict__ prev, u16* __restrict__ pad)
{
  const int id = blockIdx.x*256 + threadIdx.x;
  const int c8 = id & 63;
  int t = id >> 6;
  const int xx = t % 66; t /= 66;
  const int yy = t % 66; const int b = t / 66;
  const int c0 = c8*8;
  uint4 o;
  if (yy==0 || yy==65 || xx==0 || xx==65){ o.x=0;o.y=0;o.z=0;o.w=0; }
  else {
    const int l = (yy-1)*64 + (xx-1);
    const float* s = (c0 < 256) ? curr + ((size_t)b*4096 + l)*256 + c0
                                : prev + ((size_t)b*4096 + l)*256 + (c0-256);
    float4 a = *(const float4*)s, bb = *(const float4*)(s+4);
    o.x = pk2(a.x,a.y); o.y = pk2(a.z,a.w); o.z = pk2(bb.x,bb.y); o.w = pk2(bb.z,bb.w);
  }
  *(uint4*)(pad + (((size_t)b*66 + yy)*66 + xx)*512 + c0) = o;
}

__global__ __launch_bounds__(256)
void ln256(const u16* __restrict__ in, long inZ, u16* __restrict__ out, long outZ,
           const float* __restrict__ gw, const float* __restrict__ bw, int pz)
{
  const int z = blockIdx.z;
  const int row = blockIdx.x*4 + (threadIdx.x>>6);
  const int l = threadIdx.x & 63;
  const u16* ip = in + (size_t)z*inZ + (size_t)row*256 + l*4;
  ushort4 rr = *(const ushort4*)ip;
  float v0=bf2f(rr.x), v1=bf2f(rr.y), v2=bf2f(rr.z), v3=bf2f(rr.w);
  float s = v0+v1+v2+v3;
  float ss = v0*v0+v1*v1+v2*v2+v3*v3;
  #pragma unroll
  for(int m=1;m<64;m<<=1){ s += __shfl_xor(s,m); ss += __shfl_xor(ss,m); }
  float mu = s*(1.f/256.f);
  float var = ss*(1.f/256.f) - mu*mu;
  float rs = rsqrtf(var + 1e-5f);
  const float* g = gw + (size_t)z*pz; const float* b = bw + (size_t)z*pz;
  int c = l*4;
  u16* op = out + (size_t)z*outZ + (size_t)row*256 + c;
  ushort4 o; o.x=f2bf((v0-mu)*rs*g[c]+b[c]); o.y=f2bf((v1-mu)*rs*g[c+1]+b[c+1]);
  o.z=f2bf((v2-mu)*rs*g[c+2]+b[c+2]); o.w=f2bf((v3-mu)*rs*g[c+3]+b[c+3]);
  *(ushort4*)op = o;
}

// sum 8 head partial SS -> inverse RMS per row
__global__ __launch_bounds__(256)
void rsumk(const float* __restrict__ RS8, float* __restrict__ RS)
{
  const int z = blockIdx.z;
  const int row = blockIdx.x*256 + threadIdx.x;
  const float* p = RS8 + ((size_t)z*16384 + row)*8;
  float4 a = *(const float4*)p, b = *(const float4*)(p+4);
  float s = a.x+a.y+a.z+a.w+b.x+b.y+b.z+b.w;
  RS[(size_t)z*16384 + row] = rsqrtf(s*(1.f/512.f) + 1e-5f);
}

// fp32 dt head: dt = softplus(xln.W_dt + b + dt_bias)
__global__ __launch_bounds__(256)
void dtk(const u16* __restrict__ xln, const float* __restrict__ minW,
         const float* __restrict__ minB, const float* __restrict__ dtb,
         float* __restrict__ DT)
{
  __shared__ float sx[32*257];
  const int z = blockIdx.z;
  const int r0 = blockIdx.x * 32;
  const int tid = threadIdx.x;
  {
    const int rr = tid >> 3, cc = (tid & 7) * 32;
    const u16* src = xln + ((size_t)z*16384 + r0 + rr)*256 + cc;
    #pragma unroll
    for (int q=0;q<4;q++){
      uint4 raw = *(const uint4*)(src + q*8);
      float v[8]; unpk8(raw, v);
      #pragma unroll
      for (int j=0;j<8;j++) sx[rr*257 + cc + q*8 + j] = v[j];
    }
  }
  __syncthreads();
  const int ri = tid >> 3, hv = tid & 7;
  const float* wrow = minW + ((size_t)z*1288 + 1280 + hv)*256;
  float acc = 0.f;
  #pragma unroll 4
  for (int k=0; k<256; k+=4){
    float4 wq = *(const float4*)(wrow + k);
    acc += sx[ri*257+k]*wq.x + sx[ri*257+k+1]*wq.y + sx[ri*257+k+2]*wq.z + sx[ri*257+k+3]*wq.w;
  }
  acc += minB[(size_t)z*1288 + 1280 + hv] + dtb[z*8 + hv];
  float dt = (acc > 20.f) ? acc : log1pf(expf(acc));
  DT[((size_t)z*16384 + r0 + ri)*8 + hv] = dt;
}

// chunk-local cumulative log-decay
__global__ __launch_bounds__(256)
void cak(const float* __restrict__ DT, float* __restrict__ CA,
         const float* __restrict__ alog, int dirBase)
{
  const int z = blockIdx.z;
  const int gidx = blockIdx.x*4 + (threadIdx.x>>6);
  const int lane = threadIdx.x & 63;
  const int c = gidx & 63, bh = gidx >> 6;
  const int b = bh >> 3, hh = bh & 7;
  const size_t row = (size_t)z*16384 + (size_t)b*4096 + c*64 + lane;
  float x = DT[row*8 + hh];
  #pragma unroll
  for (int m=1;m<64;m<<=1){ float o = __shfl_up(x, m); if (lane >= m) x += o; }
  float eA = expf(alog[(dirBase+z)*8 + hh]);
  CA[row*8 + hh] = -eA * x;
}

// fused: conv1d(4)+SiLU on B/C columns + C-half -> BCC + B-transpose -> BT
//        + head-shared raw scores S -> SR.   grid (256,1,nd) per (b,c)
__global__ __launch_bounds__(256)
void bck(const u16* __restrict__ xbcr, u16* __restrict__ bcc, u16* __restrict__ bt,
         u16* __restrict__ SR, const float* __restrict__ cw, const float* __restrict__ cb)
{
  __shared__ u16 BCs[64*264];   // [s][B:0..127, C:128..255]
  __shared__ u16 Tb[128*72];    // [n][s] transposed B
  __shared__ float cwS[4][256];
  __shared__ float cbS[256];
  const int bx = blockIdx.x, z = blockIdx.z;
  const int c = bx & 63, b = bx >> 6;
  const int tid = threadIdx.x, l = tid & 63, w = tid >> 6;
  const u16* xb = xbcr + (size_t)z*16777216 + (size_t)b*4096*768;
  const float* cwp = cw + (size_t)z*3072;
  const float* cbp = cb + (size_t)z*768;
  {
    float4 w4 = *(const float4*)(cwp + (512 + tid)*4);
    cwS[0][tid]=w4.x; cwS[1][tid]=w4.y; cwS[2][tid]=w4.z; cwS[3][tid]=w4.w;
    cbS[tid] = cbp[512 + tid];
  }
  __syncthreads();
  // conv B/C: 2048 units of 8 cols
  #pragma unroll
  for (int u=0; u<8; ++u){
    int idx = u*256 + tid;
    int s = idx >> 5, c8 = idx & 31;
    int li = c*64 + s;
    int col = 512 + c8*8;
    float acc[8];
    #pragma unroll
    for (int j=0;j<8;j++) acc[j] = cbS[c8*8+j];
    #pragma unroll
    for (int tap=0; tap<4; ++tap){
      int lt = li - 3 + tap;
      if (lt >= 0){
        uint4 raw = *(const uint4*)(xb + (size_t)lt*768 + col);
        float v[8]; unpk8(raw, v);
        #pragma unroll
        for (int j=0;j<8;j++) acc[j] = fmaf(v[j], cwS[tap][c8*8+j], acc[j]);
      }
    }
    u16 o8[8];
    #pragma unroll
    for (int j=0;j<8;j++) o8[j] = f2bf(acc[j] / (1.f + __expf(-acc[j])));
    *(uint4*)&BCs[s*264 + c8*8] = *(const uint4*)o8;
    if (c8 >= 16){
      *(uint4*)(bcc + ((size_t)z*16384 + (size_t)b*4096 + li)*256 + c8*8) = *(const uint4*)o8;
    } else {
      #pragma unroll
      for (int j=0;j<8;j++) Tb[(c8*8+j)*72 + s] = o8[j];
    }
  }
  __syncthreads();
  // S = C@B^T (16 MFMA)
  bfx8 av[4];
  #pragma unroll
  for (int kk=0; kk<4; ++kk)
    av[kk] = *(const bfx8*)&BCs[(w*16 + (l&15))*264 + 128 + kk*32 + (l>>4)*8];
  f32x4 sacc[4];
  #pragma unroll
  for (int i=0;i<4;i++) sacc[i] = (f32x4){0.f,0.f,0.f,0.f};
  #pragma unroll
  for (int kk=0; kk<4; ++kk)
    #pragma unroll
    for (int st=0; st<4; ++st){
      bfx8 bv = *(const bfx8*)&BCs[(st*16 + (l&15))*264 + kk*32 + (l>>4)*8];
      sacc[st] = __builtin_amdgcn_mfma_f32_16x16x32_bf16(av[kk], bv, sacc[st], 0, 0, 0);
    }
  // SR stride per (z,b) is 262144 u16 (64 chunks x 4096) — R10 bug was 524288
  u16* Sd = SR + ((size_t)z*4 + b)*262144 + (size_t)c*4096;
  const int t0 = w*16 + ((l>>4)<<2);
  #pragma unroll
  for (int st=0; st<4; ++st){
    int s = st*16 + (l&15);
    u32* cp = (u32*)&Sd[(size_t)s*64 + t0];
    cp[0] = pk2(sacc[st][0], sacc[st][1]);
    cp[1] = pk2(sacc[st][2], sacc[st][3]);
  }
  // BT global write from Tb (vectorized)
  #pragma unroll
  for (int u=0; u<4; ++u){
    int idx = u*256 + tid;
    int n = idx >> 3, sg = idx & 7;
    uint4 v = *(const uint4*)&Tb[n*72 + sg*8];
    *(uint4*)(bt + (size_t)z*2097152 + (size_t)n*16384 + (size_t)b*4096 + c*64 + sg*8) = v;
  }
}

// conv1d(4)+SiLU on X cols (raw 0..511) + transpose -> XCT[p][g]
__global__ __launch_bounds__(256)
void convx(const u16* __restrict__ xbcr, u16* __restrict__ xct,
           const float* __restrict__ cw, const float* __restrict__ cb)
{
  __shared__ u16 T[128*72];
  __shared__ float cwX[4][128];
  __shared__ float cbX[128];
  const int bx = blockIdx.x, z = blockIdx.z;
  const int pq = bx & 3, c = (bx>>2) & 63, b = bx >> 8;
  const int tid = threadIdx.x;
  const u16* xb = xbcr + (size_t)z*16777216 + (size_t)b*4096*768;
  if (tid < 128){
    float4 w4 = *(const float4*)(cw + (size_t)z*3072 + (pq*128+tid)*4);
    cwX[0][tid]=w4.x; cwX[1][tid]=w4.y; cwX[2][tid]=w4.z; cwX[3][tid]=w4.w;
    cbX[tid] = cb[z*768 + pq*128 + tid];
  }
  __syncthreads();
  #pragma unroll
  for (int u=0; u<4; ++u){
    int idx = u*256 + tid;
    int s = idx >> 4, seg = idx & 15;
    int li = c*64 + s;
    int col = pq*128 + seg*8;
    float acc[8];
    #pragma unroll
    for (int j=0;j<8;j++) acc[j] = cbX[seg*8+j];
    #pragma unroll
    for (int tap=0; tap<4; ++tap){
      int lt = li - 3 + tap;
      if (lt >= 0){
        uint4 raw = *(const uint4*)(xb + (size_t)lt*768 + col);
        float v[8]; unpk8(raw, v);
        #pragma unroll
        for (int j=0;j<8;j++) acc[j] = fmaf(v[j], cwX[tap][seg*8+j], acc[j]);
      }
    }
    #pragma unroll
    for (int j=0;j<8;j++)
      T[(seg*8+j)*72 + s] = f2bf(acc[j] / (1.f + __expf(-acc[j])));
  }
  __syncthreads();
  #pragma unroll
  for (int u=0; u<4; ++u){
    int idx = u*256 + tid;
    int pl = idx >> 3, sg = idx & 7;
    uint4 v = *(const uint4*)&T[pl*72 + sg*8];
    *(uint4*)(xct + (size_t)z*8388608 + (size_t)(pq*128+pl)*16384 + b*4096 + c*64 + sg*8) = v;
  }
}

// per-chunk outer products, heads fused, p-quarter per block; grid (1024,1,nd)
__global__ __launch_bounds__(256)
void csk(const u16* __restrict__ xct, const u16* __restrict__ bt,
         const float* __restrict__ DT, const float* __restrict__ CA,
         u16* __restrict__ CS)
{
  __shared__ u16 Xw[128*72];
  __shared__ u16 Bt[128*72];
  __shared__ float wS[64*2];
  const int bx = blockIdx.x, z = blockIdx.z;
  const int pq = bx & 3, c = (bx>>2) & 63, b = bx >> 8;
  const int tid = threadIdx.x, l = tid & 63, w = tid >> 6;
  const size_t rowb = (size_t)z*16384 + (size_t)b*4096;
  const int p0 = pq*128;
  if (tid < 128){
    int s = tid & 63, hi = tid >> 6;
    int hh = pq*2 + hi;
    float ca63 = CA[(rowb + c*64 + 63)*8 + hh];
    float cav  = CA[(rowb + c*64 + s)*8 + hh];
    float dtv  = DT[(rowb + c*64 + s)*8 + hh];
    wS[s*2+hi] = __expf(ca63 - cav) * dtv;
  }
  __syncthreads();
  #pragma unroll
  for (int u=0; u<4; ++u){
    int idx = u*256 + tid;
    int pl = idx >> 3, sg = idx & 7;
    int hi = pl >> 6;
    uint4 raw = *(const uint4*)(xct + (size_t)z*8388608 + (size_t)(p0+pl)*16384 + b*4096 + c*64 + sg*8);
    float v[8]; unpk8(raw, v);
    uint4 o;
    o.x = pk2(v[0]*wS[(sg*8+0)*2+hi], v[1]*wS[(sg*8+1)*2+hi]);
    o.y = pk2(v[2]*wS[(sg*8+2)*2+hi], v[3]*wS[(sg*8+3)*2+hi]);
    o.z = pk2(v[4]*wS[(sg*8+4)*2+hi], v[5]*wS[(sg*8+5)*2+hi]);
    o.w = pk2(v[6]*wS[(sg*8+6)*2+hi], v[7]*wS[(sg*8+7)*2+hi]);
    *(uint4*)&Xw[pl*72 + sg*8] = o;
  }
  #pragma unroll
  for (int u=0; u<4; ++u){
    int idx = u*256 + tid;
    int n = idx >> 3, sg = idx & 7;
    *(uint4*)&Bt[n*72 + sg*8] =
      *(const uint4*)(bt + (size_t)z*2097152 + (size_t)n*16384 + b*4096 + c*64 + sg*8);
  }
  __syncthreads();
  f32x4 acc[8][2];
  #pragma unroll
  for (int i=0;i<8;i++)
    #pragma unroll
    for (int j=0;j<2;j++) acc[i][j] = (f32x4){0.f,0.f,0.f,0.f};
  #pragma unroll
  for (int kk=0; kk<2; ++kk){
    bfx8 bvp[2];
    #pragma unroll
    for (int ni=0; ni<2; ++ni)
      bvp[ni] = *(const bfx8*)&Xw[(w*32 + ni*16 + (l&15))*72 + kk*32 + (l>>4)*8];
    #pragma unroll
    for (int mi=0; mi<8; ++mi){
      bfx8 av = *(const bfx8*)&Bt[(mi*16 + (l&15))*72 + kk*32 + (l>>4)*8];
      #pragma unroll
      for (int ni=0; ni<2; ++ni)
        acc[mi][ni] = __builtin_amdgcn_mfma_f32_16x16x32_bf16(av, bvp[ni], acc[mi][ni], 0, 0, 0);
    }
  }
  #pragma unroll
  for (int mi=0; mi<8; ++mi){
    #pragma unroll
    for (int ni=0; ni<2; ++ni){
      int gp = p0 + w*32 + ni*16 + (l&15);
      int bhx = b*8 + (gp>>6); int pin = gp & 63;
      int n0 = mi*16 + ((l>>4)<<2);
      u32* cp = (u32*)&CS[(size_t)z*16777216 + (size_t)bhx*524288 + (size_t)c*8192 + (size_t)pin*128 + n0];
      cp[0] = pk2(acc[mi][ni][0], acc[mi][ni][1]);
      cp[1] = pk2(acc[mi][ni][2], acc[mi][ni][3]);
    }
  }
}

// sequential 64-step combine IN PLACE (H aliases CS); 2x n-split
__global__ __launch_bounds__(256)
void combk(const u16* __restrict__ CS, const float* __restrict__ CA,
           u16* __restrict__ H)
{
  __shared__ float aL[64];
  const int bx = blockIdx.x;
  const int z = blockIdx.z;
  const int nh = bx & 1, pg = (bx >> 1) & 3, bh = bx >> 3;
  const int b = bh >> 3, hh = bh & 7;
  const int tid = threadIdx.x;
  const int p = pg*16 + (tid >> 4), n = nh*64 + (tid & 15)*4;
  const size_t rowb = (size_t)z*16384 + (size_t)b*4096;
  if (tid < 64) aL[tid] = __expf(CA[(rowb + tid*64 + 63)*8 + hh]);
  __syncthreads();
  const u16* Cs = CS + (size_t)z*16777216 + (size_t)bh*524288 + (size_t)p*128 + n;
  u16* Hd = H + (size_t)z*16777216 + (size_t)bh*524288 + (size_t)p*128 + n;
  float h[4];
  #pragma unroll
  for (int j=0;j<4;j++) h[j]=0.f;
  uint2 pf = *(const uint2*)Cs;
  #pragma unroll 1
  for (int c=0; c<64; ++c){
    uint2 cur = pf;
    if (c < 63) pf = *(const uint2*)(Cs + (size_t)(c+1)*8192);
    uint2 o;
    o.x = pk2(h[0],h[1]); o.y = pk2(h[2],h[3]);
    *(uint2*)(Hd + (size_t)c*8192) = o;
    float v[4]; unpk4(cur, v);
    const float a = aL[c];
    #pragma unroll
    for (int j=0;j<4;j++) h[j] = fmaf(h[j], a, v[j]);
  }
}

// per-chunk output: Y = (S_decayed @ X + diag(exp(ca)) * (C @ H[c]) + Dh*x) * silu(z)
// + per-(row,head) sum-of-squares for fused RMS (non-atomic, exclusive ownership)
__global__ __launch_bounds__(256)
void yk2(const u16* __restrict__ bcc, const u16* __restrict__ xct,
         const u16* __restrict__ SR,
         const float* __restrict__ DT, const float* __restrict__ CA,
         const u16* __restrict__ H, const float* __restrict__ Dp,
         u16* __restrict__ Y, float* __restrict__ RS8)
{
  __shared__ u16 Ss[64*72];
  __shared__ u16 Hs[64*136];
  __shared__ u16 Xt[64*72];
  __shared__ u16 Sm[64*72];
  __shared__ float caL[64], dtL[64];
  const int bx = blockIdx.x, z = blockIdx.z;
  const int c = bx & 63, bh = bx >> 6;
  const int b = bh >> 3, hh = bh & 7;
  const int tid = threadIdx.x, l = tid & 63, w = tid >> 6;
  const size_t rowb = (size_t)z*16384 + (size_t)b*4096;
  const u16* bcp = bcc + (rowb + c*64)*256;
  const u16* Hd = H + (size_t)z*16777216 + (size_t)bh*524288 + (size_t)c*8192;
  const u16* xcp = xct + (size_t)z*8388608 + (size_t)(hh*64)*16384 + b*4096 + c*64;
  // SR stride per (z,b) is 262144 u16 — matches bck (R10 bug was 524288)
  const u16* Sd = SR + ((size_t)z*4 + b)*262144 + (size_t)c*4096;
  const float Dh = Dp[z*8 + hh];

  bfx8 av[4];
  #pragma unroll
  for (int kk=0; kk<4; ++kk)
    av[kk] = *(const bfx8*)(bcp + (size_t)(w*16 + (l&15))*256 + 128 + kk*32 + (l>>4)*8);

  if (tid < 64){
    caL[tid] = CA[(rowb + c*64 + tid)*8 + hh];
    dtL[tid] = DT[(rowb + c*64 + tid)*8 + hh];
  }
  #pragma unroll
  for (int u=0; u<2; ++u){
    int idx = u*256 + tid; int s = idx >> 3, sg = idx & 7;
    *(uint4*)&Ss[s*72 + sg*8] = *(const uint4*)(Sd + (size_t)s*64 + sg*8);
  }
  #pragma unroll
  for (int u=0; u<4; ++u){
    int idx = u*256 + tid; int p = idx >> 4, sg = idx & 15;
    *(uint4*)&Hs[p*136 + sg*8] = *(const uint4*)(Hd + (size_t)p*128 + sg*8);
  }
  #pragma unroll
  for (int u=0; u<2; ++u){
    int idx = u*256 + tid; int p = idx >> 3, sg = idx & 7;
    *(uint4*)&Xt[p*72 + sg*8] = *(const uint4*)(xcp + (size_t)p*16384 + sg*8);
  }
  __syncthreads();

  f32x4 acc2[4];
  #pragma unroll
  for (int i=0;i<4;i++) acc2[i] = (f32x4){0.f,0.f,0.f,0.f};
  #pragma unroll
  for (int kk=0; kk<4; ++kk)
    #pragma unroll
    for (int st=0; st<4; ++st){
      bfx8 hv = *(const bfx8*)&Hs[(st*16 + (l&15))*136 + kk*32 + (l>>4)*8];
      acc2[st] = __builtin_amdgcn_mfma_f32_16x16x32_bf16(av[kk], hv, acc2[st], 0, 0, 0);
    }
  #pragma unroll
  for (int st=0; st<4; ++st){
    #pragma unroll
    for (int q=0;q<4;q++){
      int t = w*16 + (l>>4)*4 + q;
      int s = st*16 + (l&15);
      float m = (s <= t) ? __expf(caL[t]-caL[s]) * dtL[s] : 0.f;
      Sm[t*72 + s] = f2bf(bf2f(Ss[s*72 + t]) * m);
    }
  }
  #pragma unroll
  for (int pt=0; pt<4; ++pt)
    #pragma unroll
    for (int q=0;q<4;q++){
      int t = w*16 + (l>>4)*4 + q;
      acc2[pt][q] *= __expf(caL[t]);
    }
  __syncthreads();
  #pragma unroll
  for (int kk=0; kk<2; ++kk){
    bfx8 sv = *(const bfx8*)&Sm[(w*16 + (l&15))*72 + kk*32 + (l>>4)*8];
    #pragma unroll
    for (int pt=0; pt<4; ++pt){
      bfx8 bv = *(const bfx8*)&Xt[(pt*16 + (l&15))*72 + kk*32 + (l>>4)*8];
      acc2[pt] = __builtin_amdgcn_mfma_f32_16x16x32_bf16(sv, bv, acc2[pt], 0, 0, 0);
    }
  }
  u16* Yrow = Y + (rowb + c*64)*512 + hh*64;
  float ssq[4] = {0.f,0.f,0.f,0.f};
  #pragma unroll
  for (int pt=0; pt<4; ++pt){
    #pragma unroll
    for (int q=0;q<4;q++){
      int t = w*16 + (l>>4)*4 + q;
      int p = pt*16 + (l&15);
      float xv = bf2f(Xt[p*72 + t]);
      float zf = bf2f(Yrow[(size_t)t*512 + p]);
      float yv = (acc2[pt][q] + Dh*xv) * (zf/(1.f+__expf(-zf)));
      ssq[q] += yv*yv;
      Yrow[(size_t)t*512 + p] = f2bf(yv);
    }
  }
  #pragma unroll
  for (int q=0;q<4;q++){
    float s = ssq[q];
    s += __shfl_xor(s, 1); s += __shfl_xor(s, 2);
    s += __shfl_xor(s, 4); s += __shfl_xor(s, 8);
    if ((l & 15) == 0){
      int t = w*16 + (l>>4)*4 + q;
      RS8[(rowb + c*64 + t)*8 + hh] = s;
    }
  }
}

__global__ __launch_bounds__(256)
void finalk(const float* __restrict__ curr, const u16* __restrict__ outs, float* __restrict__ o)
{
  const int row = blockIdx.x*4 + (threadIdx.x>>6);
  const int c4 = (threadIdx.x & 63)*4;
  const int b = row >> 12, li = row & 4095;
  const int T = ((li & 63) << 6) | (li >> 6);
  const size_t rb = (size_t)b*4096;
  const ushort4 a0 = *(const ushort4*)(outs + (size_t)0*4194304 + ((rb+li)*256 + c4));
  const ushort4 a1 = *(const ushort4*)(outs + (size_t)1*4194304 + ((rb+T)*256 + c4));
  const ushort4 a2 = *(const ushort4*)(outs + (size_t)2*4194304 + ((rb+4095-li)*256 + c4));
  const ushort4 a3 = *(const ushort4*)(outs + (size_t)3*4194304 + ((rb+4095-T)*256 + c4));
  float4 cv = *(const float4*)(curr + (size_t)row*256 + c4);
  float4 r;
  r.x = cv.x + 0.25f*(bf2f(a0.x)+bf2f(a1.x)+bf2f(a2.x)+bf2f(a3.x));
  r.y = cv.y + 0.25f*(bf2f(a0.y)+bf2f(a1.y)+bf2f(a2.y)+bf2f(a3.y));
  r.z = cv.z + 0.25f*(bf2f(a0.z)+bf2f(a1.z)+bf2f(a2.z)+bf2f(a3.z));
  r.w = cv.w + 0.25f*(bf2f(a0.w)+bf2f(a1.w)+bf2f(a2.w)+bf2f(a3.w));
  *(float4*)(o + (size_t)row*256 + c4) = r;
}

// ---------------------------------------------------------------------------
extern "C" void kernel_launch(void* const* d_in, const int* in_sizes, int n_in,
                              void* d_out, int out_size, void* d_ws, size_t ws_size,
                              hipStream_t stream)
{
  (void)in_sizes; (void)n_in; (void)out_size;
  const float* curr   = (const float*)d_in[0];
  const float* prev   = (const float*)d_in[1];
  const float* conv3w = (const float*)d_in[2];
  const float* bn3g=(const float*)d_in[3], *bn3b=(const float*)d_in[4], *bn3m=(const float*)d_in[5], *bn3v=(const float*)d_in[6];
  const float* conv1w = (const float*)d_in[7];
  const float* bn1g=(const float*)d_in[8], *bn1b=(const float*)d_in[9], *bn1m=(const float*)d_in[10], *bn1v=(const float*)d_in[11];
  const float* fuseW=(const float*)d_in[12], *fuseB=(const float*)d_in[13];
  const float* lng=(const float*)d_in[14], *lnb=(const float*)d_in[15];
  const float* inpW=(const float*)d_in[16], *inpB=(const float*)d_in[17];
  const float* mlng=(const float*)d_in[18], *mlnb=(const float*)d_in[19];
  const float* minW=(const float*)d_in[20], *minB=(const float*)d_in[21];
  const float* cw=(const float*)d_in[22], *cb=(const float*)d_in[23];
  const float* alog=(const float*)d_in[24], *Dp=(const float*)d_in[25], *dtb=(const float*)d_in[26];
  const float* mng=(const float*)d_in[27];
  const float* moutW=(const float*)d_in[28], *moutB=(const float*)d_in[29];
  const float* outpW=(const float*)d_in[30], *outpB=(const float*)d_in[31];

  // ---- persistent layout ----
  char* ws = (char*)d_ws;
  size_t off = 0;
  auto alloc = [&](size_t bytes){ size_t o = off; off = (off + bytes + 1023) & ~(size_t)1023; return o; };
  const size_t O_WFUSE = alloc((size_t)256*256*2);
  const size_t O_WINP  = alloc((size_t)4*256*256*2);
  const size_t O_WMIN  = alloc((size_t)4*1288*256*2);
  const size_t O_WMOUT = alloc((size_t)4*256*512*2);
  const size_t O_WOUTP = alloc((size_t)4*256*256*2);
  const size_t O_WC3   = alloc((size_t)128*4608*2);
  const size_t O_WC1   = alloc((size_t)128*512*2);
  const size_t O_BNSS  = alloc(512*4);
  const size_t O_ZF    = alloc((size_t)16384*256*2);
  const size_t O_OUTS  = alloc((size_t)4*16384*256*2);
  const size_t O_P     = off;

  // per-dir sizes (bytes)
  const size_t S0d  = (size_t)16384*256*2;
  const size_t XLNd = (size_t)16384*256*2;
  const size_t Yd   = (size_t)16384*512*2;
  const size_t XCTd = (size_t)512*16384*2;
  const size_t BTd  = (size_t)128*16384*2;
  const size_t DTd  = (size_t)16384*8*4;
  const size_t CAd  = (size_t)16384*8*4;
  const size_t SRd  = (size_t)4*64*4096*2;
  const size_t RSd  = (size_t)16384*4;
  const size_t RS8d = (size_t)16384*8*4;
  const size_t XHd  = (size_t)16777216*2;
  const size_t perdir = S0d + XLNd + Yd + XCTd + BTd + DTd + CAd + SRd + RSd + RS8d + XHd;

  const size_t PADsz = (size_t)4*66*66*512*2;
  const size_t CPsz  = (size_t)9*16384*128*2;   // bf16 partials
  const size_t PREsz = PADsz + CPsz + (size_t)16384*256*2*2 + 4096;

  int nd = 0;
  for (int cand = 4; cand >= 1; cand >>= 1) {
    size_t need = (size_t)cand*perdir; if (need < PREsz) need = PREsz;
    if (O_P + need <= ws_size) { nd = cand; break; }
  }
  if (nd == 0) return;

  #define WP(o) ((u16*)(ws + (o)))
  #define FP(o) ((float*)(ws + (o)))

  const size_t O_PAD = O_P;
  const size_t O_CP  = O_PAD + PADsz;
  const size_t O_ZIN = O_CP + CPsz;
  const size_t O_ZFT = O_ZIN + (size_t)16384*256*2;

  // 1. BN scale/shift + weight conversions
  bnssk<<<1, 256, 0, stream>>>(bn3g,bn3b,bn3m,bn3v, bn1g,bn1b,bn1m,bn1v, FP(O_BNSS));
  castk<<<64, 256, 0, stream>>>(fuseW, WP(O_WFUSE), 65536);
  castk<<<256, 256, 0, stream>>>(inpW, WP(O_WINP), 262144);
  castk<<<1288, 256, 0, stream>>>(minW, WP(O_WMIN), 1318912);
  castg<<<512, 256, 0, stream>>>(moutW, mng, WP(O_WMOUT));
  castk<<<256, 256, 0, stream>>>(outpW, WP(O_WOUTP), 262144);
  castk<<<64, 256, 0, stream>>>(conv1w, WP(O_WC1), 65536);
  c3rep<<<2304, 256, 0, stream>>>(conv3w, WP(O_WC3));
  // 2. padded concat input (bf16)
  padk<<<4356, 256, 0, stream>>>(curr, prev, WP(O_PAD));

  GemmArgs a;
  // 3. conv3 split-K over 9 taps -> bf16 partials -> reduce+BN+ReLU
  a = {}; a.A = WP(O_PAD); a.pad = WP(O_PAD);
  a.Bw = WP(O_WC3); a.bZ = 512; a.ldb = 4608;
  a.C = WP(O_CP); a.cZ = 2097152; a.ldc = 128; a.colOff = 0; a.K = 512;
  gemm_bt<2,6><<<dim3(128,1,9), 256, 0, stream>>>(a);
  c3red<<<1024, 256, 0, stream>>>(WP(O_CP), FP(O_BNSS), WP(O_ZIN));
  // 4. conv1 -> zin[:,128:256]
  a = {}; a.A = WP(O_PAD); a.pad = WP(O_PAD); a.Bw = WP(O_WC1); a.bZ = 0; a.ldb = 512;
  a.scale = FP(O_BNSS)+256; a.shift = FP(O_BNSS)+384;
  a.C = WP(O_ZIN); a.cZ = 0; a.ldc = 256; a.colOff = 128; a.K = 512;
  gemm_bt<3,2><<<dim3(128,1,1), 256, 0, stream>>>(a);
  // 5. fuse GEMM -> zft
  a = {}; a.A = WP(O_ZIN); a.aZ = 0; a.lda = 256; a.Bw = WP(O_WFUSE); a.bZ = 0; a.ldb = 256;
  a.bias = fuseB; a.biasZ = 0; a.C = WP(O_ZFT); a.cZ = 0; a.ldc = 256; a.colOff = 0; a.K = 256;
  gemm_bt<0,0><<<dim3(128,2,1), 256, 0, stream>>>(a);
  // 6. LN -> zf (persistent)
  ln256<<<dim3(4096,1,1), 256, 0, stream>>>(WP(O_ZFT), 0, WP(O_ZF), 0, lng, lnb, 0);

  // ---- phases over directions ----
  for (int d0 = 0; d0 < 4; d0 += nd) {
    size_t o = O_P;
    const size_t O_S0  = o; o += (size_t)nd*S0d;
    const size_t O_XLN = o; o += (size_t)nd*XLNd;
    const size_t O_Y   = o; o += (size_t)nd*Yd;
    const size_t O_XCT = o; o += (size_t)nd*XCTd;
    const size_t O_BT  = o; o += (size_t)nd*BTd;
    const size_t O_DT  = o; o += (size_t)nd*DTd;
    const size_t O_CA  = o; o += (size_t)nd*CAd;
    const size_t O_SR  = o; o += (size_t)nd*SRd;
    const size_t O_RS  = o; o += (size_t)nd*RSd;
    const size_t O_RS8 = o; o += (size_t)nd*RS8d;
    const size_t O_XH  = o;
    const size_t O_BCC = O_XLN;
    const size_t O_S1  = O_XLN;

    // 7. inp GEMM (permuted rows per dir) -> s0
    a = {}; a.A = WP(O_ZF); a.aZ = 0; a.lda = 256;
    a.Bw = WP(O_WINP) + (size_t)d0*65536; a.bZ = 65536; a.ldb = 256;
    a.bias = inpB + d0*256; a.biasZ = 256;
    a.C = WP(O_S0); a.cZ = 4194304; a.ldc = 256; a.colOff = 0; a.K = 256; a.dirBase = d0;
    gemm_bt<1,0><<<dim3(128,2,nd), 256, 0, stream>>>(a);
    // 8. per-dir LN(s0) -> xln
    ln256<<<dim3(4096,1,nd), 256, 0, stream>>>(WP(O_S0), 4194304, WP(O_XLN), 4194304,
                                               mlng + d0*256, mlnb + d0*256, 256);
    // 9. dt, chunk log-decay
    dtk<<<dim3(512,1,nd), 256, 0, stream>>>(WP(O_XLN), minW + (size_t)d0*329728,
                                            minB + d0*1288, dtb + d0*8, FP(O_DT));
    cak<<<dim3(512,1,nd), 256, 0, stream>>>(FP(O_DT), FP(O_CA), alog, d0);
    // 10. z-gate GEMM -> Y
    a = {}; a.A = WP(O_XLN); a.aZ = 4194304; a.lda = 256;
    a.Bw = WP(O_WMIN) + (size_t)d0*329728; a.bZ = 329728; a.ldb = 256;
    a.bias = minB + d0*1288; a.biasZ = 1288;
    a.C = WP(O_Y); a.cZ = 8388608; a.ldc = 512; a.colOff = 0; a.K = 256;
    gemm_bt<0,0><<<dim3(128,4,nd), 256, 0, stream>>>(a);
    // 11. xBC GEMM -> raw xbc   [last reader of XLN]
    a = {}; a.A = WP(O_XLN); a.aZ = 4194304; a.lda = 256;
    a.Bw = WP(O_WMIN) + (size_t)d0*329728 + (size_t)512*256; a.bZ = 329728; a.ldb = 256;
    a.bias = minB + d0*1288 + 512; a.biasZ = 1288;
    a.C = WP(O_XH); a.cZ = 16777216; a.ldc = 768; a.colOff = 0; a.K = 256;
    gemm_bt<0,0><<<dim3(128,6,nd), 256, 0, stream>>>(a);
    // 12. conv1d+SiLU+transpose X -> XCT
    convx<<<dim3(1024,1,nd), 256, 0, stream>>>(WP(O_XH), WP(O_XCT), cw + d0*3072, cb + d0*768);
    // 13. fused conv B/C + BCC(C-half) + BT + head-shared scores SR
    bck<<<dim3(256,1,nd), 256, 0, stream>>>(WP(O_XH), WP(O_BCC), WP(O_BT), WP(O_SR),
                                            cw + d0*3072, cb + d0*768);
    // 14. per-chunk outer products -> CS (overlays raw xbc; after 12&13)
    csk<<<dim3(1024,1,nd), 256, 0, stream>>>(WP(O_XCT), WP(O_BT), FP(O_DT), FP(O_CA), WP(O_XH));
    // 15. 64-step combine in place -> H
    combk<<<dim3(256,1,nd), 256, 0, stream>>>(WP(O_XH), FP(O_CA), WP(O_XH));
    // 16. per-chunk outputs -> Y in place, + per-(row,head) SS
    yk2<<<dim3(2048,1,nd), 256, 0, stream>>>(WP(O_BCC), WP(O_XCT), WP(O_SR),
                                             FP(O_DT), FP(O_CA), WP(O_XH), Dp + d0*8,
                                             WP(O_Y), FP(O_RS8));
    // 17. inverse RMS per row
    rsumk<<<dim3(64,1,nd), 256, 0, stream>>>(FP(O_RS8), FP(O_RS));
    // 18. m_out GEMM (norm fused) + s0 residual -> s1
    a = {}; a.A = WP(O_Y); a.aZ = 8388608; a.lda = 512;
    a.Bw = WP(O_WMOUT) + (size_t)d0*131072; a.bZ = 131072; a.ldb = 512;
    a.bias = moutB + d0*256; a.biasZ = 256;
    a.add = WP(O_S0); a.addZ = 4194304;
    a.rowsc = FP(O_RS); a.rowscZ = 16384;
    a.C = WP(O_S1); a.cZ = 4194304; a.ldc = 256; a.colOff = 0; a.K = 512;
    gemm_bt<0,5><<<dim3(128,2,nd), 256, 0, stream>>>(a);
    // 19. outp GEMM -> outs (persistent)
    a = {}; a.A = WP(O_S1); a.aZ = 4194304; a.lda = 256;
    a.Bw = WP(O_WOUTP) + (size_t)d0*65536; a.bZ = 65536; a.ldb = 256;
    a.bias = outpB + d0*256; a.biasZ = 256;
    a.C = WP(O_OUTS) + (size_t)d0*4194304; a.cZ = 4194304; a.ldc = 256; a.colOff = 0; a.K = 256;
    gemm_bt<0,0><<<dim3(128,2,nd), 256, 0, stream>>>(a);
  }

  // 20. final inverse-permute average + residual
  finalk<<<4096, 256, 0, stream>>>(curr, WP(O_OUTS), (float*)d_out);

  #undef WP
  #undef FP
}

// Round 12
// 709.340 us; speedup vs baseline: 5.4509x; 1.0033x over previous
//
#include <hip/hip_runtime.h>
#include <hip/hip_bf16.h>
#include <cstdint>
#include <cstddef>

typedef unsigned short u16;
typedef unsigned int u32;
typedef __attribute__((ext_vector_type(8))) __bf16 bfx8;
typedef __attribute__((ext_vector_type(4))) float f32x4;

static __device__ __forceinline__ float bitf(u32 v){ float f; __builtin_memcpy(&f,&v,4); return f; }
static __device__ __forceinline__ float bf2f(u16 v){ return bitf(((u32)v)<<16); }
static __device__ __forceinline__ u16 f2bf(float f){ __bf16 b=(__bf16)f; u16 r; __builtin_memcpy(&r,&b,2); return r; }
static __device__ __forceinline__ u32 pk2(float a,float b){ return (u32)f2bf(a) | ((u32)f2bf(b)<<16); }
static __device__ __forceinline__ void unpk8(uint4 r, float* o){
  o[0]=bitf(r.x<<16); o[1]=bitf(r.x&0xffff0000u);
  o[2]=bitf(r.y<<16); o[3]=bitf(r.y&0xffff0000u);
  o[4]=bitf(r.z<<16); o[5]=bitf(r.z&0xffff0000u);
  o[6]=bitf(r.w<<16); o[7]=bitf(r.w&0xffff0000u);
}
static __device__ __forceinline__ void unpk4(uint2 r, float* o){
  o[0]=bitf(r.x<<16); o[1]=bitf(r.x&0xffff0000u);
  o[2]=bitf(r.y<<16); o[3]=bitf(r.y&0xffff0000u);
}
static __device__ __forceinline__ void async16(void* lds, const void* g){
  __builtin_amdgcn_global_load_lds((const __attribute__((address_space(1))) u32*)g,
                                   (__attribute__((address_space(3))) u32*)lds, 16, 0, 0);
}

// ---------------- GEMM: C[M][N] = A[M][K] @ B[N][K]^T (+ epilogue) -----------
// EPI: 0=+bias, 2=BN+ReLU, 3=+bias+add, 4=raw fp32, 5=*rowsc+bias+add, 6=raw bf16
struct GemmArgs {
  const u16* A; long aZ; int lda;
  const u16* Bw; long bZ; int ldb;
  const float* bias; int biasZ;
  const float* scale; const float* shift;
  const u16* add; long addZ;
  const float* rowsc; long rowscZ;
  u16* C; long cZ; int ldc; int colOff;
  int K;
  const u16* pad;
  int dirBase;
};

template<int AMODE, int EPI>
__global__ __launch_bounds__(256)
void gemm_bt(GemmArgs g)
{
  __shared__ u16 smA[128*64];
  __shared__ u16 smB[128*64];
  const int tid = threadIdx.x;
  const int l = tid & 63;
  const int wv = tid >> 6;
  const int wr = wv >> 1, wc = wv & 1;
  const int z = blockIdx.z;
  const int r0 = blockIdx.x * 128;
  const int n0 = blockIdx.y * 128;

  const u16* Abase = g.A + (size_t)z * g.aZ;
  const u16* Bbase = g.Bw + (size_t)z * g.bZ;
  const int ldb = g.ldb ? g.ldb : g.K;

  f32x4 acc[4][4];
  #pragma unroll
  for (int i=0;i<4;i++)
    #pragma unroll
    for (int j=0;j<4;j++) acc[i][j] = (f32x4){0.f,0.f,0.f,0.f};

  const int nkt = g.K >> 6;
  #pragma unroll 1
  for (int kt=0; kt<nkt; ++kt) {
    const int k0 = kt << 6;
    #pragma unroll
    for (int it=0; it<4; ++it) {
      const int s = it*256 + tid;
      const int row = s >> 3, ch = s & 7;
      const u16* ga;
      if (AMODE == 0) {
        ga = Abase + (size_t)(r0+row) * g.lda + k0 + ch*8;
      } else if (AMODE == 1) {
        int rr = r0 + row; int li = rr & 4095; int bb = rr >> 12;
        int dir = g.dirBase + z;
        int l2 = (dir & 2) ? (4095 - li) : li;
        int sl = (dir & 1) ? (((l2 & 63) << 6) | (l2 >> 6)) : l2;
        ga = Abase + (size_t)((bb << 12) | sl) * g.lda + k0 + ch*8;
      } else if (AMODE == 2) {
        int rr = r0 + row; int bb = rr >> 12; int li = rr & 4095;
        int yy = li >> 6, xx = li & 63;
        int tap = z, kin = k0;
        int dy = tap / 3 - 1, dx = tap % 3 - 1;
        ga = g.pad + (((size_t)(bb*66 + yy+dy+1))*66 + (xx+dx+1))*512 + kin + ch*8;
      } else {
        int rr = r0 + row; int bb = rr >> 12; int li = rr & 4095;
        int yy = li >> 6, xx = li & 63;
        ga = g.pad + (((size_t)(bb*66 + yy+1))*66 + (xx+1))*512 + k0 + ch*8;
      }
      async16(&smA[(size_t)(it*256 + (tid & ~63))*8], ga);
      const u16* gb = Bbase + (size_t)(n0+row) * ldb + k0 + ch*8;
      async16(&smB[(size_t)(it*256 + (tid & ~63))*8], gb);
    }
    __syncthreads();
    #pragma unroll
    for (int kk=0; kk<2; ++kk) {
      bfx8 av[4], bv[4];
      #pragma unroll
      for (int mi=0; mi<4; ++mi) {
        int ra = wr*64 + mi*16 + (l & 15);
        av[mi] = *(const bfx8*)&smA[ra*64 + kk*32 + (l>>4)*8];
      }
      #pragma unroll
      for (int ni=0; ni<4; ++ni) {
        int rb = wc*64 + ni*16 + (l & 15);
        bv[ni] = *(const bfx8*)&smB[rb*64 + kk*32 + (l>>4)*8];
      }
      #pragma unroll
      for (int mi=0; mi<4; ++mi)
        #pragma unroll
        for (int ni=0; ni<4; ++ni)
          acc[mi][ni] = __builtin_amdgcn_mfma_f32_16x16x32_bf16(av[mi], bv[ni], acc[mi][ni], 0, 0, 0);
    }
    __syncthreads();
  }

  const float* bias_d = (EPI == 0 || EPI == 3 || EPI == 5) ? g.bias + (size_t)z * g.biasZ : nullptr;
  const u16* add_d = (EPI == 3 || EPI == 5) ? g.add + (size_t)z * g.addZ : nullptr;
  const float* rowsc_d = (EPI == 5) ? g.rowsc + (size_t)z * g.rowscZ : nullptr;
  u16* Cd = g.C + (size_t)z * g.cZ;
  float* Cf = (float*)g.C + (size_t)z * g.cZ;
  #pragma unroll
  for (int mi=0; mi<4; ++mi) {
    #pragma unroll
    for (int ni=0; ni<4; ++ni) {
      f32x4 v = acc[mi][ni];
      const int gr = r0 + wr*64 + mi*16 + ((l >> 4) << 2);
      const int gc = n0 + wc*64 + ni*16 + (l & 15);
      #pragma unroll
      for (int q=0; q<4; ++q) {
        const int r = gr + q;
        float x = v[q];
        if (EPI == 2) {
          x = fmaxf(fmaf(x, g.scale[gc], g.shift[gc]), 0.f);
          Cd[(size_t)r * g.ldc + g.colOff + gc] = f2bf(x);
        } else if (EPI == 3) {
          x += bias_d[gc] + bf2f(add_d[(size_t)r * g.ldc + gc]);
          Cd[(size_t)r * g.ldc + g.colOff + gc] = f2bf(x);
        } else if (EPI == 5) {
          x = x * rowsc_d[r] + bias_d[gc] + bf2f(add_d[(size_t)r * g.ldc + gc]);
          Cd[(size_t)r * g.ldc + g.colOff + gc] = f2bf(x);
        } else if (EPI == 4) {
          Cf[(size_t)r * g.ldc + g.colOff + gc] = x;
        } else if (EPI == 6) {
          Cd[(size_t)r * g.ldc + g.colOff + gc] = f2bf(x);
        } else {
          x += bias_d[gc];
          Cd[(size_t)r * g.ldc + g.colOff + gc] = f2bf(x);
        }
      }
    }
  }
}

// ---------------- small utility kernels --------------------------------------
__global__ void castk(const float* __restrict__ s, u16* __restrict__ d, int n)
{
  int i = (blockIdx.x*256 + threadIdx.x)*4;
  if (i < n){
    float4 v = *(const float4*)(s+i);
    ushort4 o; o.x=f2bf(v.x); o.y=f2bf(v.y); o.z=f2bf(v.z); o.w=f2bf(v.w);
    *(ushort4*)(d+i) = o;
  }
}

// cast m_out W with norm gain folded in
__global__ void castg(const float* __restrict__ s, const float* __restrict__ gw,
                      u16* __restrict__ d)
{
  int i = (blockIdx.x*256 + threadIdx.x)*4;
  int dd = i >> 17, k = i & 511;
  float4 v = *(const float4*)(s+i);
  float4 g4 = *(const float4*)(gw + dd*512 + k);
  ushort4 o; o.x=f2bf(v.x*g4.x); o.y=f2bf(v.y*g4.y); o.z=f2bf(v.z*g4.z); o.w=f2bf(v.w*g4.w);
  *(ushort4*)(d+i) = o;
}

__global__ void c3rep(const float* __restrict__ w, u16* __restrict__ o)
{
  int id = blockIdx.x*256 + threadIdx.x;
  int oc = id / 4608, rem = id % 4608;
  int tap = rem >> 9, ic = rem & 511;
  o[id] = f2bf(w[((size_t)oc*512 + ic)*9 + tap]);
}

__global__ void bnssk(const float* g3,const float* b3,const float* m3,const float* v3,
                      const float* g1,const float* b1,const float* m1,const float* v1,
                      float* out)
{
  int t = threadIdx.x; int i = t & 127;
  if (t < 128){ float sc = g3[i]*rsqrtf(v3[i]+1e-5f); out[i]=sc; out[128+i]=b3[i]-m3[i]*sc; }
  else        { float sc = g1[i]*rsqrtf(v1[i]+1e-5f); out[256+i]=sc; out[384+i]=b1[i]-m1[i]*sc; }
}

// reduce 9 bf16 partials -> BN+ReLU -> bf16 into zin cols 0..127
__global__ __launch_bounds__(256)
void c3red(const u16* __restrict__ P, const float* __restrict__ bnss, u16* __restrict__ zin)
{
  const int id = blockIdx.x*256 + threadIdx.x;
  const size_t base = (size_t)id * 8;
  const int r = (int)(base >> 7), c = (int)(base & 127);
  float s[8] = {0,0,0,0,0,0,0,0};
  #pragma unroll
  for (int z=0; z<9; ++z){
    uint4 raw = *(const uint4*)(P + (size_t)z*2097152 + base);
    float v[8]; unpk8(raw, v);
    #pragma unroll
    for (int j=0;j<8;j++) s[j] += v[j];
  }
  uint4 o;
  float r8[8];
  #pragma unroll
  for (int j=0;j<8;j++)
    r8[j] = fmaxf(fmaf(s[j], bnss[c+j], bnss[128+c+j]), 0.f);
  o.x = pk2(r8[0],r8[1]); o.y = pk2(r8[2],r8[3]);
  o.z = pk2(r8[4],r8[5]); o.w = pk2(r8[6],r8[7]);
  *(uint4*)(zin + (size_t)r*256 + c) = o;
}

__global__ __launch_bounds__(256)
void padk(const float* __restrict__ curr, const float* __restrict__ prev, u16* __restrict__ pad)
{
  const int id = blockIdx.x*256 + threadIdx.x;
  const int c8 = id & 63;
  int t = id >> 6;
  const int xx = t % 66; t /= 66;
  const int yy = t % 66; const int b = t / 66;
  const int c0 = c8*8;
  uint4 o;
  if (yy==0 || yy==65 || xx==0 || xx==65){ o.x=0;o.y=0;o.z=0;o.w=0; }
  else {
    const int l = (yy-1)*64 + (xx-1);
    const float* s = (c0 < 256) ? curr + ((size_t)b*4096 + l)*256 + c0
                                : prev + ((size_t)b*4096 + l)*256 + (c0-256);
    float4 a = *(const float4*)s, bb = *(const float4*)(s+4);
    o.x = pk2(a.x,a.y); o.y = pk2(a.z,a.w); o.z = pk2(bb.x,bb.y); o.w = pk2(bb.z,bb.w);
  }
  *(uint4*)(pad + (((size_t)b*66 + yy)*66 + xx)*512 + c0) = o;
}

__global__ __launch_bounds__(256)
void ln256(const u16* __restrict__ in, long inZ, u16* __restrict__ out, long outZ,
           const float* __restrict__ gw, const float* __restrict__ bw, int pz)
{
  const int z = blockIdx.z;
  const int row = blockIdx.x*4 + (threadIdx.x>>6);
  const int l = threadIdx.x & 63;
  const u16* ip = in + (size_t)z*inZ + (size_t)row*256 + l*4;
  ushort4 rr = *(const ushort4*)ip;
  float v0=bf2f(rr.x), v1=bf2f(rr.y), v2=bf2f(rr.z), v3=bf2f(rr.w);
  float s = v0+v1+v2+v3;
  float ss = v0*v0+v1*v1+v2*v2+v3*v3;
  #pragma unroll
  for(int m=1;m<64;m<<=1){ s += __shfl_xor(s,m); ss += __shfl_xor(ss,m); }
  float mu = s*(1.f/256.f);
  float var = ss*(1.f/256.f) - mu*mu;
  float rs = rsqrtf(var + 1e-5f);
  const float* g = gw + (size_t)z*pz; const float* b = bw + (size_t)z*pz;
  int c = l*4;
  u16* op = out + (size_t)z*outZ + (size_t)row*256 + c;
  ushort4 o; o.x=f2bf((v0-mu)*rs*g[c]+b[c]); o.y=f2bf((v1-mu)*rs*g[c+1]+b[c+1]);
  o.z=f2bf((v2-mu)*rs*g[c+2]+b[c+2]); o.w=f2bf((v3-mu)*rs*g[c+3]+b[c+3]);
  *(ushort4*)op = o;
}

// sum 8 head partial SS -> inverse RMS per row
__global__ __launch_bounds__(256)
void rsumk(const float* __restrict__ RS8, float* __restrict__ RS)
{
  const int z = blockIdx.z;
  const int row = blockIdx.x*256 + threadIdx.x;
  const float* p = RS8 + ((size_t)z*16384 + row)*8;
  float4 a = *(const float4*)p, b = *(const float4*)(p+4);
  float s = a.x+a.y+a.z+a.w+b.x+b.y+b.z+b.w;
  RS[(size_t)z*16384 + row] = rsqrtf(s*(1.f/512.f) + 1e-5f);
}

// fp32 dt head: dt = softplus(xln.W_dt + b + dt_bias)
__global__ __launch_bounds__(256)
void dtk(const u16* __restrict__ xln, const float* __restrict__ minW,
         const float* __restrict__ minB, const float* __restrict__ dtb,
         float* __restrict__ DT)
{
  __shared__ float sx[32*257];
  const int z = blockIdx.z;
  const int r0 = blockIdx.x * 32;
  const int tid = threadIdx.x;
  {
    const int rr = tid >> 3, cc = (tid & 7) * 32;
    const u16* src = xln + ((size_t)z*16384 + r0 + rr)*256 + cc;
    #pragma unroll
    for (int q=0;q<4;q++){
      uint4 raw = *(const uint4*)(src + q*8);
      float v[8]; unpk8(raw, v);
      #pragma unroll
      for (int j=0;j<8;j++) sx[rr*257 + cc + q*8 + j] = v[j];
    }
  }
  __syncthreads();
  const int ri = tid >> 3, hv = tid & 7;
  const float* wrow = minW + ((size_t)z*1288 + 1280 + hv)*256;
  float acc = 0.f;
  #pragma unroll 4
  for (int k=0; k<256; k+=4){
    float4 wq = *(const float4*)(wrow + k);
    acc += sx[ri*257+k]*wq.x + sx[ri*257+k+1]*wq.y + sx[ri*257+k+2]*wq.z + sx[ri*257+k+3]*wq.w;
  }
  acc += minB[(size_t)z*1288 + 1280 + hv] + dtb[z*8 + hv];
  float dt = (acc > 20.f) ? acc : log1pf(expf(acc));
  DT[((size_t)z*16384 + r0 + ri)*8 + hv] = dt;
}

// chunk-local cumulative log-decay
__global__ __launch_bounds__(256)
void cak(const float* __restrict__ DT, float* __restrict__ CA,
         const float* __restrict__ alog, int dirBase)
{
  const int z = blockIdx.z;
  const int gidx = blockIdx.x*4 + (threadIdx.x>>6);
  const int lane = threadIdx.x & 63;
  const int c = gidx & 63, bh = gidx >> 6;
  const int b = bh >> 3, hh = bh & 7;
  const size_t row = (size_t)z*16384 + (size_t)b*4096 + c*64 + lane;
  float x = DT[row*8 + hh];
  #pragma unroll
  for (int m=1;m<64;m<<=1){ float o = __shfl_up(x, m); if (lane >= m) x += o; }
  float eA = expf(alog[(dirBase+z)*8 + hh]);
  CA[row*8 + hh] = -eA * x;
}

// fused: conv1d(4)+SiLU on B/C columns + C-half -> BCC + B-transpose -> BT
//        + head-shared raw scores S -> SR.   grid (256,1,nd) per (b,c)
__global__ __launch_bounds__(256)
void bck(const u16* __restrict__ xbcr, u16* __restrict__ bcc, u16* __restrict__ bt,
         u16* __restrict__ SR, const float* __restrict__ cw, const float* __restrict__ cb)
{
  __shared__ u16 BCs[64*264];   // [s][B:0..127, C:128..255]
  __shared__ u16 Tb[128*72];    // [n][s] transposed B
  __shared__ float cwS[4][256];
  __shared__ float cbS[256];
  const int bx = blockIdx.x, z = blockIdx.z;
  const int c = bx & 63, b = bx >> 6;
  const int tid = threadIdx.x, l = tid & 63, w = tid >> 6;
  const u16* xb = xbcr + (size_t)z*16777216 + (size_t)b*4096*768;
  const float* cwp = cw + (size_t)z*3072;
  const float* cbp = cb + (size_t)z*768;
  {
    float4 w4 = *(const float4*)(cwp + (512 + tid)*4);
    cwS[0][tid]=w4.x; cwS[1][tid]=w4.y; cwS[2][tid]=w4.z; cwS[3][tid]=w4.w;
    cbS[tid] = cbp[512 + tid];
  }
  __syncthreads();
  #pragma unroll
  for (int u=0; u<8; ++u){
    int idx = u*256 + tid;
    int s = idx >> 5, c8 = idx & 31;
    int li = c*64 + s;
    int col = 512 + c8*8;
    float acc[8];
    #pragma unroll
    for (int j=0;j<8;j++) acc[j] = cbS[c8*8+j];
    #pragma unroll
    for (int tap=0; tap<4; ++tap){
      int lt = li - 3 + tap;
      if (lt >= 0){
        uint4 raw = *(const uint4*)(xb + (size_t)lt*768 + col);
        float v[8]; unpk8(raw, v);
        #pragma unroll
        for (int j=0;j<8;j++) acc[j] = fmaf(v[j], cwS[tap][c8*8+j], acc[j]);
      }
    }
    u16 o8[8];
    #pragma unroll
    for (int j=0;j<8;j++) o8[j] = f2bf(acc[j] / (1.f + __expf(-acc[j])));
    *(uint4*)&BCs[s*264 + c8*8] = *(const uint4*)o8;
    if (c8 >= 16){
      *(uint4*)(bcc + ((size_t)z*16384 + (size_t)b*4096 + li)*256 + c8*8) = *(const uint4*)o8;
    } else {
      #pragma unroll
      for (int j=0;j<8;j++) Tb[(c8*8+j)*72 + s] = o8[j];
    }
  }
  __syncthreads();
  // S = C@B^T (16 MFMA)
  bfx8 av[4];
  #pragma unroll
  for (int kk=0; kk<4; ++kk)
    av[kk] = *(const bfx8*)&BCs[(w*16 + (l&15))*264 + 128 + kk*32 + (l>>4)*8];
  f32x4 sacc[4];
  #pragma unroll
  for (int i=0;i<4;i++) sacc[i] = (f32x4){0.f,0.f,0.f,0.f};
  #pragma unroll
  for (int kk=0; kk<4; ++kk)
    #pragma unroll
    for (int st=0; st<4; ++st){
      bfx8 bv = *(const bfx8*)&BCs[(st*16 + (l&15))*264 + kk*32 + (l>>4)*8];
      sacc[st] = __builtin_amdgcn_mfma_f32_16x16x32_bf16(av[kk], bv, sacc[st], 0, 0, 0);
    }
  // SR stride per (z,b) is 262144 u16 (64 chunks x 4096)
  u16* Sd = SR + ((size_t)z*4 + b)*262144 + (size_t)c*4096;
  const int t0 = w*16 + ((l>>4)<<2);
  #pragma unroll
  for (int st=0; st<4; ++st){
    int s = st*16 + (l&15);
    u32* cp = (u32*)&Sd[(size_t)s*64 + t0];
    cp[0] = pk2(sacc[st][0], sacc[st][1]);
    cp[1] = pk2(sacc[st][2], sacc[st][3]);
  }
  #pragma unroll
  for (int u=0; u<4; ++u){
    int idx = u*256 + tid;
    int n = idx >> 3, sg = idx & 7;
    uint4 v = *(const uint4*)&Tb[n*72 + sg*8];
    *(uint4*)(bt + (size_t)z*2097152 + (size_t)n*16384 + (size_t)b*4096 + c*64 + sg*8) = v;
  }
}

// conv1d(4)+SiLU on X cols (raw 0..511) + transpose -> XCT[p][g]
__global__ __launch_bounds__(256)
void convx(const u16* __restrict__ xbcr, u16* __restrict__ xct,
           const float* __restrict__ cw, const float* __restrict__ cb)
{
  __shared__ u16 T[128*72];
  __shared__ float cwX[4][128];
  __shared__ float cbX[128];
  const int bx = blockIdx.x, z = blockIdx.z;
  const int pq = bx & 3, c = (bx>>2) & 63, b = bx >> 8;
  const int tid = threadIdx.x;
  const u16* xb = xbcr + (size_t)z*16777216 + (size_t)b*4096*768;
  if (tid < 128){
    float4 w4 = *(const float4*)(cw + (size_t)z*3072 + (pq*128+tid)*4);
    cwX[0][tid]=w4.x; cwX[1][tid]=w4.y; cwX[2][tid]=w4.z; cwX[3][tid]=w4.w;
    cbX[tid] = cb[z*768 + pq*128 + tid];
  }
  __syncthreads();
  #pragma unroll
  for (int u=0; u<4; ++u){
    int idx = u*256 + tid;
    int s = idx >> 4, seg = idx & 15;
    int li = c*64 + s;
    int col = pq*128 + seg*8;
    float acc[8];
    #pragma unroll
    for (int j=0;j<8;j++) acc[j] = cbX[seg*8+j];
    #pragma unroll
    for (int tap=0; tap<4; ++tap){
      int lt = li - 3 + tap;
      if (lt >= 0){
        uint4 raw = *(const uint4*)(xb + (size_t)lt*768 + col);
        float v[8]; unpk8(raw, v);
        #pragma unroll
        for (int j=0;j<8;j++) acc[j] = fmaf(v[j], cwX[tap][seg*8+j], acc[j]);
      }
    }
    #pragma unroll
    for (int j=0;j<8;j++)
      T[(seg*8+j)*72 + s] = f2bf(acc[j] / (1.f + __expf(-acc[j])));
  }
  __syncthreads();
  #pragma unroll
  for (int u=0; u<4; ++u){
    int idx = u*256 + tid;
    int pl = idx >> 3, sg = idx & 7;
    uint4 v = *(const uint4*)&T[pl*72 + sg*8];
    *(uint4*)(xct + (size_t)z*8388608 + (size_t)(pq*128+pl)*16384 + b*4096 + c*64 + sg*8) = v;
  }
}

// per-chunk outer products, heads fused, p-quarter per block; grid (1024,1,nd)
__global__ __launch_bounds__(256)
void csk(const u16* __restrict__ xct, const u16* __restrict__ bt,
         const float* __restrict__ DT, const float* __restrict__ CA,
         u16* __restrict__ CS)
{
  __shared__ u16 Xw[128*72];
  __shared__ u16 Bt[128*72];
  __shared__ float wS[64*2];
  const int bx = blockIdx.x, z = blockIdx.z;
  const int pq = bx & 3, c = (bx>>2) & 63, b = bx >> 8;
  const int tid = threadIdx.x, l = tid & 63, w = tid >> 6;
  const size_t rowb = (size_t)z*16384 + (size_t)b*4096;
  const int p0 = pq*128;
  if (tid < 128){
    int s = tid & 63, hi = tid >> 6;
    int hh = pq*2 + hi;
    float ca63 = CA[(rowb + c*64 + 63)*8 + hh];
    float cav  = CA[(rowb + c*64 + s)*8 + hh];
    float dtv  = DT[(rowb + c*64 + s)*8 + hh];
    wS[s*2+hi] = __expf(ca63 - cav) * dtv;
  }
  __syncthreads();
  #pragma unroll
  for (int u=0; u<4; ++u){
    int idx = u*256 + tid;
    int pl = idx >> 3, sg = idx & 7;
    int hi = pl >> 6;
    uint4 raw = *(const uint4*)(xct + (size_t)z*8388608 + (size_t)(p0+pl)*16384 + b*4096 + c*64 + sg*8);
    float v[8]; unpk8(raw, v);
    uint4 o;
    o.x = pk2(v[0]*wS[(sg*8+0)*2+hi], v[1]*wS[(sg*8+1)*2+hi]);
    o.y = pk2(v[2]*wS[(sg*8+2)*2+hi], v[3]*wS[(sg*8+3)*2+hi]);
    o.z = pk2(v[4]*wS[(sg*8+4)*2+hi], v[5]*wS[(sg*8+5)*2+hi]);
    o.w = pk2(v[6]*wS[(sg*8+6)*2+hi], v[7]*wS[(sg*8+7)*2+hi]);
    *(uint4*)&Xw[pl*72 + sg*8] = o;
  }
  #pragma unroll
  for (int u=0; u<4; ++u){
    int idx = u*256 + tid;
    int n = idx >> 3, sg = idx & 7;
    *(uint4*)&Bt[n*72 + sg*8] =
      *(const uint4*)(bt + (size_t)z*2097152 + (size_t)n*16384 + b*4096 + c*64 + sg*8);
  }
  __syncthreads();
  f32x4 acc[8][2];
  #pragma unroll
  for (int i=0;i<8;i++)
    #pragma unroll
    for (int j=0;j<2;j++) acc[i][j] = (f32x4){0.f,0.f,0.f,0.f};
  #pragma unroll
  for (int kk=0; kk<2; ++kk){
    bfx8 bvp[2];
    #pragma unroll
    for (int ni=0; ni<2; ++ni)
      bvp[ni] = *(const bfx8*)&Xw[(w*32 + ni*16 + (l&15))*72 + kk*32 + (l>>4)*8];
    #pragma unroll
    for (int mi=0; mi<8; ++mi){
      bfx8 av = *(const bfx8*)&Bt[(mi*16 + (l&15))*72 + kk*32 + (l>>4)*8];
      #pragma unroll
      for (int ni=0; ni<2; ++ni)
        acc[mi][ni] = __builtin_amdgcn_mfma_f32_16x16x32_bf16(av, bvp[ni], acc[mi][ni], 0, 0, 0);
    }
  }
  #pragma unroll
  for (int mi=0; mi<8; ++mi){
    #pragma unroll
    for (int ni=0; ni<2; ++ni){
      int gp = p0 + w*32 + ni*16 + (l&15);
      int bhx = b*8 + (gp>>6); int pin = gp & 63;
      int n0 = mi*16 + ((l>>4)<<2);
      u32* cp = (u32*)&CS[(size_t)z*16777216 + (size_t)bhx*524288 + (size_t)c*8192 + (size_t)pin*128 + n0];
      cp[0] = pk2(acc[mi][ni][0], acc[mi][ni][1]);
      cp[1] = pk2(acc[mi][ni][2], acc[mi][ni][3]);
    }
  }
}

// sequential 64-step combine IN PLACE (H aliases CS); 2x n-split
__global__ __launch_bounds__(256)
void combk(const u16* __restrict__ CS, const float* __restrict__ CA,
           u16* __restrict__ H)
{
  __shared__ float aL[64];
  const int bx = blockIdx.x;
  const int z = blockIdx.z;
  const int nh = bx & 1, pg = (bx >> 1) & 3, bh = bx >> 3;
  const int b = bh >> 3, hh = bh & 7;
  const int tid = threadIdx.x;
  const int p = pg*16 + (tid >> 4), n = nh*64 + (tid & 15)*4;
  const size_t rowb = (size_t)z*16384 + (size_t)b*4096;
  if (tid < 64) aL[tid] = __expf(CA[(rowb + tid*64 + 63)*8 + hh]);
  __syncthreads();
  const u16* Cs = CS + (size_t)z*16777216 + (size_t)bh*524288 + (size_t)p*128 + n;
  u16* Hd = H + (size_t)z*16777216 + (size_t)bh*524288 + (size_t)p*128 + n;
  float h[4];
  #pragma unroll
  for (int j=0;j<4;j++) h[j]=0.f;
  uint2 pf = *(const uint2*)Cs;
  #pragma unroll 1
  for (int c=0; c<64; ++c){
    uint2 cur = pf;
    if (c < 63) pf = *(const uint2*)(Cs + (size_t)(c+1)*8192);
    uint2 o;
    o.x = pk2(h[0],h[1]); o.y = pk2(h[2],h[3]);
    *(uint2*)(Hd + (size_t)c*8192) = o;
    float v[4]; unpk4(cur, v);
    const float a = aL[c];
    #pragma unroll
    for (int j=0;j<4;j++) h[j] = fmaf(h[j], a, v[j]);
  }
}

// per-chunk output: Y = (S_decayed @ X + diag(exp(ca)) * (C @ H[c]) + Dh*x) * silu(z)
// epilogue bounced through LDS (Zs reuses Ss) -> vectorized global I/O
__global__ __launch_bounds__(256)
void yk2(const u16* __restrict__ bcc, const u16* __restrict__ xct,
         const u16* __restrict__ SR,
         const float* __restrict__ DT, const float* __restrict__ CA,
         const u16* __restrict__ H, const float* __restrict__ Dp,
         u16* __restrict__ Y, float* __restrict__ RS8)
{
  __shared__ u16 Ss[64*72];     // scores early; z/y tile late (Zs)
  __shared__ u16 Hs[64*136];
  __shared__ u16 Xt[64*72];
  __shared__ u16 Sm[64*72];
  __shared__ float caL[64], dtL[64];
  const int bx = blockIdx.x, z = blockIdx.z;
  const int c = bx & 63, bh = bx >> 6;
  const int b = bh >> 3, hh = bh & 7;
  const int tid = threadIdx.x, l = tid & 63, w = tid >> 6;
  const size_t rowb = (size_t)z*16384 + (size_t)b*4096;
  const u16* bcp = bcc + (rowb + c*64)*256;
  const u16* Hd = H + (size_t)z*16777216 + (size_t)bh*524288 + (size_t)c*8192;
  const u16* xcp = xct + (size_t)z*8388608 + (size_t)(hh*64)*16384 + b*4096 + c*64;
  const u16* Sd = SR + ((size_t)z*4 + b)*262144 + (size_t)c*4096;
  const float Dh = Dp[z*8 + hh];

  bfx8 av[4];
  #pragma unroll
  for (int kk=0; kk<4; ++kk)
    av[kk] = *(const bfx8*)(bcp + (size_t)(w*16 + (l&15))*256 + 128 + kk*32 + (l>>4)*8);

  if (tid < 64){
    caL[tid] = CA[(rowb + c*64 + tid)*8 + hh];
    dtL[tid] = DT[(rowb + c*64 + tid)*8 + hh];
  }
  #pragma unroll
  for (int u=0; u<2; ++u){
    int idx = u*256 + tid; int s = idx >> 3, sg = idx & 7;
    *(uint4*)&Ss[s*72 + sg*8] = *(const uint4*)(Sd + (size_t)s*64 + sg*8);
  }
  #pragma unroll
  for (int u=0; u<4; ++u){
    int idx = u*256 + tid; int p = idx >> 4, sg = idx & 15;
    *(uint4*)&Hs[p*136 + sg*8] = *(const uint4*)(Hd + (size_t)p*128 + sg*8);
  }
  #pragma unroll
  for (int u=0; u<2; ++u){
    int idx = u*256 + tid; int p = idx >> 3, sg = idx & 7;
    *(uint4*)&Xt[p*72 + sg*8] = *(const uint4*)(xcp + (size_t)p*16384 + sg*8);
  }
  __syncthreads();

  // inter part: acc2 = C @ H[c]
  f32x4 acc2[4];
  #pragma unroll
  for (int i=0;i<4;i++) acc2[i] = (f32x4){0.f,0.f,0.f,0.f};
  #pragma unroll
  for (int kk=0; kk<4; ++kk)
    #pragma unroll
    for (int st=0; st<4; ++st){
      bfx8 hv = *(const bfx8*)&Hs[(st*16 + (l&15))*136 + kk*32 + (l>>4)*8];
      acc2[st] = __builtin_amdgcn_mfma_f32_16x16x32_bf16(av[kk], hv, acc2[st], 0, 0, 0);
    }
  // decay+mask precomputed scores -> Sm (consumes Ss)
  #pragma unroll
  for (int st=0; st<4; ++st){
    #pragma unroll
    for (int q=0;q<4;q++){
      int t = w*16 + (l>>4)*4 + q;
      int s = st*16 + (l&15);
      float m = (s <= t) ? __expf(caL[t]-caL[s]) * dtL[s] : 0.f;
      Sm[t*72 + s] = f2bf(bf2f(Ss[s*72 + t]) * m);
    }
  }
  #pragma unroll
  for (int pt=0; pt<4; ++pt)
    #pragma unroll
    for (int q=0;q<4;q++){
      int t = w*16 + (l>>4)*4 + q;
      acc2[pt][q] *= __expf(caL[t]);
    }
  __syncthreads();          // Sm ready; Ss dead from here
  // intra: acc2 += Sm @ Xt
  #pragma unroll
  for (int kk=0; kk<2; ++kk){
    bfx8 sv = *(const bfx8*)&Sm[(w*16 + (l&15))*72 + kk*32 + (l>>4)*8];
    #pragma unroll
    for (int pt=0; pt<4; ++pt){
      bfx8 bv = *(const bfx8*)&Xt[(pt*16 + (l&15))*72 + kk*32 + (l>>4)*8];
      acc2[pt] = __builtin_amdgcn_mfma_f32_16x16x32_bf16(sv, bv, acc2[pt], 0, 0, 0);
    }
  }
  // stage z-tile into Zs (reuse Ss) with vectorized reads
  u16* Zs = Ss;
  u16* Yrow = Y + (rowb + c*64)*512 + hh*64;
  #pragma unroll
  for (int u=0; u<2; ++u){
    int idx = u*256 + tid; int t = idx >> 3, sg = idx & 7;
    *(uint4*)&Zs[t*72 + sg*8] = *(const uint4*)(Yrow + (size_t)t*512 + sg*8);
  }
  __syncthreads();          // Zs ready
  // epilogue in LDS: each (t,p) owned by exactly one thread
  float ssq[4] = {0.f,0.f,0.f,0.f};
  #pragma unroll
  for (int pt=0; pt<4; ++pt){
    #pragma unroll
    for (int q=0;q<4;q++){
      int t = w*16 + (l>>4)*4 + q;
      int p = pt*16 + (l&15);
      float xv = bf2f(Xt[p*72 + t]);
      float zf = bf2f(Zs[t*72 + p]);
      float yv = (acc2[pt][q] + Dh*xv) * (zf/(1.f+__expf(-zf)));
      ssq[q] += yv*yv;
      Zs[t*72 + p] = f2bf(yv);
    }
  }
  #pragma unroll
  for (int q=0;q<4;q++){
    float s = ssq[q];
    s += __shfl_xor(s, 1); s += __shfl_xor(s, 2);
    s += __shfl_xor(s, 4); s += __shfl_xor(s, 8);
    if ((l & 15) == 0){
      int t = w*16 + (l>>4)*4 + q;
      RS8[(rowb + c*64 + t)*8 + hh] = s;
    }
  }
  __syncthreads();          // all yv in Zs
  #pragma unroll
  for (int u=0; u<2; ++u){
    int idx = u*256 + tid; int t = idx >> 3, sg = idx & 7;
    *(uint4*)(Yrow + (size_t)t*512 + sg*8) = *(const uint4*)&Zs[t*72 + sg*8];
  }
}

__global__ __launch_bounds__(256)
void finalk(const float* __restrict__ curr, const u16* __restrict__ outs, float* __restrict__ o)
{
  const int row = blockIdx.x*4 + (threadIdx.x>>6);
  const int c4 = (threadIdx.x & 63)*4;
  const int b = row >> 12, li = row & 4095;
  const int T = ((li & 63) << 6) | (li >> 6);
  const size_t rb = (size_t)b*4096;
  const ushort4 a0 = *(const ushort4*)(outs + (size_t)0*4194304 + ((rb+li)*256 + c4));
  const ushort4 a1 = *(const ushort4*)(outs + (size_t)1*4194304 + ((rb+T)*256 + c4));
  const ushort4 a2 = *(const ushort4*)(outs + (size_t)2*4194304 + ((rb+4095-li)*256 + c4));
  const ushort4 a3 = *(const ushort4*)(outs + (size_t)3*4194304 + ((rb+4095-T)*256 + c4));
  float4 cv = *(const float4*)(curr + (size_t)row*256 + c4);
  float4 r;
  r.x = cv.x + 0.25f*(bf2f(a0.x)+bf2f(a1.x)+bf2f(a2.x)+bf2f(a3.x));
  r.y = cv.y + 0.25f*(bf2f(a0.y)+bf2f(a1.y)+bf2f(a2.y)+bf2f(a3.y));
  r.z = cv.z + 0.25f*(bf2f(a0.z)+bf2f(a1.z)+bf2f(a2.z)+bf2f(a3.z));
  r.w = cv.w + 0.25f*(bf2f(a0.w)+bf2f(a1.w)+bf2f(a2.w)+bf2f(a3.w));
  *(float4*)(o + (size_t)row*256 + c4) = r;
}

// ---------------------------------------------------------------------------
extern "C" void kernel_launch(void* const* d_in, const int* in_sizes, int n_in,
                              void* d_out, int out_size, void* d_ws, size_t ws_size,
                              hipStream_t stream)
{
  (void)in_sizes; (void)n_in; (void)out_size;
  const float* curr   = (const float*)d_in[0];
  const float* prev   = (const float*)d_in[1];
  const float* conv3w = (const float*)d_in[2];
  const float* bn3g=(const float*)d_in[3], *bn3b=(const float*)d_in[4], *bn3m=(const float*)d_in[5], *bn3v=(const float*)d_in[6];
  const float* conv1w = (const float*)d_in[7];
  const float* bn1g=(const float*)d_in[8], *bn1b=(const float*)d_in[9], *bn1m=(const float*)d_in[10], *bn1v=(const float*)d_in[11];
  const float* fuseW=(const float*)d_in[12], *fuseB=(const float*)d_in[13];
  const float* lng=(const float*)d_in[14], *lnb=(const float*)d_in[15];
  const float* inpW=(const float*)d_in[16], *inpB=(const float*)d_in[17];
  const float* mlng=(const float*)d_in[18], *mlnb=(const float*)d_in[19];
  const float* minW=(const float*)d_in[20], *minB=(const float*)d_in[21];
  const float* cw=(const float*)d_in[22], *cb=(const float*)d_in[23];
  const float* alog=(const float*)d_in[24], *Dp=(const float*)d_in[25], *dtb=(const float*)d_in[26];
  const float* mng=(const float*)d_in[27];
  const float* moutW=(const float*)d_in[28], *moutB=(const float*)d_in[29];
  const float* outpW=(const float*)d_in[30], *outpB=(const float*)d_in[31];

  // ---- persistent layout ----
  char* ws = (char*)d_ws;
  size_t off = 0;
  auto alloc = [&](size_t bytes){ size_t o = off; off = (off + bytes + 1023) & ~(size_t)1023; return o; };
  const size_t O_WFUSE = alloc((size_t)256*256*2);
  const size_t O_WINP  = alloc((size_t)4*256*256*2);
  const size_t O_WMIN  = alloc((size_t)4*1288*256*2);
  const size_t O_WMOUT = alloc((size_t)4*256*512*2);
  const size_t O_WOUTP = alloc((size_t)4*256*256*2);
  const size_t O_WC3   = alloc((size_t)128*4608*2);
  const size_t O_WC1   = alloc((size_t)128*512*2);
  const size_t O_BNSS  = alloc(512*4);
  const size_t O_ZF    = alloc((size_t)16384*256*2);
  const size_t O_OUTS  = alloc((size_t)4*16384*256*2);
  const size_t O_P     = off;

  // per-dir sizes (bytes)
  const size_t S0d  = (size_t)16384*256*2;
  const size_t XLNd = (size_t)16384*256*2;
  const size_t Yd   = (size_t)16384*512*2;
  const size_t XCTd = (size_t)512*16384*2;
  const size_t BTd  = (size_t)128*16384*2;
  const size_t DTd  = (size_t)16384*8*4;
  const size_t CAd  = (size_t)16384*8*4;
  const size_t SRd  = (size_t)4*64*4096*2;
  const size_t RSd  = (size_t)16384*4;
  const size_t RS8d = (size_t)16384*8*4;
  const size_t XHd  = (size_t)16777216*2;
  const size_t perdir = S0d + XLNd + Yd + XCTd + BTd + DTd + CAd + SRd + RSd + RS8d + XHd;

  const size_t PADsz = (size_t)4*66*66*512*2;
  const size_t CPsz  = (size_t)9*16384*128*2;
  const size_t PREsz = PADsz + CPsz + (size_t)16384*256*2*2 + 4096;

  int nd = 0;
  for (int cand = 4; cand >= 1; cand >>= 1) {
    size_t need = (size_t)cand*perdir; if (need < PREsz) need = PREsz;
    if (O_P + need <= ws_size) { nd = cand; break; }
  }
  if (nd == 0) return;

  #define WP(o) ((u16*)(ws + (o)))
  #define FP(o) ((float*)(ws + (o)))

  const size_t O_PAD = O_P;
  const size_t O_CP  = O_PAD + PADsz;
  const size_t O_ZIN = O_CP + CPsz;
  const size_t O_ZFT = O_ZIN + (size_t)16384*256*2;

  // 1. BN scale/shift + weight conversions
  bnssk<<<1, 256, 0, stream>>>(bn3g,bn3b,bn3m,bn3v, bn1g,bn1b,bn1m,bn1v, FP(O_BNSS));
  castk<<<64, 256, 0, stream>>>(fuseW, WP(O_WFUSE), 65536);
  castk<<<256, 256, 0, stream>>>(inpW, WP(O_WINP), 262144);
  castk<<<1288, 256, 0, stream>>>(minW, WP(O_WMIN), 1318912);
  castg<<<512, 256, 0, stream>>>(moutW, mng, WP(O_WMOUT));
  castk<<<256, 256, 0, stream>>>(outpW, WP(O_WOUTP), 262144);
  castk<<<64, 256, 0, stream>>>(conv1w, WP(O_WC1), 65536);
  c3rep<<<2304, 256, 0, stream>>>(conv3w, WP(O_WC3));
  // 2. padded concat input (bf16)
  padk<<<4356, 256, 0, stream>>>(curr, prev, WP(O_PAD));

  GemmArgs a;
  // 3. conv3 split-K over 9 taps -> bf16 partials -> reduce+BN+ReLU
  a = {}; a.A = WP(O_PAD); a.pad = WP(O_PAD);
  a.Bw = WP(O_WC3); a.bZ = 512; a.ldb = 4608;
  a.C = WP(O_CP); a.cZ = 2097152; a.ldc = 128; a.colOff = 0; a.K = 512;
  gemm_bt<2,6><<<dim3(128,1,9), 256, 0, stream>>>(a);
  c3red<<<1024, 256, 0, stream>>>(WP(O_CP), FP(O_BNSS), WP(O_ZIN));
  // 4. conv1 -> zin[:,128:256]
  a = {}; a.A = WP(O_PAD); a.pad = WP(O_PAD); a.Bw = WP(O_WC1); a.bZ = 0; a.ldb = 512;
  a.scale = FP(O_BNSS)+256; a.shift = FP(O_BNSS)+384;
  a.C = WP(O_ZIN); a.cZ = 0; a.ldc = 256; a.colOff = 128; a.K = 512;
  gemm_bt<3,2><<<dim3(128,1,1), 256, 0, stream>>>(a);
  // 5. fuse GEMM -> zft
  a = {}; a.A = WP(O_ZIN); a.aZ = 0; a.lda = 256; a.Bw = WP(O_WFUSE); a.bZ = 0; a.ldb = 256;
  a.bias = fuseB; a.biasZ = 0; a.C = WP(O_ZFT); a.cZ = 0; a.ldc = 256; a.colOff = 0; a.K = 256;
  gemm_bt<0,0><<<dim3(128,2,1), 256, 0, stream>>>(a);
  // 6. LN -> zf (persistent)
  ln256<<<dim3(4096,1,1), 256, 0, stream>>>(WP(O_ZFT), 0, WP(O_ZF), 0, lng, lnb, 0);

  // ---- phases over directions ----
  for (int d0 = 0; d0 < 4; d0 += nd) {
    size_t o = O_P;
    const size_t O_S0  = o; o += (size_t)nd*S0d;
    const size_t O_XLN = o; o += (size_t)nd*XLNd;
    const size_t O_Y   = o; o += (size_t)nd*Yd;
    const size_t O_XCT = o; o += (size_t)nd*XCTd;
    const size_t O_BT  = o; o += (size_t)nd*BTd;
    const size_t O_DT  = o; o += (size_t)nd*DTd;
    const size_t O_CA  = o; o += (size_t)nd*CAd;
    const size_t O_SR  = o; o += (size_t)nd*SRd;
    const size_t O_RS  = o; o += (size_t)nd*RSd;
    const size_t O_RS8 = o; o += (size_t)nd*RS8d;
    const size_t O_XH  = o;
    const size_t O_BCC = O_XLN;
    const size_t O_S1  = O_XLN;

    // 7. inp GEMM (permuted rows per dir) -> s0
    a = {}; a.A = WP(O_ZF); a.aZ = 0; a.lda = 256;
    a.Bw = WP(O_WINP) + (size_t)d0*65536; a.bZ = 65536; a.ldb = 256;
    a.bias = inpB + d0*256; a.biasZ = 256;
    a.C = WP(O_S0); a.cZ = 4194304; a.ldc = 256; a.colOff = 0; a.K = 256; a.dirBase = d0;
    gemm_bt<1,0><<<dim3(128,2,nd), 256, 0, stream>>>(a);
    // 8. per-dir LN(s0) -> xln
    ln256<<<dim3(4096,1,nd), 256, 0, stream>>>(WP(O_S0), 4194304, WP(O_XLN), 4194304,
                                               mlng + d0*256, mlnb + d0*256, 256);
    // 9. dt, chunk log-decay
    dtk<<<dim3(512,1,nd), 256, 0, stream>>>(WP(O_XLN), minW + (size_t)d0*329728,
                                            minB + d0*1288, dtb + d0*8, FP(O_DT));
    cak<<<dim3(512,1,nd), 256, 0, stream>>>(FP(O_DT), FP(O_CA), alog, d0);
    // 10. z-gate GEMM -> Y
    a = {}; a.A = WP(O_XLN); a.aZ = 4194304; a.lda = 256;
    a.Bw = WP(O_WMIN) + (size_t)d0*329728; a.bZ = 329728; a.ldb = 256;
    a.bias = minB + d0*1288; a.biasZ = 1288;
    a.C = WP(O_Y); a.cZ = 8388608; a.ldc = 512; a.colOff = 0; a.K = 256;
    gemm_bt<0,0><<<dim3(128,4,nd), 256, 0, stream>>>(a);
    // 11. xBC GEMM -> raw xbc   [last reader of XLN]
    a = {}; a.A = WP(O_XLN); a.aZ = 4194304; a.lda = 256;
    a.Bw = WP(O_WMIN) + (size_t)d0*329728 + (size_t)512*256; a.bZ = 329728; a.ldb = 256;
    a.bias = minB + d0*1288 + 512; a.biasZ = 1288;
    a.C = WP(O_XH); a.cZ = 16777216; a.ldc = 768; a.colOff = 0; a.K = 256;
    gemm_bt<0,0><<<dim3(128,6,nd), 256, 0, stream>>>(a);
    // 12. conv1d+SiLU+transpose X -> XCT
    convx<<<dim3(1024,1,nd), 256, 0, stream>>>(WP(O_XH), WP(O_XCT), cw + d0*3072, cb + d0*768);
    // 13. fused conv B/C + BCC(C-half) + BT + head-shared scores SR
    bck<<<dim3(256,1,nd), 256, 0, stream>>>(WP(O_XH), WP(O_BCC), WP(O_BT), WP(O_SR),
                                            cw + d0*3072, cb + d0*768);
    // 14. per-chunk outer products -> CS (overlays raw xbc; after 12&13)
    csk<<<dim3(1024,1,nd), 256, 0, stream>>>(WP(O_XCT), WP(O_BT), FP(O_DT), FP(O_CA), WP(O_XH));
    // 15. 64-step combine in place -> H
    combk<<<dim3(256,1,nd), 256, 0, stream>>>(WP(O_XH), FP(O_CA), WP(O_XH));
    // 16. per-chunk outputs -> Y in place, + per-(row,head) SS
    yk2<<<dim3(2048,1,nd), 256, 0, stream>>>(WP(O_BCC), WP(O_XCT), WP(O_SR),
                                             FP(O_DT), FP(O_CA), WP(O_XH), Dp + d0*8,
                                             WP(O_Y), FP(O_RS8));
    // 17. inverse RMS per row
    rsumk<<<dim3(64,1,nd), 256, 0, stream>>>(FP(O_RS8), FP(O_RS));
    // 18. m_out GEMM (norm fused) + s0 residual -> s1
    a = {}; a.A = WP(O_Y); a.aZ = 8388608; a.lda = 512;
    a.Bw = WP(O_WMOUT) + (size_t)d0*131072; a.bZ = 131072; a.ldb = 512;
    a.bias = moutB + d0*256; a.biasZ = 256;
    a.add = WP(O_S0); a.addZ = 4194304;
    a.rowsc = FP(O_RS); a.rowscZ = 16384;
    a.C = WP(O_S1); a.cZ = 4194304; a.ldc = 256; a.colOff = 0; a.K = 512;
    gemm_bt<0,5><<<dim3(128,2,nd), 256, 0, stream>>>(a);
    // 19. outp GEMM -> outs (persistent)
    a = {}; a.A = WP(O_S1); a.aZ = 4194304; a.lda = 256;
    a.Bw = WP(O_WOUTP) + (size_t)d0*65536; a.bZ = 65536; a.ldb = 256;
    a.bias = outpB + d0*256; a.biasZ = 256;
    a.C = WP(O_OUTS) + (size_t)d0*4194304; a.cZ = 4194304; a.ldc = 256; a.colOff = 0; a.K = 256;
    gemm_bt<0,0><<<dim3(128,2,nd), 256, 0, stream>>>(a);
  }

  // 20. final inverse-permute average + residual
  finalk<<<4096, 256, 0, stream>>>(curr, WP(O_OUTS), (float*)d_out);

  #undef WP
  #undef FP
}

// Round 13
// 700.449 us; speedup vs baseline: 5.5200x; 1.0127x over previous
//
#include <hip/hip_runtime.h>
#include <hip/hip_bf16.h>
#include <cstdint>
#include <cstddef>

typedef unsigned short u16;
typedef unsigned int u32;
typedef __attribute__((ext_vector_type(8))) __bf16 bfx8;
typedef __attribute__((ext_vector_type(4))) float f32x4;

static __device__ __forceinline__ float bitf(u32 v){ float f; __builtin_memcpy(&f,&v,4); return f; }
static __device__ __forceinline__ float bf2f(u16 v){ return bitf(((u32)v)<<16); }
static __device__ __forceinline__ u16 f2bf(float f){ __bf16 b=(__bf16)f; u16 r; __builtin_memcpy(&r,&b,2); return r; }
static __device__ __forceinline__ u32 pk2(float a,float b){ return (u32)f2bf(a) | ((u32)f2bf(b)<<16); }
static __device__ __forceinline__ void unpk8(uint4 r, float* o){
  o[0]=bitf(r.x<<16); o[1]=bitf(r.x&0xffff0000u);
  o[2]=bitf(r.y<<16); o[3]=bitf(r.y&0xffff0000u);
  o[4]=bitf(r.z<<16); o[5]=bitf(r.z&0xffff0000u);
  o[6]=bitf(r.w<<16); o[7]=bitf(r.w&0xffff0000u);
}
static __device__ __forceinline__ void unpk4(uint2 r, float* o){
  o[0]=bitf(r.x<<16); o[1]=bitf(r.x&0xffff0000u);
  o[2]=bitf(r.y<<16); o[3]=bitf(r.y&0xffff0000u);
}
static __device__ __forceinline__ void async16(void* lds, const void* g){
  __builtin_amdgcn_global_load_lds((const __attribute__((address_space(1))) u32*)g,
                                   (__attribute__((address_space(3))) u32*)lds, 16, 0, 0);
}

// ---------------- GEMM: C[M][N] = A[M][K] @ B[N][K]^T (+ epilogue) -----------
// EPI: 0=+bias, 2=BN+ReLU, 3=+bias+add, 4=raw fp32, 5=*rowsc+bias+add, 6=raw bf16
struct GemmArgs {
  const u16* A; long aZ; int lda;
  const u16* Bw; long bZ; int ldb;
  const float* bias; int biasZ;
  const float* scale; const float* shift;
  const u16* add; long addZ;
  const float* rowsc; long rowscZ;
  u16* C; long cZ; int ldc; int colOff;
  int K;
  const u16* pad;
  int dirBase;
};

template<int AMODE, int EPI>
__global__ __launch_bounds__(256)
void gemm_bt(GemmArgs g)
{
  __shared__ u16 smA[128*64];
  __shared__ u16 smB[128*64];
  const int tid = threadIdx.x;
  const int l = tid & 63;
  const int wv = tid >> 6;
  const int wr = wv >> 1, wc = wv & 1;
  const int z = blockIdx.z;
  const int r0 = blockIdx.x * 128;
  const int n0 = blockIdx.y * 128;

  const u16* Abase = g.A + (size_t)z * g.aZ;
  const u16* Bbase = g.Bw + (size_t)z * g.bZ;
  const int ldb = g.ldb ? g.ldb : g.K;

  f32x4 acc[4][4];
  #pragma unroll
  for (int i=0;i<4;i++)
    #pragma unroll
    for (int j=0;j<4;j++) acc[i][j] = (f32x4){0.f,0.f,0.f,0.f};

  const int nkt = g.K >> 6;
  #pragma unroll 1
  for (int kt=0; kt<nkt; ++kt) {
    const int k0 = kt << 6;
    #pragma unroll
    for (int it=0; it<4; ++it) {
      const int s = it*256 + tid;
      const int row = s >> 3, ch = s & 7;
      const u16* ga;
      if (AMODE == 0) {
        ga = Abase + (size_t)(r0+row) * g.lda + k0 + ch*8;
      } else if (AMODE == 1) {
        int rr = r0 + row; int li = rr & 4095; int bb = rr >> 12;
        int dir = g.dirBase + z;
        int l2 = (dir & 2) ? (4095 - li) : li;
        int sl = (dir & 1) ? (((l2 & 63) << 6) | (l2 >> 6)) : l2;
        ga = Abase + (size_t)((bb << 12) | sl) * g.lda + k0 + ch*8;
      } else if (AMODE == 2) {
        int rr = r0 + row; int bb = rr >> 12; int li = rr & 4095;
        int yy = li >> 6, xx = li & 63;
        int tap = z, kin = k0;
        int dy = tap / 3 - 1, dx = tap % 3 - 1;
        ga = g.pad + (((size_t)(bb*66 + yy+dy+1))*66 + (xx+dx+1))*512 + kin + ch*8;
      } else {
        int rr = r0 + row; int bb = rr >> 12; int li = rr & 4095;
        int yy = li >> 6, xx = li & 63;
        ga = g.pad + (((size_t)(bb*66 + yy+1))*66 + (xx+1))*512 + k0 + ch*8;
      }
      async16(&smA[(size_t)(it*256 + (tid & ~63))*8], ga);
      const u16* gb = Bbase + (size_t)(n0+row) * ldb + k0 + ch*8;
      async16(&smB[(size_t)(it*256 + (tid & ~63))*8], gb);
    }
    __syncthreads();
    #pragma unroll
    for (int kk=0; kk<2; ++kk) {
      bfx8 av[4], bv[4];
      #pragma unroll
      for (int mi=0; mi<4; ++mi) {
        int ra = wr*64 + mi*16 + (l & 15);
        av[mi] = *(const bfx8*)&smA[ra*64 + kk*32 + (l>>4)*8];
      }
      #pragma unroll
      for (int ni=0; ni<4; ++ni) {
        int rb = wc*64 + ni*16 + (l & 15);
        bv[ni] = *(const bfx8*)&smB[rb*64 + kk*32 + (l>>4)*8];
      }
      #pragma unroll
      for (int mi=0; mi<4; ++mi)
        #pragma unroll
        for (int ni=0; ni<4; ++ni)
          acc[mi][ni] = __builtin_amdgcn_mfma_f32_16x16x32_bf16(av[mi], bv[ni], acc[mi][ni], 0, 0, 0);
    }
    __syncthreads();
  }

  const float* bias_d = (EPI == 0 || EPI == 3 || EPI == 5) ? g.bias + (size_t)z * g.biasZ : nullptr;
  const u16* add_d = (EPI == 3 || EPI == 5) ? g.add + (size_t)z * g.addZ : nullptr;
  const float* rowsc_d = (EPI == 5) ? g.rowsc + (size_t)z * g.rowscZ : nullptr;
  u16* Cd = g.C + (size_t)z * g.cZ;
  float* Cf = (float*)g.C + (size_t)z * g.cZ;
  #pragma unroll
  for (int mi=0; mi<4; ++mi) {
    #pragma unroll
    for (int ni=0; ni<4; ++ni) {
      f32x4 v = acc[mi][ni];
      const int gr = r0 + wr*64 + mi*16 + ((l >> 4) << 2);
      const int gc = n0 + wc*64 + ni*16 + (l & 15);
      #pragma unroll
      for (int q=0; q<4; ++q) {
        const int r = gr + q;
        float x = v[q];
        if (EPI == 2) {
          x = fmaxf(fmaf(x, g.scale[gc], g.shift[gc]), 0.f);
          Cd[(size_t)r * g.ldc + g.colOff + gc] = f2bf(x);
        } else if (EPI == 3) {
          x += bias_d[gc] + bf2f(add_d[(size_t)r * g.ldc + gc]);
          Cd[(size_t)r * g.ldc + g.colOff + gc] = f2bf(x);
        } else if (EPI == 5) {
          x = x * rowsc_d[r] + bias_d[gc] + bf2f(add_d[(size_t)r * g.ldc + gc]);
          Cd[(size_t)r * g.ldc + g.colOff + gc] = f2bf(x);
        } else if (EPI == 4) {
          Cf[(size_t)r * g.ldc + g.colOff + gc] = x;
        } else if (EPI == 6) {
          Cd[(size_t)r * g.ldc + g.colOff + gc] = f2bf(x);
        } else {
          x += bias_d[gc];
          Cd[(size_t)r * g.ldc + g.colOff + gc] = f2bf(x);
        }
      }
    }
  }
}

// ---------------- small utility kernels --------------------------------------
__global__ void castk(const float* __restrict__ s, u16* __restrict__ d, int n)
{
  int i = (blockIdx.x*256 + threadIdx.x)*4;
  if (i < n){
    float4 v = *(const float4*)(s+i);
    ushort4 o; o.x=f2bf(v.x); o.y=f2bf(v.y); o.z=f2bf(v.z); o.w=f2bf(v.w);
    *(ushort4*)(d+i) = o;
  }
}

// cast m_out W with norm gain folded in
__global__ void castg(const float* __restrict__ s, const float* __restrict__ gw,
                      u16* __restrict__ d)
{
  int i = (blockIdx.x*256 + threadIdx.x)*4;
  int dd = i >> 17, k = i & 511;
  float4 v = *(const float4*)(s+i);
  float4 g4 = *(const float4*)(gw + dd*512 + k);
  ushort4 o; o.x=f2bf(v.x*g4.x); o.y=f2bf(v.y*g4.y); o.z=f2bf(v.z*g4.z); o.w=f2bf(v.w*g4.w);
  *(ushort4*)(d+i) = o;
}

__global__ void c3rep(const float* __restrict__ w, u16* __restrict__ o)
{
  int id = blockIdx.x*256 + threadIdx.x;
  int oc = id / 4608, rem = id % 4608;
  int tap = rem >> 9, ic = rem & 511;
  o[id] = f2bf(w[((size_t)oc*512 + ic)*9 + tap]);
}

__global__ void bnssk(const float* g3,const float* b3,const float* m3,const float* v3,
                      const float* g1,const float* b1,const float* m1,const float* v1,
                      float* out)
{
  int t = threadIdx.x; int i = t & 127;
  if (t < 128){ float sc = g3[i]*rsqrtf(v3[i]+1e-5f); out[i]=sc; out[128+i]=b3[i]-m3[i]*sc; }
  else        { float sc = g1[i]*rsqrtf(v1[i]+1e-5f); out[256+i]=sc; out[384+i]=b1[i]-m1[i]*sc; }
}

// reduce 9 bf16 partials -> BN+ReLU -> bf16 into zin cols 0..127
__global__ __launch_bounds__(256)
void c3red(const u16* __restrict__ P, const float* __restrict__ bnss, u16* __restrict__ zin)
{
  const int id = blockIdx.x*256 + threadIdx.x;
  const size_t base = (size_t)id * 8;
  const int r = (int)(base >> 7), c = (int)(base & 127);
  float s[8] = {0,0,0,0,0,0,0,0};
  #pragma unroll
  for (int z=0; z<9; ++z){
    uint4 raw = *(const uint4*)(P + (size_t)z*2097152 + base);
    float v[8]; unpk8(raw, v);
    #pragma unroll
    for (int j=0;j<8;j++) s[j] += v[j];
  }
  uint4 o;
  float r8[8];
  #pragma unroll
  for (int j=0;j<8;j++)
    r8[j] = fmaxf(fmaf(s[j], bnss[c+j], bnss[128+c+j]), 0.f);
  o.x = pk2(r8[0],r8[1]); o.y = pk2(r8[2],r8[3]);
  o.z = pk2(r8[4],r8[5]); o.w = pk2(r8[6],r8[7]);
  *(uint4*)(zin + (size_t)r*256 + c) = o;
}

__global__ __launch_bounds__(256)
void padk(const float* __restrict__ curr, const float* __restrict__ prev, u16* __restrict__ pad)
{
  const int id = blockIdx.x*256 + threadIdx.x;
  const int c8 = id & 63;
  int t = id >> 6;
  const int xx = t % 66; t /= 66;
  const int yy = t % 66; const int b = t / 66;
  const int c0 = c8*8;
  uint4 o;
  if (yy==0 || yy==65 || xx==0 || xx==65){ o.x=0;o.y=0;o.z=0;o.w=0; }
  else {
    const int l = (yy-1)*64 + (xx-1);
    const float* s = (c0 < 256) ? curr + ((size_t)b*4096 + l)*256 + c0
                                : prev + ((size_t)b*4096 + l)*256 + (c0-256);
    float4 a = *(const float4*)s, bb = *(const float4*)(s+4);
    o.x = pk2(a.x,a.y); o.y = pk2(a.z,a.w); o.z = pk2(bb.x,bb.y); o.w = pk2(bb.z,bb.w);
  }
  *(uint4*)(pad + (((size_t)b*66 + yy)*66 + xx)*512 + c0) = o;
}

__global__ __launch_bounds__(256)
void ln256(const u16* __restrict__ in, long inZ, u16* __restrict__ out, long outZ,
           const float* __restrict__ gw, const float* __restrict__ bw, int pz)
{
  const int z = blockIdx.z;
  const int row = blockIdx.x*4 + (threadIdx.x>>6);
  const int l = threadIdx.x & 63;
  const u16* ip = in + (size_t)z*inZ + (size_t)row*256 + l*4;
  ushort4 rr = *(const ushort4*)ip;
  float v0=bf2f(rr.x), v1=bf2f(rr.y), v2=bf2f(rr.z), v3=bf2f(rr.w);
  float s = v0+v1+v2+v3;
  float ss = v0*v0+v1*v1+v2*v2+v3*v3;
  #pragma unroll
  for(int m=1;m<64;m<<=1){ s += __shfl_xor(s,m); ss += __shfl_xor(ss,m); }
  float mu = s*(1.f/256.f);
  float var = ss*(1.f/256.f) - mu*mu;
  float rs = rsqrtf(var + 1e-5f);
  const float* g = gw + (size_t)z*pz; const float* b = bw + (size_t)z*pz;
  int c = l*4;
  u16* op = out + (size_t)z*outZ + (size_t)row*256 + c;
  ushort4 o; o.x=f2bf((v0-mu)*rs*g[c]+b[c]); o.y=f2bf((v1-mu)*rs*g[c+1]+b[c+1]);
  o.z=f2bf((v2-mu)*rs*g[c+2]+b[c+2]); o.w=f2bf((v3-mu)*rs*g[c+3]+b[c+3]);
  *(ushort4*)op = o;
}

// sum 8 head partial SS -> inverse RMS per row
__global__ __launch_bounds__(256)
void rsumk(const float* __restrict__ RS8, float* __restrict__ RS)
{
  const int z = blockIdx.z;
  const int row = blockIdx.x*256 + threadIdx.x;
  const float* p = RS8 + ((size_t)z*16384 + row)*8;
  float4 a = *(const float4*)p, b = *(const float4*)(p+4);
  float s = a.x+a.y+a.z+a.w+b.x+b.y+b.z+b.w;
  RS[(size_t)z*16384 + row] = rsqrtf(s*(1.f/512.f) + 1e-5f);
}

// fp32 dt head: dt = softplus(xln.W_dt + b + dt_bias)
__global__ __launch_bounds__(256)
void dtk(const u16* __restrict__ xln, const float* __restrict__ minW,
         const float* __restrict__ minB, const float* __restrict__ dtb,
         float* __restrict__ DT)
{
  __shared__ float sx[32*257];
  const int z = blockIdx.z;
  const int r0 = blockIdx.x * 32;
  const int tid = threadIdx.x;
  {
    const int rr = tid >> 3, cc = (tid & 7) * 32;
    const u16* src = xln + ((size_t)z*16384 + r0 + rr)*256 + cc;
    #pragma unroll
    for (int q=0;q<4;q++){
      uint4 raw = *(const uint4*)(src + q*8);
      float v[8]; unpk8(raw, v);
      #pragma unroll
      for (int j=0;j<8;j++) sx[rr*257 + cc + q*8 + j] = v[j];
    }
  }
  __syncthreads();
  const int ri = tid >> 3, hv = tid & 7;
  const float* wrow = minW + ((size_t)z*1288 + 1280 + hv)*256;
  float acc = 0.f;
  #pragma unroll 4
  for (int k=0; k<256; k+=4){
    float4 wq = *(const float4*)(wrow + k);
    acc += sx[ri*257+k]*wq.x + sx[ri*257+k+1]*wq.y + sx[ri*257+k+2]*wq.z + sx[ri*257+k+3]*wq.w;
  }
  acc += minB[(size_t)z*1288 + 1280 + hv] + dtb[z*8 + hv];
  float dt = (acc > 20.f) ? acc : log1pf(expf(acc));
  DT[((size_t)z*16384 + r0 + ri)*8 + hv] = dt;
}

// chunk-local cumulative log-decay
__global__ __launch_bounds__(256)
void cak(const float* __restrict__ DT, float* __restrict__ CA,
         const float* __restrict__ alog, int dirBase)
{
  const int z = blockIdx.z;
  const int gidx = blockIdx.x*4 + (threadIdx.x>>6);
  const int lane = threadIdx.x & 63;
  const int c = gidx & 63, bh = gidx >> 6;
  const int b = bh >> 3, hh = bh & 7;
  const size_t row = (size_t)z*16384 + (size_t)b*4096 + c*64 + lane;
  float x = DT[row*8 + hh];
  #pragma unroll
  for (int m=1;m<64;m<<=1){ float o = __shfl_up(x, m); if (lane >= m) x += o; }
  float eA = expf(alog[(dirBase+z)*8 + hh]);
  CA[row*8 + hh] = -eA * x;
}

// fused: conv1d(4)+SiLU on B/C columns + C-half -> BCC + B-transpose -> BT
//        + head-shared raw scores S -> SR.   grid (256,1,nd) per (b,c)
__global__ __launch_bounds__(256)
void bck(const u16* __restrict__ xbcr, u16* __restrict__ bcc, u16* __restrict__ bt,
         u16* __restrict__ SR, const float* __restrict__ cw, const float* __restrict__ cb)
{
  __shared__ u16 BCs[64*264];   // [s][B:0..127, C:128..255]
  __shared__ u16 Tb[128*72];    // [n][s] transposed B
  __shared__ float cwS[4][256];
  __shared__ float cbS[256];
  const int bx = blockIdx.x, z = blockIdx.z;
  const int c = bx & 63, b = bx >> 6;
  const int tid = threadIdx.x, l = tid & 63, w = tid >> 6;
  const u16* xb = xbcr + (size_t)z*16777216 + (size_t)b*4096*768;
  const float* cwp = cw + (size_t)z*3072;
  const float* cbp = cb + (size_t)z*768;
  {
    float4 w4 = *(const float4*)(cwp + (512 + tid)*4);
    cwS[0][tid]=w4.x; cwS[1][tid]=w4.y; cwS[2][tid]=w4.z; cwS[3][tid]=w4.w;
    cbS[tid] = cbp[512 + tid];
  }
  __syncthreads();
  #pragma unroll
  for (int u=0; u<8; ++u){
    int idx = u*256 + tid;
    int s = idx >> 5, c8 = idx & 31;
    int li = c*64 + s;
    int col = 512 + c8*8;
    float acc[8];
    #pragma unroll
    for (int j=0;j<8;j++) acc[j] = cbS[c8*8+j];
    #pragma unroll
    for (int tap=0; tap<4; ++tap){
      int lt = li - 3 + tap;
      if (lt >= 0){
        uint4 raw = *(const uint4*)(xb + (size_t)lt*768 + col);
        float v[8]; unpk8(raw, v);
        #pragma unroll
        for (int j=0;j<8;j++) acc[j] = fmaf(v[j], cwS[tap][c8*8+j], acc[j]);
      }
    }
    u16 o8[8];
    #pragma unroll
    for (int j=0;j<8;j++) o8[j] = f2bf(acc[j] / (1.f + __expf(-acc[j])));
    *(uint4*)&BCs[s*264 + c8*8] = *(const uint4*)o8;
    if (c8 >= 16){
      *(uint4*)(bcc + ((size_t)z*16384 + (size_t)b*4096 + li)*256 + c8*8) = *(const uint4*)o8;
    } else {
      #pragma unroll
      for (int j=0;j<8;j++) Tb[(c8*8+j)*72 + s] = o8[j];
    }
  }
  __syncthreads();
  // S = C@B^T (16 MFMA)
  bfx8 av[4];
  #pragma unroll
  for (int kk=0; kk<4; ++kk)
    av[kk] = *(const bfx8*)&BCs[(w*16 + (l&15))*264 + 128 + kk*32 + (l>>4)*8];
  f32x4 sacc[4];
  #pragma unroll
  for (int i=0;i<4;i++) sacc[i] = (f32x4){0.f,0.f,0.f,0.f};
  #pragma unroll
  for (int kk=0; kk<4; ++kk)
    #pragma unroll
    for (int st=0; st<4; ++st){
      bfx8 bv = *(const bfx8*)&BCs[(st*16 + (l&15))*264 + kk*32 + (l>>4)*8];
      sacc[st] = __builtin_amdgcn_mfma_f32_16x16x32_bf16(av[kk], bv, sacc[st], 0, 0, 0);
    }
  // SR stride per (z,b) is 262144 u16 (64 chunks x 4096)
  u16* Sd = SR + ((size_t)z*4 + b)*262144 + (size_t)c*4096;
  const int t0 = w*16 + ((l>>4)<<2);
  #pragma unroll
  for (int st=0; st<4; ++st){
    int s = st*16 + (l&15);
    u32* cp = (u32*)&Sd[(size_t)s*64 + t0];
    cp[0] = pk2(sacc[st][0], sacc[st][1]);
    cp[1] = pk2(sacc[st][2], sacc[st][3]);
  }
  #pragma unroll
  for (int u=0; u<4; ++u){
    int idx = u*256 + tid;
    int n = idx >> 3, sg = idx & 7;
    uint4 v = *(const uint4*)&Tb[n*72 + sg*8];
    *(uint4*)(bt + (size_t)z*2097152 + (size_t)n*16384 + (size_t)b*4096 + c*64 + sg*8) = v;
  }
}

// conv1d(4)+SiLU on X cols (raw 0..511) + transpose -> XCT[p][g]
__global__ __launch_bounds__(256)
void convx(const u16* __restrict__ xbcr, u16* __restrict__ xct,
           const float* __restrict__ cw, const float* __restrict__ cb)
{
  __shared__ u16 T[128*72];
  __shared__ float cwX[4][128];
  __shared__ float cbX[128];
  const int bx = blockIdx.x, z = blockIdx.z;
  const int pq = bx & 3, c = (bx>>2) & 63, b = bx >> 8;
  const int tid = threadIdx.x;
  const u16* xb = xbcr + (size_t)z*16777216 + (size_t)b*4096*768;
  if (tid < 128){
    float4 w4 = *(const float4*)(cw + (size_t)z*3072 + (pq*128+tid)*4);
    cwX[0][tid]=w4.x; cwX[1][tid]=w4.y; cwX[2][tid]=w4.z; cwX[3][tid]=w4.w;
    cbX[tid] = cb[z*768 + pq*128 + tid];
  }
  __syncthreads();
  #pragma unroll
  for (int u=0; u<4; ++u){
    int idx = u*256 + tid;
    int s = idx >> 4, seg = idx & 15;
    int li = c*64 + s;
    int col = pq*128 + seg*8;
    float acc[8];
    #pragma unroll
    for (int j=0;j<8;j++) acc[j] = cbX[seg*8+j];
    #pragma unroll
    for (int tap=0; tap<4; ++tap){
      int lt = li - 3 + tap;
      if (lt >= 0){
        uint4 raw = *(const uint4*)(xb + (size_t)lt*768 + col);
        float v[8]; unpk8(raw, v);
        #pragma unroll
        for (int j=0;j<8;j++) acc[j] = fmaf(v[j], cwX[tap][seg*8+j], acc[j]);
      }
    }
    #pragma unroll
    for (int j=0;j<8;j++)
      T[(seg*8+j)*72 + s] = f2bf(acc[j] / (1.f + __expf(-acc[j])));
  }
  __syncthreads();
  #pragma unroll
  for (int u=0; u<4; ++u){
    int idx = u*256 + tid;
    int pl = idx >> 3, sg = idx & 7;
    uint4 v = *(const uint4*)&T[pl*72 + sg*8];
    *(uint4*)(xct + (size_t)z*8388608 + (size_t)(pq*128+pl)*16384 + b*4096 + c*64 + sg*8) = v;
  }
}

// per-chunk outer products, heads fused, p-quarter per block; grid (1024,1,nd)
__global__ __launch_bounds__(256)
void csk(const u16* __restrict__ xct, const u16* __restrict__ bt,
         const float* __restrict__ DT, const float* __restrict__ CA,
         u16* __restrict__ CS)
{
  __shared__ u16 Xw[128*72];
  __shared__ u16 Bt[128*72];
  __shared__ float wS[64*2];
  const int bx = blockIdx.x, z = blockIdx.z;
  const int pq = bx & 3, c = (bx>>2) & 63, b = bx >> 8;
  const int tid = threadIdx.x, l = tid & 63, w = tid >> 6;
  const size_t rowb = (size_t)z*16384 + (size_t)b*4096;
  const int p0 = pq*128;
  if (tid < 128){
    int s = tid & 63, hi = tid >> 6;
    int hh = pq*2 + hi;
    float ca63 = CA[(rowb + c*64 + 63)*8 + hh];
    float cav  = CA[(rowb + c*64 + s)*8 + hh];
    float dtv  = DT[(rowb + c*64 + s)*8 + hh];
    wS[s*2+hi] = __expf(ca63 - cav) * dtv;
  }
  __syncthreads();
  #pragma unroll
  for (int u=0; u<4; ++u){
    int idx = u*256 + tid;
    int pl = idx >> 3, sg = idx & 7;
    int hi = pl >> 6;
    uint4 raw = *(const uint4*)(xct + (size_t)z*8388608 + (size_t)(p0+pl)*16384 + b*4096 + c*64 + sg*8);
    float v[8]; unpk8(raw, v);
    uint4 o;
    o.x = pk2(v[0]*wS[(sg*8+0)*2+hi], v[1]*wS[(sg*8+1)*2+hi]);
    o.y = pk2(v[2]*wS[(sg*8+2)*2+hi], v[3]*wS[(sg*8+3)*2+hi]);
    o.z = pk2(v[4]*wS[(sg*8+4)*2+hi], v[5]*wS[(sg*8+5)*2+hi]);
    o.w = pk2(v[6]*wS[(sg*8+6)*2+hi], v[7]*wS[(sg*8+7)*2+hi]);
    *(uint4*)&Xw[pl*72 + sg*8] = o;
  }
  #pragma unroll
  for (int u=0; u<4; ++u){
    int idx = u*256 + tid;
    int n = idx >> 3, sg = idx & 7;
    *(uint4*)&Bt[n*72 + sg*8] =
      *(const uint4*)(bt + (size_t)z*2097152 + (size_t)n*16384 + b*4096 + c*64 + sg*8);
  }
  __syncthreads();
  f32x4 acc[8][2];
  #pragma unroll
  for (int i=0;i<8;i++)
    #pragma unroll
    for (int j=0;j<2;j++) acc[i][j] = (f32x4){0.f,0.f,0.f,0.f};
  #pragma unroll
  for (int kk=0; kk<2; ++kk){
    bfx8 bvp[2];
    #pragma unroll
    for (int ni=0; ni<2; ++ni)
      bvp[ni] = *(const bfx8*)&Xw[(w*32 + ni*16 + (l&15))*72 + kk*32 + (l>>4)*8];
    #pragma unroll
    for (int mi=0; mi<8; ++mi){
      bfx8 av = *(const bfx8*)&Bt[(mi*16 + (l&15))*72 + kk*32 + (l>>4)*8];
      #pragma unroll
      for (int ni=0; ni<2; ++ni)
        acc[mi][ni] = __builtin_amdgcn_mfma_f32_16x16x32_bf16(av, bvp[ni], acc[mi][ni], 0, 0, 0);
    }
  }
  #pragma unroll
  for (int mi=0; mi<8; ++mi){
    #pragma unroll
    for (int ni=0; ni<2; ++ni){
      int gp = p0 + w*32 + ni*16 + (l&15);
      int bhx = b*8 + (gp>>6); int pin = gp & 63;
      int n0 = mi*16 + ((l>>4)<<2);
      u32* cp = (u32*)&CS[(size_t)z*16777216 + (size_t)bhx*524288 + (size_t)c*8192 + (size_t)pin*128 + n0];
      cp[0] = pk2(acc[mi][ni][0], acc[mi][ni][1]);
      cp[1] = pk2(acc[mi][ni][2], acc[mi][ni][3]);
    }
  }
}

// sequential 64-step combine IN PLACE (H aliases CS); 2x n-split
__global__ __launch_bounds__(256)
void combk(const u16* __restrict__ CS, const float* __restrict__ CA,
           u16* __restrict__ H)
{
  __shared__ float aL[64];
  const int bx = blockIdx.x;
  const int z = blockIdx.z;
  const int nh = bx & 1, pg = (bx >> 1) & 3, bh = bx >> 3;
  const int b = bh >> 3, hh = bh & 7;
  const int tid = threadIdx.x;
  const int p = pg*16 + (tid >> 4), n = nh*64 + (tid & 15)*4;
  const size_t rowb = (size_t)z*16384 + (size_t)b*4096;
  if (tid < 64) aL[tid] = __expf(CA[(rowb + tid*64 + 63)*8 + hh]);
  __syncthreads();
  const u16* Cs = CS + (size_t)z*16777216 + (size_t)bh*524288 + (size_t)p*128 + n;
  u16* Hd = H + (size_t)z*16777216 + (size_t)bh*524288 + (size_t)p*128 + n;
  float h[4];
  #pragma unroll
  for (int j=0;j<4;j++) h[j]=0.f;
  uint2 pf = *(const uint2*)Cs;
  #pragma unroll 1
  for (int c=0; c<64; ++c){
    uint2 cur = pf;
    if (c < 63) pf = *(const uint2*)(Cs + (size_t)(c+1)*8192);
    uint2 o;
    o.x = pk2(h[0],h[1]); o.y = pk2(h[2],h[3]);
    *(uint2*)(Hd + (size_t)c*8192) = o;
    float v[4]; unpk4(cur, v);
    const float a = aL[c];
    #pragma unroll
    for (int j=0;j<4;j++) h[j] = fmaf(h[j], a, v[j]);
  }
}

// per-chunk output: Y = (S_decayed @ X + diag(exp(ca)) * (C @ H[c]) + Dh*x) * silu(z)
// scores loaded direct to regs (no Ss buffer); LDS 36.4KB -> 4 blocks/CU
__global__ __launch_bounds__(256)
void yk2(const u16* __restrict__ bcc, const u16* __restrict__ xct,
         const u16* __restrict__ SR,
         const float* __restrict__ DT, const float* __restrict__ CA,
         const u16* __restrict__ H, const float* __restrict__ Dp,
         u16* __restrict__ Y, float* __restrict__ RS8)
{
  __shared__ u16 Hs[64*136];
  __shared__ u16 Xt[64*72];
  __shared__ u16 Sm[64*72];     // decayed scores; reused as Z/Y tile late
  __shared__ float caL[64], dtL[64];
  const int bx = blockIdx.x, z = blockIdx.z;
  const int c = bx & 63, bh = bx >> 6;
  const int b = bh >> 3, hh = bh & 7;
  const int tid = threadIdx.x, l = tid & 63, w = tid >> 6;
  const size_t rowb = (size_t)z*16384 + (size_t)b*4096;
  const u16* bcp = bcc + (rowb + c*64)*256;
  const u16* Hd = H + (size_t)z*16777216 + (size_t)bh*524288 + (size_t)c*8192;
  const u16* xcp = xct + (size_t)z*8388608 + (size_t)(hh*64)*16384 + b*4096 + c*64;
  const u16* Sd = SR + ((size_t)z*4 + b)*262144 + (size_t)c*4096;
  const float Dh = Dp[z*8 + hh];
  const int t0 = w*16 + ((l>>4)<<2);

  // score fragments direct from global: S[s][t0..t0+3] for s = st*16+(l&15)
  uint2 sv[4];
  #pragma unroll
  for (int st=0; st<4; ++st)
    sv[st] = *(const uint2*)(Sd + (size_t)(st*16 + (l&15))*64 + t0);
  // C-operand fragments direct from global
  bfx8 av[4];
  #pragma unroll
  for (int kk=0; kk<4; ++kk)
    av[kk] = *(const bfx8*)(bcp + (size_t)(w*16 + (l&15))*256 + 128 + kk*32 + (l>>4)*8);

  if (tid < 64){
    caL[tid] = CA[(rowb + c*64 + tid)*8 + hh];
    dtL[tid] = DT[(rowb + c*64 + tid)*8 + hh];
  }
  #pragma unroll
  for (int u=0; u<4; ++u){
    int idx = u*256 + tid; int p = idx >> 4, sg = idx & 15;
    *(uint4*)&Hs[p*136 + sg*8] = *(const uint4*)(Hd + (size_t)p*128 + sg*8);
  }
  #pragma unroll
  for (int u=0; u<2; ++u){
    int idx = u*256 + tid; int p = idx >> 3, sg = idx & 7;
    *(uint4*)&Xt[p*72 + sg*8] = *(const uint4*)(xcp + (size_t)p*16384 + sg*8);
  }
  __syncthreads();

  // inter part: acc2 = C @ H[c]
  f32x4 acc2[4];
  #pragma unroll
  for (int i=0;i<4;i++) acc2[i] = (f32x4){0.f,0.f,0.f,0.f};
  #pragma unroll
  for (int kk=0; kk<4; ++kk)
    #pragma unroll
    for (int st=0; st<4; ++st){
      bfx8 hv = *(const bfx8*)&Hs[(st*16 + (l&15))*136 + kk*32 + (l>>4)*8];
      acc2[st] = __builtin_amdgcn_mfma_f32_16x16x32_bf16(av[kk], hv, acc2[st], 0, 0, 0);
    }
  // decay+mask scores (from regs) -> Sm
  #pragma unroll
  for (int st=0; st<4; ++st){
    int s = st*16 + (l&15);
    #pragma unroll
    for (int q=0;q<4;q++){
      int t = t0 + q;
      u32 wv2 = (q < 2) ? sv[st].x : sv[st].y;
      u16 sraw = (q & 1) ? (u16)(wv2 >> 16) : (u16)(wv2 & 0xffff);
      float m = (s <= t) ? __expf(caL[t]-caL[s]) * dtL[s] : 0.f;
      Sm[t*72 + s] = f2bf(bf2f(sraw) * m);
    }
  }
  #pragma unroll
  for (int pt=0; pt<4; ++pt)
    #pragma unroll
    for (int q=0;q<4;q++){
      int t = t0 + q;
      acc2[pt][q] *= __expf(caL[t]);
    }
  __syncthreads();          // Sm ready
  // intra: acc2 += Sm @ Xt
  #pragma unroll
  for (int kk=0; kk<2; ++kk){
    bfx8 svx = *(const bfx8*)&Sm[(w*16 + (l&15))*72 + kk*32 + (l>>4)*8];
    #pragma unroll
    for (int pt=0; pt<4; ++pt){
      bfx8 bv = *(const bfx8*)&Xt[(pt*16 + (l&15))*72 + kk*32 + (l>>4)*8];
      acc2[pt] = __builtin_amdgcn_mfma_f32_16x16x32_bf16(svx, bv, acc2[pt], 0, 0, 0);
    }
  }
  __syncthreads();          // all Sm reads done; Sm reusable as Zs
  // stage z-tile into Zs (reuse Sm) with vectorized reads
  u16* Zs = Sm;
  u16* Yrow = Y + (rowb + c*64)*512 + hh*64;
  #pragma unroll
  for (int u=0; u<2; ++u){
    int idx = u*256 + tid; int t = idx >> 3, sg = idx & 7;
    *(uint4*)&Zs[t*72 + sg*8] = *(const uint4*)(Yrow + (size_t)t*512 + sg*8);
  }
  __syncthreads();          // Zs ready
  // epilogue in LDS: each (t,p) owned by exactly one thread
  float ssq[4] = {0.f,0.f,0.f,0.f};
  #pragma unroll
  for (int pt=0; pt<4; ++pt){
    #pragma unroll
    for (int q=0;q<4;q++){
      int t = t0 + q;
      int p = pt*16 + (l&15);
      float xv = bf2f(Xt[p*72 + t]);
      float zf = bf2f(Zs[t*72 + p]);
      float yv = (acc2[pt][q] + Dh*xv) * (zf/(1.f+__expf(-zf)));
      ssq[q] += yv*yv;
      Zs[t*72 + p] = f2bf(yv);
    }
  }
  #pragma unroll
  for (int q=0;q<4;q++){
    float s = ssq[q];
    s += __shfl_xor(s, 1); s += __shfl_xor(s, 2);
    s += __shfl_xor(s, 4); s += __shfl_xor(s, 8);
    if ((l & 15) == 0){
      int t = t0 + q;
      RS8[(rowb + c*64 + t)*8 + hh] = s;
    }
  }
  __syncthreads();          // all yv in Zs
  #pragma unroll
  for (int u=0; u<2; ++u){
    int idx = u*256 + tid; int t = idx >> 3, sg = idx & 7;
    *(uint4*)(Yrow + (size_t)t*512 + sg*8) = *(const uint4*)&Zs[t*72 + sg*8];
  }
}

__global__ __launch_bounds__(256)
void finalk(const float* __restrict__ curr, const u16* __restrict__ outs, float* __restrict__ o)
{
  const int row = blockIdx.x*4 + (threadIdx.x>>6);
  const int c4 = (threadIdx.x & 63)*4;
  const int b = row >> 12, li = row & 4095;
  const int T = ((li & 63) << 6) | (li >> 6);
  const size_t rb = (size_t)b*4096;
  const ushort4 a0 = *(const ushort4*)(outs + (size_t)0*4194304 + ((rb+li)*256 + c4));
  const ushort4 a1 = *(const ushort4*)(outs + (size_t)1*4194304 + ((rb+T)*256 + c4));
  const ushort4 a2 = *(const ushort4*)(outs + (size_t)2*4194304 + ((rb+4095-li)*256 + c4));
  const ushort4 a3 = *(const ushort4*)(outs + (size_t)3*4194304 + ((rb+4095-T)*256 + c4));
  float4 cv = *(const float4*)(curr + (size_t)row*256 + c4);
  float4 r;
  r.x = cv.x + 0.25f*(bf2f(a0.x)+bf2f(a1.x)+bf2f(a2.x)+bf2f(a3.x));
  r.y = cv.y + 0.25f*(bf2f(a0.y)+bf2f(a1.y)+bf2f(a2.y)+bf2f(a3.y));
  r.z = cv.z + 0.25f*(bf2f(a0.z)+bf2f(a1.z)+bf2f(a2.z)+bf2f(a3.z));
  r.w = cv.w + 0.25f*(bf2f(a0.w)+bf2f(a1.w)+bf2f(a2.w)+bf2f(a3.w));
  *(float4*)(o + (size_t)row*256 + c4) = r;
}

// ---------------------------------------------------------------------------
extern "C" void kernel_launch(void* const* d_in, const int* in_sizes, int n_in,
                              void* d_out, int out_size, void* d_ws, size_t ws_size,
                              hipStream_t stream)
{
  (void)in_sizes; (void)n_in; (void)out_size;
  const float* curr   = (const float*)d_in[0];
  const float* prev   = (const float*)d_in[1];
  const float* conv3w = (const float*)d_in[2];
  const float* bn3g=(const float*)d_in[3], *bn3b=(const float*)d_in[4], *bn3m=(const float*)d_in[5], *bn3v=(const float*)d_in[6];
  const float* conv1w = (const float*)d_in[7];
  const float* bn1g=(const float*)d_in[8], *bn1b=(const float*)d_in[9], *bn1m=(const float*)d_in[10], *bn1v=(const float*)d_in[11];
  const float* fuseW=(const float*)d_in[12], *fuseB=(const float*)d_in[13];
  const float* lng=(const float*)d_in[14], *lnb=(const float*)d_in[15];
  const float* inpW=(const float*)d_in[16], *inpB=(const float*)d_in[17];
  const float* mlng=(const float*)d_in[18], *mlnb=(const float*)d_in[19];
  const float* minW=(const float*)d_in[20], *minB=(const float*)d_in[21];
  const float* cw=(const float*)d_in[22], *cb=(const float*)d_in[23];
  const float* alog=(const float*)d_in[24], *Dp=(const float*)d_in[25], *dtb=(const float*)d_in[26];
  const float* mng=(const float*)d_in[27];
  const float* moutW=(const float*)d_in[28], *moutB=(const float*)d_in[29];
  const float* outpW=(const float*)d_in[30], *outpB=(const float*)d_in[31];

  // ---- persistent layout ----
  char* ws = (char*)d_ws;
  size_t off = 0;
  auto alloc = [&](size_t bytes){ size_t o = off; off = (off + bytes + 1023) & ~(size_t)1023; return o; };
  const size_t O_WFUSE = alloc((size_t)256*256*2);
  const size_t O_WINP  = alloc((size_t)4*256*256*2);
  const size_t O_WMIN  = alloc((size_t)4*1288*256*2);
  const size_t O_WMOUT = alloc((size_t)4*256*512*2);
  const size_t O_WOUTP = alloc((size_t)4*256*256*2);
  const size_t O_WC3   = alloc((size_t)128*4608*2);
  const size_t O_WC1   = alloc((size_t)128*512*2);
  const size_t O_BNSS  = alloc(512*4);
  const size_t O_ZF    = alloc((size_t)16384*256*2);
  const size_t O_OUTS  = alloc((size_t)4*16384*256*2);
  const size_t O_P     = off;

  // per-dir sizes (bytes)
  const size_t S0d  = (size_t)16384*256*2;
  const size_t XLNd = (size_t)16384*256*2;
  const size_t Yd   = (size_t)16384*512*2;
  const size_t XCTd = (size_t)512*16384*2;
  const size_t BTd  = (size_t)128*16384*2;
  const size_t DTd  = (size_t)16384*8*4;
  const size_t CAd  = (size_t)16384*8*4;
  const size_t SRd  = (size_t)4*64*4096*2;
  const size_t RSd  = (size_t)16384*4;
  const size_t RS8d = (size_t)16384*8*4;
  const size_t XHd  = (size_t)16777216*2;
  const size_t perdir = S0d + XLNd + Yd + XCTd + BTd + DTd + CAd + SRd + RSd + RS8d + XHd;

  const size_t PADsz = (size_t)4*66*66*512*2;
  const size_t CPsz  = (size_t)9*16384*128*2;
  const size_t PREsz = PADsz + CPsz + (size_t)16384*256*2*2 + 4096;

  int nd = 0;
  for (int cand = 4; cand >= 1; cand >>= 1) {
    size_t need = (size_t)cand*perdir; if (need < PREsz) need = PREsz;
    if (O_P + need <= ws_size) { nd = cand; break; }
  }
  if (nd == 0) return;

  #define WP(o) ((u16*)(ws + (o)))
  #define FP(o) ((float*)(ws + (o)))

  const size_t O_PAD = O_P;
  const size_t O_CP  = O_PAD + PADsz;
  const size_t O_ZIN = O_CP + CPsz;
  const size_t O_ZFT = O_ZIN + (size_t)16384*256*2;

  // 1. BN scale/shift + weight conversions
  bnssk<<<1, 256, 0, stream>>>(bn3g,bn3b,bn3m,bn3v, bn1g,bn1b,bn1m,bn1v, FP(O_BNSS));
  castk<<<64, 256, 0, stream>>>(fuseW, WP(O_WFUSE), 65536);
  castk<<<256, 256, 0, stream>>>(inpW, WP(O_WINP), 262144);
  castk<<<1288, 256, 0, stream>>>(minW, WP(O_WMIN), 1318912);
  castg<<<512, 256, 0, stream>>>(moutW, mng, WP(O_WMOUT));
  castk<<<256, 256, 0, stream>>>(outpW, WP(O_WOUTP), 262144);
  castk<<<64, 256, 0, stream>>>(conv1w, WP(O_WC1), 65536);
  c3rep<<<2304, 256, 0, stream>>>(conv3w, WP(O_WC3));
  // 2. padded concat input (bf16)
  padk<<<4356, 256, 0, stream>>>(curr, prev, WP(O_PAD));

  GemmArgs a;
  // 3. conv3 split-K over 9 taps -> bf16 partials -> reduce+BN+ReLU
  a = {}; a.A = WP(O_PAD); a.pad = WP(O_PAD);
  a.Bw = WP(O_WC3); a.bZ = 512; a.ldb = 4608;
  a.C = WP(O_CP); a.cZ = 2097152; a.ldc = 128; a.colOff = 0; a.K = 512;
  gemm_bt<2,6><<<dim3(128,1,9), 256, 0, stream>>>(a);
  c3red<<<1024, 256, 0, stream>>>(WP(O_CP), FP(O_BNSS), WP(O_ZIN));
  // 4. conv1 -> zin[:,128:256]
  a = {}; a.A = WP(O_PAD); a.pad = WP(O_PAD); a.Bw = WP(O_WC1); a.bZ = 0; a.ldb = 512;
  a.scale = FP(O_BNSS)+256; a.shift = FP(O_BNSS)+384;
  a.C = WP(O_ZIN); a.cZ = 0; a.ldc = 256; a.colOff = 128; a.K = 512;
  gemm_bt<3,2><<<dim3(128,1,1), 256, 0, stream>>>(a);
  // 5. fuse GEMM -> zft
  a = {}; a.A = WP(O_ZIN); a.aZ = 0; a.lda = 256; a.Bw = WP(O_WFUSE); a.bZ = 0; a.ldb = 256;
  a.bias = fuseB; a.biasZ = 0; a.C = WP(O_ZFT); a.cZ = 0; a.ldc = 256; a.colOff = 0; a.K = 256;
  gemm_bt<0,0><<<dim3(128,2,1), 256, 0, stream>>>(a);
  // 6. LN -> zf (persistent)
  ln256<<<dim3(4096,1,1), 256, 0, stream>>>(WP(O_ZFT), 0, WP(O_ZF), 0, lng, lnb, 0);

  // ---- phases over directions ----
  for (int d0 = 0; d0 < 4; d0 += nd) {
    size_t o = O_P;
    const size_t O_S0  = o; o += (size_t)nd*S0d;
    const size_t O_XLN = o; o += (size_t)nd*XLNd;
    const size_t O_Y   = o; o += (size_t)nd*Yd;
    const size_t O_XCT = o; o += (size_t)nd*XCTd;
    const size_t O_BT  = o; o += (size_t)nd*BTd;
    const size_t O_DT  = o; o += (size_t)nd*DTd;
    const size_t O_CA  = o; o += (size_t)nd*CAd;
    const size_t O_SR  = o; o += (size_t)nd*SRd;
    const size_t O_RS  = o; o += (size_t)nd*RSd;
    const size_t O_RS8 = o; o += (size_t)nd*RS8d;
    const size_t O_XH  = o;
    const size_t O_BCC = O_XLN;
    const size_t O_S1  = O_XLN;

    // 7. inp GEMM (permuted rows per dir) -> s0
    a = {}; a.A = WP(O_ZF); a.aZ = 0; a.lda = 256;
    a.Bw = WP(O_WINP) + (size_t)d0*65536; a.bZ = 65536; a.ldb = 256;
    a.bias = inpB + d0*256; a.biasZ = 256;
    a.C = WP(O_S0); a.cZ = 4194304; a.ldc = 256; a.colOff = 0; a.K = 256; a.dirBase = d0;
    gemm_bt<1,0><<<dim3(128,2,nd), 256, 0, stream>>>(a);
    // 8. per-dir LN(s0) -> xln
    ln256<<<dim3(4096,1,nd), 256, 0, stream>>>(WP(O_S0), 4194304, WP(O_XLN), 4194304,
                                               mlng + d0*256, mlnb + d0*256, 256);
    // 9. dt, chunk log-decay
    dtk<<<dim3(512,1,nd), 256, 0, stream>>>(WP(O_XLN), minW + (size_t)d0*329728,
                                            minB + d0*1288, dtb + d0*8, FP(O_DT));
    cak<<<dim3(512,1,nd), 256, 0, stream>>>(FP(O_DT), FP(O_CA), alog, d0);
    // 10. z-gate GEMM -> Y
    a = {}; a.A = WP(O_XLN); a.aZ = 4194304; a.lda = 256;
    a.Bw = WP(O_WMIN) + (size_t)d0*329728; a.bZ = 329728; a.ldb = 256;
    a.bias = minB + d0*1288; a.biasZ = 1288;
    a.C = WP(O_Y); a.cZ = 8388608; a.ldc = 512; a.colOff = 0; a.K = 256;
    gemm_bt<0,0><<<dim3(128,4,nd), 256, 0, stream>>>(a);
    // 11. xBC GEMM -> raw xbc   [last reader of XLN]
    a = {}; a.A = WP(O_XLN); a.aZ = 4194304; a.lda = 256;
    a.Bw = WP(O_WMIN) + (size_t)d0*329728 + (size_t)512*256; a.bZ = 329728; a.ldb = 256;
    a.bias = minB + d0*1288 + 512; a.biasZ = 1288;
    a.C = WP(O_XH); a.cZ = 16777216; a.ldc = 768; a.colOff = 0; a.K = 256;
    gemm_bt<0,0><<<dim3(128,6,nd), 256, 0, stream>>>(a);
    // 12. conv1d+SiLU+transpose X -> XCT
    convx<<<dim3(1024,1,nd), 256, 0, stream>>>(WP(O_XH), WP(O_XCT), cw + d0*3072, cb + d0*768);
    // 13. fused conv B/C + BCC(C-half) + BT + head-shared scores SR
    bck<<<dim3(256,1,nd), 256, 0, stream>>>(WP(O_XH), WP(O_BCC), WP(O_BT), WP(O_SR),
                                            cw + d0*3072, cb + d0*768);
    // 14. per-chunk outer products -> CS (overlays raw xbc; after 12&13)
    csk<<<dim3(1024,1,nd), 256, 0, stream>>>(WP(O_XCT), WP(O_BT), FP(O_DT), FP(O_CA), WP(O_XH));
    // 15. 64-step combine in place -> H
    combk<<<dim3(256,1,nd), 256, 0, stream>>>(WP(O_XH), FP(O_CA), WP(O_XH));
    // 16. per-chunk outputs -> Y in place, + per-(row,head) SS
    yk2<<<dim3(2048,1,nd), 256, 0, stream>>>(WP(O_BCC), WP(O_XCT), WP(O_SR),
                                             FP(O_DT), FP(O_CA), WP(O_XH), Dp + d0*8,
                                             WP(O_Y), FP(O_RS8));
    // 17. inverse RMS per row
    rsumk<<<dim3(64,1,nd), 256, 0, stream>>>(FP(O_RS8), FP(O_RS));
    // 18. m_out GEMM (norm fused) + s0 residual -> s1
    a = {}; a.A = WP(O_Y); a.aZ = 8388608; a.lda = 512;
    a.Bw = WP(O_WMOUT) + (size_t)d0*131072; a.bZ = 131072; a.ldb = 512;
    a.bias = moutB + d0*256; a.biasZ = 256;
    a.add = WP(O_S0); a.addZ = 4194304;
    a.rowsc = FP(O_RS); a.rowscZ = 16384;
    a.C = WP(O_S1); a.cZ = 4194304; a.ldc = 256; a.colOff = 0; a.K = 512;
    gemm_bt<0,5><<<dim3(128,2,nd), 256, 0, stream>>>(a);
    // 19. outp GEMM -> outs (persistent)
    a = {}; a.A = WP(O_S1); a.aZ = 4194304; a.lda = 256;
    a.Bw = WP(O_WOUTP) + (size_t)d0*65536; a.bZ = 65536; a.ldb = 256;
    a.bias = outpB + d0*256; a.biasZ = 256;
    a.C = WP(O_OUTS) + (size_t)d0*4194304; a.cZ = 4194304; a.ldc = 256; a.colOff = 0; a.K = 256;
    gemm_bt<0,0><<<dim3(128,2,nd), 256, 0, stream>>>(a);
  }

  // 20. final inverse-permute average + residual
  finalk<<<4096, 256, 0, stream>>>(curr, WP(O_OUTS), (float*)d_out);

  #undef WP
  #undef FP
}

// Round 14
// 697.789 us; speedup vs baseline: 5.5411x; 1.0038x over previous
//
#include <hip/hip_runtime.h>
#include <hip/hip_bf16.h>
#include <cstdint>
#include <cstddef>

typedef unsigned short u16;
typedef unsigned int u32;
typedef __attribute__((ext_vector_type(8))) __bf16 bfx8;
typedef __attribute__((ext_vector_type(4))) float f32x4;

static __device__ __forceinline__ float bitf(u32 v){ float f; __builtin_memcpy(&f,&v,4); return f; }
static __device__ __forceinline__ float bf2f(u16 v){ return bitf(((u32)v)<<16); }
static __device__ __forceinline__ u16 f2bf(float f){ __bf16 b=(__bf16)f; u16 r; __builtin_memcpy(&r,&b,2); return r; }
static __device__ __forceinline__ u32 pk2(float a,float b){ return (u32)f2bf(a) | ((u32)f2bf(b)<<16); }
static __device__ __forceinline__ void unpk8(uint4 r, float* o){
  o[0]=bitf(r.x<<16); o[1]=bitf(r.x&0xffff0000u);
  o[2]=bitf(r.y<<16); o[3]=bitf(r.y&0xffff0000u);
  o[4]=bitf(r.z<<16); o[5]=bitf(r.z&0xffff0000u);
  o[6]=bitf(r.w<<16); o[7]=bitf(r.w&0xffff0000u);
}
static __device__ __forceinline__ void unpk4(uint2 r, float* o){
  o[0]=bitf(r.x<<16); o[1]=bitf(r.x&0xffff0000u);
  o[2]=bitf(r.y<<16); o[3]=bitf(r.y&0xffff0000u);
}
static __device__ __forceinline__ void async16(void* lds, const void* g){
  __builtin_amdgcn_global_load_lds((const __attribute__((address_space(1))) u32*)g,
                                   (__attribute__((address_space(3))) u32*)lds, 16, 0, 0);
}

// ---------------- GEMM: C[M][N] = A[M][K] @ B[N][K]^T (+ epilogue) -----------
// EPI: 0=+bias, 2=BN+ReLU, 3=+bias+add, 4=raw fp32, 5=*rowsc+bias+add, 6=raw bf16
// AMODE 2: conv3 dy-grouped split-K (z = dy+1, K=1536, dx from k0>>9)
struct GemmArgs {
  const u16* A; long aZ; int lda;
  const u16* Bw; long bZ; int ldb;
  const float* bias; int biasZ;
  const float* scale; const float* shift;
  const u16* add; long addZ;
  const float* rowsc; long rowscZ;
  u16* C; long cZ; int ldc; int colOff;
  int K;
  const u16* pad;
  int dirBase;
};

template<int AMODE, int EPI>
__global__ __launch_bounds__(256)
void gemm_bt(GemmArgs g)
{
  __shared__ u16 smA[128*64];
  __shared__ u16 smB[128*64];
  const int tid = threadIdx.x;
  const int l = tid & 63;
  const int wv = tid >> 6;
  const int wr = wv >> 1, wc = wv & 1;
  const int z = blockIdx.z;
  const int r0 = blockIdx.x * 128;
  const int n0 = blockIdx.y * 128;

  const u16* Abase = g.A + (size_t)z * g.aZ;
  const u16* Bbase = g.Bw + (size_t)z * g.bZ;
  const int ldb = g.ldb ? g.ldb : g.K;

  f32x4 acc[4][4];
  #pragma unroll
  for (int i=0;i<4;i++)
    #pragma unroll
    for (int j=0;j<4;j++) acc[i][j] = (f32x4){0.f,0.f,0.f,0.f};

  const int nkt = g.K >> 6;
  #pragma unroll 1
  for (int kt=0; kt<nkt; ++kt) {
    const int k0 = kt << 6;
    #pragma unroll
    for (int it=0; it<4; ++it) {
      const int s = it*256 + tid;
      const int row = s >> 3, ch = s & 7;
      const u16* ga;
      if (AMODE == 0) {
        ga = Abase + (size_t)(r0+row) * g.lda + k0 + ch*8;
      } else if (AMODE == 1) {
        int rr = r0 + row; int li = rr & 4095; int bb = rr >> 12;
        int dir = g.dirBase + z;
        int l2 = (dir & 2) ? (4095 - li) : li;
        int sl = (dir & 1) ? (((l2 & 63) << 6) | (l2 >> 6)) : l2;
        ga = Abase + (size_t)((bb << 12) | sl) * g.lda + k0 + ch*8;
      } else if (AMODE == 2) {
        int rr = r0 + row; int bb = rr >> 12; int li = rr & 4095;
        int yy = li >> 6, xx = li & 63;
        int dy = z - 1, dx = (k0 >> 9) - 1, kin = k0 & 511;
        ga = g.pad + (((size_t)(bb*66 + yy+dy+1))*66 + (xx+dx+1))*512 + kin + ch*8;
      } else {
        int rr = r0 + row; int bb = rr >> 12; int li = rr & 4095;
        int yy = li >> 6, xx = li & 63;
        ga = g.pad + (((size_t)(bb*66 + yy+1))*66 + (xx+1))*512 + k0 + ch*8;
      }
      async16(&smA[(size_t)(it*256 + (tid & ~63))*8], ga);
      const u16* gb = Bbase + (size_t)(n0+row) * ldb + k0 + ch*8;
      async16(&smB[(size_t)(it*256 + (tid & ~63))*8], gb);
    }
    __syncthreads();
    #pragma unroll
    for (int kk=0; kk<2; ++kk) {
      bfx8 av[4], bv[4];
      #pragma unroll
      for (int mi=0; mi<4; ++mi) {
        int ra = wr*64 + mi*16 + (l & 15);
        av[mi] = *(const bfx8*)&smA[ra*64 + kk*32 + (l>>4)*8];
      }
      #pragma unroll
      for (int ni=0; ni<4; ++ni) {
        int rb = wc*64 + ni*16 + (l & 15);
        bv[ni] = *(const bfx8*)&smB[rb*64 + kk*32 + (l>>4)*8];
      }
      #pragma unroll
      for (int mi=0; mi<4; ++mi)
        #pragma unroll
        for (int ni=0; ni<4; ++ni)
          acc[mi][ni] = __builtin_amdgcn_mfma_f32_16x16x32_bf16(av[mi], bv[ni], acc[mi][ni], 0, 0, 0);
    }
    __syncthreads();
  }

  const float* bias_d = (EPI == 0 || EPI == 3 || EPI == 5) ? g.bias + (size_t)z * g.biasZ : nullptr;
  const u16* add_d = (EPI == 3 || EPI == 5) ? g.add + (size_t)z * g.addZ : nullptr;
  const float* rowsc_d = (EPI == 5) ? g.rowsc + (size_t)z * g.rowscZ : nullptr;
  u16* Cd = g.C + (size_t)z * g.cZ;
  float* Cf = (float*)g.C + (size_t)z * g.cZ;
  #pragma unroll
  for (int mi=0; mi<4; ++mi) {
    #pragma unroll
    for (int ni=0; ni<4; ++ni) {
      f32x4 v = acc[mi][ni];
      const int gr = r0 + wr*64 + mi*16 + ((l >> 4) << 2);
      const int gc = n0 + wc*64 + ni*16 + (l & 15);
      #pragma unroll
      for (int q=0; q<4; ++q) {
        const int r = gr + q;
        float x = v[q];
        if (EPI == 2) {
          x = fmaxf(fmaf(x, g.scale[gc], g.shift[gc]), 0.f);
          Cd[(size_t)r * g.ldc + g.colOff + gc] = f2bf(x);
        } else if (EPI == 3) {
          x += bias_d[gc] + bf2f(add_d[(size_t)r * g.ldc + gc]);
          Cd[(size_t)r * g.ldc + g.colOff + gc] = f2bf(x);
        } else if (EPI == 5) {
          x = x * rowsc_d[r] + bias_d[gc] + bf2f(add_d[(size_t)r * g.ldc + gc]);
          Cd[(size_t)r * g.ldc + g.colOff + gc] = f2bf(x);
        } else if (EPI == 4) {
          Cf[(size_t)r * g.ldc + g.colOff + gc] = x;
        } else if (EPI == 6) {
          Cd[(size_t)r * g.ldc + g.colOff + gc] = f2bf(x);
        } else {
          x += bias_d[gc];
          Cd[(size_t)r * g.ldc + g.colOff + gc] = f2bf(x);
        }
      }
    }
  }
}

// ---------------- small utility kernels --------------------------------------
__global__ void castk(const float* __restrict__ s, u16* __restrict__ d, int n)
{
  int i = (blockIdx.x*256 + threadIdx.x)*4;
  if (i < n){
    float4 v = *(const float4*)(s+i);
    ushort4 o; o.x=f2bf(v.x); o.y=f2bf(v.y); o.z=f2bf(v.z); o.w=f2bf(v.w);
    *(ushort4*)(d+i) = o;
  }
}

// cast m_out W with norm gain folded in
__global__ void castg(const float* __restrict__ s, const float* __restrict__ gw,
                      u16* __restrict__ d)
{
  int i = (blockIdx.x*256 + threadIdx.x)*4;
  int dd = i >> 17, k = i & 511;
  float4 v = *(const float4*)(s+i);
  float4 g4 = *(const float4*)(gw + dd*512 + k);
  ushort4 o; o.x=f2bf(v.x*g4.x); o.y=f2bf(v.y*g4.y); o.z=f2bf(v.z*g4.z); o.w=f2bf(v.w*g4.w);
  *(ushort4*)(d+i) = o;
}

__global__ void c3rep(const float* __restrict__ w, u16* __restrict__ o)
{
  int id = blockIdx.x*256 + threadIdx.x;
  int oc = id / 4608, rem = id % 4608;
  int tap = rem >> 9, ic = rem & 511;
  o[id] = f2bf(w[((size_t)oc*512 + ic)*9 + tap]);
}

__global__ void bnssk(const float* g3,const float* b3,const float* m3,const float* v3,
                      const float* g1,const float* b1,const float* m1,const float* v1,
                      float* out)
{
  int t = threadIdx.x; int i = t & 127;
  if (t < 128){ float sc = g3[i]*rsqrtf(v3[i]+1e-5f); out[i]=sc; out[128+i]=b3[i]-m3[i]*sc; }
  else        { float sc = g1[i]*rsqrtf(v1[i]+1e-5f); out[256+i]=sc; out[384+i]=b1[i]-m1[i]*sc; }
}

// reduce 3 bf16 partials -> BN+ReLU -> bf16 into zin cols 0..127
__global__ __launch_bounds__(256)
void c3red(const u16* __restrict__ P, const float* __restrict__ bnss, u16* __restrict__ zin)
{
  const int id = blockIdx.x*256 + threadIdx.x;
  const size_t base = (size_t)id * 8;
  const int r = (int)(base >> 7), c = (int)(base & 127);
  float s[8] = {0,0,0,0,0,0,0,0};
  #pragma unroll
  for (int z=0; z<3; ++z){
    uint4 raw = *(const uint4*)(P + (size_t)z*2097152 + base);
    float v[8]; unpk8(raw, v);
    #pragma unroll
    for (int j=0;j<8;j++) s[j] += v[j];
  }
  uint4 o;
  float r8[8];
  #pragma unroll
  for (int j=0;j<8;j++)
    r8[j] = fmaxf(fmaf(s[j], bnss[c+j], bnss[128+c+j]), 0.f);
  o.x = pk2(r8[0],r8[1]); o.y = pk2(r8[2],r8[3]);
  o.z = pk2(r8[4],r8[5]); o.w = pk2(r8[6],r8[7]);
  *(uint4*)(zin + (size_t)r*256 + c) = o;
}

__global__ __launch_bounds__(256)
void padk(const float* __restrict__ curr, const float* __restrict__ prev, u16* __restrict__ pad)
{
  const int id = blockIdx.x*256 + threadIdx.x;
  const int c8 = id & 63;
  int t = id >> 6;
  const int xx = t % 66; t /= 66;
  const int yy = t % 66; const int b = t / 66;
  const int c0 = c8*8;
  uint4 o;
  if (yy==0 || yy==65 || xx==0 || xx==65){ o.x=0;o.y=0;o.z=0;o.w=0; }
  else {
    const int l = (yy-1)*64 + (xx-1);
    const float* s = (c0 < 256) ? curr + ((size_t)b*4096 + l)*256 + c0
                                : prev + ((size_t)b*4096 + l)*256 + (c0-256);
    float4 a = *(const float4*)s, bb = *(const float4*)(s+4);
    o.x = pk2(a.x,a.y); o.y = pk2(a.z,a.w); o.z = pk2(bb.x,bb.y); o.w = pk2(bb.z,bb.w);
  }
  *(uint4*)(pad + (((size_t)b*66 + yy)*66 + xx)*512 + c0) = o;
}

__global__ __launch_bounds__(256)
void ln256(const u16* __restrict__ in, long inZ, u16* __restrict__ out, long outZ,
           const float* __restrict__ gw, const float* __restrict__ bw, int pz)
{
  const int z = blockIdx.z;
  const int row = blockIdx.x*4 + (threadIdx.x>>6);
  const int l = threadIdx.x & 63;
  const u16* ip = in + (size_t)z*inZ + (size_t)row*256 + l*4;
  ushort4 rr = *(const ushort4*)ip;
  float v0=bf2f(rr.x), v1=bf2f(rr.y), v2=bf2f(rr.z), v3=bf2f(rr.w);
  float s = v0+v1+v2+v3;
  float ss = v0*v0+v1*v1+v2*v2+v3*v3;
  #pragma unroll
  for(int m=1;m<64;m<<=1){ s += __shfl_xor(s,m); ss += __shfl_xor(ss,m); }
  float mu = s*(1.f/256.f);
  float var = ss*(1.f/256.f) - mu*mu;
  float rs = rsqrtf(var + 1e-5f);
  const float* g = gw + (size_t)z*pz; const float* b = bw + (size_t)z*pz;
  int c = l*4;
  u16* op = out + (size_t)z*outZ + (size_t)row*256 + c;
  ushort4 o; o.x=f2bf((v0-mu)*rs*g[c]+b[c]); o.y=f2bf((v1-mu)*rs*g[c+1]+b[c+1]);
  o.z=f2bf((v2-mu)*rs*g[c+2]+b[c+2]); o.w=f2bf((v3-mu)*rs*g[c+3]+b[c+3]);
  *(ushort4*)op = o;
}

// sum 8 head partial SS -> inverse RMS per row
__global__ __launch_bounds__(256)
void rsumk(const float* __restrict__ RS8, float* __restrict__ RS)
{
  const int z = blockIdx.z;
  const int row = blockIdx.x*256 + threadIdx.x;
  const float* p = RS8 + ((size_t)z*16384 + row)*8;
  float4 a = *(const float4*)p, b = *(const float4*)(p+4);
  float s = a.x+a.y+a.z+a.w+b.x+b.y+b.z+b.w;
  RS[(size_t)z*16384 + row] = rsqrtf(s*(1.f/512.f) + 1e-5f);
}

// fp32 dt head: dt = softplus(xln.W_dt + b + dt_bias)
__global__ __launch_bounds__(256)
void dtk(const u16* __restrict__ xln, const float* __restrict__ minW,
         const float* __restrict__ minB, const float* __restrict__ dtb,
         float* __restrict__ DT)
{
  __shared__ float sx[32*257];
  const int z = blockIdx.z;
  const int r0 = blockIdx.x * 32;
  const int tid = threadIdx.x;
  {
    const int rr = tid >> 3, cc = (tid & 7) * 32;
    const u16* src = xln + ((size_t)z*16384 + r0 + rr)*256 + cc;
    #pragma unroll
    for (int q=0;q<4;q++){
      uint4 raw = *(const uint4*)(src + q*8);
      float v[8]; unpk8(raw, v);
      #pragma unroll
      for (int j=0;j<8;j++) sx[rr*257 + cc + q*8 + j] = v[j];
    }
  }
  __syncthreads();
  const int ri = tid >> 3, hv = tid & 7;
  const float* wrow = minW + ((size_t)z*1288 + 1280 + hv)*256;
  float acc = 0.f;
  #pragma unroll 4
  for (int k=0; k<256; k+=4){
    float4 wq = *(const float4*)(wrow + k);
    acc += sx[ri*257+k]*wq.x + sx[ri*257+k+1]*wq.y + sx[ri*257+k+2]*wq.z + sx[ri*257+k+3]*wq.w;
  }
  acc += minB[(size_t)z*1288 + 1280 + hv] + dtb[z*8 + hv];
  float dt = (acc > 20.f) ? acc : log1pf(expf(acc));
  DT[((size_t)z*16384 + r0 + ri)*8 + hv] = dt;
}

// chunk-local cumulative log-decay
__global__ __launch_bounds__(256)
void cak(const float* __restrict__ DT, float* __restrict__ CA,
         const float* __restrict__ alog, int dirBase)
{
  const int z = blockIdx.z;
  const int gidx = blockIdx.x*4 + (threadIdx.x>>6);
  const int lane = threadIdx.x & 63;
  const int c = gidx & 63, bh = gidx >> 6;
  const int b = bh >> 3, hh = bh & 7;
  const size_t row = (size_t)z*16384 + (size_t)b*4096 + c*64 + lane;
  float x = DT[row*8 + hh];
  #pragma unroll
  for (int m=1;m<64;m<<=1){ float o = __shfl_up(x, m); if (lane >= m) x += o; }
  float eA = expf(alog[(dirBase+z)*8 + hh]);
  CA[row*8 + hh] = -eA * x;
}

// fused: conv1d(4)+SiLU on B/C columns + C-half -> BCC + B-transpose -> BT
//        + head-shared raw scores S -> SR.   grid (256,1,nd) per (b,c)
__global__ __launch_bounds__(256)
void bck(const u16* __restrict__ xbcr, u16* __restrict__ bcc, u16* __restrict__ bt,
         u16* __restrict__ SR, const float* __restrict__ cw, const float* __restrict__ cb)
{
  __shared__ u16 BCs[64*264];   // [s][B:0..127, C:128..255]
  __shared__ u16 Tb[128*72];    // [n][s] transposed B
  __shared__ float cwS[4][256];
  __shared__ float cbS[256];
  const int bx = blockIdx.x, z = blockIdx.z;
  const int c = bx & 63, b = bx >> 6;
  const int tid = threadIdx.x, l = tid & 63, w = tid >> 6;
  const u16* xb = xbcr + (size_t)z*16777216 + (size_t)b*4096*768;
  const float* cwp = cw + (size_t)z*3072;
  const float* cbp = cb + (size_t)z*768;
  {
    float4 w4 = *(const float4*)(cwp + (512 + tid)*4);
    cwS[0][tid]=w4.x; cwS[1][tid]=w4.y; cwS[2][tid]=w4.z; cwS[3][tid]=w4.w;
    cbS[tid] = cbp[512 + tid];
  }
  __syncthreads();
  #pragma unroll
  for (int u=0; u<8; ++u){
    int idx = u*256 + tid;
    int s = idx >> 5, c8 = idx & 31;
    int li = c*64 + s;
    int col = 512 + c8*8;
    float acc[8];
    #pragma unroll
    for (int j=0;j<8;j++) acc[j] = cbS[c8*8+j];
    #pragma unroll
    for (int tap=0; tap<4; ++tap){
      int lt = li - 3 + tap;
      if (lt >= 0){
        uint4 raw = *(const uint4*)(xb + (size_t)lt*768 + col);
        float v[8]; unpk8(raw, v);
        #pragma unroll
        for (int j=0;j<8;j++) acc[j] = fmaf(v[j], cwS[tap][c8*8+j], acc[j]);
      }
    }
    u16 o8[8];
    #pragma unroll
    for (int j=0;j<8;j++) o8[j] = f2bf(acc[j] / (1.f + __expf(-acc[j])));
    *(uint4*)&BCs[s*264 + c8*8] = *(const uint4*)o8;
    if (c8 >= 16){
      *(uint4*)(bcc + ((size_t)z*16384 + (size_t)b*4096 + li)*256 + c8*8) = *(const uint4*)o8;
    } else {
      #pragma unroll
      for (int j=0;j<8;j++) Tb[(c8*8+j)*72 + s] = o8[j];
    }
  }
  __syncthreads();
  // S = C@B^T (16 MFMA)
  bfx8 av[4];
  #pragma unroll
  for (int kk=0; kk<4; ++kk)
    av[kk] = *(const bfx8*)&BCs[(w*16 + (l&15))*264 + 128 + kk*32 + (l>>4)*8];
  f32x4 sacc[4];
  #pragma unroll
  for (int i=0;i<4;i++) sacc[i] = (f32x4){0.f,0.f,0.f,0.f};
  #pragma unroll
  for (int kk=0; kk<4; ++kk)
    #pragma unroll
    for (int st=0; st<4; ++st){
      bfx8 bv = *(const bfx8*)&BCs[(st*16 + (l&15))*264 + kk*32 + (l>>4)*8];
      sacc[st] = __builtin_amdgcn_mfma_f32_16x16x32_bf16(av[kk], bv, sacc[st], 0, 0, 0);
    }
  // SR stride per (z,b) is 262144 u16 (64 chunks x 4096)
  u16* Sd = SR + ((size_t)z*4 + b)*262144 + (size_t)c*4096;
  const int t0 = w*16 + ((l>>4)<<2);
  #pragma unroll
  for (int st=0; st<4; ++st){
    int s = st*16 + (l&15);
    u32* cp = (u32*)&Sd[(size_t)s*64 + t0];
    cp[0] = pk2(sacc[st][0], sacc[st][1]);
    cp[1] = pk2(sacc[st][2], sacc[st][3]);
  }
  #pragma unroll
  for (int u=0; u<4; ++u){
    int idx = u*256 + tid;
    int n = idx >> 3, sg = idx & 7;
    uint4 v = *(const uint4*)&Tb[n*72 + sg*8];
    *(uint4*)(bt + (size_t)z*2097152 + (size_t)n*16384 + (size_t)b*4096 + c*64 + sg*8) = v;
  }
}

// conv1d(4)+SiLU on X cols (raw 0..511) + transpose -> XCT[p][g]
__global__ __launch_bounds__(256)
void convx(const u16* __restrict__ xbcr, u16* __restrict__ xct,
           const float* __restrict__ cw, const float* __restrict__ cb)
{
  __shared__ u16 T[128*72];
  __shared__ float cwX[4][128];
  __shared__ float cbX[128];
  const int bx = blockIdx.x, z = blockIdx.z;
  const int pq = bx & 3, c = (bx>>2) & 63, b = bx >> 8;
  const int tid = threadIdx.x;
  const u16* xb = xbcr + (size_t)z*16777216 + (size_t)b*4096*768;
  if (tid < 128){
    float4 w4 = *(const float4*)(cw + (size_t)z*3072 + (pq*128+tid)*4);
    cwX[0][tid]=w4.x; cwX[1][tid]=w4.y; cwX[2][tid]=w4.z; cwX[3][tid]=w4.w;
    cbX[tid] = cb[z*768 + pq*128 + tid];
  }
  __syncthreads();
  #pragma unroll
  for (int u=0; u<4; ++u){
    int idx = u*256 + tid;
    int s = idx >> 4, seg = idx & 15;
    int li = c*64 + s;
    int col = pq*128 + seg*8;
    float acc[8];
    #pragma unroll
    for (int j=0;j<8;j++) acc[j] = cbX[seg*8+j];
    #pragma unroll
    for (int tap=0; tap<4; ++tap){
      int lt = li - 3 + tap;
      if (lt >= 0){
        uint4 raw = *(const uint4*)(xb + (size_t)lt*768 + col);
        float v[8]; unpk8(raw, v);
        #pragma unroll
        for (int j=0;j<8;j++) acc[j] = fmaf(v[j], cwX[tap][seg*8+j], acc[j]);
      }
    }
    #pragma unroll
    for (int j=0;j<8;j++)
      T[(seg*8+j)*72 + s] = f2bf(acc[j] / (1.f + __expf(-acc[j])));
  }
  __syncthreads();
  #pragma unroll
  for (int u=0; u<4; ++u){
    int idx = u*256 + tid;
    int pl = idx >> 3, sg = idx & 7;
    uint4 v = *(const uint4*)&T[pl*72 + sg*8];
    *(uint4*)(xct + (size_t)z*8388608 + (size_t)(pq*128+pl)*16384 + b*4096 + c*64 + sg*8) = v;
  }
}

// per-chunk outer products, heads fused, p-quarter per block; grid (1024,1,nd)
__global__ __launch_bounds__(256)
void csk(const u16* __restrict__ xct, const u16* __restrict__ bt,
         const float* __restrict__ DT, const float* __restrict__ CA,
         u16* __restrict__ CS)
{
  __shared__ u16 Xw[128*72];
  __shared__ u16 Bt[128*72];
  __shared__ float wS[64*2];
  const int bx = blockIdx.x, z = blockIdx.z;
  const int pq = bx & 3, c = (bx>>2) & 63, b = bx >> 8;
  const int tid = threadIdx.x, l = tid & 63, w = tid >> 6;
  const size_t rowb = (size_t)z*16384 + (size_t)b*4096;
  const int p0 = pq*128;
  if (tid < 128){
    int s = tid & 63, hi = tid >> 6;
    int hh = pq*2 + hi;
    float ca63 = CA[(rowb + c*64 + 63)*8 + hh];
    float cav  = CA[(rowb + c*64 + s)*8 + hh];
    float dtv  = DT[(rowb + c*64 + s)*8 + hh];
    wS[s*2+hi] = __expf(ca63 - cav) * dtv;
  }
  __syncthreads();
  #pragma unroll
  for (int u=0; u<4; ++u){
    int idx = u*256 + tid;
    int pl = idx >> 3, sg = idx & 7;
    int hi = pl >> 6;
    uint4 raw = *(const uint4*)(xct + (size_t)z*8388608 + (size_t)(p0+pl)*16384 + b*4096 + c*64 + sg*8);
    float v[8]; unpk8(raw, v);
    uint4 o;
    o.x = pk2(v[0]*wS[(sg*8+0)*2+hi], v[1]*wS[(sg*8+1)*2+hi]);
    o.y = pk2(v[2]*wS[(sg*8+2)*2+hi], v[3]*wS[(sg*8+3)*2+hi]);
    o.z = pk2(v[4]*wS[(sg*8+4)*2+hi], v[5]*wS[(sg*8+5)*2+hi]);
    o.w = pk2(v[6]*wS[(sg*8+6)*2+hi], v[7]*wS[(sg*8+7)*2+hi]);
    *(uint4*)&Xw[pl*72 + sg*8] = o;
  }
  #pragma unroll
  for (int u=0; u<4; ++u){
    int idx = u*256 + tid;
    int n = idx >> 3, sg = idx & 7;
    *(uint4*)&Bt[n*72 + sg*8] =
      *(const uint4*)(bt + (size_t)z*2097152 + (size_t)n*16384 + b*4096 + c*64 + sg*8);
  }
  __syncthreads();
  f32x4 acc[8][2];
  #pragma unroll
  for (int i=0;i<8;i++)
    #pragma unroll
    for (int j=0;j<2;j++) acc[i][j] = (f32x4){0.f,0.f,0.f,0.f};
  #pragma unroll
  for (int kk=0; kk<2; ++kk){
    bfx8 bvp[2];
    #pragma unroll
    for (int ni=0; ni<2; ++ni)
      bvp[ni] = *(const bfx8*)&Xw[(w*32 + ni*16 + (l&15))*72 + kk*32 + (l>>4)*8];
    #pragma unroll
    for (int mi=0; mi<8; ++mi){
      bfx8 av = *(const bfx8*)&Bt[(mi*16 + (l&15))*72 + kk*32 + (l>>4)*8];
      #pragma unroll
      for (int ni=0; ni<2; ++ni)
        acc[mi][ni] = __builtin_amdgcn_mfma_f32_16x16x32_bf16(av, bvp[ni], acc[mi][ni], 0, 0, 0);
    }
  }
  #pragma unroll
  for (int mi=0; mi<8; ++mi){
    #pragma unroll
    for (int ni=0; ni<2; ++ni){
      int gp = p0 + w*32 + ni*16 + (l&15);
      int bhx = b*8 + (gp>>6); int pin = gp & 63;
      int n0 = mi*16 + ((l>>4)<<2);
      u32* cp = (u32*)&CS[(size_t)z*16777216 + (size_t)bhx*524288 + (size_t)c*8192 + (size_t)pin*128 + n0];
      cp[0] = pk2(acc[mi][ni][0], acc[mi][ni][1]);
      cp[1] = pk2(acc[mi][ni][2], acc[mi][ni][3]);
    }
  }
}

// sequential 64-step combine IN PLACE (H aliases CS); 2x n-split
__global__ __launch_bounds__(256)
void combk(const u16* __restrict__ CS, const float* __restrict__ CA,
           u16* __restrict__ H)
{
  __shared__ float aL[64];
  const int bx = blockIdx.x;
  const int z = blockIdx.z;
  const int nh = bx & 1, pg = (bx >> 1) & 3, bh = bx >> 3;
  const int b = bh >> 3, hh = bh & 7;
  const int tid = threadIdx.x;
  const int p = pg*16 + (tid >> 4), n = nh*64 + (tid & 15)*4;
  const size_t rowb = (size_t)z*16384 + (size_t)b*4096;
  if (tid < 64) aL[tid] = __expf(CA[(rowb + tid*64 + 63)*8 + hh]);
  __syncthreads();
  const u16* Cs = CS + (size_t)z*16777216 + (size_t)bh*524288 + (size_t)p*128 + n;
  u16* Hd = H + (size_t)z*16777216 + (size_t)bh*524288 + (size_t)p*128 + n;
  float h[4];
  #pragma unroll
  for (int j=0;j<4;j++) h[j]=0.f;
  uint2 pf = *(const uint2*)Cs;
  #pragma unroll 1
  for (int c=0; c<64; ++c){
    uint2 cur = pf;
    if (c < 63) pf = *(const uint2*)(Cs + (size_t)(c+1)*8192);
    uint2 o;
    o.x = pk2(h[0],h[1]); o.y = pk2(h[2],h[3]);
    *(uint2*)(Hd + (size_t)c*8192) = o;
    float v[4]; unpk4(cur, v);
    const float a = aL[c];
    #pragma unroll
    for (int j=0;j<4;j++) h[j] = fmaf(h[j], a, v[j]);
  }
}

// per-chunk output: Y = (S_decayed @ X + diag(exp(ca)) * (C @ H[c]) + Dh*x) * silu(z)
// scores loaded direct to regs; LDS 36.4KB -> 4 blocks/CU
__global__ __launch_bounds__(256)
void yk2(const u16* __restrict__ bcc, const u16* __restrict__ xct,
         const u16* __restrict__ SR,
         const float* __restrict__ DT, const float* __restrict__ CA,
         const u16* __restrict__ H, const float* __restrict__ Dp,
         u16* __restrict__ Y, float* __restrict__ RS8)
{
  __shared__ u16 Hs[64*136];
  __shared__ u16 Xt[64*72];
  __shared__ u16 Sm[64*72];     // decayed scores; reused as Z/Y tile late
  __shared__ float caL[64], dtL[64];
  const int bx = blockIdx.x, z = blockIdx.z;
  const int c = bx & 63, bh = bx >> 6;
  const int b = bh >> 3, hh = bh & 7;
  const int tid = threadIdx.x, l = tid & 63, w = tid >> 6;
  const size_t rowb = (size_t)z*16384 + (size_t)b*4096;
  const u16* bcp = bcc + (rowb + c*64)*256;
  const u16* Hd = H + (size_t)z*16777216 + (size_t)bh*524288 + (size_t)c*8192;
  const u16* xcp = xct + (size_t)z*8388608 + (size_t)(hh*64)*16384 + b*4096 + c*64;
  const u16* Sd = SR + ((size_t)z*4 + b)*262144 + (size_t)c*4096;
  const float Dh = Dp[z*8 + hh];
  const int t0 = w*16 + ((l>>4)<<2);

  uint2 sv[4];
  #pragma unroll
  for (int st=0; st<4; ++st)
    sv[st] = *(const uint2*)(Sd + (size_t)(st*16 + (l&15))*64 + t0);
  bfx8 av[4];
  #pragma unroll
  for (int kk=0; kk<4; ++kk)
    av[kk] = *(const bfx8*)(bcp + (size_t)(w*16 + (l&15))*256 + 128 + kk*32 + (l>>4)*8);

  if (tid < 64){
    caL[tid] = CA[(rowb + c*64 + tid)*8 + hh];
    dtL[tid] = DT[(rowb + c*64 + tid)*8 + hh];
  }
  #pragma unroll
  for (int u=0; u<4; ++u){
    int idx = u*256 + tid; int p = idx >> 4, sg = idx & 15;
    *(uint4*)&Hs[p*136 + sg*8] = *(const uint4*)(Hd + (size_t)p*128 + sg*8);
  }
  #pragma unroll
  for (int u=0; u<2; ++u){
    int idx = u*256 + tid; int p = idx >> 3, sg = idx & 7;
    *(uint4*)&Xt[p*72 + sg*8] = *(const uint4*)(xcp + (size_t)p*16384 + sg*8);
  }
  __syncthreads();

  f32x4 acc2[4];
  #pragma unroll
  for (int i=0;i<4;i++) acc2[i] = (f32x4){0.f,0.f,0.f,0.f};
  #pragma unroll
  for (int kk=0; kk<4; ++kk)
    #pragma unroll
    for (int st=0; st<4; ++st){
      bfx8 hv = *(const bfx8*)&Hs[(st*16 + (l&15))*136 + kk*32 + (l>>4)*8];
      acc2[st] = __builtin_amdgcn_mfma_f32_16x16x32_bf16(av[kk], hv, acc2[st], 0, 0, 0);
    }
  #pragma unroll
  for (int st=0; st<4; ++st){
    int s = st*16 + (l&15);
    #pragma unroll
    for (int q=0;q<4;q++){
      int t = t0 + q;
      u32 wv2 = (q < 2) ? sv[st].x : sv[st].y;
      u16 sraw = (q & 1) ? (u16)(wv2 >> 16) : (u16)(wv2 & 0xffff);
      float m = (s <= t) ? __expf(caL[t]-caL[s]) * dtL[s] : 0.f;
      Sm[t*72 + s] = f2bf(bf2f(sraw) * m);
    }
  }
  #pragma unroll
  for (int pt=0; pt<4; ++pt)
    #pragma unroll
    for (int q=0;q<4;q++){
      int t = t0 + q;
      acc2[pt][q] *= __expf(caL[t]);
    }
  __syncthreads();          // Sm ready
  #pragma unroll
  for (int kk=0; kk<2; ++kk){
    bfx8 svx = *(const bfx8*)&Sm[(w*16 + (l&15))*72 + kk*32 + (l>>4)*8];
    #pragma unroll
    for (int pt=0; pt<4; ++pt){
      bfx8 bv = *(const bfx8*)&Xt[(pt*16 + (l&15))*72 + kk*32 + (l>>4)*8];
      acc2[pt] = __builtin_amdgcn_mfma_f32_16x16x32_bf16(svx, bv, acc2[pt], 0, 0, 0);
    }
  }
  __syncthreads();          // Sm reads done; reuse as Zs
  u16* Zs = Sm;
  u16* Yrow = Y + (rowb + c*64)*512 + hh*64;
  #pragma unroll
  for (int u=0; u<2; ++u){
    int idx = u*256 + tid; int t = idx >> 3, sg = idx & 7;
    *(uint4*)&Zs[t*72 + sg*8] = *(const uint4*)(Yrow + (size_t)t*512 + sg*8);
  }
  __syncthreads();          // Zs ready
  float ssq[4] = {0.f,0.f,0.f,0.f};
  #pragma unroll
  for (int pt=0; pt<4; ++pt){
    #pragma unroll
    for (int q=0;q<4;q++){
      int t = t0 + q;
      int p = pt*16 + (l&15);
      float xv = bf2f(Xt[p*72 + t]);
      float zf = bf2f(Zs[t*72 + p]);
      float yv = (acc2[pt][q] + Dh*xv) * (zf/(1.f+__expf(-zf)));
      ssq[q] += yv*yv;
      Zs[t*72 + p] = f2bf(yv);
    }
  }
  #pragma unroll
  for (int q=0;q<4;q++){
    float s = ssq[q];
    s += __shfl_xor(s, 1); s += __shfl_xor(s, 2);
    s += __shfl_xor(s, 4); s += __shfl_xor(s, 8);
    if ((l & 15) == 0){
      int t = t0 + q;
      RS8[(rowb + c*64 + t)*8 + hh] = s;
    }
  }
  __syncthreads();
  #pragma unroll
  for (int u=0; u<2; ++u){
    int idx = u*256 + tid; int t = idx >> 3, sg = idx & 7;
    *(uint4*)(Yrow + (size_t)t*512 + sg*8) = *(const uint4*)&Zs[t*72 + sg*8];
  }
}

__global__ __launch_bounds__(256)
void finalk(const float* __restrict__ curr, const u16* __restrict__ outs, float* __restrict__ o)
{
  const int row = blockIdx.x*4 + (threadIdx.x>>6);
  const int c4 = (threadIdx.x & 63)*4;
  const int b = row >> 12, li = row & 4095;
  const int T = ((li & 63) << 6) | (li >> 6);
  const size_t rb = (size_t)b*4096;
  const ushort4 a0 = *(const ushort4*)(outs + (size_t)0*4194304 + ((rb+li)*256 + c4));
  const ushort4 a1 = *(const ushort4*)(outs + (size_t)1*4194304 + ((rb+T)*256 + c4));
  const ushort4 a2 = *(const ushort4*)(outs + (size_t)2*4194304 + ((rb+4095-li)*256 + c4));
  const ushort4 a3 = *(const ushort4*)(outs + (size_t)3*4194304 + ((rb+4095-T)*256 + c4));
  float4 cv = *(const float4*)(curr + (size_t)row*256 + c4);
  float4 r;
  r.x = cv.x + 0.25f*(bf2f(a0.x)+bf2f(a1.x)+bf2f(a2.x)+bf2f(a3.x));
  r.y = cv.y + 0.25f*(bf2f(a0.y)+bf2f(a1.y)+bf2f(a2.y)+bf2f(a3.y));
  r.z = cv.z + 0.25f*(bf2f(a0.z)+bf2f(a1.z)+bf2f(a2.z)+bf2f(a3.z));
  r.w = cv.w + 0.25f*(bf2f(a0.w)+bf2f(a1.w)+bf2f(a2.w)+bf2f(a3.w));
  *(float4*)(o + (size_t)row*256 + c4) = r;
}

// ---------------------------------------------------------------------------
extern "C" void kernel_launch(void* const* d_in, const int* in_sizes, int n_in,
                              void* d_out, int out_size, void* d_ws, size_t ws_size,
                              hipStream_t stream)
{
  (void)in_sizes; (void)n_in; (void)out_size;
  const float* curr   = (const float*)d_in[0];
  const float* prev   = (const float*)d_in[1];
  const float* conv3w = (const float*)d_in[2];
  const float* bn3g=(const float*)d_in[3], *bn3b=(const float*)d_in[4], *bn3m=(const float*)d_in[5], *bn3v=(const float*)d_in[6];
  const float* conv1w = (const float*)d_in[7];
  const float* bn1g=(const float*)d_in[8], *bn1b=(const float*)d_in[9], *bn1m=(const float*)d_in[10], *bn1v=(const float*)d_in[11];
  const float* fuseW=(const float*)d_in[12], *fuseB=(const float*)d_in[13];
  const float* lng=(const float*)d_in[14], *lnb=(const float*)d_in[15];
  const float* inpW=(const float*)d_in[16], *inpB=(const float*)d_in[17];
  const float* mlng=(const float*)d_in[18], *mlnb=(const float*)d_in[19];
  const float* minW=(const float*)d_in[20], *minB=(const float*)d_in[21];
  const float* cw=(const float*)d_in[22], *cb=(const float*)d_in[23];
  const float* alog=(const float*)d_in[24], *Dp=(const float*)d_in[25], *dtb=(const float*)d_in[26];
  const float* mng=(const float*)d_in[27];
  const float* moutW=(const float*)d_in[28], *moutB=(const float*)d_in[29];
  const float* outpW=(const float*)d_in[30], *outpB=(const float*)d_in[31];

  // ---- persistent layout ----
  char* ws = (char*)d_ws;
  size_t off = 0;
  auto alloc = [&](size_t bytes){ size_t o = off; off = (off + bytes + 1023) & ~(size_t)1023; return o; };
  const size_t O_WFUSE = alloc((size_t)256*256*2);
  const size_t O_WINP  = alloc((size_t)4*256*256*2);
  const size_t O_WMIN  = alloc((size_t)4*1288*256*2);
  const size_t O_WMOUT = alloc((size_t)4*256*512*2);
  const size_t O_WOUTP = alloc((size_t)4*256*256*2);
  const size_t O_WC3   = alloc((size_t)128*4608*2);
  const size_t O_WC1   = alloc((size_t)128*512*2);
  const size_t O_BNSS  = alloc(512*4);
  const size_t O_ZF    = alloc((size_t)16384*256*2);
  const size_t O_OUTS  = alloc((size_t)4*16384*256*2);
  const size_t O_P     = off;

  // per-dir sizes (bytes)
  const size_t S0d  = (size_t)16384*256*2;
  const size_t XLNd = (size_t)16384*256*2;
  const size_t Yd   = (size_t)16384*512*2;
  const size_t XCTd = (size_t)512*16384*2;
  const size_t BTd  = (size_t)128*16384*2;
  const size_t DTd  = (size_t)16384*8*4;
  const size_t CAd  = (size_t)16384*8*4;
  const size_t SRd  = (size_t)4*64*4096*2;
  const size_t RSd  = (size_t)16384*4;
  const size_t RS8d = (size_t)16384*8*4;
  const size_t XHd  = (size_t)16777216*2;
  const size_t perdir = S0d + XLNd + Yd + XCTd + BTd + DTd + CAd + SRd + RSd + RS8d + XHd;

  const size_t PADsz = (size_t)4*66*66*512*2;
  const size_t CPsz  = (size_t)3*16384*128*2;   // 3 bf16 partials (dy-grouped)
  const size_t PREsz = PADsz + CPsz + (size_t)16384*256*2*2 + 4096;

  int nd = 0;
  for (int cand = 4; cand >= 1; cand >>= 1) {
    size_t need = (size_t)cand*perdir; if (need < PREsz) need = PREsz;
    if (O_P + need <= ws_size) { nd = cand; break; }
  }
  if (nd == 0) return;

  #define WP(o) ((u16*)(ws + (o)))
  #define FP(o) ((float*)(ws + (o)))

  const size_t O_PAD = O_P;
  const size_t O_CP  = O_PAD + PADsz;
  const size_t O_ZIN = O_CP + CPsz;
  const size_t O_ZFT = O_ZIN + (size_t)16384*256*2;

  // 1. BN scale/shift + weight conversions
  bnssk<<<1, 256, 0, stream>>>(bn3g,bn3b,bn3m,bn3v, bn1g,bn1b,bn1m,bn1v, FP(O_BNSS));
  castk<<<64, 256, 0, stream>>>(fuseW, WP(O_WFUSE), 65536);
  castk<<<256, 256, 0, stream>>>(inpW, WP(O_WINP), 262144);
  castk<<<1288, 256, 0, stream>>>(minW, WP(O_WMIN), 1318912);
  castg<<<512, 256, 0, stream>>>(moutW, mng, WP(O_WMOUT));
  castk<<<256, 256, 0, stream>>>(outpW, WP(O_WOUTP), 262144);
  castk<<<64, 256, 0, stream>>>(conv1w, WP(O_WC1), 65536);
  c3rep<<<2304, 256, 0, stream>>>(conv3w, WP(O_WC3));
  // 2. padded concat input (bf16)
  padk<<<4356, 256, 0, stream>>>(curr, prev, WP(O_PAD));

  GemmArgs a;
  // 3. conv3 dy-grouped split-K (3 passes, K=1536) -> bf16 partials -> reduce+BN+ReLU
  a = {}; a.A = WP(O_PAD); a.pad = WP(O_PAD);
  a.Bw = WP(O_WC3); a.bZ = 1536; a.ldb = 4608;
  a.C = WP(O_CP); a.cZ = 2097152; a.ldc = 128; a.colOff = 0; a.K = 1536;
  gemm_bt<2,6><<<dim3(128,1,3), 256, 0, stream>>>(a);
  c3red<<<1024, 256, 0, stream>>>(WP(O_CP), FP(O_BNSS), WP(O_ZIN));
  // 4. conv1 -> zin[:,128:256]
  a = {}; a.A = WP(O_PAD); a.pad = WP(O_PAD); a.Bw = WP(O_WC1); a.bZ = 0; a.ldb = 512;
  a.scale = FP(O_BNSS)+256; a.shift = FP(O_BNSS)+384;
  a.C = WP(O_ZIN); a.cZ = 0; a.ldc = 256; a.colOff = 128; a.K = 512;
  gemm_bt<3,2><<<dim3(128,1,1), 256, 0, stream>>>(a);
  // 5. fuse GEMM -> zft
  a = {}; a.A = WP(O_ZIN); a.aZ = 0; a.lda = 256; a.Bw = WP(O_WFUSE); a.bZ = 0; a.ldb = 256;
  a.bias = fuseB; a.biasZ = 0; a.C = WP(O_ZFT); a.cZ = 0; a.ldc = 256; a.colOff = 0; a.K = 256;
  gemm_bt<0,0><<<dim3(128,2,1), 256, 0, stream>>>(a);
  // 6. LN -> zf (persistent)
  ln256<<<dim3(4096,1,1), 256, 0, stream>>>(WP(O_ZFT), 0, WP(O_ZF), 0, lng, lnb, 0);

  // ---- phases over directions ----
  for (int d0 = 0; d0 < 4; d0 += nd) {
    size_t o = O_P;
    const size_t O_S0  = o; o += (size_t)nd*S0d;
    const size_t O_XLN = o; o += (size_t)nd*XLNd;
    const size_t O_Y   = o; o += (size_t)nd*Yd;
    const size_t O_XCT = o; o += (size_t)nd*XCTd;
    const size_t O_BT  = o; o += (size_t)nd*BTd;
    const size_t O_DT  = o; o += (size_t)nd*DTd;
    const size_t O_CA  = o; o += (size_t)nd*CAd;
    const size_t O_SR  = o; o += (size_t)nd*SRd;
    const size_t O_RS  = o; o += (size_t)nd*RSd;
    const size_t O_RS8 = o; o += (size_t)nd*RS8d;
    const size_t O_XH  = o;
    const size_t O_BCC = O_XLN;
    const size_t O_S1  = O_XLN;

    // 7. inp GEMM (permuted rows per dir) -> s0
    a = {}; a.A = WP(O_ZF); a.aZ = 0; a.lda = 256;
    a.Bw = WP(O_WINP) + (size_t)d0*65536; a.bZ = 65536; a.ldb = 256;
    a.bias = inpB + d0*256; a.biasZ = 256;
    a.C = WP(O_S0); a.cZ = 4194304; a.ldc = 256; a.colOff = 0; a.K = 256; a.dirBase = d0;
    gemm_bt<1,0><<<dim3(128,2,nd), 256, 0, stream>>>(a);
    // 8. per-dir LN(s0) -> xln
    ln256<<<dim3(4096,1,nd), 256, 0, stream>>>(WP(O_S0), 4194304, WP(O_XLN), 4194304,
                                               mlng + d0*256, mlnb + d0*256, 256);
    // 9. dt, chunk log-decay
    dtk<<<dim3(512,1,nd), 256, 0, stream>>>(WP(O_XLN), minW + (size_t)d0*329728,
                                            minB + d0*1288, dtb + d0*8, FP(O_DT));
    cak<<<dim3(512,1,nd), 256, 0, stream>>>(FP(O_DT), FP(O_CA), alog, d0);
    // 10. z-gate GEMM -> Y
    a = {}; a.A = WP(O_XLN); a.aZ = 4194304; a.lda = 256;
    a.Bw = WP(O_WMIN) + (size_t)d0*329728; a.bZ = 329728; a.ldb = 256;
    a.bias = minB + d0*1288; a.biasZ = 1288;
    a.C = WP(O_Y); a.cZ = 8388608; a.ldc = 512; a.colOff = 0; a.K = 256;
    gemm_bt<0,0><<<dim3(128,4,nd), 256, 0, stream>>>(a);
    // 11. xBC GEMM -> raw xbc   [last reader of XLN]
    a = {}; a.A = WP(O_XLN); a.aZ = 4194304; a.lda = 256;
    a.Bw = WP(O_WMIN) + (size_t)d0*329728 + (size_t)512*256; a.bZ = 329728; a.ldb = 256;
    a.bias = minB + d0*1288 + 512; a.biasZ = 1288;
    a.C = WP(O_XH); a.cZ = 16777216; a.ldc = 768; a.colOff = 0; a.K = 256;
    gemm_bt<0,0><<<dim3(128,6,nd), 256, 0, stream>>>(a);
    // 12. conv1d+SiLU+transpose X -> XCT
    convx<<<dim3(1024,1,nd), 256, 0, stream>>>(WP(O_XH), WP(O_XCT), cw + d0*3072, cb + d0*768);
    // 13. fused conv B/C + BCC(C-half) + BT + head-shared scores SR
    bck<<<dim3(256,1,nd), 256, 0, stream>>>(WP(O_XH), WP(O_BCC), WP(O_BT), WP(O_SR),
                                            cw + d0*3072, cb + d0*768);
    // 14. per-chunk outer products -> CS (overlays raw xbc; after 12&13)
    csk<<<dim3(1024,1,nd), 256, 0, stream>>>(WP(O_XCT), WP(O_BT), FP(O_DT), FP(O_CA), WP(O_XH));
    // 15. 64-step combine in place -> H
    combk<<<dim3(256,1,nd), 256, 0, stream>>>(WP(O_XH), FP(O_CA), WP(O_XH));
    // 16. per-chunk outputs -> Y in place, + per-(row,head) SS
    yk2<<<dim3(2048,1,nd), 256, 0, stream>>>(WP(O_BCC), WP(O_XCT), WP(O_SR),
                                             FP(O_DT), FP(O_CA), WP(O_XH), Dp + d0*8,
                                             WP(O_Y), FP(O_RS8));
    // 17. inverse RMS per row
    rsumk<<<dim3(64,1,nd), 256, 0, stream>>>(FP(O_RS8), FP(O_RS));
    // 18. m_out GEMM (norm fused) + s0 residual -> s1
    a = {}; a.A = WP(O_Y); a.aZ = 8388608; a.lda = 512;
    a.Bw = WP(O_WMOUT) + (size_t)d0*131072; a.bZ = 131072; a.ldb = 512;
    a.bias = moutB + d0*256; a.biasZ = 256;
    a.add = WP(O_S0); a.addZ = 4194304;
    a.rowsc = FP(O_RS); a.rowscZ = 16384;
    a.C = WP(O_S1); a.cZ = 4194304; a.ldc = 256; a.colOff = 0; a.K = 512;
    gemm_bt<0,5><<<dim3(128,2,nd), 256, 0, stream>>>(a);
    // 19. outp GEMM -> outs (persistent)
    a = {}; a.A = WP(O_S1); a.aZ = 4194304; a.lda = 256;
    a.Bw = WP(O_WOUTP) + (size_t)d0*65536; a.bZ = 65536; a.ldb = 256;
    a.bias = outpB + d0*256; a.biasZ = 256;
    a.C = WP(O_OUTS) + (size_t)d0*4194304; a.cZ = 4194304; a.ldc = 256; a.colOff = 0; a.K = 256;
    gemm_bt<0,0><<<dim3(128,2,nd), 256, 0, stream>>>(a);
  }

  // 20. final inverse-permute average + residual
  finalk<<<4096, 256, 0, stream>>>(curr, WP(O_OUTS), (float*)d_out);

  #undef WP
  #undef FP
}